// Round 1
// 1381.423 us; speedup vs baseline: 1.0181x; 1.0181x over previous
//
#include <hip/hip_runtime.h>

// ---------------------------------------------------------------------------
// B=8, N=1024, CIN=2048, HID=1024, HC=64, LV=512, NH_SSD=16, HD=128, DS=64.
// Encoder rows = 4096. Decoder collapsed to 1 row/batch. All large GEMMs:
// split-bf16 MFMA (x3 passes = f32-grade pre-quantizer; x1 post-quantizer),
// staged via __builtin_amdgcn_global_load_lds width=16 (DIRECT path,
// unpadded LDS rows -> lane-contiguous dest, conflict-free b128 reads).
// SSD intra-chunk = fused MFMA kernel; D-skip folded into W diagonal.
// ---------------------------------------------------------------------------

typedef short bf16x8 __attribute__((ext_vector_type(8)));
typedef float f32x4 __attribute__((ext_vector_type(4)));

__device__ __forceinline__ unsigned short bf16_rne(float f) {
    unsigned u = __float_as_uint(f);
    unsigned r = u + 0x7FFFu + ((u >> 16) & 1u);
    return (unsigned short)(r >> 16);
}
__device__ __forceinline__ float bf16_tof(unsigned short h) {
    return __uint_as_float(((unsigned)h) << 16);
}
__device__ __forceinline__ void store_pair(unsigned short* dst, long long row,
                                           int width, int c, float v) {
    unsigned short hi = bf16_rne(v);
    unsigned short lo = bf16_rne(v - bf16_tof(hi));
    long long base = row * (2LL * width);
    dst[base + c] = hi;
    dst[base + width + c] = lo;
}
// Async global->LDS, 16B per lane. LDS dest = wave-uniform base + lane*16.
__device__ __forceinline__ void async_ld16(const unsigned short* g, unsigned short* l) {
    __builtin_amdgcn_global_load_lds(
        (const __attribute__((address_space(1))) unsigned int*)g,
        (__attribute__((address_space(3))) unsigned int*)l, 16, 0, 0);
}

// ---------------------------------------------------------------------------
// Reduction helpers (blockDim 256)
// ---------------------------------------------------------------------------
__device__ __forceinline__ float block_sum256(float v) {
    #pragma unroll
    for (int o = 32; o > 0; o >>= 1) v += __shfl_xor(v, o, 64);
    __shared__ float sm[4];
    int w = threadIdx.x >> 6;
    __syncthreads();
    if ((threadIdx.x & 63) == 0) sm[w] = v;
    __syncthreads();
    return sm[0] + sm[1] + sm[2] + sm[3];
}
__device__ __forceinline__ float block_max256(float v) {
    #pragma unroll
    for (int o = 32; o > 0; o >>= 1) v = fmaxf(v, __shfl_xor(v, o, 64));
    __shared__ float smx[4];
    int w = threadIdx.x >> 6;
    __syncthreads();
    if ((threadIdx.x & 63) == 0) smx[w] = v;
    __syncthreads();
    return fmaxf(fmaxf(smx[0], smx[1]), fmaxf(smx[2], smx[3]));
}

// ---------------------------------------------------------------------------
// Split-bf16 MFMA GEMM. C[m,n] = alpha * sum_k A[m,k]*B[n,k] (+bias)(+res)
// NPASS=3: hh+lh+hl (f32-grade). NPASS=1: hh only.
// OUT=0: f32 C. OUT=1: split-pair C. OUT=2: transposed split-pair per
// 512-row batch. DIRECT=true: global_load_lds staging (requires N full
// through the tile grid); false: guarded reg staging (ragged N ok).
// ---------------------------------------------------------------------------
template<int NPASS, int OUT, bool DIRECT>
__global__ __launch_bounds__(256, 2) void gemm_bf16_k(
    int M, int N, int K,
    const unsigned short* __restrict__ A2, int lda2, int aLo, long long sAb, long long sAh,
    const unsigned short* __restrict__ B2, int ldb2, int bLo, long long sBb, long long sBh,
    void* __restrict__ Cv, int ldc, int cLo, long long sCb, long long sCh,
    const float* __restrict__ bias, const float* __restrict__ res, int ldr,
    float alpha, int nh)
{
    constexpr int ST = DIRECT ? 32 : 40;
    __shared__ unsigned short Ah[128 * ST];
    __shared__ unsigned short Bh[128 * ST];
    __shared__ unsigned short Al[128 * ST];
    __shared__ unsigned short Bl[128 * ST];

    const int z  = blockIdx.z;
    const int bb = z / nh, hh = z - bb * nh;
    A2 += bb * sAb + hh * sAh;
    B2 += bb * sBb + hh * sBh;

    const int t    = threadIdx.x;
    const int m0   = blockIdx.y * 128;
    const int n0   = blockIdx.x * 128;
    const int lane = t & 63, wave = t >> 6;
    const int wm   = (wave >> 1) * 64, wn = (wave & 1) * 64;
    const int lr   = lane & 15, quad = lane >> 4;

    f32x4 acc[4][4];
    #pragma unroll
    for (int i = 0; i < 4; ++i)
        #pragma unroll
        for (int j = 0; j < 4; ++j) acc[i][j] = (f32x4){0.f, 0.f, 0.f, 0.f};

    // staging coords
    const int srow = t >> 2;          // ragged path: row 0..63 (+64)
    const int scol = (t & 3) * 8;
    const int drow = lane >> 2;       // DIRECT: row within 16-row chunk
    const int dcol = (lane & 3) * 8;

    for (int k0 = 0; k0 < K; k0 += 32) {
        __syncthreads();
        if (DIRECT) {
            #pragma unroll
            for (int j = 0; j < 2; ++j) {
                int rr = wave * 32 + j * 16;          // chunk base row
                int gr = rr + drow;
                const unsigned short* gA = A2 + (long long)(m0 + gr) * lda2 + k0 + dcol;
                async_ld16(gA, &Ah[rr * 32]);
                if (NPASS == 3) async_ld16(gA + aLo, &Al[rr * 32]);
                const unsigned short* gB = B2 + (long long)(n0 + gr) * ldb2 + k0 + dcol;
                async_ld16(gB, &Bh[rr * 32]);
                if (NPASS == 3) async_ld16(gB + bLo, &Bl[rr * 32]);
            }
        } else {
            #pragma unroll
            for (int half = 0; half < 2; ++half) {
                int r = srow + half * 64;
                const unsigned short* pA = A2 + (long long)(m0 + r) * lda2 + k0 + scol;
                *(uint4*)&Ah[r * ST + scol] = *(const uint4*)pA;
                if (NPASS == 3)
                    *(uint4*)&Al[r * ST + scol] = *(const uint4*)(pA + aLo);
                int rb = n0 + r;
                uint4 vh = {0u, 0u, 0u, 0u}, vl = {0u, 0u, 0u, 0u};
                if (rb < N) {
                    const unsigned short* pB = B2 + (long long)rb * ldb2 + k0 + scol;
                    vh = *(const uint4*)pB;
                    if (NPASS == 3) vl = *(const uint4*)(pB + bLo);
                }
                *(uint4*)&Bh[r * ST + scol] = vh;
                if (NPASS == 3) *(uint4*)&Bl[r * ST + scol] = vl;
            }
        }
        __syncthreads();

        bf16x8 ah[4], bh[4], al[4], bl[4];
        #pragma unroll
        for (int i = 0; i < 4; ++i) {
            int ra = (wm + i * 16 + lr) * ST + quad * 8;
            int rb = (wn + i * 16 + lr) * ST + quad * 8;
            ah[i] = *(const bf16x8*)&Ah[ra];
            bh[i] = *(const bf16x8*)&Bh[rb];
            if (NPASS == 3) {
                al[i] = *(const bf16x8*)&Al[ra];
                bl[i] = *(const bf16x8*)&Bl[rb];
            }
        }
        #pragma unroll
        for (int mi = 0; mi < 4; ++mi)
            #pragma unroll
            for (int ni = 0; ni < 4; ++ni) {
                acc[mi][ni] = __builtin_amdgcn_mfma_f32_16x16x32_bf16(
                    ah[mi], bh[ni], acc[mi][ni], 0, 0, 0);
                if (NPASS == 3) {
                    acc[mi][ni] = __builtin_amdgcn_mfma_f32_16x16x32_bf16(
                        al[mi], bh[ni], acc[mi][ni], 0, 0, 0);
                    acc[mi][ni] = __builtin_amdgcn_mfma_f32_16x16x32_bf16(
                        ah[mi], bl[ni], acc[mi][ni], 0, 0, 0);
                }
            }
    }

    // D layout: col = lane&15, row = quad*4 + r
    if (OUT == 0) {
        float* C = (float*)Cv + bb * sCb + hh * sCh;
        #pragma unroll
        for (int mi = 0; mi < 4; ++mi)
            #pragma unroll
            for (int ni = 0; ni < 4; ++ni) {
                int col = n0 + wn + ni * 16 + lr;
                if (col >= N) continue;
                float bv = bias ? bias[col] : 0.f;
                #pragma unroll
                for (int r = 0; r < 4; ++r) {
                    int row = m0 + wm + mi * 16 + quad * 4 + r;
                    float v = alpha * acc[mi][ni][r] + bv;
                    if (res) v += res[(long long)row * ldr + col];
                    C[(long long)row * ldc + col] = v;
                }
            }
    } else if (OUT == 1) {
        unsigned short* C = (unsigned short*)Cv + bb * sCb + hh * sCh;
        #pragma unroll
        for (int mi = 0; mi < 4; ++mi)
            #pragma unroll
            for (int ni = 0; ni < 4; ++ni) {
                int col = n0 + wn + ni * 16 + lr;
                if (col >= N) continue;
                float bv = bias ? bias[col] : 0.f;
                #pragma unroll
                for (int r = 0; r < 4; ++r) {
                    int row = m0 + wm + mi * 16 + quad * 4 + r;
                    float v = alpha * acc[mi][ni][r] + bv;
                    if (res) v += res[(long long)row * ldr + col];
                    unsigned short hi = bf16_rne(v);
                    unsigned short lo = bf16_rne(v - bf16_tof(hi));
                    long long p = (long long)row * ldc + col;
                    C[p] = hi;
                    C[p + cLo] = lo;
                }
            }
    } else {  // OUT == 2: transposed pairs per 512-row batch
        unsigned short* C = (unsigned short*)Cv;
        #pragma unroll
        for (int mi = 0; mi < 4; ++mi)
            #pragma unroll
            for (int ni = 0; ni < 4; ++ni) {
                int col = n0 + wn + ni * 16 + lr;
                if (col >= N) continue;
                int row0 = m0 + wm + mi * 16 + quad * 4;
                int b = row0 >> 9, seq0 = row0 & 511;
                ushort4 h4, l4;
                unsigned short* hp = (unsigned short*)&h4;
                unsigned short* lp = (unsigned short*)&l4;
                #pragma unroll
                for (int r = 0; r < 4; ++r) {
                    float v = acc[mi][ni][r];
                    unsigned short hi = bf16_rne(v);
                    hp[r] = hi;
                    lp[r] = bf16_rne(v - bf16_tof(hi));
                }
                long long p = b * sCb + (long long)col * ldc + seq0;
                *(ushort4*)&C[p] = h4;
                *(ushort4*)&C[p + cLo] = l4;
            }
    }
}

// ---------------------------------------------------------------------------
// Fused SSD intra-chunk MFMA kernel, v3.
// Per (b,h): Y[l,p] = sum_{s<=l} W[l,s]*XC[s,p];
// W = G*exp(cAl-cAs)*dt[s], with D-skip folded in: W[l,l] += D[h].
// v3 vs v2 (v2: 119us, MfmaUtil 5%, VALUBusy 25%, occ 26%, 1.97M LDS
// bank-conflict cycles — latency/imbalance-bound, nothing saturated):
//  * 64-row x 128-chan tiles (ph halves merged): W-gen VALU per MFMA flop
//    halved, G re-reads halved.
//  * UNIFORM work per block: block q runs row-tile pair (7-q, q)
//    sequentially -> exactly 18 k-tiles/block for every q. v2's causally
//    skewed blocks (4..16 tiles) clustered same-mt blocks on the same CU
//    under round-robin dispatch -> up to 8x per-CU load skew (the ~70%
//    idle). Pairing balances under ANY dispatch order.
//  * double-buffered W in LDS, ONE barrier per k-tile (v2 had two); X-frag
//    global loads issued before the G loads so MFMA vmcnt waits don't
//    drain W-gen loads (T14 issue-early/consume-late).
//  * XOR-swizzled W tile (16B slot ^= (row>>1)&3): conflict-free b128
//    reads/writes (v2: 8-way read conflict on 64B-stride rows).
//  * interior tiles (k0+32 <= m0) skip causal mask + diagonal add.
// grid (4 = row-tile pairs, 16 h, 8 b), block 256 (4 waves x 16l x 128p).
// ---------------------------------------------------------------------------
__global__ __launch_bounds__(256, 2) void ssd_mfma_k(
    const float* __restrict__ G, const float* __restrict__ CUMA,
    const float* __restrict__ DT, const unsigned short* __restrict__ XCT2,
    const float* __restrict__ Z, const float* __restrict__ Dv,
    unsigned short* __restrict__ YS2)
{
    __shared__ unsigned short Wh[2][64 * 32];
    __shared__ unsigned short Wl[2][64 * 32];
    __shared__ float Cs[512];
    __shared__ float Ds[512];
    const int q = blockIdx.x;
    const int h = blockIdx.y, b = blockIdx.z;
    const int t = threadIdx.x;
    const int lane = t & 63, wave = t >> 6;
    const int lr = lane & 15, quad = lane >> 4;

    const float* cbase = CUMA + (b * 16 + h) * 512;
    const float* dtb = DT + (long long)b * 512 * 16 + h;
    for (int s = t; s < 512; s += 256) {
        Cs[s] = cbase[s];
        Ds[s] = dtb[(long long)s * 16];
    }
    const float Dh = Dv[h];

    const int wr = t >> 2;                        // W-gen row 0..63
    const int sw = t & 3;                         // logical 16B slot 0..3
    const int wbase = wr * 32 + ((sw ^ ((wr >> 1) & 3)) << 3);
    const int frow = wave * 16 + lr;              // frag row 0..63
    const int fbase = frow * 32 + ((quad ^ ((frow >> 1) & 3)) << 3);
    const unsigned short* XB = XCT2 + (long long)b * 2097152
                             + (long long)(h * 128) * 1024;
    __syncthreads();

    for (int ph = 0; ph < 2; ++ph) {
        const int mt = ph ? q : 7 - q;            // heavy row-tile first
        const int m0 = mt * 64;
        const int kend = m0 + 64;
        const int lglob = m0 + wr;
        const float cAl = Cs[lglob];
        const float* grow = G + ((long long)(b * 512 + lglob)) * 512;

        float pg[8], pc[8], pd[8];
        auto gen_load = [&](int k0g) {
            const int sb = k0g + sw * 8;
            float4 g0 = *(const float4*)(grow + sb);
            float4 g1 = *(const float4*)(grow + sb + 4);
            float4 c0 = *(const float4*)&Cs[sb];
            float4 c1 = *(const float4*)&Cs[sb + 4];
            float4 d0 = *(const float4*)&Ds[sb];
            float4 d1 = *(const float4*)&Ds[sb + 4];
            pg[0] = g0.x; pg[1] = g0.y; pg[2] = g0.z; pg[3] = g0.w;
            pg[4] = g1.x; pg[5] = g1.y; pg[6] = g1.z; pg[7] = g1.w;
            pc[0] = c0.x; pc[1] = c0.y; pc[2] = c0.z; pc[3] = c0.w;
            pc[4] = c1.x; pc[5] = c1.y; pc[6] = c1.z; pc[7] = c1.w;
            pd[0] = d0.x; pd[1] = d0.y; pd[2] = d0.z; pd[3] = d0.w;
            pd[4] = d1.x; pd[5] = d1.y; pd[6] = d1.z; pd[7] = d1.w;
        };
        auto gen_finish = [&](int k0g, int buf) {
            const int sb = k0g + sw * 8;
            const bool edge = (k0g + 32 > m0);    // tile touches causal edge
            unsigned short hv[8], lv[8];
            #pragma unroll
            for (int e = 0; e < 8; ++e) {
                float w = pg[e] * __expf(cAl - pc[e]) * pd[e];
                if (edge) {
                    int sg = sb + e;
                    w = (sg <= lglob) ? w : 0.f;  // select AFTER: kills inf/nan
                    if (sg == lglob) w += Dh;
                }
                unsigned short hi = bf16_rne(w);
                hv[e] = hi;
                lv[e] = bf16_rne(w - bf16_tof(hi));
            }
            *(uint4*)&Wh[buf][wbase] = *(uint4*)hv;
            *(uint4*)&Wl[buf][wbase] = *(uint4*)lv;
        };

        f32x4 acc[8];
        #pragma unroll
        for (int j = 0; j < 8; ++j) acc[j] = (f32x4){0.f, 0.f, 0.f, 0.f};

        gen_load(0);
        gen_finish(0, 0);
        __syncthreads();

        for (int k0 = 0; k0 < kend; k0 += 32) {
            const int cur = (k0 >> 5) & 1;
            const bool pf = (k0 + 32 < kend);
            bf16x8 bh[8], bl[8];
            #pragma unroll
            for (int ni = 0; ni < 8; ++ni) {      // X frags first (oldest vmem)
                const unsigned short* pB =
                    XB + (long long)(ni * 16 + lr) * 1024 + k0 + quad * 8;
                bh[ni] = *(const bf16x8*)pB;
                bl[ni] = *(const bf16x8*)(pB + 512);
            }
            if (pf) gen_load(k0 + 32);            // G loads after X: MFMA waits
                                                  // don't drain them
            bf16x8 ah = *(const bf16x8*)&Wh[cur][fbase];
            bf16x8 al = *(const bf16x8*)&Wl[cur][fbase];
            #pragma unroll
            for (int ni = 0; ni < 8; ++ni) {
                acc[ni] = __builtin_amdgcn_mfma_f32_16x16x32_bf16(
                    ah, bh[ni], acc[ni], 0, 0, 0);
                acc[ni] = __builtin_amdgcn_mfma_f32_16x16x32_bf16(
                    al, bh[ni], acc[ni], 0, 0, 0);
                acc[ni] = __builtin_amdgcn_mfma_f32_16x16x32_bf16(
                    ah, bl[ni], acc[ni], 0, 0, 0);
            }
            if (pf) gen_finish(k0 + 32, cur ^ 1); // exp/split overlaps MFMA drain
            __syncthreads();                      // single barrier per k-tile
        }

        const int row0 = m0 + wave * 16 + quad * 4;
        #pragma unroll
        for (int ni = 0; ni < 8; ++ni) {
            int chan = h * 128 + ni * 16 + lr;
            #pragma unroll
            for (int r = 0; r < 4; ++r) {
                long long row = (long long)(b * 512 + row0 + r);
                float zz = Z[row * 2048 + chan];
                float y = acc[ni][r] * (zz / (1.f + expf(-zz)));
                store_pair(YS2, row, 2048, chan, y);
            }
        }
    }
}

// ---------------------------------------------------------------------------
// Tiled f32 GEMM (only for the small batched G = Cm @ Bm^T)
// ---------------------------------------------------------------------------
__global__ __launch_bounds__(256) void gemm_f32_k(
    int M, int N, int K,
    const float* __restrict__ A, int lda, long long sAb,
    const float* __restrict__ B, int ldb, long long sBb,
    float* __restrict__ C, int ldc, long long sCb)
{
    __shared__ float As[32][132];
    __shared__ float Bs[32][132];
    const int z = blockIdx.z;
    A += z * sAb; B += z * sBb; C += z * sCb;
    const int n0 = blockIdx.x * 128;
    const int m0 = blockIdx.y * 128;
    const int t  = threadIdx.x;
    const int tx = t & 15, ty = t >> 4;

    float acc[4][16];
    #pragma unroll
    for (int a = 0; a < 4; ++a)
        #pragma unroll
        for (int q = 0; q < 16; ++q) acc[a][q] = 0.f;

    const int ka = (t & 7) << 2;
    const int ra = t >> 3;

    for (int k0 = 0; k0 < K; k0 += 32) {
        __syncthreads();
        #pragma unroll
        for (int i = 0; i < 4; ++i) {
            int row = m0 + ra + i * 32;
            float4 v = *(const float4*)(A + (long long)row * lda + (k0 + ka));
            As[ka + 0][ra + i * 32] = v.x;
            As[ka + 1][ra + i * 32] = v.y;
            As[ka + 2][ra + i * 32] = v.z;
            As[ka + 3][ra + i * 32] = v.w;
            int rowb = n0 + ra + i * 32;
            float4 w = *(const float4*)(B + (long long)rowb * ldb + (k0 + ka));
            Bs[ka + 0][ra + i * 32] = w.x;
            Bs[ka + 1][ra + i * 32] = w.y;
            Bs[ka + 2][ra + i * 32] = w.z;
            Bs[ka + 3][ra + i * 32] = w.w;
        }
        __syncthreads();
        #pragma unroll
        for (int kk = 0; kk < 32; ++kk) {
            float a[8], bm[8];
            *(float4*)&a[0]  = *(const float4*)&As[kk][ty * 4];
            *(float4*)&a[4]  = *(const float4*)&As[kk][64 + ty * 4];
            *(float4*)&bm[0] = *(const float4*)&Bs[kk][tx * 4];
            *(float4*)&bm[4] = *(const float4*)&Bs[kk][64 + tx * 4];
            #pragma unroll
            for (int ri = 0; ri < 2; ++ri)
                #pragma unroll
                for (int ci = 0; ci < 2; ++ci)
                    #pragma unroll
                    for (int i = 0; i < 4; ++i)
                        #pragma unroll
                        for (int j = 0; j < 4; ++j)
                            acc[ri * 2 + ci][i * 4 + j] =
                                fmaf(a[ri * 4 + i], bm[ci * 4 + j], acc[ri * 2 + ci][i * 4 + j]);
        }
    }
    #pragma unroll
    for (int ri = 0; ri < 2; ++ri)
        #pragma unroll
        for (int ci = 0; ci < 2; ++ci) {
            int colb = n0 + ci * 64 + tx * 4;
            #pragma unroll
            for (int i = 0; i < 4; ++i) {
                int row = m0 + ri * 64 + ty * 4 + i;
                *(float4*)(C + (long long)row * ldc + colb) =
                    *(float4*)&acc[ri * 2 + ci][i * 4];
            }
        }
}

// ---------------------------------------------------------------------------
// Elementwise / norm kernels
// ---------------------------------------------------------------------------
__global__ __launch_bounds__(256) void pairify_k(
    const float* __restrict__ src, unsigned short* __restrict__ dst,
    int k_log2, long long n)
{
    long long idx = (long long)blockIdx.x * 256 + threadIdx.x;
    if (idx >= n) return;
    long long r = idx >> k_log2;
    int c = (int)(idx & ((1 << k_log2) - 1));
    store_pair(dst, r, 1 << k_log2, c, src[idx]);
}

__global__ __launch_bounds__(256) void layernorm_k(
    const float* __restrict__ in, float* __restrict__ out,
    const float* __restrict__ w, const float* __restrict__ b,
    int width, int rows_per_b, long long in_bstride)
{
    long long r = blockIdx.x;
    const float* x = in + (r / rows_per_b) * in_bstride + (r % rows_per_b) * (long long)width;
    int t = threadIdx.x;
    float s = 0.f;
    for (int c = t; c < width; c += 256) s += x[c];
    s = block_sum256(s);
    float m = s / (float)width;
    float vs = 0.f;
    for (int c = t; c < width; c += 256) { float d = x[c] - m; vs += d * d; }
    vs = block_sum256(vs);
    float rs = 1.f / sqrtf(vs / (float)width + 1e-5f);
    float* o = out + r * (long long)width;
    for (int c = t; c < width; c += 256) o[c] = (x[c] - m) * rs * w[c] + b[c];
}

__global__ __launch_bounds__(256) void layernorm_pair_k(
    const float* __restrict__ in, unsigned short* __restrict__ out2,
    const float* __restrict__ w, const float* __restrict__ b,
    int width, int rows_per_b, long long in_bstride)
{
    long long r = blockIdx.x;
    const float* x = in + (r / rows_per_b) * in_bstride + (r % rows_per_b) * (long long)width;
    int t = threadIdx.x;
    float s = 0.f;
    for (int c = t; c < width; c += 256) s += x[c];
    s = block_sum256(s);
    float m = s / (float)width;
    float vs = 0.f;
    for (int c = t; c < width; c += 256) { float d = x[c] - m; vs += d * d; }
    vs = block_sum256(vs);
    float rs = 1.f / sqrtf(vs / (float)width + 1e-5f);
    for (int c = t; c < width; c += 256)
        store_pair(out2, r, width, c, (x[c] - m) * rs * w[c] + b[c]);
}

__global__ __launch_bounds__(256) void rmsnorm_pair_k(
    const float* __restrict__ in, unsigned short* __restrict__ out2,
    const float* __restrict__ w, int width)
{
    long long r = blockIdx.x;
    const float* x = in + r * (long long)width;
    int t = threadIdx.x;
    float s = 0.f;
    for (int c = t; c < width; c += 256) { float v = x[c]; s += v * v; }
    s = block_sum256(s);
    float rs = 1.f / sqrtf(s / (float)width + 1e-5f);
    for (int c = t; c < width; c += 256)
        store_pair(out2, r, width, c, x[c] * rs * w[c]);
}

// Softmax over 512-wide rows, f32 in -> split-pair out IN-PLACE (same bytes).
__global__ __launch_bounds__(256) void softmax_pair_k(float* __restrict__ S,
                                                      unsigned short* __restrict__ P2)
{
    long long r = blockIdx.x;
    float* x = S + r * 512;
    unsigned short* p = P2 + r * 1024;
    int t = threadIdx.x;
    float v0 = x[t], v1 = x[t + 256];
    float mx = block_max256(fmaxf(v0, v1));
    v0 = expf(v0 - mx); v1 = expf(v1 - mx);
    float sum = block_sum256(v0 + v1);
    float inv = 1.f / sum;
    v0 *= inv; v1 *= inv;
    __syncthreads();
    unsigned short h0 = bf16_rne(v0);
    p[t] = h0;       p[512 + t] = bf16_rne(v0 - bf16_tof(h0));
    unsigned short h1 = bf16_rne(v1);
    p[t + 256] = h1; p[512 + t + 256] = bf16_rne(v1 - bf16_tof(h1));
}

// Causal grouped conv with LDS-tile transpose: writes seq-major pairs XC2
// AND chan-major pairs XCT2, both coalesced.
__global__ __launch_bounds__(256) void conv_k(
    const float* __restrict__ XS, const float* __restrict__ W,
    unsigned short* __restrict__ XC2, unsigned short* __restrict__ XCT2)
{
    __shared__ float tile[64][65];
    const int o0  = blockIdx.x * 64;
    const int tt0 = blockIdx.y * 64;
    const int b   = blockIdx.z;
    const int t   = threadIdx.x;

    const int o  = o0 + (t & 63);
    const int g2 = (o >> 1) << 1;
    const float* Wo = W + o * 8;
    float w0 = Wo[0], w1 = Wo[1], w2 = Wo[2], w3 = Wo[3];
    float w4 = Wo[4], w5 = Wo[5], w6 = Wo[6], w7 = Wo[7];
    #pragma unroll
    for (int i = 0; i < 16; ++i) {
        int sl = (t >> 6) + 4 * i;
        int tt = tt0 + sl;
        const float* xb = XS + ((long long)(b * 512 + tt)) * 2048 + g2;
        float acc = w3 * xb[0] + w7 * xb[1];
        if (tt >= 1) acc += w2 * xb[-2048] + w6 * xb[-2047];
        if (tt >= 2) acc += w1 * xb[-4096] + w5 * xb[-4095];
        if (tt >= 3) acc += w0 * xb[-6144] + w4 * xb[-6143];
        tile[sl][t & 63] = acc;
    }
    __syncthreads();
    #pragma unroll
    for (int i = 0; i < 16; ++i) {
        int idx = t + 256 * i;
        int sl = idx >> 6, ol = idx & 63;
        float v = tile[sl][ol];
        unsigned short hi = bf16_rne(v);
        unsigned short lo = bf16_rne(v - bf16_tof(hi));
        long long row = (long long)(b * 512 + tt0 + sl);
        XC2[row * 4096 + o0 + ol] = hi;
        XC2[row * 4096 + 2048 + o0 + ol] = lo;
    }
    #pragma unroll
    for (int i = 0; i < 16; ++i) {
        int idx = t + 256 * i;
        int cl = idx >> 6, s = idx & 63;
        float v = tile[s][cl];
        unsigned short hi = bf16_rne(v);
        unsigned short lo = bf16_rne(v - bf16_tof(hi));
        long long tb = (long long)b * 2097152 + (long long)(o0 + cl) * 1024 + tt0 + s;
        XCT2[tb] = hi;
        XCT2[tb + 512] = lo;
    }
}

__global__ __launch_bounds__(256) void dt_k(
    const float* __restrict__ dtBC, const float* __restrict__ dt_bias, float* __restrict__ DT)
{
    int idx = blockIdx.x * 256 + threadIdx.x;
    int r = idx >> 4, h = idx & 15;
    float xv = dtBC[r * 144 + h] + dt_bias[h];
    DT[idx] = (xv > 20.f) ? xv : log1pf(expf(xv));
}

__global__ __launch_bounds__(64) void cuma_k(
    const float* __restrict__ DT, const float* __restrict__ A_log, float* __restrict__ CUMA)
{
    int h = blockIdx.x, b = blockIdx.y;
    int ln = threadIdx.x;
    float Ah = -expf(A_log[h]);
    float v[8];
    float run = 0.f;
    #pragma unroll
    for (int i = 0; i < 8; ++i) {
        run += Ah * DT[((b * 512) + (ln * 8 + i)) * 16 + h];
        v[i] = run;
    }
    float tot = run;
    float sc = tot;
    #pragma unroll
    for (int o = 1; o <= 32; o <<= 1) {
        float u = __shfl_up(sc, o, 64);
        if (ln >= o) sc += u;
    }
    float excl = sc - tot;
    #pragma unroll
    for (int i = 0; i < 8; ++i)
        CUMA[(b * 16 + h) * 512 + ln * 8 + i] = excl + v[i];
}

// hc = LayerNorm64(G1) -> {-1,+1} as split pairs (lo = 0)
__global__ __launch_bounds__(64) void hc_quant_k(
    const float* __restrict__ G1, const float* __restrict__ w,
    const float* __restrict__ b, unsigned short* __restrict__ HCQ2)
{
    int r = blockIdx.x, ln = threadIdx.x;
    float v = G1[r * 64 + ln];
    float s = v;
    #pragma unroll
    for (int o = 32; o > 0; o >>= 1) s += __shfl_xor(s, o, 64);
    float m = s * (1.f / 64.f);
    float d = v - m;
    float vs = d * d;
    #pragma unroll
    for (int o = 32; o > 0; o >>= 1) vs += __shfl_xor(vs, o, 64);
    vs *= (1.f / 64.f);
    float hc = d * (1.f / sqrtf(vs + 1e-5f)) * w[ln] + b[ln];
    HCQ2[r * 128 + ln] = (hc > 0.f) ? 0x3F80 : 0xBF80;
    HCQ2[r * 128 + 64 + ln] = 0;
}

__global__ __launch_bounds__(256) void dxm_k(
    const float* __restrict__ mtok, const float* __restrict__ e2d, float* __restrict__ dxm)
{
    int c = blockIdx.x * 256 + threadIdx.x;
    float acc = 0.f;
    #pragma unroll
    for (int j = 0; j < 64; ++j) acc = fmaf(mtok[j], e2d[c * 64 + j], acc);
    dxm[c] = acc;
}

__global__ __launch_bounds__(256) void projm_k(
    const float* __restrict__ lnm,
    const float* __restrict__ bWq, const float* __restrict__ bWk, const float* __restrict__ bWv,
    float* __restrict__ qm, float* __restrict__ km, float* __restrict__ vm)
{
    int idx = blockIdx.x * 256 + threadIdx.x;
    int sel = idx >> 10, c = idx & 1023;
    const float* W = (sel == 0) ? bWq : (sel == 1) ? bWk : bWv;
    float* O = (sel == 0) ? qm : (sel == 1) ? km : vm;
    const float* wr = W + (long long)c * 1024;
    float acc = 0.f;
    for (int j = 0; j < 1024; j += 4) {
        float4 a = *(const float4*)(lnm + j);
        float4 w4 = *(const float4*)(wr + j);
        acc = fmaf(a.x, w4.x, fmaf(a.y, w4.y, fmaf(a.z, w4.z, fmaf(a.w, w4.w, acc))));
    }
    O[c] = acc;
}

// Collapsed decoder attention: 1 query/(b,h); keys = 512 visible + mask key x512.
__global__ __launch_bounds__(256) void dec_attn_k(
    const float* __restrict__ Kv, const float* __restrict__ Vv,
    const float* __restrict__ qm, const float* __restrict__ km,
    const float* __restrict__ vm, float* __restrict__ OBm)
{
    int h = blockIdx.x, b = blockIdx.y;
    int t = threadIdx.x;
    __shared__ __align__(16) float qs[256];
    __shared__ __align__(16) float ps[512];
    qs[t] = qm[h * 256 + t];
    __syncthreads();
    float s[2];
    #pragma unroll
    for (int i = 0; i < 2; ++i) {
        int r = t + i * 256;
        const float* kr = Kv + ((long long)(b * 512 + r)) * 1024 + h * 256;
        float acc = 0.f;
        for (int c = 0; c < 256; c += 4) {
            float4 k4 = *(const float4*)(kr + c);
            float4 q4 = *(const float4*)(qs + c);
            acc = fmaf(k4.x, q4.x, fmaf(k4.y, q4.y, fmaf(k4.z, q4.z, fmaf(k4.w, q4.w, acc))));
        }
        s[i] = acc * (1.f / 16.f);
    }
    float accm = 0.f;
    for (int c = 0; c < 256; c += 4) {
        float4 k4 = *(const float4*)(km + h * 256 + c);
        float4 q4 = *(const float4*)(qs + c);
        accm = fmaf(k4.x, q4.x, fmaf(k4.y, q4.y, fmaf(k4.z, q4.z, fmaf(k4.w, q4.w, accm))));
    }
    float smv = accm * (1.f / 16.f);
    float mx = block_max256(fmaxf(fmaxf(s[0], s[1]), smv));
    float p0 = expf(s[0] - mx), p1 = expf(s[1] - mx);
    ps[t] = p0; ps[t + 256] = p1;
    float pm = expf(smv - mx) * 512.f;
    float sum = block_sum256(p0 + p1) + pm;
    float inv = 1.f / sum;
    __syncthreads();
    float o = pm * vm[h * 256 + t];
    const float* vcol = Vv + (long long)b * 512 * 1024 + h * 256 + t;
    for (int j = 0; j < 512; ++j)
        o = fmaf(ps[j], vcol[(long long)j * 1024], o);
    OBm[b * 1024 + h * 256 + t] = o * inv;
}

__global__ __launch_bounds__(256) void ydm_k(
    const float* __restrict__ OBm, const float* __restrict__ bWo,
    const float* __restrict__ bWo_b, const float* __restrict__ dxm,
    float* __restrict__ ydm)
{
    int idx = blockIdx.x * 256 + threadIdx.x;
    int b = idx >> 10, c = idx & 1023;
    const float* ar = OBm + b * 1024;
    const float* wr = bWo + (long long)c * 1024;
    float acc = 0.f;
    for (int j = 0; j < 1024; j += 4) {
        float4 a = *(const float4*)(ar + j);
        float4 w4 = *(const float4*)(wr + j);
        acc = fmaf(a.x, w4.x, fmaf(a.y, w4.y, fmaf(a.z, w4.z, fmaf(a.w, w4.w, acc))));
    }
    ydm[idx] = acc + bWo_b[c] + dxm[c];
}

__global__ __launch_bounds__(256) void outm_k(
    const float* __restrict__ ydm, const float* __restrict__ dout_W,
    const float* __restrict__ dout_b, float* __restrict__ outm)
{
    int idx = blockIdx.x * 256 + threadIdx.x;
    int b = idx >> 11, c = idx & 2047;
    const float* ar = ydm + b * 1024;
    const float* wr = dout_W + (long long)c * 1024;
    float acc = 0.f;
    for (int j = 0; j < 1024; j += 4) {
        float4 a = *(const float4*)(ar + j);
        float4 w4 = *(const float4*)(wr + j);
        acc = fmaf(a.x, w4.x, fmaf(a.y, w4.y, fmaf(a.z, w4.z, fmaf(a.w, w4.w, acc))));
    }
    outm[idx] = acc + dout_b[c];
}

__global__ __launch_bounds__(256) void bcast_k(
    const float* __restrict__ outm, float* __restrict__ out)
{
    int idx = blockIdx.x * 256 + threadIdx.x;
    int c4 = idx & 511;
    int b = idx >> 18;
    ((float4*)out)[idx] = ((const float4*)outm)[b * 512 + c4];
}

// ---------------------------------------------------------------------------
// Host-side launcher
// ---------------------------------------------------------------------------
static inline void pairify(hipStream_t s, const float* src, unsigned short* dst,
                           int k_log2, long long n)
{
    pairify_k<<<(int)((n + 255) / 256), 256, 0, s>>>(src, dst, k_log2, n);
}

extern "C" void kernel_launch(void* const* d_in, const int* in_sizes, int n_in,
                              void* d_out, int out_size, void* d_ws, size_t ws_size,
                              hipStream_t stream)
{
    const float* x       = (const float*)d_in[0];
    const float* ln0_w   = (const float*)d_in[1];
    const float* ln0_b   = (const float*)d_in[2];
    const float* in_W    = (const float*)d_in[3];
    const float* rms_w   = (const float*)d_in[4];
    const float* exp_W   = (const float*)d_in[5];
    const float* conv_W  = (const float*)d_in[6];
    const float* xproj_W = (const float*)d_in[7];
    const float* dt_bias = (const float*)d_in[8];
    const float* A_log   = (const float*)d_in[9];
    const float* Dv      = (const float*)d_in[10];
    const float* outp_W  = (const float*)d_in[11];
    const float* outp_b  = (const float*)d_in[12];
    const float* n1_w    = (const float*)d_in[13];
    const float* n1_b    = (const float*)d_in[14];
    const float* aWq     = (const float*)d_in[15];
    const float* aWk     = (const float*)d_in[16];
    const float* aWv     = (const float*)d_in[17];
    const float* aWo     = (const float*)d_in[18];
    const float* aWo_b   = (const float*)d_in[19];
    const float* h_W     = (const float*)d_in[20];
    const float* h_b     = (const float*)d_in[21];
    const float* h_lnw   = (const float*)d_in[22];
    const float* h_lnb   = (const float*)d_in[23];
    const float* mtok    = (const float*)d_in[24];
    const float* e2d_W   = (const float*)d_in[25];
    const float* dn_w    = (const float*)d_in[26];
    const float* dn_b    = (const float*)d_in[27];
    const float* bWq     = (const float*)d_in[28];
    const float* bWk     = (const float*)d_in[29];
    const float* bWv     = (const float*)d_in[30];
    const float* bWo     = (const float*)d_in[31];
    const float* bWo_b   = (const float*)d_in[32];
    const float* dout_W  = (const float*)d_in[33];
    const float* dout_b  = (const float*)d_in[34];

    float* ws  = (float*)d_ws;
    float* out = (float*)d_out;

    float* S1 = ws;
    float* S2 = ws + 8388608;
    float* S3 = ws + 16777216;
    float* S4 = ws + 25165824;
    float* S5 = ws + 33554432;
    float* S6 = ws + 37748736;
    float* S7 = ws + 41943040;
    float* S8 = ws + 46137344;
    float* S9 = ws + 50331648;
    float* SP = ws + 54525952;

    unsigned short* XV2     = (unsigned short*)S1;
    unsigned short* exp_W2  = (unsigned short*)S1;
    unsigned short* XCT2    = (unsigned short*)S1;
    float*          SA      = S1;
    unsigned short* P2      = (unsigned short*)S1;
    float*          Kv      = S1;
    float*          Vv      = S1 + 4194304;
    unsigned short* in_W2   = (unsigned short*)S2;
    float*          XS      = S2;
    unsigned short* YS2     = (unsigned short*)S2;
    unsigned short* XC2     = (unsigned short*)S3;
    unsigned short* outp_W2 = (unsigned short*)S3;
    float*          DXV     = S3;
    unsigned short* LNDXV2  = (unsigned short*)(S3 + 4194304);
    float*          Z       = S4;
    unsigned short* aWq2    = (unsigned short*)S4;
    unsigned short* aWk2    = (unsigned short*)S4 + 2097152;
    unsigned short* aWv2    = (unsigned short*)S4 + 4194304;
    unsigned short* aWo2    = (unsigned short*)S4 + 6291456;
    unsigned short* bWk2    = (unsigned short*)S4 + 8388608;
    unsigned short* bWv2    = (unsigned short*)S4 + 10485760;
    float*          T       = S5;
    unsigned short* QA2     = (unsigned short*)S5;
    unsigned short* Y22     = (unsigned short*)S5;
    unsigned short* HR2     = (unsigned short*)S6;
    float*          Y1      = S6;
    unsigned short* LNY2    = (unsigned short*)S7;
    unsigned short* OA2     = (unsigned short*)S7;
    unsigned short* KA2     = (unsigned short*)S8;
    unsigned short* VT2     = (unsigned short*)S9;

    float* dtBC = SP;
    float* DT   = SP + 589824;
    float* CUMA = SP + 655360;
    float* G    = SP + 720896;
    unsigned short* xprojW2 = (unsigned short*)(SP + 2818048);
    unsigned short* hW2     = (unsigned short*)(SP + 3112960);
    unsigned short* e2dW2   = (unsigned short*)(SP + 3178496);
    float* G1   = SP + 720896;
    unsigned short* HCQ2 = (unsigned short*)(SP + 983040);
    float* dxm  = SP + 1245184;
    float* lnm  = SP + 1246208;
    float* qm   = SP + 1247232;
    float* km   = SP + 1248256;
    float* vm   = SP + 1249280;
    float* OBm  = SP + 1250304;
    float* ydm  = SP + 1258496;
    float* outm = SP + 1266688;

    const long long LL0 = 0;
    #define G3D(OUTM, GX, GY, GZ, ...) \
        gemm_bf16_k<3, OUTM, true><<<dim3(GX, GY, GZ), 256, 0, stream>>>(__VA_ARGS__)
    #define G3R(OUTM, GX, GY, GZ, ...) \
        gemm_bf16_k<3, OUTM, false><<<dim3(GX, GY, GZ), 256, 0, stream>>>(__VA_ARGS__)
    #define G1D(OUTM, GX, GY, GZ, ...) \
        gemm_bf16_k<1, OUTM, true><<<dim3(GX, GY, GZ), 256, 0, stream>>>(__VA_ARGS__)

    // ---- weight prep (phase A) ----
    pairify(stream, in_W,    in_W2,   11, 1024LL * 2048);
    pairify(stream, xproj_W, xprojW2, 11, 144LL * 2048);
    pairify(stream, h_W,     hW2,     10, 64LL * 1024);
    pairify(stream, e2d_W,   e2dW2,    6, 1024LL * 64);

    // ---- encoder trunk ----
    layernorm_pair_k<<<4096, 256, 0, stream>>>(x, XV2, ln0_w, ln0_b, 2048, 512,
                                               (long long)1024 * 2048);
    G3D(0, 8, 32, 1, 4096, 1024, 2048, XV2, 4096, 2048, LL0, LL0,
        in_W2, 4096, 2048, LL0, LL0, T, 1024, 0, LL0, LL0,
        nullptr, nullptr, 0, 1.f, 1);
    pairify(stream, exp_W, exp_W2, 10, 4096LL * 1024);   // S1 (XV2 dead)
    rmsnorm_pair_k<<<4096, 256, 0, stream>>>(T, HR2, rms_w, 1024);
    G3D(0, 16, 32, 1, 4096, 2048, 1024, HR2, 2048, 1024, LL0, LL0,
        exp_W2, 2048, 1024, LL0, LL0, XS, 2048, 0, LL0, LL0,
        nullptr, nullptr, 0, 1.f, 1);
    G3D(0, 16, 32, 1, 4096, 2048, 1024, HR2, 2048, 1024, LL0, LL0,
        exp_W2 + 2048LL * 2048, 2048, 1024, LL0, LL0, Z, 2048, 0, LL0, LL0,
        nullptr, nullptr, 0, 1.f, 1);
    conv_k<<<dim3(32, 8, 8), 256, 0, stream>>>(XS, conv_W, XC2, XCT2);
    G3R(0, 2, 32, 1, 4096, 144, 2048, XC2, 4096, 2048, LL0, LL0,
        xprojW2, 4096, 2048, LL0, LL0, dtBC, 144, 0, LL0, LL0,
        nullptr, nullptr, 0, 1.f, 1);
    dt_k<<<256, 256, 0, stream>>>(dtBC, dt_bias, DT);
    cuma_k<<<dim3(16, 8), 64, 0, stream>>>(DT, A_log, CUMA);
    gemm_f32_k<<<dim3(4, 4, 8), 256, 0, stream>>>(
        512, 512, 64, dtBC + 80, 144, (long long)512 * 144,
        dtBC + 16, 144, (long long)512 * 144, G, 512, (long long)512 * 512);
    ssd_mfma_k<<<dim3(4, 16, 8), 256, 0, stream>>>(G, CUMA, DT, XCT2, Z, Dv, YS2);

    // ---- weight prep (phase B: S3/S4 now dead) ----
    pairify(stream, outp_W, outp_W2, 11, 1024LL * 2048);
    pairify(stream, aWq, aWq2, 10, 1024LL * 1024);
    pairify(stream, aWk, aWk2, 10, 1024LL * 1024);
    pairify(stream, aWv, aWv2, 10, 1024LL * 1024);
    pairify(stream, aWo, aWo2, 10, 1024LL * 1024);
    pairify(stream, bWk, bWk2, 10, 1024LL * 1024);
    pairify(stream, bWv, bWv2, 10, 1024LL * 1024);

    G3D(0, 8, 32, 1, 4096, 1024, 2048, YS2, 4096, 2048, LL0, LL0,
        outp_W2, 4096, 2048, LL0, LL0, Y1, 1024, 0, LL0, LL0,
        outp_b, T, 1024, 1.f, 1);

    // ---- encoder attention (all MFMA) ----
    layernorm_pair_k<<<4096, 256, 0, stream>>>(Y1, LNY2, n1_w, n1_b, 1024, 4096, LL0);
    G3D(1, 8, 32, 1, 4096, 1024, 1024, LNY2, 2048, 1024, LL0, LL0,
        aWq2, 2048, 1024, LL0, LL0, QA2, 2048, 1024, LL0, LL0,
        nullptr, nullptr, 0, 1.f, 1);
    G3D(1, 8, 32, 1, 4096, 1024, 1024, LNY2, 2048, 1024, LL0, LL0,
        aWk2, 2048, 1024, LL0, LL0, KA2, 2048, 1024, LL0, LL0,
        nullptr, nullptr, 0, 1.f, 1);
    G3D(2, 8, 32, 1, 4096, 1024, 1024, LNY2, 2048, 1024, LL0, LL0,
        aWv2, 2048, 1024, LL0, LL0, VT2, 1024, 512, (long long)1024 * 1024, LL0,
        nullptr, nullptr, 0, 1.f, 1);
    G3D(0, 4, 4, 32, 512, 512, 256,
        QA2, 2048, 1024, (long long)512 * 2048, 256,
        KA2, 2048, 1024, (long long)512 * 2048, 256,
        SA, 512, 0, (long long)4 * 512 * 512, (long long)512 * 512,
        nullptr, nullptr, 0, 1.f / 16.f, 4);
    softmax_pair_k<<<16384, 256, 0, stream>>>(SA, P2);
    G3D(1, 2, 4, 32, 512, 256, 512,
        P2, 1024, 512, (long long)4 * 512 * 1024, (long long)512 * 1024,
        VT2, 1024, 512, (long long)1024 * 1024, (long long)256 * 1024,
        OA2, 2048, 1024, (long long)512 * 2048, 256,
        nullptr, nullptr, 0, 1.f, 4);
    G3D(1, 8, 32, 1, 4096, 1024, 1024, OA2, 2048, 1024, LL0, LL0,
        aWo2, 2048, 1024, LL0, LL0, Y22, 2048, 1024, LL0, LL0,
        aWo_b, Y1, 1024, 1.f, 1);

    // ---- quantize ----
    G3R(0, 1, 32, 1, 4096, 64, 1024, Y22, 2048, 1024, LL0, LL0,
        hW2, 2048, 1024, LL0, LL0, G1, 64, 0, LL0, LL0,
        h_b, nullptr, 0, 1.f, 1);
    hc_quant_k<<<4096, 64, 0, stream>>>(G1, h_lnw, h_lnb, HCQ2);

    // ---- decoder (collapsed masked rows) ----
    G3D(0, 8, 32, 1, 4096, 1024, 64, HCQ2, 128, 64, LL0, LL0,
        e2dW2, 128, 64, LL0, LL0, DXV, 1024, 0, LL0, LL0,
        nullptr, nullptr, 0, 1.f, 1);
    dxm_k<<<4, 256, 0, stream>>>(mtok, e2d_W, dxm);
    layernorm_k<<<1, 256, 0, stream>>>(dxm, lnm, dn_w, dn_b, 1024, 1, LL0);
    layernorm_pair_k<<<4096, 256, 0, stream>>>(DXV, LNDXV2, dn_w, dn_b, 1024, 4096, LL0);
    projm_k<<<12, 256, 0, stream>>>(lnm, bWq, bWk, bWv, qm, km, vm);
    G1D(0, 8, 32, 1, 4096, 1024, 1024, LNDXV2, 2048, 1024, LL0, LL0,
        bWk2, 2048, 1024, LL0, LL0, Kv, 1024, 0, LL0, LL0,
        nullptr, nullptr, 0, 1.f, 1);
    G1D(0, 8, 32, 1, 4096, 1024, 1024, LNDXV2, 2048, 1024, LL0, LL0,
        bWv2, 2048, 1024, LL0, LL0, Vv, 1024, 0, LL0, LL0,
        nullptr, nullptr, 0, 1.f, 1);
    dec_attn_k<<<dim3(4, 8), 256, 0, stream>>>(Kv, Vv, qm, km, vm, OBm);
    ydm_k<<<32, 256, 0, stream>>>(OBm, bWo, bWo_b, dxm, ydm);
    outm_k<<<64, 256, 0, stream>>>(ydm, dout_W, dout_b, outm);
    bcast_k<<<8192, 256, 0, stream>>>(outm, out);
    #undef G3D
    #undef G3R
    #undef G1D
}

// Round 2
// 1295.626 us; speedup vs baseline: 1.0855x; 1.0662x over previous
//
#include <hip/hip_runtime.h>

// ---------------------------------------------------------------------------
// B=8, N=1024, CIN=2048, HID=1024, HC=64, LV=512, NH_SSD=16, HD=128, DS=64.
// Encoder rows = 4096. Decoder collapsed to 1 row/batch. All large GEMMs:
// split-bf16 MFMA (x3 passes = f32-grade pre-quantizer; x1 post-quantizer),
// staged via __builtin_amdgcn_global_load_lds width=16 (DIRECT path).
// DIRECT GEMM v2: triple-buffered LDS + counted vmcnt (never 0 in steady
// state) + raw s_barrier -> software pipeline replaces the missing TLP at
// 1 block/CU (grid 256 = 1 wave/SIMD). Source-swizzled staging kills the
// 8-way ds_read_b128 bank conflict. SSD intra-chunk = fused MFMA kernel.
// ---------------------------------------------------------------------------

typedef short bf16x8 __attribute__((ext_vector_type(8)));
typedef float f32x4 __attribute__((ext_vector_type(4)));

__device__ __forceinline__ unsigned short bf16_rne(float f) {
    unsigned u = __float_as_uint(f);
    unsigned r = u + 0x7FFFu + ((u >> 16) & 1u);
    return (unsigned short)(r >> 16);
}
__device__ __forceinline__ float bf16_tof(unsigned short h) {
    return __uint_as_float(((unsigned)h) << 16);
}
__device__ __forceinline__ void store_pair(unsigned short* dst, long long row,
                                           int width, int c, float v) {
    unsigned short hi = bf16_rne(v);
    unsigned short lo = bf16_rne(v - bf16_tof(hi));
    long long base = row * (2LL * width);
    dst[base + c] = hi;
    dst[base + width + c] = lo;
}
// Async global->LDS, 16B per lane. LDS dest = wave-uniform base + lane*16.
__device__ __forceinline__ void async_ld16(const unsigned short* g, unsigned short* l) {
    __builtin_amdgcn_global_load_lds(
        (const __attribute__((address_space(1))) unsigned int*)g,
        (__attribute__((address_space(3))) unsigned int*)l, 16, 0, 0);
}

// ---------------------------------------------------------------------------
// Reduction helpers (blockDim 256)
// ---------------------------------------------------------------------------
__device__ __forceinline__ float block_sum256(float v) {
    #pragma unroll
    for (int o = 32; o > 0; o >>= 1) v += __shfl_xor(v, o, 64);
    __shared__ float sm[4];
    int w = threadIdx.x >> 6;
    __syncthreads();
    if ((threadIdx.x & 63) == 0) sm[w] = v;
    __syncthreads();
    return sm[0] + sm[1] + sm[2] + sm[3];
}
__device__ __forceinline__ float block_max256(float v) {
    #pragma unroll
    for (int o = 32; o > 0; o >>= 1) v = fmaxf(v, __shfl_xor(v, o, 64));
    __shared__ float smx[4];
    int w = threadIdx.x >> 6;
    __syncthreads();
    if ((threadIdx.x & 63) == 0) smx[w] = v;
    __syncthreads();
    return fmaxf(fmaxf(smx[0], smx[1]), fmaxf(smx[2], smx[3]));
}

// ---------------------------------------------------------------------------
// Split-bf16 MFMA GEMM. C[m,n] = alpha * sum_k A[m,k]*B[n,k] (+bias)(+res)
// NPASS=3: hh+lh+hl (f32-grade). NPASS=1: hh only.
// OUT=0: f32 C. OUT=1: split-pair C. OUT=2: transposed split-pair per
// 512-row batch.
// DIRECT=true: global_load_lds staging, triple-buffered, counted-vmcnt
//   pipeline (depth-2 prefetch), source-swizzled for conflict-free b128:
//   LDS slot (row, q) holds the global 16B-chunk q ^ t(row),
//   t(r) = (r&3)^((r>>2)&3)  -> max 2-way bank aliasing (free).
//   Requires full tiles (N covered by grid) and K % 32 == 0.
// DIRECT=false: guarded reg staging (ragged N ok), original 2-barrier loop.
// ---------------------------------------------------------------------------
template<int NPASS, int OUT, bool DIRECT>
__global__ __launch_bounds__(256, DIRECT ? 1 : 2) void gemm_bf16_k(
    int M, int N, int K,
    const unsigned short* __restrict__ A2, int lda2, int aLo, long long sAb, long long sAh,
    const unsigned short* __restrict__ B2, int ldb2, int bLo, long long sBb, long long sBh,
    void* __restrict__ Cv, int ldc, int cLo, long long sCb, long long sCh,
    const float* __restrict__ bias, const float* __restrict__ res, int ldr,
    float alpha, int nh)
{
    constexpr int ST   = DIRECT ? 32 : 40;
    constexpr int NARR = (NPASS == 3) ? 4 : 2;
    constexpr int NB   = DIRECT ? 3 : 1;
    constexpr int O_AH = 0;
    constexpr int O_BH = 128 * ST;
    constexpr int O_AL = 2 * 128 * ST;
    constexpr int O_BL = 3 * 128 * ST;
    constexpr int BUFSZ = 128 * ST * NARR;
    __shared__ unsigned short SM[NB * BUFSZ];

    const int z  = blockIdx.z;
    const int bb = z / nh, hh = z - bb * nh;
    A2 += bb * sAb + hh * sAh;
    B2 += bb * sBb + hh * sBh;

    const int t    = threadIdx.x;
    const int m0   = blockIdx.y * 128;
    const int n0   = blockIdx.x * 128;
    const int lane = t & 63, wave = t >> 6;
    const int wm   = (wave >> 1) * 64, wn = (wave & 1) * 64;
    const int lr   = lane & 15, quad = lane >> 4;

    f32x4 acc[4][4];
    #pragma unroll
    for (int i = 0; i < 4; ++i)
        #pragma unroll
        for (int j = 0; j < 4; ++j) acc[i][j] = (f32x4){0.f, 0.f, 0.f, 0.f};

    if constexpr (DIRECT) {
        // ---- pipelined path ----
        const int drow  = lane >> 2;                       // row in 16-chunk
        // swizzled global 16B-chunk for this lane's LDS slot (lane&3):
        const int dcswz = (((lane & 3) ^ ((lane >> 2) & 3) ^ ((lane >> 4) & 3)) << 3);
        // frag-read slot XOR (per-lane constant):
        const int rsw   = ((quad ^ ((lr & 3) ^ (lr >> 2))) << 3);

        auto stage = [&](int k0, int buf) {
            unsigned short* bp = &SM[buf * BUFSZ];
            #pragma unroll
            for (int j = 0; j < 2; ++j) {
                int rr = wave * 32 + j * 16;               // chunk base row
                int gr = rr + drow;
                const unsigned short* gA = A2 + (long long)(m0 + gr) * lda2 + k0 + dcswz;
                async_ld16(gA, &bp[O_AH + rr * 32]);
                if (NPASS == 3) async_ld16(gA + aLo, &bp[O_AL + rr * 32]);
                const unsigned short* gB = B2 + (long long)(n0 + gr) * ldb2 + k0 + dcswz;
                async_ld16(gB, &bp[O_BH + rr * 32]);
                if (NPASS == 3) async_ld16(gB + bLo, &bp[O_BL + rr * 32]);
            }
        };

        const int nt = K >> 5;
        stage(0, 0);
        if (nt > 1) stage(32, 1);
        int cur = 0, pre = 2;
        for (int it = 0; it < nt; ++it) {
            // wait for tile it's loads (keep next tile's in flight), all waves
            if (it + 1 < nt) {
                if (NPASS == 3) asm volatile("s_waitcnt vmcnt(8)" ::: "memory");
                else            asm volatile("s_waitcnt vmcnt(4)" ::: "memory");
            } else {
                asm volatile("s_waitcnt vmcnt(0)" ::: "memory");
            }
            __builtin_amdgcn_s_barrier();
            // prefetch tile it+2 into the buffer consumed at iter it-1
            // (safe: its ds_reads were lgkm-consumed before this barrier)
            if (it + 2 < nt) stage((it + 2) << 5, pre);

            const unsigned short* bp = &SM[cur * BUFSZ];
            bf16x8 ah[4], bh[4], al[4], bl[4];
            #pragma unroll
            for (int i = 0; i < 4; ++i) {
                int ra = O_AH + (wm + i * 16 + lr) * 32 + rsw;
                int rb = O_BH + (wn + i * 16 + lr) * 32 + rsw;
                ah[i] = *(const bf16x8*)&bp[ra];
                bh[i] = *(const bf16x8*)&bp[rb];
                if (NPASS == 3) {
                    al[i] = *(const bf16x8*)&bp[ra + (O_AL - O_AH)];
                    bl[i] = *(const bf16x8*)&bp[rb + (O_BL - O_BH)];
                }
            }
            #pragma unroll
            for (int mi = 0; mi < 4; ++mi)
                #pragma unroll
                for (int ni = 0; ni < 4; ++ni) {
                    acc[mi][ni] = __builtin_amdgcn_mfma_f32_16x16x32_bf16(
                        ah[mi], bh[ni], acc[mi][ni], 0, 0, 0);
                    if (NPASS == 3) {
                        acc[mi][ni] = __builtin_amdgcn_mfma_f32_16x16x32_bf16(
                            al[mi], bh[ni], acc[mi][ni], 0, 0, 0);
                        acc[mi][ni] = __builtin_amdgcn_mfma_f32_16x16x32_bf16(
                            ah[mi], bl[ni], acc[mi][ni], 0, 0, 0);
                    }
                }
            cur = (cur == 2) ? 0 : cur + 1;
            pre = (pre == 2) ? 0 : pre + 1;
        }
    } else {
        // ---- ragged reg-staging path (original structure) ----
        const int srow = t >> 2;          // row 0..63 (+64)
        const int scol = (t & 3) * 8;

        for (int k0 = 0; k0 < K; k0 += 32) {
            __syncthreads();
            #pragma unroll
            for (int half = 0; half < 2; ++half) {
                int r = srow + half * 64;
                const unsigned short* pA = A2 + (long long)(m0 + r) * lda2 + k0 + scol;
                *(uint4*)&SM[O_AH + r * ST + scol] = *(const uint4*)pA;
                if (NPASS == 3)
                    *(uint4*)&SM[O_AL + r * ST + scol] = *(const uint4*)(pA + aLo);
                int rb = n0 + r;
                uint4 vh = {0u, 0u, 0u, 0u}, vl = {0u, 0u, 0u, 0u};
                if (rb < N) {
                    const unsigned short* pB = B2 + (long long)rb * ldb2 + k0 + scol;
                    vh = *(const uint4*)pB;
                    if (NPASS == 3) vl = *(const uint4*)(pB + bLo);
                }
                *(uint4*)&SM[O_BH + r * ST + scol] = vh;
                if (NPASS == 3) *(uint4*)&SM[O_BL + r * ST + scol] = vl;
            }
            __syncthreads();

            bf16x8 ah[4], bh[4], al[4], bl[4];
            #pragma unroll
            for (int i = 0; i < 4; ++i) {
                int ra = (wm + i * 16 + lr) * ST + quad * 8;
                int rb = (wn + i * 16 + lr) * ST + quad * 8;
                ah[i] = *(const bf16x8*)&SM[O_AH + ra];
                bh[i] = *(const bf16x8*)&SM[O_BH + rb];
                if (NPASS == 3) {
                    al[i] = *(const bf16x8*)&SM[O_AL + ra];
                    bl[i] = *(const bf16x8*)&SM[O_BL + rb];
                }
            }
            #pragma unroll
            for (int mi = 0; mi < 4; ++mi)
                #pragma unroll
                for (int ni = 0; ni < 4; ++ni) {
                    acc[mi][ni] = __builtin_amdgcn_mfma_f32_16x16x32_bf16(
                        ah[mi], bh[ni], acc[mi][ni], 0, 0, 0);
                    if (NPASS == 3) {
                        acc[mi][ni] = __builtin_amdgcn_mfma_f32_16x16x32_bf16(
                            al[mi], bh[ni], acc[mi][ni], 0, 0, 0);
                        acc[mi][ni] = __builtin_amdgcn_mfma_f32_16x16x32_bf16(
                            ah[mi], bl[ni], acc[mi][ni], 0, 0, 0);
                    }
                }
        }
    }

    // D layout: col = lane&15, row = quad*4 + r
    if (OUT == 0) {
        float* C = (float*)Cv + bb * sCb + hh * sCh;
        #pragma unroll
        for (int mi = 0; mi < 4; ++mi)
            #pragma unroll
            for (int ni = 0; ni < 4; ++ni) {
                int col = n0 + wn + ni * 16 + lr;
                if (col >= N) continue;
                float bv = bias ? bias[col] : 0.f;
                #pragma unroll
                for (int r = 0; r < 4; ++r) {
                    int row = m0 + wm + mi * 16 + quad * 4 + r;
                    float v = alpha * acc[mi][ni][r] + bv;
                    if (res) v += res[(long long)row * ldr + col];
                    C[(long long)row * ldc + col] = v;
                }
            }
    } else if (OUT == 1) {
        unsigned short* C = (unsigned short*)Cv + bb * sCb + hh * sCh;
        #pragma unroll
        for (int mi = 0; mi < 4; ++mi)
            #pragma unroll
            for (int ni = 0; ni < 4; ++ni) {
                int col = n0 + wn + ni * 16 + lr;
                if (col >= N) continue;
                float bv = bias ? bias[col] : 0.f;
                #pragma unroll
                for (int r = 0; r < 4; ++r) {
                    int row = m0 + wm + mi * 16 + quad * 4 + r;
                    float v = alpha * acc[mi][ni][r] + bv;
                    if (res) v += res[(long long)row * ldr + col];
                    unsigned short hi = bf16_rne(v);
                    unsigned short lo = bf16_rne(v - bf16_tof(hi));
                    long long p = (long long)row * ldc + col;
                    C[p] = hi;
                    C[p + cLo] = lo;
                }
            }
    } else {  // OUT == 2: transposed pairs per 512-row batch
        unsigned short* C = (unsigned short*)Cv;
        #pragma unroll
        for (int mi = 0; mi < 4; ++mi)
            #pragma unroll
            for (int ni = 0; ni < 4; ++ni) {
                int col = n0 + wn + ni * 16 + lr;
                if (col >= N) continue;
                int row0 = m0 + wm + mi * 16 + quad * 4;
                int b = row0 >> 9, seq0 = row0 & 511;
                ushort4 h4, l4;
                unsigned short* hp = (unsigned short*)&h4;
                unsigned short* lp = (unsigned short*)&l4;
                #pragma unroll
                for (int r = 0; r < 4; ++r) {
                    float v = acc[mi][ni][r];
                    unsigned short hi = bf16_rne(v);
                    hp[r] = hi;
                    lp[r] = bf16_rne(v - bf16_tof(hi));
                }
                long long p = b * sCb + (long long)col * ldc + seq0;
                *(ushort4*)&C[p] = h4;
                *(ushort4*)&C[p + cLo] = l4;
            }
    }
}

// ---------------------------------------------------------------------------
// Fused SSD intra-chunk MFMA kernel, v3.
// Per (b,h): Y[l,p] = sum_{s<=l} W[l,s]*XC[s,p];
// W = G*exp(cAl-cAs)*dt[s], with D-skip folded in: W[l,l] += D[h].
//  * 64-row x 128-chan tiles; uniform work per block: block q runs row-tile
//    pair (7-q, q) sequentially -> 18 k-tiles/block for every q.
//  * double-buffered W in LDS, ONE barrier per k-tile; X-frag global loads
//    issued before the G loads (issue-early/consume-late).
//  * XOR-swizzled W tile: conflict-free b128 reads/writes.
//  * interior tiles skip causal mask + diagonal add.
// grid (4 = row-tile pairs, 16 h, 8 b), block 256 (4 waves x 16l x 128p).
// ---------------------------------------------------------------------------
__global__ __launch_bounds__(256, 2) void ssd_mfma_k(
    const float* __restrict__ G, const float* __restrict__ CUMA,
    const float* __restrict__ DT, const unsigned short* __restrict__ XCT2,
    const float* __restrict__ Z, const float* __restrict__ Dv,
    unsigned short* __restrict__ YS2)
{
    __shared__ unsigned short Wh[2][64 * 32];
    __shared__ unsigned short Wl[2][64 * 32];
    __shared__ float Cs[512];
    __shared__ float Ds[512];
    const int q = blockIdx.x;
    const int h = blockIdx.y, b = blockIdx.z;
    const int t = threadIdx.x;
    const int lane = t & 63, wave = t >> 6;
    const int lr = lane & 15, quad = lane >> 4;

    const float* cbase = CUMA + (b * 16 + h) * 512;
    const float* dtb = DT + (long long)b * 512 * 16 + h;
    for (int s = t; s < 512; s += 256) {
        Cs[s] = cbase[s];
        Ds[s] = dtb[(long long)s * 16];
    }
    const float Dh = Dv[h];

    const int wr = t >> 2;                        // W-gen row 0..63
    const int sw = t & 3;                         // logical 16B slot 0..3
    const int wbase = wr * 32 + ((sw ^ ((wr >> 1) & 3)) << 3);
    const int frow = wave * 16 + lr;              // frag row 0..63
    const int fbase = frow * 32 + ((quad ^ ((frow >> 1) & 3)) << 3);
    const unsigned short* XB = XCT2 + (long long)b * 2097152
                             + (long long)(h * 128) * 1024;
    __syncthreads();

    for (int ph = 0; ph < 2; ++ph) {
        const int mt = ph ? q : 7 - q;            // heavy row-tile first
        const int m0 = mt * 64;
        const int kend = m0 + 64;
        const int lglob = m0 + wr;
        const float cAl = Cs[lglob];
        const float* grow = G + ((long long)(b * 512 + lglob)) * 512;

        float pg[8], pc[8], pd[8];
        auto gen_load = [&](int k0g) {
            const int sb = k0g + sw * 8;
            float4 g0 = *(const float4*)(grow + sb);
            float4 g1 = *(const float4*)(grow + sb + 4);
            float4 c0 = *(const float4*)&Cs[sb];
            float4 c1 = *(const float4*)&Cs[sb + 4];
            float4 d0 = *(const float4*)&Ds[sb];
            float4 d1 = *(const float4*)&Ds[sb + 4];
            pg[0] = g0.x; pg[1] = g0.y; pg[2] = g0.z; pg[3] = g0.w;
            pg[4] = g1.x; pg[5] = g1.y; pg[6] = g1.z; pg[7] = g1.w;
            pc[0] = c0.x; pc[1] = c0.y; pc[2] = c0.z; pc[3] = c0.w;
            pc[4] = c1.x; pc[5] = c1.y; pc[6] = c1.z; pc[7] = c1.w;
            pd[0] = d0.x; pd[1] = d0.y; pd[2] = d0.z; pd[3] = d0.w;
            pd[4] = d1.x; pd[5] = d1.y; pd[6] = d1.z; pd[7] = d1.w;
        };
        auto gen_finish = [&](int k0g, int buf) {
            const int sb = k0g + sw * 8;
            const bool edge = (k0g + 32 > m0);    // tile touches causal edge
            unsigned short hv[8], lv[8];
            #pragma unroll
            for (int e = 0; e < 8; ++e) {
                float w = pg[e] * __expf(cAl - pc[e]) * pd[e];
                if (edge) {
                    int sg = sb + e;
                    w = (sg <= lglob) ? w : 0.f;  // select AFTER: kills inf/nan
                    if (sg == lglob) w += Dh;
                }
                unsigned short hi = bf16_rne(w);
                hv[e] = hi;
                lv[e] = bf16_rne(w - bf16_tof(hi));
            }
            *(uint4*)&Wh[buf][wbase] = *(uint4*)hv;
            *(uint4*)&Wl[buf][wbase] = *(uint4*)lv;
        };

        f32x4 acc[8];
        #pragma unroll
        for (int j = 0; j < 8; ++j) acc[j] = (f32x4){0.f, 0.f, 0.f, 0.f};

        gen_load(0);
        gen_finish(0, 0);
        __syncthreads();

        for (int k0 = 0; k0 < kend; k0 += 32) {
            const int cur = (k0 >> 5) & 1;
            const bool pf = (k0 + 32 < kend);
            bf16x8 bh[8], bl[8];
            #pragma unroll
            for (int ni = 0; ni < 8; ++ni) {      // X frags first (oldest vmem)
                const unsigned short* pB =
                    XB + (long long)(ni * 16 + lr) * 1024 + k0 + quad * 8;
                bh[ni] = *(const bf16x8*)pB;
                bl[ni] = *(const bf16x8*)(pB + 512);
            }
            if (pf) gen_load(k0 + 32);            // G loads after X: MFMA waits
                                                  // don't drain them
            bf16x8 ah = *(const bf16x8*)&Wh[cur][fbase];
            bf16x8 al = *(const bf16x8*)&Wl[cur][fbase];
            #pragma unroll
            for (int ni = 0; ni < 8; ++ni) {
                acc[ni] = __builtin_amdgcn_mfma_f32_16x16x32_bf16(
                    ah, bh[ni], acc[ni], 0, 0, 0);
                acc[ni] = __builtin_amdgcn_mfma_f32_16x16x32_bf16(
                    al, bh[ni], acc[ni], 0, 0, 0);
                acc[ni] = __builtin_amdgcn_mfma_f32_16x16x32_bf16(
                    ah, bl[ni], acc[ni], 0, 0, 0);
            }
            if (pf) gen_finish(k0 + 32, cur ^ 1); // exp/split overlaps MFMA drain
            __syncthreads();                      // single barrier per k-tile
        }

        const int row0 = m0 + wave * 16 + quad * 4;
        #pragma unroll
        for (int ni = 0; ni < 8; ++ni) {
            int chan = h * 128 + ni * 16 + lr;
            #pragma unroll
            for (int r = 0; r < 4; ++r) {
                long long row = (long long)(b * 512 + row0 + r);
                float zz = Z[row * 2048 + chan];
                float y = acc[ni][r] * (zz / (1.f + expf(-zz)));
                store_pair(YS2, row, 2048, chan, y);
            }
        }
    }
}

// ---------------------------------------------------------------------------
// Tiled f32 GEMM (only for the small batched G = Cm @ Bm^T)
// ---------------------------------------------------------------------------
__global__ __launch_bounds__(256) void gemm_f32_k(
    int M, int N, int K,
    const float* __restrict__ A, int lda, long long sAb,
    const float* __restrict__ B, int ldb, long long sBb,
    float* __restrict__ C, int ldc, long long sCb)
{
    __shared__ float As[32][132];
    __shared__ float Bs[32][132];
    const int z = blockIdx.z;
    A += z * sAb; B += z * sBb; C += z * sCb;
    const int n0 = blockIdx.x * 128;
    const int m0 = blockIdx.y * 128;
    const int t  = threadIdx.x;
    const int tx = t & 15, ty = t >> 4;

    float acc[4][16];
    #pragma unroll
    for (int a = 0; a < 4; ++a)
        #pragma unroll
        for (int q = 0; q < 16; ++q) acc[a][q] = 0.f;

    const int ka = (t & 7) << 2;
    const int ra = t >> 3;

    for (int k0 = 0; k0 < K; k0 += 32) {
        __syncthreads();
        #pragma unroll
        for (int i = 0; i < 4; ++i) {
            int row = m0 + ra + i * 32;
            float4 v = *(const float4*)(A + (long long)row * lda + (k0 + ka));
            As[ka + 0][ra + i * 32] = v.x;
            As[ka + 1][ra + i * 32] = v.y;
            As[ka + 2][ra + i * 32] = v.z;
            As[ka + 3][ra + i * 32] = v.w;
            int rowb = n0 + ra + i * 32;
            float4 w = *(const float4*)(B + (long long)rowb * ldb + (k0 + ka));
            Bs[ka + 0][ra + i * 32] = w.x;
            Bs[ka + 1][ra + i * 32] = w.y;
            Bs[ka + 2][ra + i * 32] = w.z;
            Bs[ka + 3][ra + i * 32] = w.w;
        }
        __syncthreads();
        #pragma unroll
        for (int kk = 0; kk < 32; ++kk) {
            float a[8], bm[8];
            *(float4*)&a[0]  = *(const float4*)&As[kk][ty * 4];
            *(float4*)&a[4]  = *(const float4*)&As[kk][64 + ty * 4];
            *(float4*)&bm[0] = *(const float4*)&Bs[kk][tx * 4];
            *(float4*)&bm[4] = *(const float4*)&Bs[kk][64 + tx * 4];
            #pragma unroll
            for (int ri = 0; ri < 2; ++ri)
                #pragma unroll
                for (int ci = 0; ci < 2; ++ci)
                    #pragma unroll
                    for (int i = 0; i < 4; ++i)
                        #pragma unroll
                        for (int j = 0; j < 4; ++j)
                            acc[ri * 2 + ci][i * 4 + j] =
                                fmaf(a[ri * 4 + i], bm[ci * 4 + j], acc[ri * 2 + ci][i * 4 + j]);
        }
    }
    #pragma unroll
    for (int ri = 0; ri < 2; ++ri)
        #pragma unroll
        for (int ci = 0; ci < 2; ++ci) {
            int colb = n0 + ci * 64 + tx * 4;
            #pragma unroll
            for (int i = 0; i < 4; ++i) {
                int row = m0 + ri * 64 + ty * 4 + i;
                *(float4*)(C + (long long)row * ldc + colb) =
                    *(float4*)&acc[ri * 2 + ci][i * 4];
            }
        }
}

// ---------------------------------------------------------------------------
// Elementwise / norm kernels
// ---------------------------------------------------------------------------
__global__ __launch_bounds__(256) void pairify_k(
    const float* __restrict__ src, unsigned short* __restrict__ dst,
    int k_log2, long long n)
{
    long long idx = (long long)blockIdx.x * 256 + threadIdx.x;
    if (idx >= n) return;
    long long r = idx >> k_log2;
    int c = (int)(idx & ((1 << k_log2) - 1));
    store_pair(dst, r, 1 << k_log2, c, src[idx]);
}

__global__ __launch_bounds__(256) void layernorm_k(
    const float* __restrict__ in, float* __restrict__ out,
    const float* __restrict__ w, const float* __restrict__ b,
    int width, int rows_per_b, long long in_bstride)
{
    long long r = blockIdx.x;
    const float* x = in + (r / rows_per_b) * in_bstride + (r % rows_per_b) * (long long)width;
    int t = threadIdx.x;
    float s = 0.f;
    for (int c = t; c < width; c += 256) s += x[c];
    s = block_sum256(s);
    float m = s / (float)width;
    float vs = 0.f;
    for (int c = t; c < width; c += 256) { float d = x[c] - m; vs += d * d; }
    vs = block_sum256(vs);
    float rs = 1.f / sqrtf(vs / (float)width + 1e-5f);
    float* o = out + r * (long long)width;
    for (int c = t; c < width; c += 256) o[c] = (x[c] - m) * rs * w[c] + b[c];
}

__global__ __launch_bounds__(256) void layernorm_pair_k(
    const float* __restrict__ in, unsigned short* __restrict__ out2,
    const float* __restrict__ w, const float* __restrict__ b,
    int width, int rows_per_b, long long in_bstride)
{
    long long r = blockIdx.x;
    const float* x = in + (r / rows_per_b) * in_bstride + (r % rows_per_b) * (long long)width;
    int t = threadIdx.x;
    float s = 0.f;
    for (int c = t; c < width; c += 256) s += x[c];
    s = block_sum256(s);
    float m = s / (float)width;
    float vs = 0.f;
    for (int c = t; c < width; c += 256) { float d = x[c] - m; vs += d * d; }
    vs = block_sum256(vs);
    float rs = 1.f / sqrtf(vs / (float)width + 1e-5f);
    for (int c = t; c < width; c += 256)
        store_pair(out2, r, width, c, (x[c] - m) * rs * w[c] + b[c]);
}

__global__ __launch_bounds__(256) void rmsnorm_pair_k(
    const float* __restrict__ in, unsigned short* __restrict__ out2,
    const float* __restrict__ w, int width)
{
    long long r = blockIdx.x;
    const float* x = in + r * (long long)width;
    int t = threadIdx.x;
    float s = 0.f;
    for (int c = t; c < width; c += 256) { float v = x[c]; s += v * v; }
    s = block_sum256(s);
    float rs = 1.f / sqrtf(s / (float)width + 1e-5f);
    for (int c = t; c < width; c += 256)
        store_pair(out2, r, width, c, x[c] * rs * w[c]);
}

// Softmax over 512-wide rows, f32 in -> split-pair out IN-PLACE (same bytes).
__global__ __launch_bounds__(256) void softmax_pair_k(float* __restrict__ S,
                                                      unsigned short* __restrict__ P2)
{
    long long r = blockIdx.x;
    float* x = S + r * 512;
    unsigned short* p = P2 + r * 1024;
    int t = threadIdx.x;
    float v0 = x[t], v1 = x[t + 256];
    float mx = block_max256(fmaxf(v0, v1));
    v0 = expf(v0 - mx); v1 = expf(v1 - mx);
    float sum = block_sum256(v0 + v1);
    float inv = 1.f / sum;
    v0 *= inv; v1 *= inv;
    __syncthreads();
    unsigned short h0 = bf16_rne(v0);
    p[t] = h0;       p[512 + t] = bf16_rne(v0 - bf16_tof(h0));
    unsigned short h1 = bf16_rne(v1);
    p[t + 256] = h1; p[512 + t + 256] = bf16_rne(v1 - bf16_tof(h1));
}

// Causal grouped conv with LDS-tile transpose: writes seq-major pairs XC2
// AND chan-major pairs XCT2, both coalesced.
__global__ __launch_bounds__(256) void conv_k(
    const float* __restrict__ XS, const float* __restrict__ W,
    unsigned short* __restrict__ XC2, unsigned short* __restrict__ XCT2)
{
    __shared__ float tile[64][65];
    const int o0  = blockIdx.x * 64;
    const int tt0 = blockIdx.y * 64;
    const int b   = blockIdx.z;
    const int t   = threadIdx.x;

    const int o  = o0 + (t & 63);
    const int g2 = (o >> 1) << 1;
    const float* Wo = W + o * 8;
    float w0 = Wo[0], w1 = Wo[1], w2 = Wo[2], w3 = Wo[3];
    float w4 = Wo[4], w5 = Wo[5], w6 = Wo[6], w7 = Wo[7];
    #pragma unroll
    for (int i = 0; i < 16; ++i) {
        int sl = (t >> 6) + 4 * i;
        int tt = tt0 + sl;
        const float* xb = XS + ((long long)(b * 512 + tt)) * 2048 + g2;
        float acc = w3 * xb[0] + w7 * xb[1];
        if (tt >= 1) acc += w2 * xb[-2048] + w6 * xb[-2047];
        if (tt >= 2) acc += w1 * xb[-4096] + w5 * xb[-4095];
        if (tt >= 3) acc += w0 * xb[-6144] + w4 * xb[-6143];
        tile[sl][t & 63] = acc;
    }
    __syncthreads();
    #pragma unroll
    for (int i = 0; i < 16; ++i) {
        int idx = t + 256 * i;
        int sl = idx >> 6, ol = idx & 63;
        float v = tile[sl][ol];
        unsigned short hi = bf16_rne(v);
        unsigned short lo = bf16_rne(v - bf16_tof(hi));
        long long row = (long long)(b * 512 + tt0 + sl);
        XC2[row * 4096 + o0 + ol] = hi;
        XC2[row * 4096 + 2048 + o0 + ol] = lo;
    }
    #pragma unroll
    for (int i = 0; i < 16; ++i) {
        int idx = t + 256 * i;
        int cl = idx >> 6, s = idx & 63;
        float v = tile[s][cl];
        unsigned short hi = bf16_rne(v);
        unsigned short lo = bf16_rne(v - bf16_tof(hi));
        long long tb = (long long)b * 2097152 + (long long)(o0 + cl) * 1024 + tt0 + s;
        XCT2[tb] = hi;
        XCT2[tb + 512] = lo;
    }
}

__global__ __launch_bounds__(256) void dt_k(
    const float* __restrict__ dtBC, const float* __restrict__ dt_bias, float* __restrict__ DT)
{
    int idx = blockIdx.x * 256 + threadIdx.x;
    int r = idx >> 4, h = idx & 15;
    float xv = dtBC[r * 144 + h] + dt_bias[h];
    DT[idx] = (xv > 20.f) ? xv : log1pf(expf(xv));
}

__global__ __launch_bounds__(64) void cuma_k(
    const float* __restrict__ DT, const float* __restrict__ A_log, float* __restrict__ CUMA)
{
    int h = blockIdx.x, b = blockIdx.y;
    int ln = threadIdx.x;
    float Ah = -expf(A_log[h]);
    float v[8];
    float run = 0.f;
    #pragma unroll
    for (int i = 0; i < 8; ++i) {
        run += Ah * DT[((b * 512) + (ln * 8 + i)) * 16 + h];
        v[i] = run;
    }
    float tot = run;
    float sc = tot;
    #pragma unroll
    for (int o = 1; o <= 32; o <<= 1) {
        float u = __shfl_up(sc, o, 64);
        if (ln >= o) sc += u;
    }
    float excl = sc - tot;
    #pragma unroll
    for (int i = 0; i < 8; ++i)
        CUMA[(b * 16 + h) * 512 + ln * 8 + i] = excl + v[i];
}

// hc = LayerNorm64(G1) -> {-1,+1} as split pairs (lo = 0)
__global__ __launch_bounds__(64) void hc_quant_k(
    const float* __restrict__ G1, const float* __restrict__ w,
    const float* __restrict__ b, unsigned short* __restrict__ HCQ2)
{
    int r = blockIdx.x, ln = threadIdx.x;
    float v = G1[r * 64 + ln];
    float s = v;
    #pragma unroll
    for (int o = 32; o > 0; o >>= 1) s += __shfl_xor(s, o, 64);
    float m = s * (1.f / 64.f);
    float d = v - m;
    float vs = d * d;
    #pragma unroll
    for (int o = 32; o > 0; o >>= 1) vs += __shfl_xor(vs, o, 64);
    vs *= (1.f / 64.f);
    float hc = d * (1.f / sqrtf(vs + 1e-5f)) * w[ln] + b[ln];
    HCQ2[r * 128 + ln] = (hc > 0.f) ? 0x3F80 : 0xBF80;
    HCQ2[r * 128 + 64 + ln] = 0;
}

__global__ __launch_bounds__(256) void dxm_k(
    const float* __restrict__ mtok, const float* __restrict__ e2d, float* __restrict__ dxm)
{
    int c = blockIdx.x * 256 + threadIdx.x;
    float acc = 0.f;
    #pragma unroll
    for (int j = 0; j < 64; ++j) acc = fmaf(mtok[j], e2d[c * 64 + j], acc);
    dxm[c] = acc;
}

__global__ __launch_bounds__(256) void projm_k(
    const float* __restrict__ lnm,
    const float* __restrict__ bWq, const float* __restrict__ bWk, const float* __restrict__ bWv,
    float* __restrict__ qm, float* __restrict__ km, float* __restrict__ vm)
{
    int idx = blockIdx.x * 256 + threadIdx.x;
    int sel = idx >> 10, c = idx & 1023;
    const float* W = (sel == 0) ? bWq : (sel == 1) ? bWk : bWv;
    float* O = (sel == 0) ? qm : (sel == 1) ? km : vm;
    const float* wr = W + (long long)c * 1024;
    float acc = 0.f;
    for (int j = 0; j < 1024; j += 4) {
        float4 a = *(const float4*)(lnm + j);
        float4 w4 = *(const float4*)(wr + j);
        acc = fmaf(a.x, w4.x, fmaf(a.y, w4.y, fmaf(a.z, w4.z, fmaf(a.w, w4.w, acc))));
    }
    O[c] = acc;
}

// Collapsed decoder attention: 1 query/(b,h); keys = 512 visible + mask key x512.
__global__ __launch_bounds__(256) void dec_attn_k(
    const float* __restrict__ Kv, const float* __restrict__ Vv,
    const float* __restrict__ qm, const float* __restrict__ km,
    const float* __restrict__ vm, float* __restrict__ OBm)
{
    int h = blockIdx.x, b = blockIdx.y;
    int t = threadIdx.x;
    __shared__ __align__(16) float qs[256];
    __shared__ __align__(16) float ps[512];
    qs[t] = qm[h * 256 + t];
    __syncthreads();
    float s[2];
    #pragma unroll
    for (int i = 0; i < 2; ++i) {
        int r = t + i * 256;
        const float* kr = Kv + ((long long)(b * 512 + r)) * 1024 + h * 256;
        float acc = 0.f;
        for (int c = 0; c < 256; c += 4) {
            float4 k4 = *(const float4*)(kr + c);
            float4 q4 = *(const float4*)(qs + c);
            acc = fmaf(k4.x, q4.x, fmaf(k4.y, q4.y, fmaf(k4.z, q4.z, fmaf(k4.w, q4.w, acc))));
        }
        s[i] = acc * (1.f / 16.f);
    }
    float accm = 0.f;
    for (int c = 0; c < 256; c += 4) {
        float4 k4 = *(const float4*)(km + h * 256 + c);
        float4 q4 = *(const float4*)(qs + c);
        accm = fmaf(k4.x, q4.x, fmaf(k4.y, q4.y, fmaf(k4.z, q4.z, fmaf(k4.w, q4.w, accm))));
    }
    float smv = accm * (1.f / 16.f);
    float mx = block_max256(fmaxf(fmaxf(s[0], s[1]), smv));
    float p0 = expf(s[0] - mx), p1 = expf(s[1] - mx);
    ps[t] = p0; ps[t + 256] = p1;
    float pm = expf(smv - mx) * 512.f;
    float sum = block_sum256(p0 + p1) + pm;
    float inv = 1.f / sum;
    __syncthreads();
    float o = pm * vm[h * 256 + t];
    const float* vcol = Vv + (long long)b * 512 * 1024 + h * 256 + t;
    for (int j = 0; j < 512; ++j)
        o = fmaf(ps[j], vcol[(long long)j * 1024], o);
    OBm[b * 1024 + h * 256 + t] = o * inv;
}

__global__ __launch_bounds__(256) void ydm_k(
    const float* __restrict__ OBm, const float* __restrict__ bWo,
    const float* __restrict__ bWo_b, const float* __restrict__ dxm,
    float* __restrict__ ydm)
{
    int idx = blockIdx.x * 256 + threadIdx.x;
    int b = idx >> 10, c = idx & 1023;
    const float* ar = OBm + b * 1024;
    const float* wr = bWo + (long long)c * 1024;
    float acc = 0.f;
    for (int j = 0; j < 1024; j += 4) {
        float4 a = *(const float4*)(ar + j);
        float4 w4 = *(const float4*)(wr + j);
        acc = fmaf(a.x, w4.x, fmaf(a.y, w4.y, fmaf(a.z, w4.z, fmaf(a.w, w4.w, acc))));
    }
    ydm[idx] = acc + bWo_b[c] + dxm[c];
}

__global__ __launch_bounds__(256) void outm_k(
    const float* __restrict__ ydm, const float* __restrict__ dout_W,
    const float* __restrict__ dout_b, float* __restrict__ outm)
{
    int idx = blockIdx.x * 256 + threadIdx.x;
    int b = idx >> 11, c = idx & 2047;
    const float* ar = ydm + b * 1024;
    const float* wr = dout_W + (long long)c * 1024;
    float acc = 0.f;
    for (int j = 0; j < 1024; j += 4) {
        float4 a = *(const float4*)(ar + j);
        float4 w4 = *(const float4*)(wr + j);
        acc = fmaf(a.x, w4.x, fmaf(a.y, w4.y, fmaf(a.z, w4.z, fmaf(a.w, w4.w, acc))));
    }
    outm[idx] = acc + dout_b[c];
}

__global__ __launch_bounds__(256) void bcast_k(
    const float* __restrict__ outm, float* __restrict__ out)
{
    int idx = blockIdx.x * 256 + threadIdx.x;
    int c4 = idx & 511;
    int b = idx >> 18;
    ((float4*)out)[idx] = ((const float4*)outm)[b * 512 + c4];
}

// ---------------------------------------------------------------------------
// Host-side launcher
// ---------------------------------------------------------------------------
static inline void pairify(hipStream_t s, const float* src, unsigned short* dst,
                           int k_log2, long long n)
{
    pairify_k<<<(int)((n + 255) / 256), 256, 0, s>>>(src, dst, k_log2, n);
}

extern "C" void kernel_launch(void* const* d_in, const int* in_sizes, int n_in,
                              void* d_out, int out_size, void* d_ws, size_t ws_size,
                              hipStream_t stream)
{
    const float* x       = (const float*)d_in[0];
    const float* ln0_w   = (const float*)d_in[1];
    const float* ln0_b   = (const float*)d_in[2];
    const float* in_W    = (const float*)d_in[3];
    const float* rms_w   = (const float*)d_in[4];
    const float* exp_W   = (const float*)d_in[5];
    const float* conv_W  = (const float*)d_in[6];
    const float* xproj_W = (const float*)d_in[7];
    const float* dt_bias = (const float*)d_in[8];
    const float* A_log   = (const float*)d_in[9];
    const float* Dv      = (const float*)d_in[10];
    const float* outp_W  = (const float*)d_in[11];
    const float* outp_b  = (const float*)d_in[12];
    const float* n1_w    = (const float*)d_in[13];
    const float* n1_b    = (const float*)d_in[14];
    const float* aWq     = (const float*)d_in[15];
    const float* aWk     = (const float*)d_in[16];
    const float* aWv     = (const float*)d_in[17];
    const float* aWo     = (const float*)d_in[18];
    const float* aWo_b   = (const float*)d_in[19];
    const float* h_W     = (const float*)d_in[20];
    const float* h_b     = (const float*)d_in[21];
    const float* h_lnw   = (const float*)d_in[22];
    const float* h_lnb   = (const float*)d_in[23];
    const float* mtok    = (const float*)d_in[24];
    const float* e2d_W   = (const float*)d_in[25];
    const float* dn_w    = (const float*)d_in[26];
    const float* dn_b    = (const float*)d_in[27];
    const float* bWq     = (const float*)d_in[28];
    const float* bWk     = (const float*)d_in[29];
    const float* bWv     = (const float*)d_in[30];
    const float* bWo     = (const float*)d_in[31];
    const float* bWo_b   = (const float*)d_in[32];
    const float* dout_W  = (const float*)d_in[33];
    const float* dout_b  = (const float*)d_in[34];

    float* ws  = (float*)d_ws;
    float* out = (float*)d_out;

    float* S1 = ws;
    float* S2 = ws + 8388608;
    float* S3 = ws + 16777216;
    float* S4 = ws + 25165824;
    float* S5 = ws + 33554432;
    float* S6 = ws + 37748736;
    float* S7 = ws + 41943040;
    float* S8 = ws + 46137344;
    float* S9 = ws + 50331648;
    float* SP = ws + 54525952;

    unsigned short* XV2     = (unsigned short*)S1;
    unsigned short* exp_W2  = (unsigned short*)S1;
    unsigned short* XCT2    = (unsigned short*)S1;
    float*          SA      = S1;
    unsigned short* P2      = (unsigned short*)S1;
    float*          Kv      = S1;
    float*          Vv      = S1 + 4194304;
    unsigned short* in_W2   = (unsigned short*)S2;
    float*          XS      = S2;
    unsigned short* YS2     = (unsigned short*)S2;
    unsigned short* XC2     = (unsigned short*)S3;
    unsigned short* outp_W2 = (unsigned short*)S3;
    float*          DXV     = S3;
    unsigned short* LNDXV2  = (unsigned short*)(S3 + 4194304);
    float*          Z       = S4;
    unsigned short* aWq2    = (unsigned short*)S4;
    unsigned short* aWk2    = (unsigned short*)S4 + 2097152;
    unsigned short* aWv2    = (unsigned short*)S4 + 4194304;
    unsigned short* aWo2    = (unsigned short*)S4 + 6291456;
    unsigned short* bWk2    = (unsigned short*)S4 + 8388608;
    unsigned short* bWv2    = (unsigned short*)S4 + 10485760;
    float*          T       = S5;
    unsigned short* QA2     = (unsigned short*)S5;
    unsigned short* Y22     = (unsigned short*)S5;
    unsigned short* HR2     = (unsigned short*)S6;
    float*          Y1      = S6;
    unsigned short* LNY2    = (unsigned short*)S7;
    unsigned short* OA2     = (unsigned short*)S7;
    unsigned short* KA2     = (unsigned short*)S8;
    unsigned short* VT2     = (unsigned short*)S9;

    float* dtBC = SP;
    float* DT   = SP + 589824;
    float* CUMA = SP + 655360;
    float* G    = SP + 720896;
    unsigned short* xprojW2 = (unsigned short*)(SP + 2818048);
    unsigned short* hW2     = (unsigned short*)(SP + 3112960);
    unsigned short* e2dW2   = (unsigned short*)(SP + 3178496);
    float* G1   = SP + 720896;
    unsigned short* HCQ2 = (unsigned short*)(SP + 983040);
    float* dxm  = SP + 1245184;
    float* lnm  = SP + 1246208;
    float* qm   = SP + 1247232;
    float* km   = SP + 1248256;
    float* vm   = SP + 1249280;
    float* OBm  = SP + 1250304;
    float* ydm  = SP + 1258496;
    float* outm = SP + 1266688;

    const long long LL0 = 0;
    #define G3D(OUTM, GX, GY, GZ, ...) \
        gemm_bf16_k<3, OUTM, true><<<dim3(GX, GY, GZ), 256, 0, stream>>>(__VA_ARGS__)
    #define G3R(OUTM, GX, GY, GZ, ...) \
        gemm_bf16_k<3, OUTM, false><<<dim3(GX, GY, GZ), 256, 0, stream>>>(__VA_ARGS__)
    #define G1D(OUTM, GX, GY, GZ, ...) \
        gemm_bf16_k<1, OUTM, true><<<dim3(GX, GY, GZ), 256, 0, stream>>>(__VA_ARGS__)

    // ---- weight prep (phase A) ----
    pairify(stream, in_W,    in_W2,   11, 1024LL * 2048);
    pairify(stream, xproj_W, xprojW2, 11, 144LL * 2048);
    pairify(stream, h_W,     hW2,     10, 64LL * 1024);
    pairify(stream, e2d_W,   e2dW2,    6, 1024LL * 64);

    // ---- encoder trunk ----
    layernorm_pair_k<<<4096, 256, 0, stream>>>(x, XV2, ln0_w, ln0_b, 2048, 512,
                                               (long long)1024 * 2048);
    G3D(0, 8, 32, 1, 4096, 1024, 2048, XV2, 4096, 2048, LL0, LL0,
        in_W2, 4096, 2048, LL0, LL0, T, 1024, 0, LL0, LL0,
        nullptr, nullptr, 0, 1.f, 1);
    pairify(stream, exp_W, exp_W2, 10, 4096LL * 1024);   // S1 (XV2 dead)
    rmsnorm_pair_k<<<4096, 256, 0, stream>>>(T, HR2, rms_w, 1024);
    G3D(0, 16, 32, 1, 4096, 2048, 1024, HR2, 2048, 1024, LL0, LL0,
        exp_W2, 2048, 1024, LL0, LL0, XS, 2048, 0, LL0, LL0,
        nullptr, nullptr, 0, 1.f, 1);
    G3D(0, 16, 32, 1, 4096, 2048, 1024, HR2, 2048, 1024, LL0, LL0,
        exp_W2 + 2048LL * 2048, 2048, 1024, LL0, LL0, Z, 2048, 0, LL0, LL0,
        nullptr, nullptr, 0, 1.f, 1);
    conv_k<<<dim3(32, 8, 8), 256, 0, stream>>>(XS, conv_W, XC2, XCT2);
    G3R(0, 2, 32, 1, 4096, 144, 2048, XC2, 4096, 2048, LL0, LL0,
        xprojW2, 4096, 2048, LL0, LL0, dtBC, 144, 0, LL0, LL0,
        nullptr, nullptr, 0, 1.f, 1);
    dt_k<<<256, 256, 0, stream>>>(dtBC, dt_bias, DT);
    cuma_k<<<dim3(16, 8), 64, 0, stream>>>(DT, A_log, CUMA);
    gemm_f32_k<<<dim3(4, 4, 8), 256, 0, stream>>>(
        512, 512, 64, dtBC + 80, 144, (long long)512 * 144,
        dtBC + 16, 144, (long long)512 * 144, G, 512, (long long)512 * 512);
    ssd_mfma_k<<<dim3(4, 16, 8), 256, 0, stream>>>(G, CUMA, DT, XCT2, Z, Dv, YS2);

    // ---- weight prep (phase B: S3/S4 now dead) ----
    pairify(stream, outp_W, outp_W2, 11, 1024LL * 2048);
    pairify(stream, aWq, aWq2, 10, 1024LL * 1024);
    pairify(stream, aWk, aWk2, 10, 1024LL * 1024);
    pairify(stream, aWv, aWv2, 10, 1024LL * 1024);
    pairify(stream, aWo, aWo2, 10, 1024LL * 1024);
    pairify(stream, bWk, bWk2, 10, 1024LL * 1024);
    pairify(stream, bWv, bWv2, 10, 1024LL * 1024);

    G3D(0, 8, 32, 1, 4096, 1024, 2048, YS2, 4096, 2048, LL0, LL0,
        outp_W2, 4096, 2048, LL0, LL0, Y1, 1024, 0, LL0, LL0,
        outp_b, T, 1024, 1.f, 1);

    // ---- encoder attention (all MFMA) ----
    layernorm_pair_k<<<4096, 256, 0, stream>>>(Y1, LNY2, n1_w, n1_b, 1024, 4096, LL0);
    G3D(1, 8, 32, 1, 4096, 1024, 1024, LNY2, 2048, 1024, LL0, LL0,
        aWq2, 2048, 1024, LL0, LL0, QA2, 2048, 1024, LL0, LL0,
        nullptr, nullptr, 0, 1.f, 1);
    G3D(1, 8, 32, 1, 4096, 1024, 1024, LNY2, 2048, 1024, LL0, LL0,
        aWk2, 2048, 1024, LL0, LL0, KA2, 2048, 1024, LL0, LL0,
        nullptr, nullptr, 0, 1.f, 1);
    G3D(2, 8, 32, 1, 4096, 1024, 1024, LNY2, 2048, 1024, LL0, LL0,
        aWv2, 2048, 1024, LL0, LL0, VT2, 1024, 512, (long long)1024 * 1024, LL0,
        nullptr, nullptr, 0, 1.f, 1);
    G3D(0, 4, 4, 32, 512, 512, 256,
        QA2, 2048, 1024, (long long)512 * 2048, 256,
        KA2, 2048, 1024, (long long)512 * 2048, 256,
        SA, 512, 0, (long long)4 * 512 * 512, (long long)512 * 512,
        nullptr, nullptr, 0, 1.f / 16.f, 4);
    softmax_pair_k<<<16384, 256, 0, stream>>>(SA, P2);
    G3D(1, 2, 4, 32, 512, 256, 512,
        P2, 1024, 512, (long long)4 * 512 * 1024, (long long)512 * 1024,
        VT2, 1024, 512, (long long)1024 * 1024, (long long)256 * 1024,
        OA2, 2048, 1024, (long long)512 * 2048, 256,
        nullptr, nullptr, 0, 1.f, 4);
    G3D(1, 8, 32, 1, 4096, 1024, 1024, OA2, 2048, 1024, LL0, LL0,
        aWo2, 2048, 1024, LL0, LL0, Y22, 2048, 1024, LL0, LL0,
        aWo_b, Y1, 1024, 1.f, 1);

    // ---- quantize ----
    G3R(0, 1, 32, 1, 4096, 64, 1024, Y22, 2048, 1024, LL0, LL0,
        hW2, 2048, 1024, LL0, LL0, G1, 64, 0, LL0, LL0,
        h_b, nullptr, 0, 1.f, 1);
    hc_quant_k<<<4096, 64, 0, stream>>>(G1, h_lnw, h_lnb, HCQ2);

    // ---- decoder (collapsed masked rows) ----
    G3D(0, 8, 32, 1, 4096, 1024, 64, HCQ2, 128, 64, LL0, LL0,
        e2dW2, 128, 64, LL0, LL0, DXV, 1024, 0, LL0, LL0,
        nullptr, nullptr, 0, 1.f, 1);
    dxm_k<<<4, 256, 0, stream>>>(mtok, e2d_W, dxm);
    layernorm_k<<<1, 256, 0, stream>>>(dxm, lnm, dn_w, dn_b, 1024, 1, LL0);
    layernorm_pair_k<<<4096, 256, 0, stream>>>(DXV, LNDXV2, dn_w, dn_b, 1024, 4096, LL0);
    projm_k<<<12, 256, 0, stream>>>(lnm, bWq, bWk, bWv, qm, km, vm);
    G1D(0, 8, 32, 1, 4096, 1024, 1024, LNDXV2, 2048, 1024, LL0, LL0,
        bWk2, 2048, 1024, LL0, LL0, Kv, 1024, 0, LL0, LL0,
        nullptr, nullptr, 0, 1.f, 1);
    G1D(0, 8, 32, 1, 4096, 1024, 1024, LNDXV2, 2048, 1024, LL0, LL0,
        bWv2, 2048, 1024, LL0, LL0, Vv, 1024, 0, LL0, LL0,
        nullptr, nullptr, 0, 1.f, 1);
    dec_attn_k<<<dim3(4, 8), 256, 0, stream>>>(Kv, Vv, qm, km, vm, OBm);
    ydm_k<<<32, 256, 0, stream>>>(OBm, bWo, bWo_b, dxm, ydm);
    outm_k<<<64, 256, 0, stream>>>(ydm, dout_W, dout_b, outm);
    bcast_k<<<8192, 256, 0, stream>>>(outm, out);
    #undef G3D
    #undef G3R
    #undef G1D
}

// Round 3
// 1242.454 us; speedup vs baseline: 1.1320x; 1.0428x over previous
//
#include <hip/hip_runtime.h>

// ---------------------------------------------------------------------------
// B=8, N=1024, CIN=2048, HID=1024, HC=64, LV=512, NH_SSD=16, HD=128, DS=64.
// Encoder rows = 4096. Decoder collapsed to 1 row/batch. All large GEMMs:
// split-bf16 MFMA (x3 passes = f32-grade pre-quantizer; x1 post-quantizer),
// staged via __builtin_amdgcn_global_load_lds width=16 (DIRECT path).
// DIRECT GEMM: triple-buffered LDS + counted vmcnt + raw s_barrier pipeline,
// source-swizzled staging (conflict-free b128). SSD intra-chunk v4: X staged
// once per block through the same pipeline (was: per-wave redundant global
// frag loads + 64-VGPR frag pressure -> latency-bound at 102us).
// ---------------------------------------------------------------------------

typedef short bf16x8 __attribute__((ext_vector_type(8)));
typedef float f32x4 __attribute__((ext_vector_type(4)));

__device__ __forceinline__ unsigned short bf16_rne(float f) {
    unsigned u = __float_as_uint(f);
    unsigned r = u + 0x7FFFu + ((u >> 16) & 1u);
    return (unsigned short)(r >> 16);
}
__device__ __forceinline__ float bf16_tof(unsigned short h) {
    return __uint_as_float(((unsigned)h) << 16);
}
__device__ __forceinline__ void store_pair(unsigned short* dst, long long row,
                                           int width, int c, float v) {
    unsigned short hi = bf16_rne(v);
    unsigned short lo = bf16_rne(v - bf16_tof(hi));
    long long base = row * (2LL * width);
    dst[base + c] = hi;
    dst[base + width + c] = lo;
}
// Async global->LDS, 16B per lane. LDS dest = wave-uniform base + lane*16.
__device__ __forceinline__ void async_ld16(const unsigned short* g, unsigned short* l) {
    __builtin_amdgcn_global_load_lds(
        (const __attribute__((address_space(1))) unsigned int*)g,
        (__attribute__((address_space(3))) unsigned int*)l, 16, 0, 0);
}

// ---------------------------------------------------------------------------
// Reduction helpers (blockDim 256)
// ---------------------------------------------------------------------------
__device__ __forceinline__ float block_sum256(float v) {
    #pragma unroll
    for (int o = 32; o > 0; o >>= 1) v += __shfl_xor(v, o, 64);
    __shared__ float sm[4];
    int w = threadIdx.x >> 6;
    __syncthreads();
    if ((threadIdx.x & 63) == 0) sm[w] = v;
    __syncthreads();
    return sm[0] + sm[1] + sm[2] + sm[3];
}
__device__ __forceinline__ float block_max256(float v) {
    #pragma unroll
    for (int o = 32; o > 0; o >>= 1) v = fmaxf(v, __shfl_xor(v, o, 64));
    __shared__ float smx[4];
    int w = threadIdx.x >> 6;
    __syncthreads();
    if ((threadIdx.x & 63) == 0) smx[w] = v;
    __syncthreads();
    return fmaxf(fmaxf(smx[0], smx[1]), fmaxf(smx[2], smx[3]));
}

// ---------------------------------------------------------------------------
// Split-bf16 MFMA GEMM. C[m,n] = alpha * sum_k A[m,k]*B[n,k] (+bias)(+res)
// NPASS=3: hh+lh+hl (f32-grade). NPASS=1: hh only.
// OUT=0: f32 C. OUT=1: split-pair C. OUT=2: transposed split-pair per
// 512-row batch.
// DIRECT=true: global_load_lds staging, triple-buffered, counted-vmcnt
//   pipeline (depth-2 prefetch), source-swizzled for conflict-free b128:
//   LDS slot (row, q) holds the global 16B-chunk q ^ t(row),
//   t(r) = (r&3)^((r>>2)&3)  -> max 2-way bank aliasing (free).
//   Requires full tiles (N covered by grid) and K % 32 == 0.
// DIRECT=false: guarded reg staging (ragged N ok), original 2-barrier loop.
// ---------------------------------------------------------------------------
template<int NPASS, int OUT, bool DIRECT>
__global__ __launch_bounds__(256, DIRECT ? 1 : 2) void gemm_bf16_k(
    int M, int N, int K,
    const unsigned short* __restrict__ A2, int lda2, int aLo, long long sAb, long long sAh,
    const unsigned short* __restrict__ B2, int ldb2, int bLo, long long sBb, long long sBh,
    void* __restrict__ Cv, int ldc, int cLo, long long sCb, long long sCh,
    const float* __restrict__ bias, const float* __restrict__ res, int ldr,
    float alpha, int nh)
{
    constexpr int ST   = DIRECT ? 32 : 40;
    constexpr int NARR = (NPASS == 3) ? 4 : 2;
    constexpr int NB   = DIRECT ? 3 : 1;
    constexpr int O_AH = 0;
    constexpr int O_BH = 128 * ST;
    constexpr int O_AL = 2 * 128 * ST;
    constexpr int O_BL = 3 * 128 * ST;
    constexpr int BUFSZ = 128 * ST * NARR;
    __shared__ unsigned short SM[NB * BUFSZ];

    const int z  = blockIdx.z;
    const int bb = z / nh, hh = z - bb * nh;
    A2 += bb * sAb + hh * sAh;
    B2 += bb * sBb + hh * sBh;

    const int t    = threadIdx.x;
    const int m0   = blockIdx.y * 128;
    const int n0   = blockIdx.x * 128;
    const int lane = t & 63, wave = t >> 6;
    const int wm   = (wave >> 1) * 64, wn = (wave & 1) * 64;
    const int lr   = lane & 15, quad = lane >> 4;

    f32x4 acc[4][4];
    #pragma unroll
    for (int i = 0; i < 4; ++i)
        #pragma unroll
        for (int j = 0; j < 4; ++j) acc[i][j] = (f32x4){0.f, 0.f, 0.f, 0.f};

    if constexpr (DIRECT) {
        // ---- pipelined path ----
        const int drow  = lane >> 2;                       // row in 16-chunk
        // swizzled global 16B-chunk for this lane's LDS slot (lane&3):
        const int dcswz = (((lane & 3) ^ ((lane >> 2) & 3) ^ ((lane >> 4) & 3)) << 3);
        // frag-read slot XOR (per-lane constant):
        const int rsw   = ((quad ^ ((lr & 3) ^ (lr >> 2))) << 3);

        auto stage = [&](int k0, int buf) {
            unsigned short* bp = &SM[buf * BUFSZ];
            #pragma unroll
            for (int j = 0; j < 2; ++j) {
                int rr = wave * 32 + j * 16;               // chunk base row
                int gr = rr + drow;
                const unsigned short* gA = A2 + (long long)(m0 + gr) * lda2 + k0 + dcswz;
                async_ld16(gA, &bp[O_AH + rr * 32]);
                if (NPASS == 3) async_ld16(gA + aLo, &bp[O_AL + rr * 32]);
                const unsigned short* gB = B2 + (long long)(n0 + gr) * ldb2 + k0 + dcswz;
                async_ld16(gB, &bp[O_BH + rr * 32]);
                if (NPASS == 3) async_ld16(gB + bLo, &bp[O_BL + rr * 32]);
            }
        };

        const int nt = K >> 5;
        stage(0, 0);
        if (nt > 1) stage(32, 1);
        int cur = 0, pre = 2;
        for (int it = 0; it < nt; ++it) {
            // wait for tile it's loads (keep next tile's in flight), all waves
            if (it + 1 < nt) {
                if (NPASS == 3) asm volatile("s_waitcnt vmcnt(8)" ::: "memory");
                else            asm volatile("s_waitcnt vmcnt(4)" ::: "memory");
            } else {
                asm volatile("s_waitcnt vmcnt(0)" ::: "memory");
            }
            __builtin_amdgcn_s_barrier();
            // prefetch tile it+2 into the buffer consumed at iter it-1
            // (safe: its ds_reads were lgkm-consumed before this barrier)
            if (it + 2 < nt) stage((it + 2) << 5, pre);

            const unsigned short* bp = &SM[cur * BUFSZ];
            bf16x8 ah[4], bh[4], al[4], bl[4];
            #pragma unroll
            for (int i = 0; i < 4; ++i) {
                int ra = O_AH + (wm + i * 16 + lr) * 32 + rsw;
                int rb = O_BH + (wn + i * 16 + lr) * 32 + rsw;
                ah[i] = *(const bf16x8*)&bp[ra];
                bh[i] = *(const bf16x8*)&bp[rb];
                if (NPASS == 3) {
                    al[i] = *(const bf16x8*)&bp[ra + (O_AL - O_AH)];
                    bl[i] = *(const bf16x8*)&bp[rb + (O_BL - O_BH)];
                }
            }
            #pragma unroll
            for (int mi = 0; mi < 4; ++mi)
                #pragma unroll
                for (int ni = 0; ni < 4; ++ni) {
                    acc[mi][ni] = __builtin_amdgcn_mfma_f32_16x16x32_bf16(
                        ah[mi], bh[ni], acc[mi][ni], 0, 0, 0);
                    if (NPASS == 3) {
                        acc[mi][ni] = __builtin_amdgcn_mfma_f32_16x16x32_bf16(
                            al[mi], bh[ni], acc[mi][ni], 0, 0, 0);
                        acc[mi][ni] = __builtin_amdgcn_mfma_f32_16x16x32_bf16(
                            ah[mi], bl[ni], acc[mi][ni], 0, 0, 0);
                    }
                }
            cur = (cur == 2) ? 0 : cur + 1;
            pre = (pre == 2) ? 0 : pre + 1;
        }
    } else {
        // ---- ragged reg-staging path (original structure) ----
        const int srow = t >> 2;          // row 0..63 (+64)
        const int scol = (t & 3) * 8;

        for (int k0 = 0; k0 < K; k0 += 32) {
            __syncthreads();
            #pragma unroll
            for (int half = 0; half < 2; ++half) {
                int r = srow + half * 64;
                const unsigned short* pA = A2 + (long long)(m0 + r) * lda2 + k0 + scol;
                *(uint4*)&SM[O_AH + r * ST + scol] = *(const uint4*)pA;
                if (NPASS == 3)
                    *(uint4*)&SM[O_AL + r * ST + scol] = *(const uint4*)(pA + aLo);
                int rb = n0 + r;
                uint4 vh = {0u, 0u, 0u, 0u}, vl = {0u, 0u, 0u, 0u};
                if (rb < N) {
                    const unsigned short* pB = B2 + (long long)rb * ldb2 + k0 + scol;
                    vh = *(const uint4*)pB;
                    if (NPASS == 3) vl = *(const uint4*)(pB + bLo);
                }
                *(uint4*)&SM[O_BH + r * ST + scol] = vh;
                if (NPASS == 3) *(uint4*)&SM[O_BL + r * ST + scol] = vl;
            }
            __syncthreads();

            bf16x8 ah[4], bh[4], al[4], bl[4];
            #pragma unroll
            for (int i = 0; i < 4; ++i) {
                int ra = (wm + i * 16 + lr) * ST + quad * 8;
                int rb = (wn + i * 16 + lr) * ST + quad * 8;
                ah[i] = *(const bf16x8*)&SM[O_AH + ra];
                bh[i] = *(const bf16x8*)&SM[O_BH + rb];
                if (NPASS == 3) {
                    al[i] = *(const bf16x8*)&SM[O_AL + ra];
                    bl[i] = *(const bf16x8*)&SM[O_BL + rb];
                }
            }
            #pragma unroll
            for (int mi = 0; mi < 4; ++mi)
                #pragma unroll
                for (int ni = 0; ni < 4; ++ni) {
                    acc[mi][ni] = __builtin_amdgcn_mfma_f32_16x16x32_bf16(
                        ah[mi], bh[ni], acc[mi][ni], 0, 0, 0);
                    if (NPASS == 3) {
                        acc[mi][ni] = __builtin_amdgcn_mfma_f32_16x16x32_bf16(
                            al[mi], bh[ni], acc[mi][ni], 0, 0, 0);
                        acc[mi][ni] = __builtin_amdgcn_mfma_f32_16x16x32_bf16(
                            ah[mi], bl[ni], acc[mi][ni], 0, 0, 0);
                    }
                }
        }
    }

    // D layout: col = lane&15, row = quad*4 + r
    if (OUT == 0) {
        float* C = (float*)Cv + bb * sCb + hh * sCh;
        #pragma unroll
        for (int mi = 0; mi < 4; ++mi)
            #pragma unroll
            for (int ni = 0; ni < 4; ++ni) {
                int col = n0 + wn + ni * 16 + lr;
                if (col >= N) continue;
                float bv = bias ? bias[col] : 0.f;
                #pragma unroll
                for (int r = 0; r < 4; ++r) {
                    int row = m0 + wm + mi * 16 + quad * 4 + r;
                    float v = alpha * acc[mi][ni][r] + bv;
                    if (res) v += res[(long long)row * ldr + col];
                    C[(long long)row * ldc + col] = v;
                }
            }
    } else if (OUT == 1) {
        unsigned short* C = (unsigned short*)Cv + bb * sCb + hh * sCh;
        #pragma unroll
        for (int mi = 0; mi < 4; ++mi)
            #pragma unroll
            for (int ni = 0; ni < 4; ++ni) {
                int col = n0 + wn + ni * 16 + lr;
                if (col >= N) continue;
                float bv = bias ? bias[col] : 0.f;
                #pragma unroll
                for (int r = 0; r < 4; ++r) {
                    int row = m0 + wm + mi * 16 + quad * 4 + r;
                    float v = alpha * acc[mi][ni][r] + bv;
                    if (res) v += res[(long long)row * ldr + col];
                    unsigned short hi = bf16_rne(v);
                    unsigned short lo = bf16_rne(v - bf16_tof(hi));
                    long long p = (long long)row * ldc + col;
                    C[p] = hi;
                    C[p + cLo] = lo;
                }
            }
    } else {  // OUT == 2: transposed pairs per 512-row batch
        unsigned short* C = (unsigned short*)Cv;
        #pragma unroll
        for (int mi = 0; mi < 4; ++mi)
            #pragma unroll
            for (int ni = 0; ni < 4; ++ni) {
                int col = n0 + wn + ni * 16 + lr;
                if (col >= N) continue;
                int row0 = m0 + wm + mi * 16 + quad * 4;
                int b = row0 >> 9, seq0 = row0 & 511;
                ushort4 h4, l4;
                unsigned short* hp = (unsigned short*)&h4;
                unsigned short* lp = (unsigned short*)&l4;
                #pragma unroll
                for (int r = 0; r < 4; ++r) {
                    float v = acc[mi][ni][r];
                    unsigned short hi = bf16_rne(v);
                    hp[r] = hi;
                    lp[r] = bf16_rne(v - bf16_tof(hi));
                }
                long long p = b * sCb + (long long)col * ldc + seq0;
                *(ushort4*)&C[p] = h4;
                *(ushort4*)&C[p + cLo] = l4;
            }
    }
}

// ---------------------------------------------------------------------------
// Fused SSD intra-chunk MFMA kernel, v4.
// Per (b,h): Y[l,p] = sum_{s<=l} W[l,s]*XC[s,p];
// W = G*exp(cAl-cAs)*dt[s], with D-skip folded in: W[l,l] += D[h].
// v4 vs v3 (v3: 102us, MfmaUtil 5%, VALU 17%, VGPR 100 — latency-bound):
//  * v3 had every wave load the SAME X subtile from global (frag addresses
//    are lane-only -> 4x redundant VMEM, 16 instrs/wave/tile) and held
//    bh[8]+bl[8] = 64 VGPRs -> ~100 VGPR, serialized load batches.
//  * v4 stages X once per block into LDS via global_load_lds (16KB/tile,
//    4 calls/thread), triple-buffered, depth-2 prefetch, counted vmcnt(4)
//    + raw s_barrier — the exact pipeline proven in the DIRECT GEMM.
//    Same source-swizzle (slot ^ (r&3)^((r>>2)&3)) -> conflict-free b128.
//  * X frags read per-ni just-in-time from LDS: 8 live VGPRs, not 64.
//  * W-gen double-buffer + single barrier kept from v3 (race-free, 0 bank
//    conflicts). lgkmcnt(0) before each barrier covers the W ds_writes.
// grid (4 = row-tile pairs, 16 h, 8 b), block 256 (4 waves x 16l x 128p).
// LDS 68KB -> 2 blocks/CU.
// ---------------------------------------------------------------------------
__global__ __launch_bounds__(256, 2) void ssd_mfma_k(
    const float* __restrict__ G, const float* __restrict__ CUMA,
    const float* __restrict__ DT, const unsigned short* __restrict__ XCT2,
    const float* __restrict__ Z, const float* __restrict__ Dv,
    unsigned short* __restrict__ YS2)
{
    __shared__ unsigned short Xh[3][128 * 32];
    __shared__ unsigned short Xl[3][128 * 32];
    __shared__ unsigned short Wh[2][64 * 32];
    __shared__ unsigned short Wl[2][64 * 32];
    __shared__ float Cs[512];
    __shared__ float Ds[512];
    const int q = blockIdx.x;
    const int h = blockIdx.y, b = blockIdx.z;
    const int t = threadIdx.x;
    const int lane = t & 63, wave = t >> 6;
    const int lr = lane & 15, quad = lane >> 4;

    const float* cbase = CUMA + (b * 16 + h) * 512;
    const float* dtb = DT + (long long)b * 512 * 16 + h;
    for (int s = t; s < 512; s += 256) {
        Cs[s] = cbase[s];
        Ds[s] = dtb[(long long)s * 16];
    }
    const float Dh = Dv[h];

    const int wr = t >> 2;                        // W-gen row 0..63
    const int sw = t & 3;                         // logical 16B slot 0..3
    const int wbase = wr * 32 + ((sw ^ ((wr >> 1) & 3)) << 3);
    const int frow = wave * 16 + lr;              // W frag row 0..63
    const int fbase = frow * 32 + ((quad ^ ((frow >> 1) & 3)) << 3);
    // X staging (GEMM-identical geometry: 128 rows x 32 shorts):
    const int drow  = lane >> 2;                  // row within 16-row chunk
    const int dcswz = (((lane & 3) ^ ((lane >> 2) & 3) ^ ((lane >> 4) & 3)) << 3);
    const int xsw   = ((quad ^ ((lr & 3) ^ ((lr >> 2) & 3))) << 3);
    const unsigned short* XB = XCT2 + (long long)b * 2097152
                             + (long long)(h * 128) * 1024;
    __syncthreads();

    for (int ph = 0; ph < 2; ++ph) {
        const int mt = ph ? q : 7 - q;            // heavy row-tile first
        const int m0 = mt * 64;
        const int nt = (m0 >> 5) + 2;             // k-tiles = kend/32
        const int lglob = m0 + wr;
        const float cAl = Cs[lglob];
        const float* grow = G + ((long long)(b * 512 + lglob)) * 512;

        float pg[8], pc[8], pd[8];
        auto gen_load = [&](int k0g) {
            const int sb = k0g + sw * 8;
            float4 g0 = *(const float4*)(grow + sb);
            float4 g1 = *(const float4*)(grow + sb + 4);
            float4 c0 = *(const float4*)&Cs[sb];
            float4 c1 = *(const float4*)&Cs[sb + 4];
            float4 d0 = *(const float4*)&Ds[sb];
            float4 d1 = *(const float4*)&Ds[sb + 4];
            pg[0] = g0.x; pg[1] = g0.y; pg[2] = g0.z; pg[3] = g0.w;
            pg[4] = g1.x; pg[5] = g1.y; pg[6] = g1.z; pg[7] = g1.w;
            pc[0] = c0.x; pc[1] = c0.y; pc[2] = c0.z; pc[3] = c0.w;
            pc[4] = c1.x; pc[5] = c1.y; pc[6] = c1.z; pc[7] = c1.w;
            pd[0] = d0.x; pd[1] = d0.y; pd[2] = d0.z; pd[3] = d0.w;
            pd[4] = d1.x; pd[5] = d1.y; pd[6] = d1.z; pd[7] = d1.w;
        };
        auto gen_finish = [&](int k0g, int buf) {
            const int sb = k0g + sw * 8;
            const bool edge = (k0g + 32 > m0);    // tile touches causal edge
            unsigned short hv[8], lv[8];
            #pragma unroll
            for (int e = 0; e < 8; ++e) {
                float w = pg[e] * __expf(cAl - pc[e]) * pd[e];
                if (edge) {
                    int sg = sb + e;
                    w = (sg <= lglob) ? w : 0.f;  // select AFTER: kills inf/nan
                    if (sg == lglob) w += Dh;
                }
                unsigned short hi = bf16_rne(w);
                hv[e] = hi;
                lv[e] = bf16_rne(w - bf16_tof(hi));
            }
            *(uint4*)&Wh[buf][wbase] = *(uint4*)hv;
            *(uint4*)&Wl[buf][wbase] = *(uint4*)lv;
        };
        auto stageX = [&](int k0, int buf) {
            #pragma unroll
            for (int j = 0; j < 2; ++j) {
                int rr = wave * 32 + j * 16;      // chunk base row (chan)
                const unsigned short* gX =
                    XB + (long long)(rr + drow) * 1024 + k0 + dcswz;
                async_ld16(gX,       &Xh[buf][rr * 32]);
                async_ld16(gX + 512, &Xl[buf][rr * 32]);
            }
        };

        f32x4 acc[8];
        #pragma unroll
        for (int j = 0; j < 8; ++j) acc[j] = (f32x4){0.f, 0.f, 0.f, 0.f};

        // prologue: G loads first, then async X stages (so gen_finish's
        // G-wait leaves the younger stage loads in flight)
        gen_load(0);
        stageX(0, 0);
        if (nt > 1) stageX(32, 1);
        gen_finish(0, 0);
        if (nt > 1) asm volatile("s_waitcnt vmcnt(4)" ::: "memory");
        else        asm volatile("s_waitcnt vmcnt(0)" ::: "memory");
        asm volatile("s_waitcnt lgkmcnt(0)" ::: "memory");
        __builtin_amdgcn_s_barrier();

        for (int it = 0; it < nt; ++it) {
            const int xb = it % 3;
            const int wb = it & 1;
            if (it + 1 < nt) gen_load((it + 1) << 5);
            if (it + 2 < nt) stageX((it + 2) << 5, (it + 2) % 3);

            bf16x8 ah = *(const bf16x8*)&Wh[wb][fbase];
            bf16x8 al = *(const bf16x8*)&Wl[wb][fbase];
            const unsigned short* xhp = &Xh[xb][0];
            const unsigned short* xlp = &Xl[xb][0];
            #pragma unroll
            for (int ni = 0; ni < 8; ++ni) {
                int base = (ni * 16 + lr) * 32 + xsw;
                bf16x8 bh = *(const bf16x8*)&xhp[base];
                bf16x8 bl = *(const bf16x8*)&xlp[base];
                acc[ni] = __builtin_amdgcn_mfma_f32_16x16x32_bf16(
                    ah, bh, acc[ni], 0, 0, 0);
                acc[ni] = __builtin_amdgcn_mfma_f32_16x16x32_bf16(
                    al, bh, acc[ni], 0, 0, 0);
                acc[ni] = __builtin_amdgcn_mfma_f32_16x16x32_bf16(
                    ah, bl, acc[ni], 0, 0, 0);
            }
            if (it + 1 < nt) gen_finish((it + 1) << 5, wb ^ 1);
            // X[it+1] (issued at it-1, older than this iter's G loads) is
            // forced complete by gen_finish's G-wait; the explicit counted
            // wait covers the tail iterations and bounds outstanding loads.
            if (it + 2 < nt) asm volatile("s_waitcnt vmcnt(4)" ::: "memory");
            else             asm volatile("s_waitcnt vmcnt(0)" ::: "memory");
            asm volatile("s_waitcnt lgkmcnt(0)" ::: "memory");
            __builtin_amdgcn_s_barrier();
        }

        const int row0 = m0 + wave * 16 + quad * 4;
        #pragma unroll
        for (int ni = 0; ni < 8; ++ni) {
            int chan = h * 128 + ni * 16 + lr;
            #pragma unroll
            for (int r = 0; r < 4; ++r) {
                long long row = (long long)(b * 512 + row0 + r);
                float zz = Z[row * 2048 + chan];
                float y = acc[ni][r] * (zz / (1.f + expf(-zz)));
                store_pair(YS2, row, 2048, chan, y);
            }
        }
    }
}

// ---------------------------------------------------------------------------
// Tiled f32 GEMM (only for the small batched G = Cm @ Bm^T)
// ---------------------------------------------------------------------------
__global__ __launch_bounds__(256) void gemm_f32_k(
    int M, int N, int K,
    const float* __restrict__ A, int lda, long long sAb,
    const float* __restrict__ B, int ldb, long long sBb,
    float* __restrict__ C, int ldc, long long sCb)
{
    __shared__ float As[32][132];
    __shared__ float Bs[32][132];
    const int z = blockIdx.z;
    A += z * sAb; B += z * sBb; C += z * sCb;
    const int n0 = blockIdx.x * 128;
    const int m0 = blockIdx.y * 128;
    const int t  = threadIdx.x;
    const int tx = t & 15, ty = t >> 4;

    float acc[4][16];
    #pragma unroll
    for (int a = 0; a < 4; ++a)
        #pragma unroll
        for (int q = 0; q < 16; ++q) acc[a][q] = 0.f;

    const int ka = (t & 7) << 2;
    const int ra = t >> 3;

    for (int k0 = 0; k0 < K; k0 += 32) {
        __syncthreads();
        #pragma unroll
        for (int i = 0; i < 4; ++i) {
            int row = m0 + ra + i * 32;
            float4 v = *(const float4*)(A + (long long)row * lda + (k0 + ka));
            As[ka + 0][ra + i * 32] = v.x;
            As[ka + 1][ra + i * 32] = v.y;
            As[ka + 2][ra + i * 32] = v.z;
            As[ka + 3][ra + i * 32] = v.w;
            int rowb = n0 + ra + i * 32;
            float4 w = *(const float4*)(B + (long long)rowb * ldb + (k0 + ka));
            Bs[ka + 0][ra + i * 32] = w.x;
            Bs[ka + 1][ra + i * 32] = w.y;
            Bs[ka + 2][ra + i * 32] = w.z;
            Bs[ka + 3][ra + i * 32] = w.w;
        }
        __syncthreads();
        #pragma unroll
        for (int kk = 0; kk < 32; ++kk) {
            float a[8], bm[8];
            *(float4*)&a[0]  = *(const float4*)&As[kk][ty * 4];
            *(float4*)&a[4]  = *(const float4*)&As[kk][64 + ty * 4];
            *(float4*)&bm[0] = *(const float4*)&Bs[kk][tx * 4];
            *(float4*)&bm[4] = *(const float4*)&Bs[kk][64 + tx * 4];
            #pragma unroll
            for (int ri = 0; ri < 2; ++ri)
                #pragma unroll
                for (int ci = 0; ci < 2; ++ci)
                    #pragma unroll
                    for (int i = 0; i < 4; ++i)
                        #pragma unroll
                        for (int j = 0; j < 4; ++j)
                            acc[ri * 2 + ci][i * 4 + j] =
                                fmaf(a[ri * 4 + i], bm[ci * 4 + j], acc[ri * 2 + ci][i * 4 + j]);
        }
    }
    #pragma unroll
    for (int ri = 0; ri < 2; ++ri)
        #pragma unroll
        for (int ci = 0; ci < 2; ++ci) {
            int colb = n0 + ci * 64 + tx * 4;
            #pragma unroll
            for (int i = 0; i < 4; ++i) {
                int row = m0 + ri * 64 + ty * 4 + i;
                *(float4*)(C + (long long)row * ldc + colb) =
                    *(float4*)&acc[ri * 2 + ci][i * 4];
            }
        }
}

// ---------------------------------------------------------------------------
// Elementwise / norm kernels
// ---------------------------------------------------------------------------
__global__ __launch_bounds__(256) void pairify_k(
    const float* __restrict__ src, unsigned short* __restrict__ dst,
    int k_log2, long long n)
{
    long long idx = (long long)blockIdx.x * 256 + threadIdx.x;
    if (idx >= n) return;
    long long r = idx >> k_log2;
    int c = (int)(idx & ((1 << k_log2) - 1));
    store_pair(dst, r, 1 << k_log2, c, src[idx]);
}

__global__ __launch_bounds__(256) void layernorm_k(
    const float* __restrict__ in, float* __restrict__ out,
    const float* __restrict__ w, const float* __restrict__ b,
    int width, int rows_per_b, long long in_bstride)
{
    long long r = blockIdx.x;
    const float* x = in + (r / rows_per_b) * in_bstride + (r % rows_per_b) * (long long)width;
    int t = threadIdx.x;
    float s = 0.f;
    for (int c = t; c < width; c += 256) s += x[c];
    s = block_sum256(s);
    float m = s / (float)width;
    float vs = 0.f;
    for (int c = t; c < width; c += 256) { float d = x[c] - m; vs += d * d; }
    vs = block_sum256(vs);
    float rs = 1.f / sqrtf(vs / (float)width + 1e-5f);
    float* o = out + r * (long long)width;
    for (int c = t; c < width; c += 256) o[c] = (x[c] - m) * rs * w[c] + b[c];
}

__global__ __launch_bounds__(256) void layernorm_pair_k(
    const float* __restrict__ in, unsigned short* __restrict__ out2,
    const float* __restrict__ w, const float* __restrict__ b,
    int width, int rows_per_b, long long in_bstride)
{
    long long r = blockIdx.x;
    const float* x = in + (r / rows_per_b) * in_bstride + (r % rows_per_b) * (long long)width;
    int t = threadIdx.x;
    float s = 0.f;
    for (int c = t; c < width; c += 256) s += x[c];
    s = block_sum256(s);
    float m = s / (float)width;
    float vs = 0.f;
    for (int c = t; c < width; c += 256) { float d = x[c] - m; vs += d * d; }
    vs = block_sum256(vs);
    float rs = 1.f / sqrtf(vs / (float)width + 1e-5f);
    for (int c = t; c < width; c += 256)
        store_pair(out2, r, width, c, (x[c] - m) * rs * w[c] + b[c]);
}

__global__ __launch_bounds__(256) void rmsnorm_pair_k(
    const float* __restrict__ in, unsigned short* __restrict__ out2,
    const float* __restrict__ w, int width)
{
    long long r = blockIdx.x;
    const float* x = in + r * (long long)width;
    int t = threadIdx.x;
    float s = 0.f;
    for (int c = t; c < width; c += 256) { float v = x[c]; s += v * v; }
    s = block_sum256(s);
    float rs = 1.f / sqrtf(s / (float)width + 1e-5f);
    for (int c = t; c < width; c += 256)
        store_pair(out2, r, width, c, x[c] * rs * w[c]);
}

// Softmax over 512-wide rows, f32 in -> split-pair out IN-PLACE (same bytes).
__global__ __launch_bounds__(256) void softmax_pair_k(float* __restrict__ S,
                                                      unsigned short* __restrict__ P2)
{
    long long r = blockIdx.x;
    float* x = S + r * 512;
    unsigned short* p = P2 + r * 1024;
    int t = threadIdx.x;
    float v0 = x[t], v1 = x[t + 256];
    float mx = block_max256(fmaxf(v0, v1));
    v0 = expf(v0 - mx); v1 = expf(v1 - mx);
    float sum = block_sum256(v0 + v1);
    float inv = 1.f / sum;
    v0 *= inv; v1 *= inv;
    __syncthreads();
    unsigned short h0 = bf16_rne(v0);
    p[t] = h0;       p[512 + t] = bf16_rne(v0 - bf16_tof(h0));
    unsigned short h1 = bf16_rne(v1);
    p[t + 256] = h1; p[512 + t + 256] = bf16_rne(v1 - bf16_tof(h1));
}

// Causal grouped conv with LDS-tile transpose: writes seq-major pairs XC2
// AND chan-major pairs XCT2, both coalesced.
__global__ __launch_bounds__(256) void conv_k(
    const float* __restrict__ XS, const float* __restrict__ W,
    unsigned short* __restrict__ XC2, unsigned short* __restrict__ XCT2)
{
    __shared__ float tile[64][65];
    const int o0  = blockIdx.x * 64;
    const int tt0 = blockIdx.y * 64;
    const int b   = blockIdx.z;
    const int t   = threadIdx.x;

    const int o  = o0 + (t & 63);
    const int g2 = (o >> 1) << 1;
    const float* Wo = W + o * 8;
    float w0 = Wo[0], w1 = Wo[1], w2 = Wo[2], w3 = Wo[3];
    float w4 = Wo[4], w5 = Wo[5], w6 = Wo[6], w7 = Wo[7];
    #pragma unroll
    for (int i = 0; i < 16; ++i) {
        int sl = (t >> 6) + 4 * i;
        int tt = tt0 + sl;
        const float* xb = XS + ((long long)(b * 512 + tt)) * 2048 + g2;
        float acc = w3 * xb[0] + w7 * xb[1];
        if (tt >= 1) acc += w2 * xb[-2048] + w6 * xb[-2047];
        if (tt >= 2) acc += w1 * xb[-4096] + w5 * xb[-4095];
        if (tt >= 3) acc += w0 * xb[-6144] + w4 * xb[-6143];
        tile[sl][t & 63] = acc;
    }
    __syncthreads();
    #pragma unroll
    for (int i = 0; i < 16; ++i) {
        int idx = t + 256 * i;
        int sl = idx >> 6, ol = idx & 63;
        float v = tile[sl][ol];
        unsigned short hi = bf16_rne(v);
        unsigned short lo = bf16_rne(v - bf16_tof(hi));
        long long row = (long long)(b * 512 + tt0 + sl);
        XC2[row * 4096 + o0 + ol] = hi;
        XC2[row * 4096 + 2048 + o0 + ol] = lo;
    }
    #pragma unroll
    for (int i = 0; i < 16; ++i) {
        int idx = t + 256 * i;
        int cl = idx >> 6, s = idx & 63;
        float v = tile[s][cl];
        unsigned short hi = bf16_rne(v);
        unsigned short lo = bf16_rne(v - bf16_tof(hi));
        long long tb = (long long)b * 2097152 + (long long)(o0 + cl) * 1024 + tt0 + s;
        XCT2[tb] = hi;
        XCT2[tb + 512] = lo;
    }
}

__global__ __launch_bounds__(256) void dt_k(
    const float* __restrict__ dtBC, const float* __restrict__ dt_bias, float* __restrict__ DT)
{
    int idx = blockIdx.x * 256 + threadIdx.x;
    int r = idx >> 4, h = idx & 15;
    float xv = dtBC[r * 144 + h] + dt_bias[h];
    DT[idx] = (xv > 20.f) ? xv : log1pf(expf(xv));
}

__global__ __launch_bounds__(64) void cuma_k(
    const float* __restrict__ DT, const float* __restrict__ A_log, float* __restrict__ CUMA)
{
    int h = blockIdx.x, b = blockIdx.y;
    int ln = threadIdx.x;
    float Ah = -expf(A_log[h]);
    float v[8];
    float run = 0.f;
    #pragma unroll
    for (int i = 0; i < 8; ++i) {
        run += Ah * DT[((b * 512) + (ln * 8 + i)) * 16 + h];
        v[i] = run;
    }
    float tot = run;
    float sc = tot;
    #pragma unroll
    for (int o = 1; o <= 32; o <<= 1) {
        float u = __shfl_up(sc, o, 64);
        if (ln >= o) sc += u;
    }
    float excl = sc - tot;
    #pragma unroll
    for (int i = 0; i < 8; ++i)
        CUMA[(b * 16 + h) * 512 + ln * 8 + i] = excl + v[i];
}

// hc = LayerNorm64(G1) -> {-1,+1} as split pairs (lo = 0)
__global__ __launch_bounds__(64) void hc_quant_k(
    const float* __restrict__ G1, const float* __restrict__ w,
    const float* __restrict__ b, unsigned short* __restrict__ HCQ2)
{
    int r = blockIdx.x, ln = threadIdx.x;
    float v = G1[r * 64 + ln];
    float s = v;
    #pragma unroll
    for (int o = 32; o > 0; o >>= 1) s += __shfl_xor(s, o, 64);
    float m = s * (1.f / 64.f);
    float d = v - m;
    float vs = d * d;
    #pragma unroll
    for (int o = 32; o > 0; o >>= 1) vs += __shfl_xor(vs, o, 64);
    vs *= (1.f / 64.f);
    float hc = d * (1.f / sqrtf(vs + 1e-5f)) * w[ln] + b[ln];
    HCQ2[r * 128 + ln] = (hc > 0.f) ? 0x3F80 : 0xBF80;
    HCQ2[r * 128 + 64 + ln] = 0;
}

__global__ __launch_bounds__(256) void dxm_k(
    const float* __restrict__ mtok, const float* __restrict__ e2d, float* __restrict__ dxm)
{
    int c = blockIdx.x * 256 + threadIdx.x;
    float acc = 0.f;
    #pragma unroll
    for (int j = 0; j < 64; ++j) acc = fmaf(mtok[j], e2d[c * 64 + j], acc);
    dxm[c] = acc;
}

__global__ __launch_bounds__(256) void projm_k(
    const float* __restrict__ lnm,
    const float* __restrict__ bWq, const float* __restrict__ bWk, const float* __restrict__ bWv,
    float* __restrict__ qm, float* __restrict__ km, float* __restrict__ vm)
{
    int idx = blockIdx.x * 256 + threadIdx.x;
    int sel = idx >> 10, c = idx & 1023;
    const float* W = (sel == 0) ? bWq : (sel == 1) ? bWk : bWv;
    float* O = (sel == 0) ? qm : (sel == 1) ? km : vm;
    const float* wr = W + (long long)c * 1024;
    float acc = 0.f;
    for (int j = 0; j < 1024; j += 4) {
        float4 a = *(const float4*)(lnm + j);
        float4 w4 = *(const float4*)(wr + j);
        acc = fmaf(a.x, w4.x, fmaf(a.y, w4.y, fmaf(a.z, w4.z, fmaf(a.w, w4.w, acc))));
    }
    O[c] = acc;
}

// Collapsed decoder attention: 1 query/(b,h); keys = 512 visible + mask key x512.
__global__ __launch_bounds__(256) void dec_attn_k(
    const float* __restrict__ Kv, const float* __restrict__ Vv,
    const float* __restrict__ qm, const float* __restrict__ km,
    const float* __restrict__ vm, float* __restrict__ OBm)
{
    int h = blockIdx.x, b = blockIdx.y;
    int t = threadIdx.x;
    __shared__ __align__(16) float qs[256];
    __shared__ __align__(16) float ps[512];
    qs[t] = qm[h * 256 + t];
    __syncthreads();
    float s[2];
    #pragma unroll
    for (int i = 0; i < 2; ++i) {
        int r = t + i * 256;
        const float* kr = Kv + ((long long)(b * 512 + r)) * 1024 + h * 256;
        float acc = 0.f;
        for (int c = 0; c < 256; c += 4) {
            float4 k4 = *(const float4*)(kr + c);
            float4 q4 = *(const float4*)(qs + c);
            acc = fmaf(k4.x, q4.x, fmaf(k4.y, q4.y, fmaf(k4.z, q4.z, fmaf(k4.w, q4.w, acc))));
        }
        s[i] = acc * (1.f / 16.f);
    }
    float accm = 0.f;
    for (int c = 0; c < 256; c += 4) {
        float4 k4 = *(const float4*)(km + h * 256 + c);
        float4 q4 = *(const float4*)(qs + c);
        accm = fmaf(k4.x, q4.x, fmaf(k4.y, q4.y, fmaf(k4.z, q4.z, fmaf(k4.w, q4.w, accm))));
    }
    float smv = accm * (1.f / 16.f);
    float mx = block_max256(fmaxf(fmaxf(s[0], s[1]), smv));
    float p0 = expf(s[0] - mx), p1 = expf(s[1] - mx);
    ps[t] = p0; ps[t + 256] = p1;
    float pm = expf(smv - mx) * 512.f;
    float sum = block_sum256(p0 + p1) + pm;
    float inv = 1.f / sum;
    __syncthreads();
    float o = pm * vm[h * 256 + t];
    const float* vcol = Vv + (long long)b * 512 * 1024 + h * 256 + t;
    for (int j = 0; j < 512; ++j)
        o = fmaf(ps[j], vcol[(long long)j * 1024], o);
    OBm[b * 1024 + h * 256 + t] = o * inv;
}

__global__ __launch_bounds__(256) void ydm_k(
    const float* __restrict__ OBm, const float* __restrict__ bWo,
    const float* __restrict__ bWo_b, const float* __restrict__ dxm,
    float* __restrict__ ydm)
{
    int idx = blockIdx.x * 256 + threadIdx.x;
    int b = idx >> 10, c = idx & 1023;
    const float* ar = OBm + b * 1024;
    const float* wr = bWo + (long long)c * 1024;
    float acc = 0.f;
    for (int j = 0; j < 1024; j += 4) {
        float4 a = *(const float4*)(ar + j);
        float4 w4 = *(const float4*)(wr + j);
        acc = fmaf(a.x, w4.x, fmaf(a.y, w4.y, fmaf(a.z, w4.z, fmaf(a.w, w4.w, acc))));
    }
    ydm[idx] = acc + bWo_b[c] + dxm[c];
}

__global__ __launch_bounds__(256) void outm_k(
    const float* __restrict__ ydm, const float* __restrict__ dout_W,
    const float* __restrict__ dout_b, float* __restrict__ outm)
{
    int idx = blockIdx.x * 256 + threadIdx.x;
    int b = idx >> 11, c = idx & 2047;
    const float* ar = ydm + b * 1024;
    const float* wr = dout_W + (long long)c * 1024;
    float acc = 0.f;
    for (int j = 0; j < 1024; j += 4) {
        float4 a = *(const float4*)(ar + j);
        float4 w4 = *(const float4*)(wr + j);
        acc = fmaf(a.x, w4.x, fmaf(a.y, w4.y, fmaf(a.z, w4.z, fmaf(a.w, w4.w, acc))));
    }
    outm[idx] = acc + dout_b[c];
}

__global__ __launch_bounds__(256) void bcast_k(
    const float* __restrict__ outm, float* __restrict__ out)
{
    int idx = blockIdx.x * 256 + threadIdx.x;
    int c4 = idx & 511;
    int b = idx >> 18;
    ((float4*)out)[idx] = ((const float4*)outm)[b * 512 + c4];
}

// ---------------------------------------------------------------------------
// Host-side launcher
// ---------------------------------------------------------------------------
static inline void pairify(hipStream_t s, const float* src, unsigned short* dst,
                           int k_log2, long long n)
{
    pairify_k<<<(int)((n + 255) / 256), 256, 0, s>>>(src, dst, k_log2, n);
}

extern "C" void kernel_launch(void* const* d_in, const int* in_sizes, int n_in,
                              void* d_out, int out_size, void* d_ws, size_t ws_size,
                              hipStream_t stream)
{
    const float* x       = (const float*)d_in[0];
    const float* ln0_w   = (const float*)d_in[1];
    const float* ln0_b   = (const float*)d_in[2];
    const float* in_W    = (const float*)d_in[3];
    const float* rms_w   = (const float*)d_in[4];
    const float* exp_W   = (const float*)d_in[5];
    const float* conv_W  = (const float*)d_in[6];
    const float* xproj_W = (const float*)d_in[7];
    const float* dt_bias = (const float*)d_in[8];
    const float* A_log   = (const float*)d_in[9];
    const float* Dv      = (const float*)d_in[10];
    const float* outp_W  = (const float*)d_in[11];
    const float* outp_b  = (const float*)d_in[12];
    const float* n1_w    = (const float*)d_in[13];
    const float* n1_b    = (const float*)d_in[14];
    const float* aWq     = (const float*)d_in[15];
    const float* aWk     = (const float*)d_in[16];
    const float* aWv     = (const float*)d_in[17];
    const float* aWo     = (const float*)d_in[18];
    const float* aWo_b   = (const float*)d_in[19];
    const float* h_W     = (const float*)d_in[20];
    const float* h_b     = (const float*)d_in[21];
    const float* h_lnw   = (const float*)d_in[22];
    const float* h_lnb   = (const float*)d_in[23];
    const float* mtok    = (const float*)d_in[24];
    const float* e2d_W   = (const float*)d_in[25];
    const float* dn_w    = (const float*)d_in[26];
    const float* dn_b    = (const float*)d_in[27];
    const float* bWq     = (const float*)d_in[28];
    const float* bWk     = (const float*)d_in[29];
    const float* bWv     = (const float*)d_in[30];
    const float* bWo     = (const float*)d_in[31];
    const float* bWo_b   = (const float*)d_in[32];
    const float* dout_W  = (const float*)d_in[33];
    const float* dout_b  = (const float*)d_in[34];

    float* ws  = (float*)d_ws;
    float* out = (float*)d_out;

    float* S1 = ws;
    float* S2 = ws + 8388608;
    float* S3 = ws + 16777216;
    float* S4 = ws + 25165824;
    float* S5 = ws + 33554432;
    float* S6 = ws + 37748736;
    float* S7 = ws + 41943040;
    float* S8 = ws + 46137344;
    float* S9 = ws + 50331648;
    float* SP = ws + 54525952;

    unsigned short* XV2     = (unsigned short*)S1;
    unsigned short* exp_W2  = (unsigned short*)S1;
    unsigned short* XCT2    = (unsigned short*)S1;
    float*          SA      = S1;
    unsigned short* P2      = (unsigned short*)S1;
    float*          Kv      = S1;
    float*          Vv      = S1 + 4194304;
    unsigned short* in_W2   = (unsigned short*)S2;
    float*          XS      = S2;
    unsigned short* YS2     = (unsigned short*)S2;
    unsigned short* XC2     = (unsigned short*)S3;
    unsigned short* outp_W2 = (unsigned short*)S3;
    float*          DXV     = S3;
    unsigned short* LNDXV2  = (unsigned short*)(S3 + 4194304);
    float*          Z       = S4;
    unsigned short* aWq2    = (unsigned short*)S4;
    unsigned short* aWk2    = (unsigned short*)S4 + 2097152;
    unsigned short* aWv2    = (unsigned short*)S4 + 4194304;
    unsigned short* aWo2    = (unsigned short*)S4 + 6291456;
    unsigned short* bWk2    = (unsigned short*)S4 + 8388608;
    unsigned short* bWv2    = (unsigned short*)S4 + 10485760;
    float*          T       = S5;
    unsigned short* QA2     = (unsigned short*)S5;
    unsigned short* Y22     = (unsigned short*)S5;
    unsigned short* HR2     = (unsigned short*)S6;
    float*          Y1      = S6;
    unsigned short* LNY2    = (unsigned short*)S7;
    unsigned short* OA2     = (unsigned short*)S7;
    unsigned short* KA2     = (unsigned short*)S8;
    unsigned short* VT2     = (unsigned short*)S9;

    float* dtBC = SP;
    float* DT   = SP + 589824;
    float* CUMA = SP + 655360;
    float* G    = SP + 720896;
    unsigned short* xprojW2 = (unsigned short*)(SP + 2818048);
    unsigned short* hW2     = (unsigned short*)(SP + 3112960);
    unsigned short* e2dW2   = (unsigned short*)(SP + 3178496);
    float* G1   = SP + 720896;
    unsigned short* HCQ2 = (unsigned short*)(SP + 983040);
    float* dxm  = SP + 1245184;
    float* lnm  = SP + 1246208;
    float* qm   = SP + 1247232;
    float* km   = SP + 1248256;
    float* vm   = SP + 1249280;
    float* OBm  = SP + 1250304;
    float* ydm  = SP + 1258496;
    float* outm = SP + 1266688;

    const long long LL0 = 0;
    #define G3D(OUTM, GX, GY, GZ, ...) \
        gemm_bf16_k<3, OUTM, true><<<dim3(GX, GY, GZ), 256, 0, stream>>>(__VA_ARGS__)
    #define G3R(OUTM, GX, GY, GZ, ...) \
        gemm_bf16_k<3, OUTM, false><<<dim3(GX, GY, GZ), 256, 0, stream>>>(__VA_ARGS__)
    #define G1D(OUTM, GX, GY, GZ, ...) \
        gemm_bf16_k<1, OUTM, true><<<dim3(GX, GY, GZ), 256, 0, stream>>>(__VA_ARGS__)

    // ---- weight prep (phase A) ----
    pairify(stream, in_W,    in_W2,   11, 1024LL * 2048);
    pairify(stream, xproj_W, xprojW2, 11, 144LL * 2048);
    pairify(stream, h_W,     hW2,     10, 64LL * 1024);
    pairify(stream, e2d_W,   e2dW2,    6, 1024LL * 64);

    // ---- encoder trunk ----
    layernorm_pair_k<<<4096, 256, 0, stream>>>(x, XV2, ln0_w, ln0_b, 2048, 512,
                                               (long long)1024 * 2048);
    G3D(0, 8, 32, 1, 4096, 1024, 2048, XV2, 4096, 2048, LL0, LL0,
        in_W2, 4096, 2048, LL0, LL0, T, 1024, 0, LL0, LL0,
        nullptr, nullptr, 0, 1.f, 1);
    pairify(stream, exp_W, exp_W2, 10, 4096LL * 1024);   // S1 (XV2 dead)
    rmsnorm_pair_k<<<4096, 256, 0, stream>>>(T, HR2, rms_w, 1024);
    G3D(0, 16, 32, 1, 4096, 2048, 1024, HR2, 2048, 1024, LL0, LL0,
        exp_W2, 2048, 1024, LL0, LL0, XS, 2048, 0, LL0, LL0,
        nullptr, nullptr, 0, 1.f, 1);
    G3D(0, 16, 32, 1, 4096, 2048, 1024, HR2, 2048, 1024, LL0, LL0,
        exp_W2 + 2048LL * 2048, 2048, 1024, LL0, LL0, Z, 2048, 0, LL0, LL0,
        nullptr, nullptr, 0, 1.f, 1);
    conv_k<<<dim3(32, 8, 8), 256, 0, stream>>>(XS, conv_W, XC2, XCT2);
    G3R(0, 2, 32, 1, 4096, 144, 2048, XC2, 4096, 2048, LL0, LL0,
        xprojW2, 4096, 2048, LL0, LL0, dtBC, 144, 0, LL0, LL0,
        nullptr, nullptr, 0, 1.f, 1);
    dt_k<<<256, 256, 0, stream>>>(dtBC, dt_bias, DT);
    cuma_k<<<dim3(16, 8), 64, 0, stream>>>(DT, A_log, CUMA);
    gemm_f32_k<<<dim3(4, 4, 8), 256, 0, stream>>>(
        512, 512, 64, dtBC + 80, 144, (long long)512 * 144,
        dtBC + 16, 144, (long long)512 * 144, G, 512, (long long)512 * 512);
    ssd_mfma_k<<<dim3(4, 16, 8), 256, 0, stream>>>(G, CUMA, DT, XCT2, Z, Dv, YS2);

    // ---- weight prep (phase B: S3/S4 now dead) ----
    pairify(stream, outp_W, outp_W2, 11, 1024LL * 2048);
    pairify(stream, aWq, aWq2, 10, 1024LL * 1024);
    pairify(stream, aWk, aWk2, 10, 1024LL * 1024);
    pairify(stream, aWv, aWv2, 10, 1024LL * 1024);
    pairify(stream, aWo, aWo2, 10, 1024LL * 1024);
    pairify(stream, bWk, bWk2, 10, 1024LL * 1024);
    pairify(stream, bWv, bWv2, 10, 1024LL * 1024);

    G3D(0, 8, 32, 1, 4096, 1024, 2048, YS2, 4096, 2048, LL0, LL0,
        outp_W2, 4096, 2048, LL0, LL0, Y1, 1024, 0, LL0, LL0,
        outp_b, T, 1024, 1.f, 1);

    // ---- encoder attention (all MFMA) ----
    layernorm_pair_k<<<4096, 256, 0, stream>>>(Y1, LNY2, n1_w, n1_b, 1024, 4096, LL0);
    G3D(1, 8, 32, 1, 4096, 1024, 1024, LNY2, 2048, 1024, LL0, LL0,
        aWq2, 2048, 1024, LL0, LL0, QA2, 2048, 1024, LL0, LL0,
        nullptr, nullptr, 0, 1.f, 1);
    G3D(1, 8, 32, 1, 4096, 1024, 1024, LNY2, 2048, 1024, LL0, LL0,
        aWk2, 2048, 1024, LL0, LL0, KA2, 2048, 1024, LL0, LL0,
        nullptr, nullptr, 0, 1.f, 1);
    G3D(2, 8, 32, 1, 4096, 1024, 1024, LNY2, 2048, 1024, LL0, LL0,
        aWv2, 2048, 1024, LL0, LL0, VT2, 1024, 512, (long long)1024 * 1024, LL0,
        nullptr, nullptr, 0, 1.f, 1);
    G3D(0, 4, 4, 32, 512, 512, 256,
        QA2, 2048, 1024, (long long)512 * 2048, 256,
        KA2, 2048, 1024, (long long)512 * 2048, 256,
        SA, 512, 0, (long long)4 * 512 * 512, (long long)512 * 512,
        nullptr, nullptr, 0, 1.f / 16.f, 4);
    softmax_pair_k<<<16384, 256, 0, stream>>>(SA, P2);
    G3D(1, 2, 4, 32, 512, 256, 512,
        P2, 1024, 512, (long long)4 * 512 * 1024, (long long)512 * 1024,
        VT2, 1024, 512, (long long)1024 * 1024, (long long)256 * 1024,
        OA2, 2048, 1024, (long long)512 * 2048, 256,
        nullptr, nullptr, 0, 1.f, 4);
    G3D(1, 8, 32, 1, 4096, 1024, 1024, OA2, 2048, 1024, LL0, LL0,
        aWo2, 2048, 1024, LL0, LL0, Y22, 2048, 1024, LL0, LL0,
        aWo_b, Y1, 1024, 1.f, 1);

    // ---- quantize ----
    G3R(0, 1, 32, 1, 4096, 64, 1024, Y22, 2048, 1024, LL0, LL0,
        hW2, 2048, 1024, LL0, LL0, G1, 64, 0, LL0, LL0,
        h_b, nullptr, 0, 1.f, 1);
    hc_quant_k<<<4096, 64, 0, stream>>>(G1, h_lnw, h_lnb, HCQ2);

    // ---- decoder (collapsed masked rows) ----
    G3D(0, 8, 32, 1, 4096, 1024, 64, HCQ2, 128, 64, LL0, LL0,
        e2dW2, 128, 64, LL0, LL0, DXV, 1024, 0, LL0, LL0,
        nullptr, nullptr, 0, 1.f, 1);
    dxm_k<<<4, 256, 0, stream>>>(mtok, e2d_W, dxm);
    layernorm_k<<<1, 256, 0, stream>>>(dxm, lnm, dn_w, dn_b, 1024, 1, LL0);
    layernorm_pair_k<<<4096, 256, 0, stream>>>(DXV, LNDXV2, dn_w, dn_b, 1024, 4096, LL0);
    projm_k<<<12, 256, 0, stream>>>(lnm, bWq, bWk, bWv, qm, km, vm);
    G1D(0, 8, 32, 1, 4096, 1024, 1024, LNDXV2, 2048, 1024, LL0, LL0,
        bWk2, 2048, 1024, LL0, LL0, Kv, 1024, 0, LL0, LL0,
        nullptr, nullptr, 0, 1.f, 1);
    G1D(0, 8, 32, 1, 4096, 1024, 1024, LNDXV2, 2048, 1024, LL0, LL0,
        bWv2, 2048, 1024, LL0, LL0, Vv, 1024, 0, LL0, LL0,
        nullptr, nullptr, 0, 1.f, 1);
    dec_attn_k<<<dim3(4, 8), 256, 0, stream>>>(Kv, Vv, qm, km, vm, OBm);
    ydm_k<<<32, 256, 0, stream>>>(OBm, bWo, bWo_b, dxm, ydm);
    outm_k<<<64, 256, 0, stream>>>(ydm, dout_W, dout_b, outm);
    bcast_k<<<8192, 256, 0, stream>>>(outm, out);
    #undef G3D
    #undef G3R
    #undef G1D
}

// Round 4
// 1148.438 us; speedup vs baseline: 1.2246x; 1.0819x over previous
//
#include <hip/hip_runtime.h>

// ---------------------------------------------------------------------------
// B=8, N=1024, CIN=2048, HID=1024, HC=64, LV=512, NH_SSD=16, HD=128, DS=64.
// Encoder rows = 4096. Decoder collapsed to 1 row/batch. All large GEMMs:
// split-bf16 MFMA (x3 passes = f32-grade pre-quantizer; x1 post-quantizer),
// staged via __builtin_amdgcn_global_load_lds width=16 (DIRECT path).
// DIRECT GEMM: triple-buffered LDS + counted vmcnt + raw s_barrier pipeline,
// source-swizzled staging (conflict-free b128). Thin-N GEMMs (xproj N=144,
// hW N=64) use split-K (8 chunks, f32 partials + reduce) — the ragged
// 64/32-block versions ran at 2.5% occupancy / 95us. SSD intra-chunk v4:
// X staged once per block through the GEMM pipeline.
// ---------------------------------------------------------------------------

typedef short bf16x8 __attribute__((ext_vector_type(8)));
typedef float f32x4 __attribute__((ext_vector_type(4)));

__device__ __forceinline__ unsigned short bf16_rne(float f) {
    unsigned u = __float_as_uint(f);
    unsigned r = u + 0x7FFFu + ((u >> 16) & 1u);
    return (unsigned short)(r >> 16);
}
__device__ __forceinline__ float bf16_tof(unsigned short h) {
    return __uint_as_float(((unsigned)h) << 16);
}
__device__ __forceinline__ void store_pair(unsigned short* dst, long long row,
                                           int width, int c, float v) {
    unsigned short hi = bf16_rne(v);
    unsigned short lo = bf16_rne(v - bf16_tof(hi));
    long long base = row * (2LL * width);
    dst[base + c] = hi;
    dst[base + width + c] = lo;
}
// Async global->LDS, 16B per lane. LDS dest = wave-uniform base + lane*16.
__device__ __forceinline__ void async_ld16(const unsigned short* g, unsigned short* l) {
    __builtin_amdgcn_global_load_lds(
        (const __attribute__((address_space(1))) unsigned int*)g,
        (__attribute__((address_space(3))) unsigned int*)l, 16, 0, 0);
}

// ---------------------------------------------------------------------------
// Reduction helpers (blockDim 256)
// ---------------------------------------------------------------------------
__device__ __forceinline__ float block_sum256(float v) {
    #pragma unroll
    for (int o = 32; o > 0; o >>= 1) v += __shfl_xor(v, o, 64);
    __shared__ float sm[4];
    int w = threadIdx.x >> 6;
    __syncthreads();
    if ((threadIdx.x & 63) == 0) sm[w] = v;
    __syncthreads();
    return sm[0] + sm[1] + sm[2] + sm[3];
}
__device__ __forceinline__ float block_max256(float v) {
    #pragma unroll
    for (int o = 32; o > 0; o >>= 1) v = fmaxf(v, __shfl_xor(v, o, 64));
    __shared__ float smx[4];
    int w = threadIdx.x >> 6;
    __syncthreads();
    if ((threadIdx.x & 63) == 0) smx[w] = v;
    __syncthreads();
    return fmaxf(fmaxf(smx[0], smx[1]), fmaxf(smx[2], smx[3]));
}

// ---------------------------------------------------------------------------
// Split-bf16 MFMA GEMM. C[m,n] = alpha * sum_k A[m,k]*B[n,k] (+bias)(+res)
// NPASS=3: hh+lh+hl (f32-grade). NPASS=1: hh only.
// OUT=0: f32 C. OUT=1: split-pair C. OUT=2: transposed split-pair per
// 512-row batch.
// DIRECT=true: global_load_lds staging, triple-buffered, counted-vmcnt
//   pipeline (depth-2 prefetch), source-swizzled for conflict-free b128:
//   LDS slot (row, q) holds the global 16B-chunk q ^ t(row),
//   t(r) = (r&3)^((r>>2)&3)  -> max 2-way bank aliasing (free).
//   Requires full tiles (N covered by grid) and K % 32 == 0.
// ---------------------------------------------------------------------------
template<int NPASS, int OUT, bool DIRECT>
__global__ __launch_bounds__(256, DIRECT ? 1 : 2) void gemm_bf16_k(
    int M, int N, int K,
    const unsigned short* __restrict__ A2, int lda2, int aLo, long long sAb, long long sAh,
    const unsigned short* __restrict__ B2, int ldb2, int bLo, long long sBb, long long sBh,
    void* __restrict__ Cv, int ldc, int cLo, long long sCb, long long sCh,
    const float* __restrict__ bias, const float* __restrict__ res, int ldr,
    float alpha, int nh)
{
    constexpr int ST   = DIRECT ? 32 : 40;
    constexpr int NARR = (NPASS == 3) ? 4 : 2;
    constexpr int NB   = DIRECT ? 3 : 1;
    constexpr int O_AH = 0;
    constexpr int O_BH = 128 * ST;
    constexpr int O_AL = 2 * 128 * ST;
    constexpr int O_BL = 3 * 128 * ST;
    constexpr int BUFSZ = 128 * ST * NARR;
    __shared__ unsigned short SM[NB * BUFSZ];

    const int z  = blockIdx.z;
    const int bb = z / nh, hh = z - bb * nh;
    A2 += bb * sAb + hh * sAh;
    B2 += bb * sBb + hh * sBh;

    const int t    = threadIdx.x;
    const int m0   = blockIdx.y * 128;
    const int n0   = blockIdx.x * 128;
    const int lane = t & 63, wave = t >> 6;
    const int wm   = (wave >> 1) * 64, wn = (wave & 1) * 64;
    const int lr   = lane & 15, quad = lane >> 4;

    f32x4 acc[4][4];
    #pragma unroll
    for (int i = 0; i < 4; ++i)
        #pragma unroll
        for (int j = 0; j < 4; ++j) acc[i][j] = (f32x4){0.f, 0.f, 0.f, 0.f};

    if constexpr (DIRECT) {
        // ---- pipelined path ----
        const int drow  = lane >> 2;                       // row in 16-chunk
        // swizzled global 16B-chunk for this lane's LDS slot (lane&3):
        const int dcswz = (((lane & 3) ^ ((lane >> 2) & 3) ^ ((lane >> 4) & 3)) << 3);
        // frag-read slot XOR (per-lane constant):
        const int rsw   = ((quad ^ ((lr & 3) ^ (lr >> 2))) << 3);

        auto stage = [&](int k0, int buf) {
            unsigned short* bp = &SM[buf * BUFSZ];
            #pragma unroll
            for (int j = 0; j < 2; ++j) {
                int rr = wave * 32 + j * 16;               // chunk base row
                int gr = rr + drow;
                const unsigned short* gA = A2 + (long long)(m0 + gr) * lda2 + k0 + dcswz;
                async_ld16(gA, &bp[O_AH + rr * 32]);
                if (NPASS == 3) async_ld16(gA + aLo, &bp[O_AL + rr * 32]);
                const unsigned short* gB = B2 + (long long)(n0 + gr) * ldb2 + k0 + dcswz;
                async_ld16(gB, &bp[O_BH + rr * 32]);
                if (NPASS == 3) async_ld16(gB + bLo, &bp[O_BL + rr * 32]);
            }
        };

        const int nt = K >> 5;
        stage(0, 0);
        if (nt > 1) stage(32, 1);
        int cur = 0, pre = 2;
        for (int it = 0; it < nt; ++it) {
            // wait for tile it's loads (keep next tile's in flight), all waves
            if (it + 1 < nt) {
                if (NPASS == 3) asm volatile("s_waitcnt vmcnt(8)" ::: "memory");
                else            asm volatile("s_waitcnt vmcnt(4)" ::: "memory");
            } else {
                asm volatile("s_waitcnt vmcnt(0)" ::: "memory");
            }
            __builtin_amdgcn_s_barrier();
            // prefetch tile it+2 into the buffer consumed at iter it-1
            // (safe: its ds_reads were lgkm-consumed before this barrier)
            if (it + 2 < nt) stage((it + 2) << 5, pre);

            const unsigned short* bp = &SM[cur * BUFSZ];
            bf16x8 ah[4], bh[4], al[4], bl[4];
            #pragma unroll
            for (int i = 0; i < 4; ++i) {
                int ra = O_AH + (wm + i * 16 + lr) * 32 + rsw;
                int rb = O_BH + (wn + i * 16 + lr) * 32 + rsw;
                ah[i] = *(const bf16x8*)&bp[ra];
                bh[i] = *(const bf16x8*)&bp[rb];
                if (NPASS == 3) {
                    al[i] = *(const bf16x8*)&bp[ra + (O_AL - O_AH)];
                    bl[i] = *(const bf16x8*)&bp[rb + (O_BL - O_BH)];
                }
            }
            #pragma unroll
            for (int mi = 0; mi < 4; ++mi)
                #pragma unroll
                for (int ni = 0; ni < 4; ++ni) {
                    acc[mi][ni] = __builtin_amdgcn_mfma_f32_16x16x32_bf16(
                        ah[mi], bh[ni], acc[mi][ni], 0, 0, 0);
                    if (NPASS == 3) {
                        acc[mi][ni] = __builtin_amdgcn_mfma_f32_16x16x32_bf16(
                            al[mi], bh[ni], acc[mi][ni], 0, 0, 0);
                        acc[mi][ni] = __builtin_amdgcn_mfma_f32_16x16x32_bf16(
                            ah[mi], bl[ni], acc[mi][ni], 0, 0, 0);
                    }
                }
            cur = (cur == 2) ? 0 : cur + 1;
            pre = (pre == 2) ? 0 : pre + 1;
        }
    } else {
        // ---- ragged reg-staging path (original structure) ----
        const int srow = t >> 2;          // row 0..63 (+64)
        const int scol = (t & 3) * 8;

        for (int k0 = 0; k0 < K; k0 += 32) {
            __syncthreads();
            #pragma unroll
            for (int half = 0; half < 2; ++half) {
                int r = srow + half * 64;
                const unsigned short* pA = A2 + (long long)(m0 + r) * lda2 + k0 + scol;
                *(uint4*)&SM[O_AH + r * ST + scol] = *(const uint4*)pA;
                if (NPASS == 3)
                    *(uint4*)&SM[O_AL + r * ST + scol] = *(const uint4*)(pA + aLo);
                int rb = n0 + r;
                uint4 vh = {0u, 0u, 0u, 0u}, vl = {0u, 0u, 0u, 0u};
                if (rb < N) {
                    const unsigned short* pB = B2 + (long long)rb * ldb2 + k0 + scol;
                    vh = *(const uint4*)pB;
                    if (NPASS == 3) vl = *(const uint4*)(pB + bLo);
                }
                *(uint4*)&SM[O_BH + r * ST + scol] = vh;
                if (NPASS == 3) *(uint4*)&SM[O_BL + r * ST + scol] = vl;
            }
            __syncthreads();

            bf16x8 ah[4], bh[4], al[4], bl[4];
            #pragma unroll
            for (int i = 0; i < 4; ++i) {
                int ra = (wm + i * 16 + lr) * ST + quad * 8;
                int rb = (wn + i * 16 + lr) * ST + quad * 8;
                ah[i] = *(const bf16x8*)&SM[O_AH + ra];
                bh[i] = *(const bf16x8*)&SM[O_BH + rb];
                if (NPASS == 3) {
                    al[i] = *(const bf16x8*)&SM[O_AL + ra];
                    bl[i] = *(const bf16x8*)&SM[O_BL + rb];
                }
            }
            #pragma unroll
            for (int mi = 0; mi < 4; ++mi)
                #pragma unroll
                for (int ni = 0; ni < 4; ++ni) {
                    acc[mi][ni] = __builtin_amdgcn_mfma_f32_16x16x32_bf16(
                        ah[mi], bh[ni], acc[mi][ni], 0, 0, 0);
                    if (NPASS == 3) {
                        acc[mi][ni] = __builtin_amdgcn_mfma_f32_16x16x32_bf16(
                            al[mi], bh[ni], acc[mi][ni], 0, 0, 0);
                        acc[mi][ni] = __builtin_amdgcn_mfma_f32_16x16x32_bf16(
                            ah[mi], bl[ni], acc[mi][ni], 0, 0, 0);
                    }
                }
        }
    }

    // D layout: col = lane&15, row = quad*4 + r
    if (OUT == 0) {
        float* C = (float*)Cv + bb * sCb + hh * sCh;
        #pragma unroll
        for (int mi = 0; mi < 4; ++mi)
            #pragma unroll
            for (int ni = 0; ni < 4; ++ni) {
                int col = n0 + wn + ni * 16 + lr;
                if (col >= N) continue;
                float bv = bias ? bias[col] : 0.f;
                #pragma unroll
                for (int r = 0; r < 4; ++r) {
                    int row = m0 + wm + mi * 16 + quad * 4 + r;
                    float v = alpha * acc[mi][ni][r] + bv;
                    if (res) v += res[(long long)row * ldr + col];
                    C[(long long)row * ldc + col] = v;
                }
            }
    } else if (OUT == 1) {
        unsigned short* C = (unsigned short*)Cv + bb * sCb + hh * sCh;
        #pragma unroll
        for (int mi = 0; mi < 4; ++mi)
            #pragma unroll
            for (int ni = 0; ni < 4; ++ni) {
                int col = n0 + wn + ni * 16 + lr;
                if (col >= N) continue;
                float bv = bias ? bias[col] : 0.f;
                #pragma unroll
                for (int r = 0; r < 4; ++r) {
                    int row = m0 + wm + mi * 16 + quad * 4 + r;
                    float v = alpha * acc[mi][ni][r] + bv;
                    if (res) v += res[(long long)row * ldr + col];
                    unsigned short hi = bf16_rne(v);
                    unsigned short lo = bf16_rne(v - bf16_tof(hi));
                    long long p = (long long)row * ldc + col;
                    C[p] = hi;
                    C[p + cLo] = lo;
                }
            }
    } else {  // OUT == 2: transposed pairs per 512-row batch
        unsigned short* C = (unsigned short*)Cv;
        #pragma unroll
        for (int mi = 0; mi < 4; ++mi)
            #pragma unroll
            for (int ni = 0; ni < 4; ++ni) {
                int col = n0 + wn + ni * 16 + lr;
                if (col >= N) continue;
                int row0 = m0 + wm + mi * 16 + quad * 4;
                int b = row0 >> 9, seq0 = row0 & 511;
                ushort4 h4, l4;
                unsigned short* hp = (unsigned short*)&h4;
                unsigned short* lp = (unsigned short*)&l4;
                #pragma unroll
                for (int r = 0; r < 4; ++r) {
                    float v = acc[mi][ni][r];
                    unsigned short hi = bf16_rne(v);
                    hp[r] = hi;
                    lp[r] = bf16_rne(v - bf16_tof(hi));
                }
                long long p = b * sCb + (long long)col * ldc + seq0;
                *(ushort4*)&C[p] = h4;
                *(ushort4*)&C[p + cLo] = l4;
            }
    }
}

// ---------------------------------------------------------------------------
// Split-K ragged GEMM for thin-N ops (xproj N=144, hW N=64).
// grid (ceil(N/128), M/128, NCHUNK); block kz accumulates K range
// [kz*KC, (kz+1)*KC) into f32 partial plane C + kz*sCk (ldc = N).
// Partials summed (+bias) by skred_k. Replaces the 64/32-block ragged
// launches that ran at 2.5% occupancy.
// ---------------------------------------------------------------------------
template<int NPASS>
__global__ __launch_bounds__(256, 2) void gemm_bf16_sk_k(
    int N, int KC,
    const unsigned short* __restrict__ A2, int lda2, int aLo,
    const unsigned short* __restrict__ B2, int ldb2, int bLo,
    float* __restrict__ C, long long sCk)
{
    constexpr int ST = 40;
    __shared__ unsigned short Ah[128 * ST];
    __shared__ unsigned short Bh[128 * ST];
    __shared__ unsigned short Al[128 * ST];
    __shared__ unsigned short Bl[128 * ST];

    const int t    = threadIdx.x;
    const int m0   = blockIdx.y * 128;
    const int n0   = blockIdx.x * 128;
    const int kbeg = blockIdx.z * KC;
    const int lane = t & 63, wave = t >> 6;
    const int wm   = (wave >> 1) * 64, wn = (wave & 1) * 64;
    const int lr   = lane & 15, quad = lane >> 4;

    f32x4 acc[4][4];
    #pragma unroll
    for (int i = 0; i < 4; ++i)
        #pragma unroll
        for (int j = 0; j < 4; ++j) acc[i][j] = (f32x4){0.f, 0.f, 0.f, 0.f};

    const int srow = t >> 2;
    const int scol = (t & 3) * 8;

    for (int k0 = kbeg; k0 < kbeg + KC; k0 += 32) {
        __syncthreads();
        #pragma unroll
        for (int half = 0; half < 2; ++half) {
            int r = srow + half * 64;
            const unsigned short* pA = A2 + (long long)(m0 + r) * lda2 + k0 + scol;
            *(uint4*)&Ah[r * ST + scol] = *(const uint4*)pA;
            if (NPASS == 3)
                *(uint4*)&Al[r * ST + scol] = *(const uint4*)(pA + aLo);
            int rb = n0 + r;
            uint4 vh = {0u, 0u, 0u, 0u}, vl = {0u, 0u, 0u, 0u};
            if (rb < N) {
                const unsigned short* pB = B2 + (long long)rb * ldb2 + k0 + scol;
                vh = *(const uint4*)pB;
                if (NPASS == 3) vl = *(const uint4*)(pB + bLo);
            }
            *(uint4*)&Bh[r * ST + scol] = vh;
            if (NPASS == 3) *(uint4*)&Bl[r * ST + scol] = vl;
        }
        __syncthreads();

        bf16x8 ah[4], bh[4], al[4], bl[4];
        #pragma unroll
        for (int i = 0; i < 4; ++i) {
            int ra = (wm + i * 16 + lr) * ST + quad * 8;
            int rb = (wn + i * 16 + lr) * ST + quad * 8;
            ah[i] = *(const bf16x8*)&Ah[ra];
            bh[i] = *(const bf16x8*)&Bh[rb];
            if (NPASS == 3) {
                al[i] = *(const bf16x8*)&Al[ra];
                bl[i] = *(const bf16x8*)&Bl[rb];
            }
        }
        #pragma unroll
        for (int mi = 0; mi < 4; ++mi)
            #pragma unroll
            for (int ni = 0; ni < 4; ++ni) {
                acc[mi][ni] = __builtin_amdgcn_mfma_f32_16x16x32_bf16(
                    ah[mi], bh[ni], acc[mi][ni], 0, 0, 0);
                if (NPASS == 3) {
                    acc[mi][ni] = __builtin_amdgcn_mfma_f32_16x16x32_bf16(
                        al[mi], bh[ni], acc[mi][ni], 0, 0, 0);
                    acc[mi][ni] = __builtin_amdgcn_mfma_f32_16x16x32_bf16(
                        ah[mi], bl[ni], acc[mi][ni], 0, 0, 0);
                }
            }
    }

    float* Cc = C + (long long)blockIdx.z * sCk;
    #pragma unroll
    for (int mi = 0; mi < 4; ++mi)
        #pragma unroll
        for (int ni = 0; ni < 4; ++ni) {
            int col = n0 + wn + ni * 16 + lr;
            if (col >= N) continue;
            #pragma unroll
            for (int r = 0; r < 4; ++r) {
                int row = m0 + wm + mi * 16 + quad * 4 + r;
                Cc[(long long)row * N + col] = acc[mi][ni][r];
            }
        }
}

__global__ __launch_bounds__(256) void skred_k(
    const float* __restrict__ P, long long sCk, int nchunk,
    const float* __restrict__ bias, int ncol,
    float* __restrict__ outp, long long n)
{
    long long idx = (long long)blockIdx.x * 256 + threadIdx.x;
    if (idx >= n) return;
    float s = 0.f;
    for (int c = 0; c < nchunk; ++c) s += P[c * sCk + idx];
    if (bias) s += bias[(int)(idx % ncol)];
    outp[idx] = s;
}

// ---------------------------------------------------------------------------
// Fused SSD intra-chunk MFMA kernel, v4.
// Per (b,h): Y[l,p] = sum_{s<=l} W[l,s]*XC[s,p];
// W = G*exp(cAl-cAs)*dt[s], with D-skip folded in: W[l,l] += D[h].
// X staged once per block into LDS via global_load_lds, triple-buffered,
// depth-2 prefetch, counted vmcnt(4) + raw s_barrier. W-gen double-buffer +
// single barrier. grid (4 = row-tile pairs, 16 h, 8 b), block 256.
// ---------------------------------------------------------------------------
__global__ __launch_bounds__(256, 2) void ssd_mfma_k(
    const float* __restrict__ G, const float* __restrict__ CUMA,
    const float* __restrict__ DT, const unsigned short* __restrict__ XCT2,
    const float* __restrict__ Z, const float* __restrict__ Dv,
    unsigned short* __restrict__ YS2)
{
    __shared__ unsigned short Xh[3][128 * 32];
    __shared__ unsigned short Xl[3][128 * 32];
    __shared__ unsigned short Wh[2][64 * 32];
    __shared__ unsigned short Wl[2][64 * 32];
    __shared__ float Cs[512];
    __shared__ float Ds[512];
    const int q = blockIdx.x;
    const int h = blockIdx.y, b = blockIdx.z;
    const int t = threadIdx.x;
    const int lane = t & 63, wave = t >> 6;
    const int lr = lane & 15, quad = lane >> 4;

    const float* cbase = CUMA + (b * 16 + h) * 512;
    const float* dtb = DT + (long long)b * 512 * 16 + h;
    for (int s = t; s < 512; s += 256) {
        Cs[s] = cbase[s];
        Ds[s] = dtb[(long long)s * 16];
    }
    const float Dh = Dv[h];

    const int wr = t >> 2;                        // W-gen row 0..63
    const int sw = t & 3;                         // logical 16B slot 0..3
    const int wbase = wr * 32 + ((sw ^ ((wr >> 1) & 3)) << 3);
    const int frow = wave * 16 + lr;              // W frag row 0..63
    const int fbase = frow * 32 + ((quad ^ ((frow >> 1) & 3)) << 3);
    // X staging (GEMM-identical geometry: 128 rows x 32 shorts):
    const int drow  = lane >> 2;                  // row within 16-row chunk
    const int dcswz = (((lane & 3) ^ ((lane >> 2) & 3) ^ ((lane >> 4) & 3)) << 3);
    const int xsw   = ((quad ^ ((lr & 3) ^ ((lr >> 2) & 3))) << 3);
    const unsigned short* XB = XCT2 + (long long)b * 2097152
                             + (long long)(h * 128) * 1024;
    __syncthreads();

    for (int ph = 0; ph < 2; ++ph) {
        const int mt = ph ? q : 7 - q;            // heavy row-tile first
        const int m0 = mt * 64;
        const int nt = (m0 >> 5) + 2;             // k-tiles = kend/32
        const int lglob = m0 + wr;
        const float cAl = Cs[lglob];
        const float* grow = G + ((long long)(b * 512 + lglob)) * 512;

        float pg[8], pc[8], pd[8];
        auto gen_load = [&](int k0g) {
            const int sb = k0g + sw * 8;
            float4 g0 = *(const float4*)(grow + sb);
            float4 g1 = *(const float4*)(grow + sb + 4);
            float4 c0 = *(const float4*)&Cs[sb];
            float4 c1 = *(const float4*)&Cs[sb + 4];
            float4 d0 = *(const float4*)&Ds[sb];
            float4 d1 = *(const float4*)&Ds[sb + 4];
            pg[0] = g0.x; pg[1] = g0.y; pg[2] = g0.z; pg[3] = g0.w;
            pg[4] = g1.x; pg[5] = g1.y; pg[6] = g1.z; pg[7] = g1.w;
            pc[0] = c0.x; pc[1] = c0.y; pc[2] = c0.z; pc[3] = c0.w;
            pc[4] = c1.x; pc[5] = c1.y; pc[6] = c1.z; pc[7] = c1.w;
            pd[0] = d0.x; pd[1] = d0.y; pd[2] = d0.z; pd[3] = d0.w;
            pd[4] = d1.x; pd[5] = d1.y; pd[6] = d1.z; pd[7] = d1.w;
        };
        auto gen_finish = [&](int k0g, int buf) {
            const int sb = k0g + sw * 8;
            const bool edge = (k0g + 32 > m0);    // tile touches causal edge
            unsigned short hv[8], lv[8];
            #pragma unroll
            for (int e = 0; e < 8; ++e) {
                float w = pg[e] * __expf(cAl - pc[e]) * pd[e];
                if (edge) {
                    int sg = sb + e;
                    w = (sg <= lglob) ? w : 0.f;  // select AFTER: kills inf/nan
                    if (sg == lglob) w += Dh;
                }
                unsigned short hi = bf16_rne(w);
                hv[e] = hi;
                lv[e] = bf16_rne(w - bf16_tof(hi));
            }
            *(uint4*)&Wh[buf][wbase] = *(uint4*)hv;
            *(uint4*)&Wl[buf][wbase] = *(uint4*)lv;
        };
        auto stageX = [&](int k0, int buf) {
            #pragma unroll
            for (int j = 0; j < 2; ++j) {
                int rr = wave * 32 + j * 16;      // chunk base row (chan)
                const unsigned short* gX =
                    XB + (long long)(rr + drow) * 1024 + k0 + dcswz;
                async_ld16(gX,       &Xh[buf][rr * 32]);
                async_ld16(gX + 512, &Xl[buf][rr * 32]);
            }
        };

        f32x4 acc[8];
        #pragma unroll
        for (int j = 0; j < 8; ++j) acc[j] = (f32x4){0.f, 0.f, 0.f, 0.f};

        // prologue: G loads first, then async X stages (so gen_finish's
        // G-wait leaves the younger stage loads in flight)
        gen_load(0);
        stageX(0, 0);
        if (nt > 1) stageX(32, 1);
        gen_finish(0, 0);
        if (nt > 1) asm volatile("s_waitcnt vmcnt(4)" ::: "memory");
        else        asm volatile("s_waitcnt vmcnt(0)" ::: "memory");
        asm volatile("s_waitcnt lgkmcnt(0)" ::: "memory");
        __builtin_amdgcn_s_barrier();

        for (int it = 0; it < nt; ++it) {
            const int xb = it % 3;
            const int wb = it & 1;
            if (it + 1 < nt) gen_load((it + 1) << 5);
            if (it + 2 < nt) stageX((it + 2) << 5, (it + 2) % 3);

            bf16x8 ah = *(const bf16x8*)&Wh[wb][fbase];
            bf16x8 al = *(const bf16x8*)&Wl[wb][fbase];
            const unsigned short* xhp = &Xh[xb][0];
            const unsigned short* xlp = &Xl[xb][0];
            #pragma unroll
            for (int ni = 0; ni < 8; ++ni) {
                int base = (ni * 16 + lr) * 32 + xsw;
                bf16x8 bh = *(const bf16x8*)&xhp[base];
                bf16x8 bl = *(const bf16x8*)&xlp[base];
                acc[ni] = __builtin_amdgcn_mfma_f32_16x16x32_bf16(
                    ah, bh, acc[ni], 0, 0, 0);
                acc[ni] = __builtin_amdgcn_mfma_f32_16x16x32_bf16(
                    al, bh, acc[ni], 0, 0, 0);
                acc[ni] = __builtin_amdgcn_mfma_f32_16x16x32_bf16(
                    ah, bl, acc[ni], 0, 0, 0);
            }
            if (it + 1 < nt) gen_finish((it + 1) << 5, wb ^ 1);
            if (it + 2 < nt) asm volatile("s_waitcnt vmcnt(4)" ::: "memory");
            else             asm volatile("s_waitcnt vmcnt(0)" ::: "memory");
            asm volatile("s_waitcnt lgkmcnt(0)" ::: "memory");
            __builtin_amdgcn_s_barrier();
        }

        const int row0 = m0 + wave * 16 + quad * 4;
        #pragma unroll
        for (int ni = 0; ni < 8; ++ni) {
            int chan = h * 128 + ni * 16 + lr;
            #pragma unroll
            for (int r = 0; r < 4; ++r) {
                long long row = (long long)(b * 512 + row0 + r);
                float zz = Z[row * 2048 + chan];
                float y = acc[ni][r] * (zz / (1.f + expf(-zz)));
                store_pair(YS2, row, 2048, chan, y);
            }
        }
    }
}

// ---------------------------------------------------------------------------
// Tiled f32 GEMM (only for the small batched G = Cm @ Bm^T)
// ---------------------------------------------------------------------------
__global__ __launch_bounds__(256) void gemm_f32_k(
    int M, int N, int K,
    const float* __restrict__ A, int lda, long long sAb,
    const float* __restrict__ B, int ldb, long long sBb,
    float* __restrict__ C, int ldc, long long sCb)
{
    __shared__ float As[32][132];
    __shared__ float Bs[32][132];
    const int z = blockIdx.z;
    A += z * sAb; B += z * sBb; C += z * sCb;
    const int n0 = blockIdx.x * 128;
    const int m0 = blockIdx.y * 128;
    const int t  = threadIdx.x;
    const int tx = t & 15, ty = t >> 4;

    float acc[4][16];
    #pragma unroll
    for (int a = 0; a < 4; ++a)
        #pragma unroll
        for (int q = 0; q < 16; ++q) acc[a][q] = 0.f;

    const int ka = (t & 7) << 2;
    const int ra = t >> 3;

    for (int k0 = 0; k0 < K; k0 += 32) {
        __syncthreads();
        #pragma unroll
        for (int i = 0; i < 4; ++i) {
            int row = m0 + ra + i * 32;
            float4 v = *(const float4*)(A + (long long)row * lda + (k0 + ka));
            As[ka + 0][ra + i * 32] = v.x;
            As[ka + 1][ra + i * 32] = v.y;
            As[ka + 2][ra + i * 32] = v.z;
            As[ka + 3][ra + i * 32] = v.w;
            int rowb = n0 + ra + i * 32;
            float4 w = *(const float4*)(B + (long long)rowb * ldb + (k0 + ka));
            Bs[ka + 0][ra + i * 32] = w.x;
            Bs[ka + 1][ra + i * 32] = w.y;
            Bs[ka + 2][ra + i * 32] = w.z;
            Bs[ka + 3][ra + i * 32] = w.w;
        }
        __syncthreads();
        #pragma unroll
        for (int kk = 0; kk < 32; ++kk) {
            float a[8], bm[8];
            *(float4*)&a[0]  = *(const float4*)&As[kk][ty * 4];
            *(float4*)&a[4]  = *(const float4*)&As[kk][64 + ty * 4];
            *(float4*)&bm[0] = *(const float4*)&Bs[kk][tx * 4];
            *(float4*)&bm[4] = *(const float4*)&Bs[kk][64 + tx * 4];
            #pragma unroll
            for (int ri = 0; ri < 2; ++ri)
                #pragma unroll
                for (int ci = 0; ci < 2; ++ci)
                    #pragma unroll
                    for (int i = 0; i < 4; ++i)
                        #pragma unroll
                        for (int j = 0; j < 4; ++j)
                            acc[ri * 2 + ci][i * 4 + j] =
                                fmaf(a[ri * 4 + i], bm[ci * 4 + j], acc[ri * 2 + ci][i * 4 + j]);
        }
    }
    #pragma unroll
    for (int ri = 0; ri < 2; ++ri)
        #pragma unroll
        for (int ci = 0; ci < 2; ++ci) {
            int colb = n0 + ci * 64 + tx * 4;
            #pragma unroll
            for (int i = 0; i < 4; ++i) {
                int row = m0 + ri * 64 + ty * 4 + i;
                *(float4*)(C + (long long)row * ldc + colb) =
                    *(float4*)&acc[ri * 2 + ci][i * 4];
            }
        }
}

// ---------------------------------------------------------------------------
// Elementwise / norm kernels
// ---------------------------------------------------------------------------
__global__ __launch_bounds__(256) void pairify_k(
    const float* __restrict__ src, unsigned short* __restrict__ dst,
    int k_log2, long long n)
{
    long long idx = (long long)blockIdx.x * 256 + threadIdx.x;
    if (idx >= n) return;
    long long r = idx >> k_log2;
    int c = (int)(idx & ((1 << k_log2) - 1));
    store_pair(dst, r, 1 << k_log2, c, src[idx]);
}

__global__ __launch_bounds__(256) void layernorm_k(
    const float* __restrict__ in, float* __restrict__ out,
    const float* __restrict__ w, const float* __restrict__ b,
    int width, int rows_per_b, long long in_bstride)
{
    long long r = blockIdx.x;
    const float* x = in + (r / rows_per_b) * in_bstride + (r % rows_per_b) * (long long)width;
    int t = threadIdx.x;
    float s = 0.f;
    for (int c = t; c < width; c += 256) s += x[c];
    s = block_sum256(s);
    float m = s / (float)width;
    float vs = 0.f;
    for (int c = t; c < width; c += 256) { float d = x[c] - m; vs += d * d; }
    vs = block_sum256(vs);
    float rs = 1.f / sqrtf(vs / (float)width + 1e-5f);
    float* o = out + r * (long long)width;
    for (int c = t; c < width; c += 256) o[c] = (x[c] - m) * rs * w[c] + b[c];
}

__global__ __launch_bounds__(256) void layernorm_pair_k(
    const float* __restrict__ in, unsigned short* __restrict__ out2,
    const float* __restrict__ w, const float* __restrict__ b,
    int width, int rows_per_b, long long in_bstride)
{
    long long r = blockIdx.x;
    const float* x = in + (r / rows_per_b) * in_bstride + (r % rows_per_b) * (long long)width;
    int t = threadIdx.x;
    float s = 0.f;
    for (int c = t; c < width; c += 256) s += x[c];
    s = block_sum256(s);
    float m = s / (float)width;
    float vs = 0.f;
    for (int c = t; c < width; c += 256) { float d = x[c] - m; vs += d * d; }
    vs = block_sum256(vs);
    float rs = 1.f / sqrtf(vs / (float)width + 1e-5f);
    for (int c = t; c < width; c += 256)
        store_pair(out2, r, width, c, (x[c] - m) * rs * w[c] + b[c]);
}

__global__ __launch_bounds__(256) void rmsnorm_pair_k(
    const float* __restrict__ in, unsigned short* __restrict__ out2,
    const float* __restrict__ w, int width)
{
    long long r = blockIdx.x;
    const float* x = in + r * (long long)width;
    int t = threadIdx.x;
    float s = 0.f;
    for (int c = t; c < width; c += 256) { float v = x[c]; s += v * v; }
    s = block_sum256(s);
    float rs = 1.f / sqrtf(s / (float)width + 1e-5f);
    for (int c = t; c < width; c += 256)
        store_pair(out2, r, width, c, x[c] * rs * w[c]);
}

// Softmax over 512-wide rows, f32 in -> split-pair out IN-PLACE (same bytes).
__global__ __launch_bounds__(256) void softmax_pair_k(float* __restrict__ S,
                                                      unsigned short* __restrict__ P2)
{
    long long r = blockIdx.x;
    float* x = S + r * 512;
    unsigned short* p = P2 + r * 1024;
    int t = threadIdx.x;
    float v0 = x[t], v1 = x[t + 256];
    float mx = block_max256(fmaxf(v0, v1));
    v0 = expf(v0 - mx); v1 = expf(v1 - mx);
    float sum = block_sum256(v0 + v1);
    float inv = 1.f / sum;
    v0 *= inv; v1 *= inv;
    __syncthreads();
    unsigned short h0 = bf16_rne(v0);
    p[t] = h0;       p[512 + t] = bf16_rne(v0 - bf16_tof(h0));
    unsigned short h1 = bf16_rne(v1);
    p[t + 256] = h1; p[512 + t + 256] = bf16_rne(v1 - bf16_tof(h1));
}

// Causal grouped conv with LDS-tile transpose: writes seq-major pairs XC2
// AND chan-major pairs XCT2, both coalesced.
__global__ __launch_bounds__(256) void conv_k(
    const float* __restrict__ XS, const float* __restrict__ W,
    unsigned short* __restrict__ XC2, unsigned short* __restrict__ XCT2)
{
    __shared__ float tile[64][65];
    const int o0  = blockIdx.x * 64;
    const int tt0 = blockIdx.y * 64;
    const int b   = blockIdx.z;
    const int t   = threadIdx.x;

    const int o  = o0 + (t & 63);
    const int g2 = (o >> 1) << 1;
    const float* Wo = W + o * 8;
    float w0 = Wo[0], w1 = Wo[1], w2 = Wo[2], w3 = Wo[3];
    float w4 = Wo[4], w5 = Wo[5], w6 = Wo[6], w7 = Wo[7];
    #pragma unroll
    for (int i = 0; i < 16; ++i) {
        int sl = (t >> 6) + 4 * i;
        int tt = tt0 + sl;
        const float* xb = XS + ((long long)(b * 512 + tt)) * 2048 + g2;
        float acc = w3 * xb[0] + w7 * xb[1];
        if (tt >= 1) acc += w2 * xb[-2048] + w6 * xb[-2047];
        if (tt >= 2) acc += w1 * xb[-4096] + w5 * xb[-4095];
        if (tt >= 3) acc += w0 * xb[-6144] + w4 * xb[-6143];
        tile[sl][t & 63] = acc;
    }
    __syncthreads();
    #pragma unroll
    for (int i = 0; i < 16; ++i) {
        int idx = t + 256 * i;
        int sl = idx >> 6, ol = idx & 63;
        float v = tile[sl][ol];
        unsigned short hi = bf16_rne(v);
        unsigned short lo = bf16_rne(v - bf16_tof(hi));
        long long row = (long long)(b * 512 + tt0 + sl);
        XC2[row * 4096 + o0 + ol] = hi;
        XC2[row * 4096 + 2048 + o0 + ol] = lo;
    }
    #pragma unroll
    for (int i = 0; i < 16; ++i) {
        int idx = t + 256 * i;
        int cl = idx >> 6, s = idx & 63;
        float v = tile[s][cl];
        unsigned short hi = bf16_rne(v);
        unsigned short lo = bf16_rne(v - bf16_tof(hi));
        long long tb = (long long)b * 2097152 + (long long)(o0 + cl) * 1024 + tt0 + s;
        XCT2[tb] = hi;
        XCT2[tb + 512] = lo;
    }
}

__global__ __launch_bounds__(256) void dt_k(
    const float* __restrict__ dtBC, const float* __restrict__ dt_bias, float* __restrict__ DT)
{
    int idx = blockIdx.x * 256 + threadIdx.x;
    int r = idx >> 4, h = idx & 15;
    float xv = dtBC[r * 144 + h] + dt_bias[h];
    DT[idx] = (xv > 20.f) ? xv : log1pf(expf(xv));
}

__global__ __launch_bounds__(64) void cuma_k(
    const float* __restrict__ DT, const float* __restrict__ A_log, float* __restrict__ CUMA)
{
    int h = blockIdx.x, b = blockIdx.y;
    int ln = threadIdx.x;
    float Ah = -expf(A_log[h]);
    float v[8];
    float run = 0.f;
    #pragma unroll
    for (int i = 0; i < 8; ++i) {
        run += Ah * DT[((b * 512) + (ln * 8 + i)) * 16 + h];
        v[i] = run;
    }
    float tot = run;
    float sc = tot;
    #pragma unroll
    for (int o = 1; o <= 32; o <<= 1) {
        float u = __shfl_up(sc, o, 64);
        if (ln >= o) sc += u;
    }
    float excl = sc - tot;
    #pragma unroll
    for (int i = 0; i < 8; ++i)
        CUMA[(b * 16 + h) * 512 + ln * 8 + i] = excl + v[i];
}

// hc = LayerNorm64(G1) -> {-1,+1} as split pairs (lo = 0)
__global__ __launch_bounds__(64) void hc_quant_k(
    const float* __restrict__ G1, const float* __restrict__ w,
    const float* __restrict__ b, unsigned short* __restrict__ HCQ2)
{
    int r = blockIdx.x, ln = threadIdx.x;
    float v = G1[r * 64 + ln];
    float s = v;
    #pragma unroll
    for (int o = 32; o > 0; o >>= 1) s += __shfl_xor(s, o, 64);
    float m = s * (1.f / 64.f);
    float d = v - m;
    float vs = d * d;
    #pragma unroll
    for (int o = 32; o > 0; o >>= 1) vs += __shfl_xor(vs, o, 64);
    vs *= (1.f / 64.f);
    float hc = d * (1.f / sqrtf(vs + 1e-5f)) * w[ln] + b[ln];
    HCQ2[r * 128 + ln] = (hc > 0.f) ? 0x3F80 : 0xBF80;
    HCQ2[r * 128 + 64 + ln] = 0;
}

__global__ __launch_bounds__(256) void dxm_k(
    const float* __restrict__ mtok, const float* __restrict__ e2d, float* __restrict__ dxm)
{
    int c = blockIdx.x * 256 + threadIdx.x;
    float acc = 0.f;
    #pragma unroll
    for (int j = 0; j < 64; ++j) acc = fmaf(mtok[j], e2d[c * 64 + j], acc);
    dxm[c] = acc;
}

__global__ __launch_bounds__(256) void projm_k(
    const float* __restrict__ lnm,
    const float* __restrict__ bWq, const float* __restrict__ bWk, const float* __restrict__ bWv,
    float* __restrict__ qm, float* __restrict__ km, float* __restrict__ vm)
{
    int idx = blockIdx.x * 256 + threadIdx.x;
    int sel = idx >> 10, c = idx & 1023;
    const float* W = (sel == 0) ? bWq : (sel == 1) ? bWk : bWv;
    float* O = (sel == 0) ? qm : (sel == 1) ? km : vm;
    const float* wr = W + (long long)c * 1024;
    float acc = 0.f;
    for (int j = 0; j < 1024; j += 4) {
        float4 a = *(const float4*)(lnm + j);
        float4 w4 = *(const float4*)(wr + j);
        acc = fmaf(a.x, w4.x, fmaf(a.y, w4.y, fmaf(a.z, w4.z, fmaf(a.w, w4.w, acc))));
    }
    O[c] = acc;
}

// Collapsed decoder attention: 1 query/(b,h); keys = 512 visible + mask key x512.
__global__ __launch_bounds__(256) void dec_attn_k(
    const float* __restrict__ Kv, const float* __restrict__ Vv,
    const float* __restrict__ qm, const float* __restrict__ km,
    const float* __restrict__ vm, float* __restrict__ OBm)
{
    int h = blockIdx.x, b = blockIdx.y;
    int t = threadIdx.x;
    __shared__ __align__(16) float qs[256];
    __shared__ __align__(16) float ps[512];
    qs[t] = qm[h * 256 + t];
    __syncthreads();
    float s[2];
    #pragma unroll
    for (int i = 0; i < 2; ++i) {
        int r = t + i * 256;
        const float* kr = Kv + ((long long)(b * 512 + r)) * 1024 + h * 256;
        float acc = 0.f;
        for (int c = 0; c < 256; c += 4) {
            float4 k4 = *(const float4*)(kr + c);
            float4 q4 = *(const float4*)(qs + c);
            acc = fmaf(k4.x, q4.x, fmaf(k4.y, q4.y, fmaf(k4.z, q4.z, fmaf(k4.w, q4.w, acc))));
        }
        s[i] = acc * (1.f / 16.f);
    }
    float accm = 0.f;
    for (int c = 0; c < 256; c += 4) {
        float4 k4 = *(const float4*)(km + h * 256 + c);
        float4 q4 = *(const float4*)(qs + c);
        accm = fmaf(k4.x, q4.x, fmaf(k4.y, q4.y, fmaf(k4.z, q4.z, fmaf(k4.w, q4.w, accm))));
    }
    float smv = accm * (1.f / 16.f);
    float mx = block_max256(fmaxf(fmaxf(s[0], s[1]), smv));
    float p0 = expf(s[0] - mx), p1 = expf(s[1] - mx);
    ps[t] = p0; ps[t + 256] = p1;
    float pm = expf(smv - mx) * 512.f;
    float sum = block_sum256(p0 + p1) + pm;
    float inv = 1.f / sum;
    __syncthreads();
    float o = pm * vm[h * 256 + t];
    const float* vcol = Vv + (long long)b * 512 * 1024 + h * 256 + t;
    for (int j = 0; j < 512; ++j)
        o = fmaf(ps[j], vcol[(long long)j * 1024], o);
    OBm[b * 1024 + h * 256 + t] = o * inv;
}

__global__ __launch_bounds__(256) void ydm_k(
    const float* __restrict__ OBm, const float* __restrict__ bWo,
    const float* __restrict__ bWo_b, const float* __restrict__ dxm,
    float* __restrict__ ydm)
{
    int idx = blockIdx.x * 256 + threadIdx.x;
    int b = idx >> 10, c = idx & 1023;
    const float* ar = OBm + b * 1024;
    const float* wr = bWo + (long long)c * 1024;
    float acc = 0.f;
    for (int j = 0; j < 1024; j += 4) {
        float4 a = *(const float4*)(ar + j);
        float4 w4 = *(const float4*)(wr + j);
        acc = fmaf(a.x, w4.x, fmaf(a.y, w4.y, fmaf(a.z, w4.z, fmaf(a.w, w4.w, acc))));
    }
    ydm[idx] = acc + bWo_b[c] + dxm[c];
}

__global__ __launch_bounds__(256) void outm_k(
    const float* __restrict__ ydm, const float* __restrict__ dout_W,
    const float* __restrict__ dout_b, float* __restrict__ outm)
{
    int idx = blockIdx.x * 256 + threadIdx.x;
    int b = idx >> 11, c = idx & 2047;
    const float* ar = ydm + b * 1024;
    const float* wr = dout_W + (long long)c * 1024;
    float acc = 0.f;
    for (int j = 0; j < 1024; j += 4) {
        float4 a = *(const float4*)(ar + j);
        float4 w4 = *(const float4*)(wr + j);
        acc = fmaf(a.x, w4.x, fmaf(a.y, w4.y, fmaf(a.z, w4.z, fmaf(a.w, w4.w, acc))));
    }
    outm[idx] = acc + dout_b[c];
}

__global__ __launch_bounds__(256) void bcast_k(
    const float* __restrict__ outm, float* __restrict__ out)
{
    int idx = blockIdx.x * 256 + threadIdx.x;
    int c4 = idx & 511;
    int b = idx >> 18;
    ((float4*)out)[idx] = ((const float4*)outm)[b * 512 + c4];
}

// ---------------------------------------------------------------------------
// Host-side launcher
// ---------------------------------------------------------------------------
static inline void pairify(hipStream_t s, const float* src, unsigned short* dst,
                           int k_log2, long long n)
{
    pairify_k<<<(int)((n + 255) / 256), 256, 0, s>>>(src, dst, k_log2, n);
}

extern "C" void kernel_launch(void* const* d_in, const int* in_sizes, int n_in,
                              void* d_out, int out_size, void* d_ws, size_t ws_size,
                              hipStream_t stream)
{
    const float* x       = (const float*)d_in[0];
    const float* ln0_w   = (const float*)d_in[1];
    const float* ln0_b   = (const float*)d_in[2];
    const float* in_W    = (const float*)d_in[3];
    const float* rms_w   = (const float*)d_in[4];
    const float* exp_W   = (const float*)d_in[5];
    const float* conv_W  = (const float*)d_in[6];
    const float* xproj_W = (const float*)d_in[7];
    const float* dt_bias = (const float*)d_in[8];
    const float* A_log   = (const float*)d_in[9];
    const float* Dv      = (const float*)d_in[10];
    const float* outp_W  = (const float*)d_in[11];
    const float* outp_b  = (const float*)d_in[12];
    const float* n1_w    = (const float*)d_in[13];
    const float* n1_b    = (const float*)d_in[14];
    const float* aWq     = (const float*)d_in[15];
    const float* aWk     = (const float*)d_in[16];
    const float* aWv     = (const float*)d_in[17];
    const float* aWo     = (const float*)d_in[18];
    const float* aWo_b   = (const float*)d_in[19];
    const float* h_W     = (const float*)d_in[20];
    const float* h_b     = (const float*)d_in[21];
    const float* h_lnw   = (const float*)d_in[22];
    const float* h_lnb   = (const float*)d_in[23];
    const float* mtok    = (const float*)d_in[24];
    const float* e2d_W   = (const float*)d_in[25];
    const float* dn_w    = (const float*)d_in[26];
    const float* dn_b    = (const float*)d_in[27];
    const float* bWq     = (const float*)d_in[28];
    const float* bWk     = (const float*)d_in[29];
    const float* bWv     = (const float*)d_in[30];
    const float* bWo     = (const float*)d_in[31];
    const float* bWo_b   = (const float*)d_in[32];
    const float* dout_W  = (const float*)d_in[33];
    const float* dout_b  = (const float*)d_in[34];

    float* ws  = (float*)d_ws;
    float* out = (float*)d_out;

    float* S1 = ws;
    float* S2 = ws + 8388608;
    float* S3 = ws + 16777216;
    float* S4 = ws + 25165824;
    float* S5 = ws + 33554432;
    float* S6 = ws + 37748736;
    float* S7 = ws + 41943040;
    float* S8 = ws + 46137344;
    float* S9 = ws + 50331648;
    float* SP = ws + 54525952;

    unsigned short* XV2     = (unsigned short*)S1;
    unsigned short* exp_W2  = (unsigned short*)S1;
    unsigned short* XCT2    = (unsigned short*)S1;
    float*          SA      = S1;
    unsigned short* P2      = (unsigned short*)S1;
    float*          Kv      = S1;
    float*          Vv      = S1 + 4194304;
    unsigned short* in_W2   = (unsigned short*)S2;
    float*          XS      = S2;
    unsigned short* YS2     = (unsigned short*)S2;
    float*          PX      = S2;            // xproj split-K partials (XS dead)
    unsigned short* XC2     = (unsigned short*)S3;
    unsigned short* outp_W2 = (unsigned short*)S3;
    float*          PH      = S3;            // hW split-K partials
    float*          DXV     = S3;
    unsigned short* LNDXV2  = (unsigned short*)(S3 + 4194304);
    float*          Z       = S4;
    unsigned short* aWq2    = (unsigned short*)S4;
    unsigned short* aWk2    = (unsigned short*)S4 + 2097152;
    unsigned short* aWv2    = (unsigned short*)S4 + 4194304;
    unsigned short* aWo2    = (unsigned short*)S4 + 6291456;
    unsigned short* bWk2    = (unsigned short*)S4 + 8388608;
    unsigned short* bWv2    = (unsigned short*)S4 + 10485760;
    float*          T       = S5;
    unsigned short* QA2     = (unsigned short*)S5;
    unsigned short* Y22     = (unsigned short*)S5;
    unsigned short* HR2     = (unsigned short*)S6;
    float*          Y1      = S6;
    unsigned short* LNY2    = (unsigned short*)S7;
    unsigned short* OA2     = (unsigned short*)S7;
    unsigned short* KA2     = (unsigned short*)S8;
    unsigned short* VT2     = (unsigned short*)S9;

    float* dtBC = SP;
    float* DT   = SP + 589824;
    float* CUMA = SP + 655360;
    float* G    = SP + 720896;
    unsigned short* xprojW2 = (unsigned short*)(SP + 2818048);
    unsigned short* hW2     = (unsigned short*)(SP + 3112960);
    unsigned short* e2dW2   = (unsigned short*)(SP + 3178496);
    float* G1   = SP + 720896;
    unsigned short* HCQ2 = (unsigned short*)(SP + 983040);
    float* dxm  = SP + 1245184;
    float* lnm  = SP + 1246208;
    float* qm   = SP + 1247232;
    float* km   = SP + 1248256;
    float* vm   = SP + 1249280;
    float* OBm  = SP + 1250304;
    float* ydm  = SP + 1258496;
    float* outm = SP + 1266688;

    const long long LL0 = 0;
    #define G3D(OUTM, GX, GY, GZ, ...) \
        gemm_bf16_k<3, OUTM, true><<<dim3(GX, GY, GZ), 256, 0, stream>>>(__VA_ARGS__)
    #define G1D(OUTM, GX, GY, GZ, ...) \
        gemm_bf16_k<1, OUTM, true><<<dim3(GX, GY, GZ), 256, 0, stream>>>(__VA_ARGS__)

    // ---- weight prep (phase A) ----
    pairify(stream, in_W,    in_W2,   11, 1024LL * 2048);
    pairify(stream, xproj_W, xprojW2, 11, 144LL * 2048);
    pairify(stream, h_W,     hW2,     10, 64LL * 1024);
    pairify(stream, e2d_W,   e2dW2,    6, 1024LL * 64);

    // ---- encoder trunk ----
    layernorm_pair_k<<<4096, 256, 0, stream>>>(x, XV2, ln0_w, ln0_b, 2048, 512,
                                               (long long)1024 * 2048);
    G3D(0, 8, 32, 1, 4096, 1024, 2048, XV2, 4096, 2048, LL0, LL0,
        in_W2, 4096, 2048, LL0, LL0, T, 1024, 0, LL0, LL0,
        nullptr, nullptr, 0, 1.f, 1);
    pairify(stream, exp_W, exp_W2, 10, 4096LL * 1024);   // S1 (XV2 dead)
    rmsnorm_pair_k<<<4096, 256, 0, stream>>>(T, HR2, rms_w, 1024);
    G3D(0, 16, 32, 1, 4096, 2048, 1024, HR2, 2048, 1024, LL0, LL0,
        exp_W2, 2048, 1024, LL0, LL0, XS, 2048, 0, LL0, LL0,
        nullptr, nullptr, 0, 1.f, 1);
    G3D(0, 16, 32, 1, 4096, 2048, 1024, HR2, 2048, 1024, LL0, LL0,
        exp_W2 + 2048LL * 2048, 2048, 1024, LL0, LL0, Z, 2048, 0, LL0, LL0,
        nullptr, nullptr, 0, 1.f, 1);
    conv_k<<<dim3(32, 8, 8), 256, 0, stream>>>(XS, conv_W, XC2, XCT2);
    // xproj: M=4096, N=144, K=2048 -> split-K x8 (512 blocks), partials in
    // PX (=S2, XS dead; consumed before YS2 overwrites S2)
    gemm_bf16_sk_k<3><<<dim3(2, 32, 8), 256, 0, stream>>>(
        144, 256, XC2, 4096, 2048, xprojW2, 4096, 2048, PX, 589824LL);
    skred_k<<<2304, 256, 0, stream>>>(PX, 589824LL, 8, nullptr, 144,
                                      dtBC, 589824LL);
    dt_k<<<256, 256, 0, stream>>>(dtBC, dt_bias, DT);
    cuma_k<<<dim3(16, 8), 64, 0, stream>>>(DT, A_log, CUMA);
    gemm_f32_k<<<dim3(4, 4, 8), 256, 0, stream>>>(
        512, 512, 64, dtBC + 80, 144, (long long)512 * 144,
        dtBC + 16, 144, (long long)512 * 144, G, 512, (long long)512 * 512);
    ssd_mfma_k<<<dim3(4, 16, 8), 256, 0, stream>>>(G, CUMA, DT, XCT2, Z, Dv, YS2);

    // ---- weight prep (phase B: S3/S4 now dead) ----
    pairify(stream, outp_W, outp_W2, 11, 1024LL * 2048);
    pairify(stream, aWq, aWq2, 10, 1024LL * 1024);
    pairify(stream, aWk, aWk2, 10, 1024LL * 1024);
    pairify(stream, aWv, aWv2, 10, 1024LL * 1024);
    pairify(stream, aWo, aWo2, 10, 1024LL * 1024);
    pairify(stream, bWk, bWk2, 10, 1024LL * 1024);
    pairify(stream, bWv, bWv2, 10, 1024LL * 1024);

    G3D(0, 8, 32, 1, 4096, 1024, 2048, YS2, 4096, 2048, LL0, LL0,
        outp_W2, 4096, 2048, LL0, LL0, Y1, 1024, 0, LL0, LL0,
        outp_b, T, 1024, 1.f, 1);

    // ---- encoder attention (all MFMA) ----
    layernorm_pair_k<<<4096, 256, 0, stream>>>(Y1, LNY2, n1_w, n1_b, 1024, 4096, LL0);
    G3D(1, 8, 32, 1, 4096, 1024, 1024, LNY2, 2048, 1024, LL0, LL0,
        aWq2, 2048, 1024, LL0, LL0, QA2, 2048, 1024, LL0, LL0,
        nullptr, nullptr, 0, 1.f, 1);
    G3D(1, 8, 32, 1, 4096, 1024, 1024, LNY2, 2048, 1024, LL0, LL0,
        aWk2, 2048, 1024, LL0, LL0, KA2, 2048, 1024, LL0, LL0,
        nullptr, nullptr, 0, 1.f, 1);
    G3D(2, 8, 32, 1, 4096, 1024, 1024, LNY2, 2048, 1024, LL0, LL0,
        aWv2, 2048, 1024, LL0, LL0, VT2, 1024, 512, (long long)1024 * 1024, LL0,
        nullptr, nullptr, 0, 1.f, 1);
    G3D(0, 4, 4, 32, 512, 512, 256,
        QA2, 2048, 1024, (long long)512 * 2048, 256,
        KA2, 2048, 1024, (long long)512 * 2048, 256,
        SA, 512, 0, (long long)4 * 512 * 512, (long long)512 * 512,
        nullptr, nullptr, 0, 1.f / 16.f, 4);
    softmax_pair_k<<<16384, 256, 0, stream>>>(SA, P2);
    G3D(1, 2, 4, 32, 512, 256, 512,
        P2, 1024, 512, (long long)4 * 512 * 1024, (long long)512 * 1024,
        VT2, 1024, 512, (long long)1024 * 1024, (long long)256 * 1024,
        OA2, 2048, 1024, (long long)512 * 2048, 256,
        nullptr, nullptr, 0, 1.f, 4);
    G3D(1, 8, 32, 1, 4096, 1024, 1024, OA2, 2048, 1024, LL0, LL0,
        aWo2, 2048, 1024, LL0, LL0, Y22, 2048, 1024, LL0, LL0,
        aWo_b, Y1, 1024, 1.f, 1);

    // ---- quantize: G1 = Y22 @ hW^T + h_b (M=4096, N=64, K=1024) ----
    // split-K x8 (256 blocks), partials in PH (=S3, outp_W2 dead, DXV later)
    gemm_bf16_sk_k<3><<<dim3(1, 32, 8), 256, 0, stream>>>(
        64, 128, Y22, 2048, 1024, hW2, 2048, 1024, PH, 262144LL);
    skred_k<<<1024, 256, 0, stream>>>(PH, 262144LL, 8, h_b, 64,
                                      G1, 262144LL);
    hc_quant_k<<<4096, 64, 0, stream>>>(G1, h_lnw, h_lnb, HCQ2);

    // ---- decoder (collapsed masked rows) ----
    G3D(0, 8, 32, 1, 4096, 1024, 64, HCQ2, 128, 64, LL0, LL0,
        e2dW2, 128, 64, LL0, LL0, DXV, 1024, 0, LL0, LL0,
        nullptr, nullptr, 0, 1.f, 1);
    dxm_k<<<4, 256, 0, stream>>>(mtok, e2d_W, dxm);
    layernorm_k<<<1, 256, 0, stream>>>(dxm, lnm, dn_w, dn_b, 1024, 1, LL0);
    layernorm_pair_k<<<4096, 256, 0, stream>>>(DXV, LNDXV2, dn_w, dn_b, 1024, 4096, LL0);
    projm_k<<<12, 256, 0, stream>>>(lnm, bWq, bWk, bWv, qm, km, vm);
    G1D(0, 8, 32, 1, 4096, 1024, 1024, LNDXV2, 2048, 1024, LL0, LL0,
        bWk2, 2048, 1024, LL0, LL0, Kv, 1024, 0, LL0, LL0,
        nullptr, nullptr, 0, 1.f, 1);
    G1D(0, 8, 32, 1, 4096, 1024, 1024, LNDXV2, 2048, 1024, LL0, LL0,
        bWv2, 2048, 1024, LL0, LL0, Vv, 1024, 0, LL0, LL0,
        nullptr, nullptr, 0, 1.f, 1);
    dec_attn_k<<<dim3(4, 8), 256, 0, stream>>>(Kv, Vv, qm, km, vm, OBm);
    ydm_k<<<32, 256, 0, stream>>>(OBm, bWo, bWo_b, dxm, ydm);
    outm_k<<<64, 256, 0, stream>>>(ydm, dout_W, dout_b, outm);
    bcast_k<<<8192, 256, 0, stream>>>(outm, out);
    #undef G3D
    #undef G1D
}

// Round 5
// 1096.043 us; speedup vs baseline: 1.2832x; 1.0478x over previous
//
#include <hip/hip_runtime.h>

// ---------------------------------------------------------------------------
// B=8, N=1024, CIN=2048, HID=1024, HC=64, LV=512, NH_SSD=16, HD=128, DS=64.
// Encoder rows = 4096. Decoder collapsed to 1 row/batch. All large GEMMs:
// split-bf16 MFMA (x3 passes = f32-grade pre-quantizer; x1 post-quantizer),
// staged via __builtin_amdgcn_global_load_lds width=16 (DIRECT path).
// DIRECT GEMM v3: double-buffered 64KB LDS (2 blocks/CU co-residency = the
// m97-structure TLP that covers vmcnt drain), m97-style vmcnt(0)+barrier,
// source-swizzled staging. 256-block GEMMs get split-K x2 (grid 512) with
// f32 partials + fused reduce epilogues; Q|K and K|V projections merged
// into single N=2048 GEMMs (weight pair-planes are contiguous).
// ---------------------------------------------------------------------------

typedef short bf16x8 __attribute__((ext_vector_type(8)));
typedef float f32x4 __attribute__((ext_vector_type(4)));

__device__ __forceinline__ unsigned short bf16_rne(float f) {
    unsigned u = __float_as_uint(f);
    unsigned r = u + 0x7FFFu + ((u >> 16) & 1u);
    return (unsigned short)(r >> 16);
}
__device__ __forceinline__ float bf16_tof(unsigned short h) {
    return __uint_as_float(((unsigned)h) << 16);
}
__device__ __forceinline__ void store_pair(unsigned short* dst, long long row,
                                           int width, int c, float v) {
    unsigned short hi = bf16_rne(v);
    unsigned short lo = bf16_rne(v - bf16_tof(hi));
    long long base = row * (2LL * width);
    dst[base + c] = hi;
    dst[base + width + c] = lo;
}
// Async global->LDS, 16B per lane. LDS dest = wave-uniform base + lane*16.
__device__ __forceinline__ void async_ld16(const unsigned short* g, unsigned short* l) {
    __builtin_amdgcn_global_load_lds(
        (const __attribute__((address_space(1))) unsigned int*)g,
        (__attribute__((address_space(3))) unsigned int*)l, 16, 0, 0);
}

// ---------------------------------------------------------------------------
// Reduction helpers (blockDim 256)
// ---------------------------------------------------------------------------
__device__ __forceinline__ float block_sum256(float v) {
    #pragma unroll
    for (int o = 32; o > 0; o >>= 1) v += __shfl_xor(v, o, 64);
    __shared__ float sm[4];
    int w = threadIdx.x >> 6;
    __syncthreads();
    if ((threadIdx.x & 63) == 0) sm[w] = v;
    __syncthreads();
    return sm[0] + sm[1] + sm[2] + sm[3];
}
__device__ __forceinline__ float block_max256(float v) {
    #pragma unroll
    for (int o = 32; o > 0; o >>= 1) v = fmaxf(v, __shfl_xor(v, o, 64));
    __shared__ float smx[4];
    int w = threadIdx.x >> 6;
    __syncthreads();
    if ((threadIdx.x & 63) == 0) smx[w] = v;
    __syncthreads();
    return fmaxf(fmaxf(smx[0], smx[1]), fmaxf(smx[2], smx[3]));
}

// ---------------------------------------------------------------------------
// Split-bf16 MFMA GEMM. C[m,n] = alpha * sum_k A[m,k]*B[n,k] (+bias)(+res)
// NPASS=3: hh+lh+hl (f32-grade). NPASS=1: hh only.
// OUT=0: f32 C. OUT=1: split-pair C. OUT=2: transposed split-pair per
// 512-row batch.
// DIRECT=true: global_load_lds staging, double-buffered (64KB @ NPASS=3 ->
//   2 blocks/CU), m97-style vmcnt(0)+barrier then stage-next, source-
//   swizzled for conflict-free b128 (slot q holds chunk q ^ t(row),
//   t(r)=(r&3)^((r>>2)&3)). Requires full tiles and K % 32 == 0.
// DIRECT=false: guarded reg staging (ragged N ok), 2-barrier loop.
// ---------------------------------------------------------------------------
template<int NPASS, int OUT, bool DIRECT>
__global__ __launch_bounds__(256, 2) void gemm_bf16_k(
    int M, int N, int K,
    const unsigned short* __restrict__ A2, int lda2, int aLo, long long sAb, long long sAh,
    const unsigned short* __restrict__ B2, int ldb2, int bLo, long long sBb, long long sBh,
    void* __restrict__ Cv, int ldc, int cLo, long long sCb, long long sCh,
    const float* __restrict__ bias, const float* __restrict__ res, int ldr,
    float alpha, int nh)
{
    constexpr int ST   = DIRECT ? 32 : 40;
    constexpr int NARR = (NPASS == 3) ? 4 : 2;
    constexpr int NB   = DIRECT ? 2 : 1;
    constexpr int O_AH = 0;
    constexpr int O_BH = 128 * ST;
    constexpr int O_AL = 2 * 128 * ST;
    constexpr int O_BL = 3 * 128 * ST;
    constexpr int BUFSZ = 128 * ST * NARR;
    __shared__ unsigned short SM[NB * BUFSZ];

    const int z  = blockIdx.z;
    const int bb = z / nh, hh = z - bb * nh;
    A2 += bb * sAb + hh * sAh;
    B2 += bb * sBb + hh * sBh;

    const int t    = threadIdx.x;
    const int m0   = blockIdx.y * 128;
    const int n0   = blockIdx.x * 128;
    const int lane = t & 63, wave = t >> 6;
    const int wm   = (wave >> 1) * 64, wn = (wave & 1) * 64;
    const int lr   = lane & 15, quad = lane >> 4;

    f32x4 acc[4][4];
    #pragma unroll
    for (int i = 0; i < 4; ++i)
        #pragma unroll
        for (int j = 0; j < 4; ++j) acc[i][j] = (f32x4){0.f, 0.f, 0.f, 0.f};

    if constexpr (DIRECT) {
        const int drow  = lane >> 2;                       // row in 16-chunk
        const int dcswz = (((lane & 3) ^ ((lane >> 2) & 3) ^ ((lane >> 4) & 3)) << 3);
        const int rsw   = ((quad ^ ((lr & 3) ^ (lr >> 2))) << 3);

        auto stage = [&](int k0, int buf) {
            unsigned short* bp = &SM[buf * BUFSZ];
            #pragma unroll
            for (int j = 0; j < 2; ++j) {
                int rr = wave * 32 + j * 16;               // chunk base row
                int gr = rr + drow;
                const unsigned short* gA = A2 + (long long)(m0 + gr) * lda2 + k0 + dcswz;
                async_ld16(gA, &bp[O_AH + rr * 32]);
                if (NPASS == 3) async_ld16(gA + aLo, &bp[O_AL + rr * 32]);
                const unsigned short* gB = B2 + (long long)(n0 + gr) * ldb2 + k0 + dcswz;
                async_ld16(gB, &bp[O_BH + rr * 32]);
                if (NPASS == 3) async_ld16(gB + bLo, &bp[O_BL + rr * 32]);
            }
        };

        const int nt = K >> 5;
        stage(0, 0);
        int cur = 0;
        for (int it = 0; it < nt; ++it) {
            asm volatile("s_waitcnt vmcnt(0)" ::: "memory");
            __builtin_amdgcn_s_barrier();
            if (it + 1 < nt) stage((it + 1) << 5, cur ^ 1);

            const unsigned short* bp = &SM[cur * BUFSZ];
            bf16x8 ah[4], bh[4], al[4], bl[4];
            #pragma unroll
            for (int i = 0; i < 4; ++i) {
                int ra = O_AH + (wm + i * 16 + lr) * 32 + rsw;
                int rb = O_BH + (wn + i * 16 + lr) * 32 + rsw;
                ah[i] = *(const bf16x8*)&bp[ra];
                bh[i] = *(const bf16x8*)&bp[rb];
                if (NPASS == 3) {
                    al[i] = *(const bf16x8*)&bp[ra + (O_AL - O_AH)];
                    bl[i] = *(const bf16x8*)&bp[rb + (O_BL - O_BH)];
                }
            }
            #pragma unroll
            for (int mi = 0; mi < 4; ++mi)
                #pragma unroll
                for (int ni = 0; ni < 4; ++ni) {
                    acc[mi][ni] = __builtin_amdgcn_mfma_f32_16x16x32_bf16(
                        ah[mi], bh[ni], acc[mi][ni], 0, 0, 0);
                    if (NPASS == 3) {
                        acc[mi][ni] = __builtin_amdgcn_mfma_f32_16x16x32_bf16(
                            al[mi], bh[ni], acc[mi][ni], 0, 0, 0);
                        acc[mi][ni] = __builtin_amdgcn_mfma_f32_16x16x32_bf16(
                            ah[mi], bl[ni], acc[mi][ni], 0, 0, 0);
                    }
                }
            cur ^= 1;
        }
    } else {
        // ---- ragged reg-staging path ----
        const int srow = t >> 2;          // row 0..63 (+64)
        const int scol = (t & 3) * 8;

        for (int k0 = 0; k0 < K; k0 += 32) {
            __syncthreads();
            #pragma unroll
            for (int half = 0; half < 2; ++half) {
                int r = srow + half * 64;
                const unsigned short* pA = A2 + (long long)(m0 + r) * lda2 + k0 + scol;
                *(uint4*)&SM[O_AH + r * ST + scol] = *(const uint4*)pA;
                if (NPASS == 3)
                    *(uint4*)&SM[O_AL + r * ST + scol] = *(const uint4*)(pA + aLo);
                int rb = n0 + r;
                uint4 vh = {0u, 0u, 0u, 0u}, vl = {0u, 0u, 0u, 0u};
                if (rb < N) {
                    const unsigned short* pB = B2 + (long long)rb * ldb2 + k0 + scol;
                    vh = *(const uint4*)pB;
                    if (NPASS == 3) vl = *(const uint4*)(pB + bLo);
                }
                *(uint4*)&SM[O_BH + r * ST + scol] = vh;
                if (NPASS == 3) *(uint4*)&SM[O_BL + r * ST + scol] = vl;
            }
            __syncthreads();

            bf16x8 ah[4], bh[4], al[4], bl[4];
            #pragma unroll
            for (int i = 0; i < 4; ++i) {
                int ra = (wm + i * 16 + lr) * ST + quad * 8;
                int rb = (wn + i * 16 + lr) * ST + quad * 8;
                ah[i] = *(const bf16x8*)&SM[O_AH + ra];
                bh[i] = *(const bf16x8*)&SM[O_BH + rb];
                if (NPASS == 3) {
                    al[i] = *(const bf16x8*)&SM[O_AL + ra];
                    bl[i] = *(const bf16x8*)&SM[O_BL + rb];
                }
            }
            #pragma unroll
            for (int mi = 0; mi < 4; ++mi)
                #pragma unroll
                for (int ni = 0; ni < 4; ++ni) {
                    acc[mi][ni] = __builtin_amdgcn_mfma_f32_16x16x32_bf16(
                        ah[mi], bh[ni], acc[mi][ni], 0, 0, 0);
                    if (NPASS == 3) {
                        acc[mi][ni] = __builtin_amdgcn_mfma_f32_16x16x32_bf16(
                            al[mi], bh[ni], acc[mi][ni], 0, 0, 0);
                        acc[mi][ni] = __builtin_amdgcn_mfma_f32_16x16x32_bf16(
                            ah[mi], bl[ni], acc[mi][ni], 0, 0, 0);
                    }
                }
        }
    }

    // D layout: col = lane&15, row = quad*4 + r
    if (OUT == 0) {
        float* C = (float*)Cv + bb * sCb + hh * sCh;
        #pragma unroll
        for (int mi = 0; mi < 4; ++mi)
            #pragma unroll
            for (int ni = 0; ni < 4; ++ni) {
                int col = n0 + wn + ni * 16 + lr;
                if (col >= N) continue;
                float bv = bias ? bias[col] : 0.f;
                #pragma unroll
                for (int r = 0; r < 4; ++r) {
                    int row = m0 + wm + mi * 16 + quad * 4 + r;
                    float v = alpha * acc[mi][ni][r] + bv;
                    if (res) v += res[(long long)row * ldr + col];
                    C[(long long)row * ldc + col] = v;
                }
            }
    } else if (OUT == 1) {
        unsigned short* C = (unsigned short*)Cv + bb * sCb + hh * sCh;
        #pragma unroll
        for (int mi = 0; mi < 4; ++mi)
            #pragma unroll
            for (int ni = 0; ni < 4; ++ni) {
                int col = n0 + wn + ni * 16 + lr;
                if (col >= N) continue;
                float bv = bias ? bias[col] : 0.f;
                #pragma unroll
                for (int r = 0; r < 4; ++r) {
                    int row = m0 + wm + mi * 16 + quad * 4 + r;
                    float v = alpha * acc[mi][ni][r] + bv;
                    if (res) v += res[(long long)row * ldr + col];
                    unsigned short hi = bf16_rne(v);
                    unsigned short lo = bf16_rne(v - bf16_tof(hi));
                    long long p = (long long)row * ldc + col;
                    C[p] = hi;
                    C[p + cLo] = lo;
                }
            }
    } else {  // OUT == 2: transposed pairs per 512-row batch
        unsigned short* C = (unsigned short*)Cv;
        #pragma unroll
        for (int mi = 0; mi < 4; ++mi)
            #pragma unroll
            for (int ni = 0; ni < 4; ++ni) {
                int col = n0 + wn + ni * 16 + lr;
                if (col >= N) continue;
                int row0 = m0 + wm + mi * 16 + quad * 4;
                int b = row0 >> 9, seq0 = row0 & 511;
                ushort4 h4, l4;
                unsigned short* hp = (unsigned short*)&h4;
                unsigned short* lp = (unsigned short*)&l4;
                #pragma unroll
                for (int r = 0; r < 4; ++r) {
                    float v = acc[mi][ni][r];
                    unsigned short hi = bf16_rne(v);
                    hp[r] = hi;
                    lp[r] = bf16_rne(v - bf16_tof(hi));
                }
                long long p = b * sCb + (long long)col * ldc + seq0;
                *(ushort4*)&C[p] = h4;
                *(ushort4*)&C[p + cLo] = l4;
            }
    }
}

// ---------------------------------------------------------------------------
// DIRECT pipelined split-K GEMM -> f32 partial planes.
// grid (N/128, M/128, nkc); block z accumulates K range [z*KC, (z+1)*KC).
// TR=0: partial[row*N + col]. TR=1 (for OUT2 consumers): partial at
// [b*(N*512) + col*512 + seq] (b=row>>9, seq=row&511), float4 along seq.
// ---------------------------------------------------------------------------
template<int NPASS, int TR>
__global__ __launch_bounds__(256, 2) void gemm_bf16_skd_k(
    int N, int KC,
    const unsigned short* __restrict__ A2, int lda2, int aLo,
    const unsigned short* __restrict__ B2, int ldb2, int bLo,
    float* __restrict__ P, long long sCk)
{
    constexpr int NARR = (NPASS == 3) ? 4 : 2;
    constexpr int O_AH = 0;
    constexpr int O_BH = 128 * 32;
    constexpr int O_AL = 2 * 128 * 32;
    constexpr int O_BL = 3 * 128 * 32;
    constexpr int BUFSZ = 128 * 32 * NARR;
    __shared__ unsigned short SM[2 * BUFSZ];

    const int t    = threadIdx.x;
    const int m0   = blockIdx.y * 128;
    const int n0   = blockIdx.x * 128;
    const int kbeg = blockIdx.z * KC;
    const int lane = t & 63, wave = t >> 6;
    const int wm   = (wave >> 1) * 64, wn = (wave & 1) * 64;
    const int lr   = lane & 15, quad = lane >> 4;

    f32x4 acc[4][4];
    #pragma unroll
    for (int i = 0; i < 4; ++i)
        #pragma unroll
        for (int j = 0; j < 4; ++j) acc[i][j] = (f32x4){0.f, 0.f, 0.f, 0.f};

    const int drow  = lane >> 2;
    const int dcswz = (((lane & 3) ^ ((lane >> 2) & 3) ^ ((lane >> 4) & 3)) << 3);
    const int rsw   = ((quad ^ ((lr & 3) ^ (lr >> 2))) << 3);

    auto stage = [&](int k0, int buf) {
        unsigned short* bp = &SM[buf * BUFSZ];
        #pragma unroll
        for (int j = 0; j < 2; ++j) {
            int rr = wave * 32 + j * 16;
            int gr = rr + drow;
            const unsigned short* gA = A2 + (long long)(m0 + gr) * lda2 + k0 + dcswz;
            async_ld16(gA, &bp[O_AH + rr * 32]);
            if (NPASS == 3) async_ld16(gA + aLo, &bp[O_AL + rr * 32]);
            const unsigned short* gB = B2 + (long long)(n0 + gr) * ldb2 + k0 + dcswz;
            async_ld16(gB, &bp[O_BH + rr * 32]);
            if (NPASS == 3) async_ld16(gB + bLo, &bp[O_BL + rr * 32]);
        }
    };

    const int nt = KC >> 5;
    stage(kbeg, 0);
    int cur = 0;
    for (int it = 0; it < nt; ++it) {
        asm volatile("s_waitcnt vmcnt(0)" ::: "memory");
        __builtin_amdgcn_s_barrier();
        if (it + 1 < nt) stage(kbeg + ((it + 1) << 5), cur ^ 1);

        const unsigned short* bp = &SM[cur * BUFSZ];
        bf16x8 ah[4], bh[4], al[4], bl[4];
        #pragma unroll
        for (int i = 0; i < 4; ++i) {
            int ra = O_AH + (wm + i * 16 + lr) * 32 + rsw;
            int rb = O_BH + (wn + i * 16 + lr) * 32 + rsw;
            ah[i] = *(const bf16x8*)&bp[ra];
            bh[i] = *(const bf16x8*)&bp[rb];
            if (NPASS == 3) {
                al[i] = *(const bf16x8*)&bp[ra + (O_AL - O_AH)];
                bl[i] = *(const bf16x8*)&bp[rb + (O_BL - O_BH)];
            }
        }
        #pragma unroll
        for (int mi = 0; mi < 4; ++mi)
            #pragma unroll
            for (int ni = 0; ni < 4; ++ni) {
                acc[mi][ni] = __builtin_amdgcn_mfma_f32_16x16x32_bf16(
                    ah[mi], bh[ni], acc[mi][ni], 0, 0, 0);
                if (NPASS == 3) {
                    acc[mi][ni] = __builtin_amdgcn_mfma_f32_16x16x32_bf16(
                        al[mi], bh[ni], acc[mi][ni], 0, 0, 0);
                    acc[mi][ni] = __builtin_amdgcn_mfma_f32_16x16x32_bf16(
                        ah[mi], bl[ni], acc[mi][ni], 0, 0, 0);
                }
            }
        cur ^= 1;
    }

    float* Pc = P + (long long)blockIdx.z * sCk;
    if (TR == 0) {
        #pragma unroll
        for (int mi = 0; mi < 4; ++mi)
            #pragma unroll
            for (int ni = 0; ni < 4; ++ni) {
                int col = n0 + wn + ni * 16 + lr;
                #pragma unroll
                for (int r = 0; r < 4; ++r) {
                    int row = m0 + wm + mi * 16 + quad * 4 + r;
                    Pc[(long long)row * N + col] = acc[mi][ni][r];
                }
            }
    } else {
        #pragma unroll
        for (int mi = 0; mi < 4; ++mi)
            #pragma unroll
            for (int ni = 0; ni < 4; ++ni) {
                int col = n0 + wn + ni * 16 + lr;
                int row0 = m0 + wm + mi * 16 + quad * 4;
                int b = row0 >> 9, seq0 = row0 & 511;
                *(float4*)&Pc[(long long)b * ((long long)N * 512)
                              + (long long)col * 512 + seq0] =
                    *(float4*)&acc[mi][ni];
            }
    }
}

// ---------------------------------------------------------------------------
// Split-K ragged GEMM for thin-N ops (xproj N=144, hW N=64).
// ---------------------------------------------------------------------------
template<int NPASS>
__global__ __launch_bounds__(256, 2) void gemm_bf16_sk_k(
    int N, int KC,
    const unsigned short* __restrict__ A2, int lda2, int aLo,
    const unsigned short* __restrict__ B2, int ldb2, int bLo,
    float* __restrict__ C, long long sCk)
{
    constexpr int ST = 40;
    __shared__ unsigned short Ah[128 * ST];
    __shared__ unsigned short Bh[128 * ST];
    __shared__ unsigned short Al[128 * ST];
    __shared__ unsigned short Bl[128 * ST];

    const int t    = threadIdx.x;
    const int m0   = blockIdx.y * 128;
    const int n0   = blockIdx.x * 128;
    const int kbeg = blockIdx.z * KC;
    const int lane = t & 63, wave = t >> 6;
    const int wm   = (wave >> 1) * 64, wn = (wave & 1) * 64;
    const int lr   = lane & 15, quad = lane >> 4;

    f32x4 acc[4][4];
    #pragma unroll
    for (int i = 0; i < 4; ++i)
        #pragma unroll
        for (int j = 0; j < 4; ++j) acc[i][j] = (f32x4){0.f, 0.f, 0.f, 0.f};

    const int srow = t >> 2;
    const int scol = (t & 3) * 8;

    for (int k0 = kbeg; k0 < kbeg + KC; k0 += 32) {
        __syncthreads();
        #pragma unroll
        for (int half = 0; half < 2; ++half) {
            int r = srow + half * 64;
            const unsigned short* pA = A2 + (long long)(m0 + r) * lda2 + k0 + scol;
            *(uint4*)&Ah[r * ST + scol] = *(const uint4*)pA;
            if (NPASS == 3)
                *(uint4*)&Al[r * ST + scol] = *(const uint4*)(pA + aLo);
            int rb = n0 + r;
            uint4 vh = {0u, 0u, 0u, 0u}, vl = {0u, 0u, 0u, 0u};
            if (rb < N) {
                const unsigned short* pB = B2 + (long long)rb * ldb2 + k0 + scol;
                vh = *(const uint4*)pB;
                if (NPASS == 3) vl = *(const uint4*)(pB + bLo);
            }
            *(uint4*)&Bh[r * ST + scol] = vh;
            if (NPASS == 3) *(uint4*)&Bl[r * ST + scol] = vl;
        }
        __syncthreads();

        bf16x8 ah[4], bh[4], al[4], bl[4];
        #pragma unroll
        for (int i = 0; i < 4; ++i) {
            int ra = (wm + i * 16 + lr) * ST + quad * 8;
            int rb = (wn + i * 16 + lr) * ST + quad * 8;
            ah[i] = *(const bf16x8*)&Ah[ra];
            bh[i] = *(const bf16x8*)&Bh[rb];
            if (NPASS == 3) {
                al[i] = *(const bf16x8*)&Al[ra];
                bl[i] = *(const bf16x8*)&Bl[rb];
            }
        }
        #pragma unroll
        for (int mi = 0; mi < 4; ++mi)
            #pragma unroll
            for (int ni = 0; ni < 4; ++ni) {
                acc[mi][ni] = __builtin_amdgcn_mfma_f32_16x16x32_bf16(
                    ah[mi], bh[ni], acc[mi][ni], 0, 0, 0);
                if (NPASS == 3) {
                    acc[mi][ni] = __builtin_amdgcn_mfma_f32_16x16x32_bf16(
                        al[mi], bh[ni], acc[mi][ni], 0, 0, 0);
                    acc[mi][ni] = __builtin_amdgcn_mfma_f32_16x16x32_bf16(
                        ah[mi], bl[ni], acc[mi][ni], 0, 0, 0);
                }
            }
    }

    float* Cc = C + (long long)blockIdx.z * sCk;
    #pragma unroll
    for (int mi = 0; mi < 4; ++mi)
        #pragma unroll
        for (int ni = 0; ni < 4; ++ni) {
            int col = n0 + wn + ni * 16 + lr;
            if (col >= N) continue;
            #pragma unroll
            for (int r = 0; r < 4; ++r) {
                int row = m0 + wm + mi * 16 + quad * 4 + r;
                Cc[(long long)row * N + col] = acc[mi][ni][r];
            }
        }
}

// ---- split-K reduce epilogues ----
__global__ __launch_bounds__(256) void skredN_k(
    const float* __restrict__ P, long long sCk, int nchunk,
    const float* __restrict__ bias, const float* __restrict__ res, int ncol,
    float* __restrict__ outp, long long n)
{
    long long idx = (long long)blockIdx.x * 256 + threadIdx.x;
    if (idx >= n) return;
    float s = 0.f;
    for (int c = 0; c < nchunk; ++c) s += P[c * sCk + idx];
    if (bias) s += bias[(int)(idx % ncol)];
    if (res) s += res[idx];
    outp[idx] = s;
}

// pairs out, N=1024 layout: pos = row*2048 + col, lo at +1024
__global__ __launch_bounds__(256) void skredP_k(
    const float* __restrict__ P, long long sCk, int nchunk,
    const float* __restrict__ bias, const float* __restrict__ res,
    unsigned short* __restrict__ out2, long long n)
{
    long long idx = (long long)blockIdx.x * 256 + threadIdx.x;
    if (idx >= n) return;
    float s = 0.f;
    for (int c = 0; c < nchunk; ++c) s += P[c * sCk + idx];
    int col = (int)(idx & 1023);
    long long row = idx >> 10;
    if (bias) s += bias[col];
    if (res) s += res[idx];
    unsigned short hi = bf16_rne(s);
    unsigned short lo = bf16_rne(s - bf16_tof(hi));
    long long pos = row * 2048 + col;
    out2[pos] = hi;
    out2[pos + 1024] = lo;
}

// transposed pairs out (VT2 layout): partials already transposed (TR=1):
// idx = b*(1024*512) + col*512 + seq -> out[b*1048576 + col*1024 + seq]
__global__ __launch_bounds__(256) void skredT_k(
    const float* __restrict__ P, long long sCk, int nchunk,
    unsigned short* __restrict__ out2, long long n)
{
    long long idx = (long long)blockIdx.x * 256 + threadIdx.x;
    if (idx >= n) return;
    float s = 0.f;
    for (int c = 0; c < nchunk; ++c) s += P[c * sCk + idx];
    int seq = (int)(idx & 511);
    int col = (int)((idx >> 9) & 1023);
    int b   = (int)(idx >> 19);
    unsigned short hi = bf16_rne(s);
    unsigned short lo = bf16_rne(s - bf16_tof(hi));
    long long pos = (long long)b * 1048576 + (long long)col * 1024 + seq;
    out2[pos] = hi;
    out2[pos + 512] = lo;
}

// ---------------------------------------------------------------------------
// Fused SSD intra-chunk MFMA kernel, v4 (unchanged from round 3).
// ---------------------------------------------------------------------------
__global__ __launch_bounds__(256, 2) void ssd_mfma_k(
    const float* __restrict__ G, const float* __restrict__ CUMA,
    const float* __restrict__ DT, const unsigned short* __restrict__ XCT2,
    const float* __restrict__ Z, const float* __restrict__ Dv,
    unsigned short* __restrict__ YS2)
{
    __shared__ unsigned short Xh[3][128 * 32];
    __shared__ unsigned short Xl[3][128 * 32];
    __shared__ unsigned short Wh[2][64 * 32];
    __shared__ unsigned short Wl[2][64 * 32];
    __shared__ float Cs[512];
    __shared__ float Ds[512];
    const int q = blockIdx.x;
    const int h = blockIdx.y, b = blockIdx.z;
    const int t = threadIdx.x;
    const int lane = t & 63, wave = t >> 6;
    const int lr = lane & 15, quad = lane >> 4;

    const float* cbase = CUMA + (b * 16 + h) * 512;
    const float* dtb = DT + (long long)b * 512 * 16 + h;
    for (int s = t; s < 512; s += 256) {
        Cs[s] = cbase[s];
        Ds[s] = dtb[(long long)s * 16];
    }
    const float Dh = Dv[h];

    const int wr = t >> 2;
    const int sw = t & 3;
    const int wbase = wr * 32 + ((sw ^ ((wr >> 1) & 3)) << 3);
    const int frow = wave * 16 + lr;
    const int fbase = frow * 32 + ((quad ^ ((frow >> 1) & 3)) << 3);
    const int drow  = lane >> 2;
    const int dcswz = (((lane & 3) ^ ((lane >> 2) & 3) ^ ((lane >> 4) & 3)) << 3);
    const int xsw   = ((quad ^ ((lr & 3) ^ ((lr >> 2) & 3))) << 3);
    const unsigned short* XB = XCT2 + (long long)b * 2097152
                             + (long long)(h * 128) * 1024;
    __syncthreads();

    for (int ph = 0; ph < 2; ++ph) {
        const int mt = ph ? q : 7 - q;
        const int m0 = mt * 64;
        const int nt = (m0 >> 5) + 2;
        const int lglob = m0 + wr;
        const float cAl = Cs[lglob];
        const float* grow = G + ((long long)(b * 512 + lglob)) * 512;

        float pg[8], pc[8], pd[8];
        auto gen_load = [&](int k0g) {
            const int sb = k0g + sw * 8;
            float4 g0 = *(const float4*)(grow + sb);
            float4 g1 = *(const float4*)(grow + sb + 4);
            float4 c0 = *(const float4*)&Cs[sb];
            float4 c1 = *(const float4*)&Cs[sb + 4];
            float4 d0 = *(const float4*)&Ds[sb];
            float4 d1 = *(const float4*)&Ds[sb + 4];
            pg[0] = g0.x; pg[1] = g0.y; pg[2] = g0.z; pg[3] = g0.w;
            pg[4] = g1.x; pg[5] = g1.y; pg[6] = g1.z; pg[7] = g1.w;
            pc[0] = c0.x; pc[1] = c0.y; pc[2] = c0.z; pc[3] = c0.w;
            pc[4] = c1.x; pc[5] = c1.y; pc[6] = c1.z; pc[7] = c1.w;
            pd[0] = d0.x; pd[1] = d0.y; pd[2] = d0.z; pd[3] = d0.w;
            pd[4] = d1.x; pd[5] = d1.y; pd[6] = d1.z; pd[7] = d1.w;
        };
        auto gen_finish = [&](int k0g, int buf) {
            const int sb = k0g + sw * 8;
            const bool edge = (k0g + 32 > m0);
            unsigned short hv[8], lv[8];
            #pragma unroll
            for (int e = 0; e < 8; ++e) {
                float w = pg[e] * __expf(cAl - pc[e]) * pd[e];
                if (edge) {
                    int sg = sb + e;
                    w = (sg <= lglob) ? w : 0.f;
                    if (sg == lglob) w += Dh;
                }
                unsigned short hi = bf16_rne(w);
                hv[e] = hi;
                lv[e] = bf16_rne(w - bf16_tof(hi));
            }
            *(uint4*)&Wh[buf][wbase] = *(uint4*)hv;
            *(uint4*)&Wl[buf][wbase] = *(uint4*)lv;
        };
        auto stageX = [&](int k0, int buf) {
            #pragma unroll
            for (int j = 0; j < 2; ++j) {
                int rr = wave * 32 + j * 16;
                const unsigned short* gX =
                    XB + (long long)(rr + drow) * 1024 + k0 + dcswz;
                async_ld16(gX,       &Xh[buf][rr * 32]);
                async_ld16(gX + 512, &Xl[buf][rr * 32]);
            }
        };

        f32x4 acc[8];
        #pragma unroll
        for (int j = 0; j < 8; ++j) acc[j] = (f32x4){0.f, 0.f, 0.f, 0.f};

        gen_load(0);
        stageX(0, 0);
        if (nt > 1) stageX(32, 1);
        gen_finish(0, 0);
        if (nt > 1) asm volatile("s_waitcnt vmcnt(4)" ::: "memory");
        else        asm volatile("s_waitcnt vmcnt(0)" ::: "memory");
        asm volatile("s_waitcnt lgkmcnt(0)" ::: "memory");
        __builtin_amdgcn_s_barrier();

        for (int it = 0; it < nt; ++it) {
            const int xb = it % 3;
            const int wb = it & 1;
            if (it + 1 < nt) gen_load((it + 1) << 5);
            if (it + 2 < nt) stageX((it + 2) << 5, (it + 2) % 3);

            bf16x8 ah = *(const bf16x8*)&Wh[wb][fbase];
            bf16x8 al = *(const bf16x8*)&Wl[wb][fbase];
            const unsigned short* xhp = &Xh[xb][0];
            const unsigned short* xlp = &Xl[xb][0];
            #pragma unroll
            for (int ni = 0; ni < 8; ++ni) {
                int base = (ni * 16 + lr) * 32 + xsw;
                bf16x8 bh = *(const bf16x8*)&xhp[base];
                bf16x8 bl = *(const bf16x8*)&xlp[base];
                acc[ni] = __builtin_amdgcn_mfma_f32_16x16x32_bf16(
                    ah, bh, acc[ni], 0, 0, 0);
                acc[ni] = __builtin_amdgcn_mfma_f32_16x16x32_bf16(
                    al, bh, acc[ni], 0, 0, 0);
                acc[ni] = __builtin_amdgcn_mfma_f32_16x16x32_bf16(
                    ah, bl, acc[ni], 0, 0, 0);
            }
            if (it + 1 < nt) gen_finish((it + 1) << 5, wb ^ 1);
            if (it + 2 < nt) asm volatile("s_waitcnt vmcnt(4)" ::: "memory");
            else             asm volatile("s_waitcnt vmcnt(0)" ::: "memory");
            asm volatile("s_waitcnt lgkmcnt(0)" ::: "memory");
            __builtin_amdgcn_s_barrier();
        }

        const int row0 = m0 + wave * 16 + quad * 4;
        #pragma unroll
        for (int ni = 0; ni < 8; ++ni) {
            int chan = h * 128 + ni * 16 + lr;
            #pragma unroll
            for (int r = 0; r < 4; ++r) {
                long long row = (long long)(b * 512 + row0 + r);
                float zz = Z[row * 2048 + chan];
                float y = acc[ni][r] * (zz / (1.f + expf(-zz)));
                store_pair(YS2, row, 2048, chan, y);
            }
        }
    }
}

// ---------------------------------------------------------------------------
// Tiled f32 GEMM (only for the small batched G = Cm @ Bm^T)
// ---------------------------------------------------------------------------
__global__ __launch_bounds__(256) void gemm_f32_k(
    int M, int N, int K,
    const float* __restrict__ A, int lda, long long sAb,
    const float* __restrict__ B, int ldb, long long sBb,
    float* __restrict__ C, int ldc, long long sCb)
{
    __shared__ float As[32][132];
    __shared__ float Bs[32][132];
    const int z = blockIdx.z;
    A += z * sAb; B += z * sBb; C += z * sCb;
    const int n0 = blockIdx.x * 128;
    const int m0 = blockIdx.y * 128;
    const int t  = threadIdx.x;
    const int tx = t & 15, ty = t >> 4;

    float acc[4][16];
    #pragma unroll
    for (int a = 0; a < 4; ++a)
        #pragma unroll
        for (int q = 0; q < 16; ++q) acc[a][q] = 0.f;

    const int ka = (t & 7) << 2;
    const int ra = t >> 3;

    for (int k0 = 0; k0 < K; k0 += 32) {
        __syncthreads();
        #pragma unroll
        for (int i = 0; i < 4; ++i) {
            int row = m0 + ra + i * 32;
            float4 v = *(const float4*)(A + (long long)row * lda + (k0 + ka));
            As[ka + 0][ra + i * 32] = v.x;
            As[ka + 1][ra + i * 32] = v.y;
            As[ka + 2][ra + i * 32] = v.z;
            As[ka + 3][ra + i * 32] = v.w;
            int rowb = n0 + ra + i * 32;
            float4 w = *(const float4*)(B + (long long)rowb * ldb + (k0 + ka));
            Bs[ka + 0][ra + i * 32] = w.x;
            Bs[ka + 1][ra + i * 32] = w.y;
            Bs[ka + 2][ra + i * 32] = w.z;
            Bs[ka + 3][ra + i * 32] = w.w;
        }
        __syncthreads();
        #pragma unroll
        for (int kk = 0; kk < 32; ++kk) {
            float a[8], bm[8];
            *(float4*)&a[0]  = *(const float4*)&As[kk][ty * 4];
            *(float4*)&a[4]  = *(const float4*)&As[kk][64 + ty * 4];
            *(float4*)&bm[0] = *(const float4*)&Bs[kk][tx * 4];
            *(float4*)&bm[4] = *(const float4*)&Bs[kk][64 + tx * 4];
            #pragma unroll
            for (int ri = 0; ri < 2; ++ri)
                #pragma unroll
                for (int ci = 0; ci < 2; ++ci)
                    #pragma unroll
                    for (int i = 0; i < 4; ++i)
                        #pragma unroll
                        for (int j = 0; j < 4; ++j)
                            acc[ri * 2 + ci][i * 4 + j] =
                                fmaf(a[ri * 4 + i], bm[ci * 4 + j], acc[ri * 2 + ci][i * 4 + j]);
        }
    }
    #pragma unroll
    for (int ri = 0; ri < 2; ++ri)
        #pragma unroll
        for (int ci = 0; ci < 2; ++ci) {
            int colb = n0 + ci * 64 + tx * 4;
            #pragma unroll
            for (int i = 0; i < 4; ++i) {
                int row = m0 + ri * 64 + ty * 4 + i;
                *(float4*)(C + (long long)row * ldc + colb) =
                    *(float4*)&acc[ri * 2 + ci][i * 4];
            }
        }
}

// ---------------------------------------------------------------------------
// Elementwise / norm kernels
// ---------------------------------------------------------------------------
__global__ __launch_bounds__(256) void pairify_k(
    const float* __restrict__ src, unsigned short* __restrict__ dst,
    int k_log2, long long n)
{
    long long idx = (long long)blockIdx.x * 256 + threadIdx.x;
    if (idx >= n) return;
    long long r = idx >> k_log2;
    int c = (int)(idx & ((1 << k_log2) - 1));
    store_pair(dst, r, 1 << k_log2, c, src[idx]);
}

__global__ __launch_bounds__(256) void layernorm_k(
    const float* __restrict__ in, float* __restrict__ out,
    const float* __restrict__ w, const float* __restrict__ b,
    int width, int rows_per_b, long long in_bstride)
{
    long long r = blockIdx.x;
    const float* x = in + (r / rows_per_b) * in_bstride + (r % rows_per_b) * (long long)width;
    int t = threadIdx.x;
    float s = 0.f;
    for (int c = t; c < width; c += 256) s += x[c];
    s = block_sum256(s);
    float m = s / (float)width;
    float vs = 0.f;
    for (int c = t; c < width; c += 256) { float d = x[c] - m; vs += d * d; }
    vs = block_sum256(vs);
    float rs = 1.f / sqrtf(vs / (float)width + 1e-5f);
    float* o = out + r * (long long)width;
    for (int c = t; c < width; c += 256) o[c] = (x[c] - m) * rs * w[c] + b[c];
}

__global__ __launch_bounds__(256) void layernorm_pair_k(
    const float* __restrict__ in, unsigned short* __restrict__ out2,
    const float* __restrict__ w, const float* __restrict__ b,
    int width, int rows_per_b, long long in_bstride)
{
    long long r = blockIdx.x;
    const float* x = in + (r / rows_per_b) * in_bstride + (r % rows_per_b) * (long long)width;
    int t = threadIdx.x;
    float s = 0.f;
    for (int c = t; c < width; c += 256) s += x[c];
    s = block_sum256(s);
    float m = s / (float)width;
    float vs = 0.f;
    for (int c = t; c < width; c += 256) { float d = x[c] - m; vs += d * d; }
    vs = block_sum256(vs);
    float rs = 1.f / sqrtf(vs / (float)width + 1e-5f);
    for (int c = t; c < width; c += 256)
        store_pair(out2, r, width, c, (x[c] - m) * rs * w[c] + b[c]);
}

__global__ __launch_bounds__(256) void rmsnorm_pair_k(
    const float* __restrict__ in, unsigned short* __restrict__ out2,
    const float* __restrict__ w, int width)
{
    long long r = blockIdx.x;
    const float* x = in + r * (long long)width;
    int t = threadIdx.x;
    float s = 0.f;
    for (int c = t; c < width; c += 256) { float v = x[c]; s += v * v; }
    s = block_sum256(s);
    float rs = 1.f / sqrtf(s / (float)width + 1e-5f);
    for (int c = t; c < width; c += 256)
        store_pair(out2, r, width, c, x[c] * rs * w[c]);
}

// Softmax over 512-wide rows, f32 in -> split-pair out IN-PLACE (same bytes).
__global__ __launch_bounds__(256) void softmax_pair_k(float* __restrict__ S,
                                                      unsigned short* __restrict__ P2)
{
    long long r = blockIdx.x;
    float* x = S + r * 512;
    unsigned short* p = P2 + r * 1024;
    int t = threadIdx.x;
    float v0 = x[t], v1 = x[t + 256];
    float mx = block_max256(fmaxf(v0, v1));
    v0 = expf(v0 - mx); v1 = expf(v1 - mx);
    float sum = block_sum256(v0 + v1);
    float inv = 1.f / sum;
    v0 *= inv; v1 *= inv;
    __syncthreads();
    unsigned short h0 = bf16_rne(v0);
    p[t] = h0;       p[512 + t] = bf16_rne(v0 - bf16_tof(h0));
    unsigned short h1 = bf16_rne(v1);
    p[t + 256] = h1; p[512 + t + 256] = bf16_rne(v1 - bf16_tof(h1));
}

// Causal grouped conv with LDS-tile transpose: writes seq-major pairs XC2
// AND chan-major pairs XCT2, both coalesced.
__global__ __launch_bounds__(256) void conv_k(
    const float* __restrict__ XS, const float* __restrict__ W,
    unsigned short* __restrict__ XC2, unsigned short* __restrict__ XCT2)
{
    __shared__ float tile[64][65];
    const int o0  = blockIdx.x * 64;
    const int tt0 = blockIdx.y * 64;
    const int b   = blockIdx.z;
    const int t   = threadIdx.x;

    const int o  = o0 + (t & 63);
    const int g2 = (o >> 1) << 1;
    const float* Wo = W + o * 8;
    float w0 = Wo[0], w1 = Wo[1], w2 = Wo[2], w3 = Wo[3];
    float w4 = Wo[4], w5 = Wo[5], w6 = Wo[6], w7 = Wo[7];
    #pragma unroll
    for (int i = 0; i < 16; ++i) {
        int sl = (t >> 6) + 4 * i;
        int tt = tt0 + sl;
        const float* xb = XS + ((long long)(b * 512 + tt)) * 2048 + g2;
        float acc = w3 * xb[0] + w7 * xb[1];
        if (tt >= 1) acc += w2 * xb[-2048] + w6 * xb[-2047];
        if (tt >= 2) acc += w1 * xb[-4096] + w5 * xb[-4095];
        if (tt >= 3) acc += w0 * xb[-6144] + w4 * xb[-6143];
        tile[sl][t & 63] = acc;
    }
    __syncthreads();
    #pragma unroll
    for (int i = 0; i < 16; ++i) {
        int idx = t + 256 * i;
        int sl = idx >> 6, ol = idx & 63;
        float v = tile[sl][ol];
        unsigned short hi = bf16_rne(v);
        unsigned short lo = bf16_rne(v - bf16_tof(hi));
        long long row = (long long)(b * 512 + tt0 + sl);
        XC2[row * 4096 + o0 + ol] = hi;
        XC2[row * 4096 + 2048 + o0 + ol] = lo;
    }
    #pragma unroll
    for (int i = 0; i < 16; ++i) {
        int idx = t + 256 * i;
        int cl = idx >> 6, s = idx & 63;
        float v = tile[s][cl];
        unsigned short hi = bf16_rne(v);
        unsigned short lo = bf16_rne(v - bf16_tof(hi));
        long long tb = (long long)b * 2097152 + (long long)(o0 + cl) * 1024 + tt0 + s;
        XCT2[tb] = hi;
        XCT2[tb + 512] = lo;
    }
}

__global__ __launch_bounds__(256) void dt_k(
    const float* __restrict__ dtBC, const float* __restrict__ dt_bias, float* __restrict__ DT)
{
    int idx = blockIdx.x * 256 + threadIdx.x;
    int r = idx >> 4, h = idx & 15;
    float xv = dtBC[r * 144 + h] + dt_bias[h];
    DT[idx] = (xv > 20.f) ? xv : log1pf(expf(xv));
}

__global__ __launch_bounds__(64) void cuma_k(
    const float* __restrict__ DT, const float* __restrict__ A_log, float* __restrict__ CUMA)
{
    int h = blockIdx.x, b = blockIdx.y;
    int ln = threadIdx.x;
    float Ah = -expf(A_log[h]);
    float v[8];
    float run = 0.f;
    #pragma unroll
    for (int i = 0; i < 8; ++i) {
        run += Ah * DT[((b * 512) + (ln * 8 + i)) * 16 + h];
        v[i] = run;
    }
    float tot = run;
    float sc = tot;
    #pragma unroll
    for (int o = 1; o <= 32; o <<= 1) {
        float u = __shfl_up(sc, o, 64);
        if (ln >= o) sc += u;
    }
    float excl = sc - tot;
    #pragma unroll
    for (int i = 0; i < 8; ++i)
        CUMA[(b * 16 + h) * 512 + ln * 8 + i] = excl + v[i];
}

// hc = LayerNorm64(G1) -> {-1,+1} as split pairs (lo = 0)
__global__ __launch_bounds__(64) void hc_quant_k(
    const float* __restrict__ G1, const float* __restrict__ w,
    const float* __restrict__ b, unsigned short* __restrict__ HCQ2)
{
    int r = blockIdx.x, ln = threadIdx.x;
    float v = G1[r * 64 + ln];
    float s = v;
    #pragma unroll
    for (int o = 32; o > 0; o >>= 1) s += __shfl_xor(s, o, 64);
    float m = s * (1.f / 64.f);
    float d = v - m;
    float vs = d * d;
    #pragma unroll
    for (int o = 32; o > 0; o >>= 1) vs += __shfl_xor(vs, o, 64);
    vs *= (1.f / 64.f);
    float hc = d * (1.f / sqrtf(vs + 1e-5f)) * w[ln] + b[ln];
    HCQ2[r * 128 + ln] = (hc > 0.f) ? 0x3F80 : 0xBF80;
    HCQ2[r * 128 + 64 + ln] = 0;
}

__global__ __launch_bounds__(256) void dxm_k(
    const float* __restrict__ mtok, const float* __restrict__ e2d, float* __restrict__ dxm)
{
    int c = blockIdx.x * 256 + threadIdx.x;
    float acc = 0.f;
    #pragma unroll
    for (int j = 0; j < 64; ++j) acc = fmaf(mtok[j], e2d[c * 64 + j], acc);
    dxm[c] = acc;
}

__global__ __launch_bounds__(256) void projm_k(
    const float* __restrict__ lnm,
    const float* __restrict__ bWq, const float* __restrict__ bWk, const float* __restrict__ bWv,
    float* __restrict__ qm, float* __restrict__ km, float* __restrict__ vm)
{
    int idx = blockIdx.x * 256 + threadIdx.x;
    int sel = idx >> 10, c = idx & 1023;
    const float* W = (sel == 0) ? bWq : (sel == 1) ? bWk : bWv;
    float* O = (sel == 0) ? qm : (sel == 1) ? km : vm;
    const float* wr = W + (long long)c * 1024;
    float acc = 0.f;
    for (int j = 0; j < 1024; j += 4) {
        float4 a = *(const float4*)(lnm + j);
        float4 w4 = *(const float4*)(wr + j);
        acc = fmaf(a.x, w4.x, fmaf(a.y, w4.y, fmaf(a.z, w4.z, fmaf(a.w, w4.w, acc))));
    }
    O[c] = acc;
}

// Collapsed decoder attention on fused KV buffer: KVm[row][0..1023]=K,
// [1024..2047]=V. 1 query/(b,h); keys = 512 visible + mask key x512.
__global__ __launch_bounds__(256) void dec_attn_k(
    const float* __restrict__ KVm,
    const float* __restrict__ qm, const float* __restrict__ km,
    const float* __restrict__ vm, float* __restrict__ OBm)
{
    int h = blockIdx.x, b = blockIdx.y;
    int t = threadIdx.x;
    __shared__ __align__(16) float qs[256];
    __shared__ __align__(16) float ps[512];
    qs[t] = qm[h * 256 + t];
    __syncthreads();
    float s[2];
    #pragma unroll
    for (int i = 0; i < 2; ++i) {
        int r = t + i * 256;
        const float* kr = KVm + ((long long)(b * 512 + r)) * 2048 + h * 256;
        float acc = 0.f;
        for (int c = 0; c < 256; c += 4) {
            float4 k4 = *(const float4*)(kr + c);
            float4 q4 = *(const float4*)(qs + c);
            acc = fmaf(k4.x, q4.x, fmaf(k4.y, q4.y, fmaf(k4.z, q4.z, fmaf(k4.w, q4.w, acc))));
        }
        s[i] = acc * (1.f / 16.f);
    }
    float accm = 0.f;
    for (int c = 0; c < 256; c += 4) {
        float4 k4 = *(const float4*)(km + h * 256 + c);
        float4 q4 = *(const float4*)(qs + c);
        accm = fmaf(k4.x, q4.x, fmaf(k4.y, q4.y, fmaf(k4.z, q4.z, fmaf(k4.w, q4.w, accm))));
    }
    float smv = accm * (1.f / 16.f);
    float mx = block_max256(fmaxf(fmaxf(s[0], s[1]), smv));
    float p0 = expf(s[0] - mx), p1 = expf(s[1] - mx);
    ps[t] = p0; ps[t + 256] = p1;
    float pm = expf(smv - mx) * 512.f;
    float sum = block_sum256(p0 + p1) + pm;
    float inv = 1.f / sum;
    __syncthreads();
    float o = pm * vm[h * 256 + t];
    const float* vcol = KVm + (long long)b * 512 * 2048 + 1024 + h * 256 + t;
    for (int j = 0; j < 512; ++j)
        o = fmaf(ps[j], vcol[(long long)j * 2048], o);
    OBm[b * 1024 + h * 256 + t] = o * inv;
}

__global__ __launch_bounds__(256) void ydm_k(
    const float* __restrict__ OBm, const float* __restrict__ bWo,
    const float* __restrict__ bWo_b, const float* __restrict__ dxm,
    float* __restrict__ ydm)
{
    int idx = blockIdx.x * 256 + threadIdx.x;
    int b = idx >> 10, c = idx & 1023;
    const float* ar = OBm + b * 1024;
    const float* wr = bWo + (long long)c * 1024;
    float acc = 0.f;
    for (int j = 0; j < 1024; j += 4) {
        float4 a = *(const float4*)(ar + j);
        float4 w4 = *(const float4*)(wr + j);
        acc = fmaf(a.x, w4.x, fmaf(a.y, w4.y, fmaf(a.z, w4.z, fmaf(a.w, w4.w, acc))));
    }
    ydm[idx] = acc + bWo_b[c] + dxm[c];
}

__global__ __launch_bounds__(256) void outm_k(
    const float* __restrict__ ydm, const float* __restrict__ dout_W,
    const float* __restrict__ dout_b, float* __restrict__ outm)
{
    int idx = blockIdx.x * 256 + threadIdx.x;
    int b = idx >> 11, c = idx & 2047;
    const float* ar = ydm + b * 1024;
    const float* wr = dout_W + (long long)c * 1024;
    float acc = 0.f;
    for (int j = 0; j < 1024; j += 4) {
        float4 a = *(const float4*)(ar + j);
        float4 w4 = *(const float4*)(wr + j);
        acc = fmaf(a.x, w4.x, fmaf(a.y, w4.y, fmaf(a.z, w4.z, fmaf(a.w, w4.w, acc))));
    }
    outm[idx] = acc + dout_b[c];
}

__global__ __launch_bounds__(256) void bcast_k(
    const float* __restrict__ outm, float* __restrict__ out)
{
    int idx = blockIdx.x * 256 + threadIdx.x;
    int c4 = idx & 511;
    int b = idx >> 18;
    ((float4*)out)[idx] = ((const float4*)outm)[b * 512 + c4];
}

// ---------------------------------------------------------------------------
// Host-side launcher
// ---------------------------------------------------------------------------
static inline void pairify(hipStream_t s, const float* src, unsigned short* dst,
                           int k_log2, long long n)
{
    pairify_k<<<(int)((n + 255) / 256), 256, 0, s>>>(src, dst, k_log2, n);
}

extern "C" void kernel_launch(void* const* d_in, const int* in_sizes, int n_in,
                              void* d_out, int out_size, void* d_ws, size_t ws_size,
                              hipStream_t stream)
{
    const float* x       = (const float*)d_in[0];
    const float* ln0_w   = (const float*)d_in[1];
    const float* ln0_b   = (const float*)d_in[2];
    const float* in_W    = (const float*)d_in[3];
    const float* rms_w   = (const float*)d_in[4];
    const float* exp_W   = (const float*)d_in[5];
    const float* conv_W  = (const float*)d_in[6];
    const float* xproj_W = (const float*)d_in[7];
    const float* dt_bias = (const float*)d_in[8];
    const float* A_log   = (const float*)d_in[9];
    const float* Dv      = (const float*)d_in[10];
    const float* outp_W  = (const float*)d_in[11];
    const float* outp_b  = (const float*)d_in[12];
    const float* n1_w    = (const float*)d_in[13];
    const float* n1_b    = (const float*)d_in[14];
    const float* aWq     = (const float*)d_in[15];
    const float* aWk     = (const float*)d_in[16];
    const float* aWv     = (const float*)d_in[17];
    const float* aWo     = (const float*)d_in[18];
    const float* aWo_b   = (const float*)d_in[19];
    const float* h_W     = (const float*)d_in[20];
    const float* h_b     = (const float*)d_in[21];
    const float* h_lnw   = (const float*)d_in[22];
    const float* h_lnb   = (const float*)d_in[23];
    const float* mtok    = (const float*)d_in[24];
    const float* e2d_W   = (const float*)d_in[25];
    const float* dn_w    = (const float*)d_in[26];
    const float* dn_b    = (const float*)d_in[27];
    const float* bWq     = (const float*)d_in[28];
    const float* bWk     = (const float*)d_in[29];
    const float* bWv     = (const float*)d_in[30];
    const float* bWo     = (const float*)d_in[31];
    const float* bWo_b   = (const float*)d_in[32];
    const float* dout_W  = (const float*)d_in[33];
    const float* dout_b  = (const float*)d_in[34];

    float* ws  = (float*)d_ws;
    float* out = (float*)d_out;

    float* S1 = ws;
    float* S2 = ws + 8388608;
    float* S3 = ws + 16777216;
    float* S4 = ws + 25165824;
    float* S5 = ws + 33554432;
    float* S6 = ws + 37748736;
    float* S7 = ws + 41943040;
    float* S8 = ws + 46137344;
    float* S9 = ws + 50331648;
    float* SP = ws + 54525952;

    unsigned short* XV2     = (unsigned short*)S1;
    unsigned short* exp_W2  = (unsigned short*)S1;
    unsigned short* XCT2    = (unsigned short*)S1;
    float*          POUTP   = S1;            // outp split-K partials
    float*          SA      = S1;
    unsigned short* P2      = (unsigned short*)S1;
    float*          KVm     = S1;            // fused K|V decoder buffer (32MB)
    unsigned short* in_W2   = (unsigned short*)S2;
    float*          XS      = S2;
    unsigned short* YS2     = (unsigned short*)S2;
    float*          PX      = S2;            // xproj split-K partials
    unsigned short* QKA2    = (unsigned short*)S2;  // merged Q|K pairs (32MB)
    float*          PB      = S2;            // bWkv... (unused alias kept)
    unsigned short* XC2     = (unsigned short*)S3;
    float*          PIN     = S3;            // in split-K partials
    unsigned short* outp_W2 = (unsigned short*)S3;
    float*          PATT    = S3;            // aWv / aWo split-K partials
    float*          PH      = S3;            // hW split-K partials
    float*          DXV     = S3;
    unsigned short* LNDXV2  = (unsigned short*)(S3 + 4194304);
    float*          Z       = S4;
    unsigned short* aWq2    = (unsigned short*)S4;
    unsigned short* aWk2    = (unsigned short*)S4 + 2097152;
    unsigned short* aWv2    = (unsigned short*)S4 + 4194304;
    unsigned short* aWo2    = (unsigned short*)S4 + 6291456;
    unsigned short* bWk2    = (unsigned short*)S4 + 8388608;
    unsigned short* bWv2    = (unsigned short*)S4 + 10485760;
    float*          T       = S5;
    unsigned short* Y22     = (unsigned short*)S5;
    unsigned short* HR2     = (unsigned short*)S6;
    float*          Y1      = S6;
    unsigned short* LNY2    = (unsigned short*)S7;
    unsigned short* OA2     = (unsigned short*)S7;
    unsigned short* VT2     = (unsigned short*)S9;

    float* dtBC = SP;
    float* DT   = SP + 589824;
    float* CUMA = SP + 655360;
    float* G    = SP + 720896;
    unsigned short* xprojW2 = (unsigned short*)(SP + 2818048);
    unsigned short* hW2     = (unsigned short*)(SP + 3112960);
    unsigned short* e2dW2   = (unsigned short*)(SP + 3178496);
    float* G1   = SP + 720896;
    unsigned short* HCQ2 = (unsigned short*)(SP + 983040);
    float* dxm  = SP + 1245184;
    float* lnm  = SP + 1246208;
    float* qm   = SP + 1247232;
    float* km   = SP + 1248256;
    float* vm   = SP + 1249280;
    float* OBm  = SP + 1250304;
    float* ydm  = SP + 1258496;
    float* outm = SP + 1266688;

    const long long LL0 = 0;
    const long long P4M = 4194304;
    #define G3D(OUTM, GX, GY, GZ, ...) \
        gemm_bf16_k<3, OUTM, true><<<dim3(GX, GY, GZ), 256, 0, stream>>>(__VA_ARGS__)
    #define G1D(OUTM, GX, GY, GZ, ...) \
        gemm_bf16_k<1, OUTM, true><<<dim3(GX, GY, GZ), 256, 0, stream>>>(__VA_ARGS__)

    // ---- weight prep (phase A) ----
    pairify(stream, in_W,    in_W2,   11, 1024LL * 2048);
    pairify(stream, xproj_W, xprojW2, 11, 144LL * 2048);
    pairify(stream, h_W,     hW2,     10, 64LL * 1024);
    pairify(stream, e2d_W,   e2dW2,    6, 1024LL * 64);

    // ---- encoder trunk ----
    layernorm_pair_k<<<4096, 256, 0, stream>>>(x, XV2, ln0_w, ln0_b, 2048, 512,
                                               (long long)1024 * 2048);
    // in: M=4096 N=1024 K=2048 -> DIRECT split-K x2 (512 blocks, 2/CU)
    gemm_bf16_skd_k<3, 0><<<dim3(8, 32, 2), 256, 0, stream>>>(
        1024, 1024, XV2, 4096, 2048, in_W2, 4096, 2048, PIN, P4M);
    skredN_k<<<16384, 256, 0, stream>>>(PIN, P4M, 2, nullptr, nullptr, 1024,
                                        T, P4M);
    pairify(stream, exp_W, exp_W2, 10, 4096LL * 1024);   // S1 (XV2 dead)
    rmsnorm_pair_k<<<4096, 256, 0, stream>>>(T, HR2, rms_w, 1024);
    G3D(0, 16, 32, 1, 4096, 2048, 1024, HR2, 2048, 1024, LL0, LL0,
        exp_W2, 2048, 1024, LL0, LL0, XS, 2048, 0, LL0, LL0,
        nullptr, nullptr, 0, 1.f, 1);
    G3D(0, 16, 32, 1, 4096, 2048, 1024, HR2, 2048, 1024, LL0, LL0,
        exp_W2 + 2048LL * 2048, 2048, 1024, LL0, LL0, Z, 2048, 0, LL0, LL0,
        nullptr, nullptr, 0, 1.f, 1);
    conv_k<<<dim3(32, 8, 8), 256, 0, stream>>>(XS, conv_W, XC2, XCT2);
    // xproj: ragged split-K x8
    gemm_bf16_sk_k<3><<<dim3(2, 32, 8), 256, 0, stream>>>(
        144, 256, XC2, 4096, 2048, xprojW2, 4096, 2048, PX, 589824LL);
    skredN_k<<<2304, 256, 0, stream>>>(PX, 589824LL, 8, nullptr, nullptr, 144,
                                       dtBC, 589824LL);
    dt_k<<<256, 256, 0, stream>>>(dtBC, dt_bias, DT);
    cuma_k<<<dim3(16, 8), 64, 0, stream>>>(DT, A_log, CUMA);
    gemm_f32_k<<<dim3(4, 4, 8), 256, 0, stream>>>(
        512, 512, 64, dtBC + 80, 144, (long long)512 * 144,
        dtBC + 16, 144, (long long)512 * 144, G, 512, (long long)512 * 512);
    ssd_mfma_k<<<dim3(4, 16, 8), 256, 0, stream>>>(G, CUMA, DT, XCT2, Z, Dv, YS2);

    // ---- weight prep (phase B: S3/S4 now dead) ----
    pairify(stream, outp_W, outp_W2, 11, 1024LL * 2048);
    pairify(stream, aWq, aWq2, 10, 1024LL * 1024);
    pairify(stream, aWk, aWk2, 10, 1024LL * 1024);
    pairify(stream, aWv, aWv2, 10, 1024LL * 1024);
    pairify(stream, aWo, aWo2, 10, 1024LL * 1024);
    pairify(stream, bWk, bWk2, 10, 1024LL * 1024);
    pairify(stream, bWv, bWv2, 10, 1024LL * 1024);

    // outp: split-K x2, partials in POUTP=S1 (XCT2 dead after ssd)
    gemm_bf16_skd_k<3, 0><<<dim3(8, 32, 2), 256, 0, stream>>>(
        1024, 1024, YS2, 4096, 2048, outp_W2, 4096, 2048, POUTP, P4M);
    skredN_k<<<16384, 256, 0, stream>>>(POUTP, P4M, 2, outp_b, T, 1024,
                                        Y1, P4M);

    // ---- encoder attention (all MFMA) ----
    layernorm_pair_k<<<4096, 256, 0, stream>>>(Y1, LNY2, n1_w, n1_b, 1024, 4096, LL0);
    // merged Q|K projection: N=2048 (aWq2 and aWk2 are contiguous), 512
    // blocks, OUT1 pairs into QKA2 (ldc=4096, cLo=2048). YS2 (S2) dead.
    G3D(1, 16, 32, 1, 4096, 2048, 1024, LNY2, 2048, 1024, LL0, LL0,
        aWq2, 2048, 1024, LL0, LL0, QKA2, 4096, 2048, LL0, LL0,
        nullptr, nullptr, 0, 1.f, 1);
    // aWv: split-K x2 with transposed partials -> VT2
    gemm_bf16_skd_k<3, 1><<<dim3(8, 32, 2), 256, 0, stream>>>(
        1024, 512, LNY2, 2048, 1024, aWv2, 2048, 1024, PATT, P4M);
    skredT_k<<<16384, 256, 0, stream>>>(PATT, P4M, 2, VT2, P4M);
    // QK^T: Q at QKA2 col 0-1023, K at col 1024-2047
    G3D(0, 4, 4, 32, 512, 512, 256,
        QKA2, 4096, 2048, (long long)512 * 4096, 256,
        QKA2 + 1024, 4096, 2048, (long long)512 * 4096, 256,
        SA, 512, 0, (long long)4 * 512 * 512, (long long)512 * 512,
        nullptr, nullptr, 0, 1.f / 16.f, 4);
    softmax_pair_k<<<16384, 256, 0, stream>>>(SA, P2);
    G3D(1, 2, 4, 32, 512, 256, 512,
        P2, 1024, 512, (long long)4 * 512 * 1024, (long long)512 * 1024,
        VT2, 1024, 512, (long long)1024 * 1024, (long long)256 * 1024,
        OA2, 2048, 1024, (long long)512 * 2048, 256,
        nullptr, nullptr, 0, 1.f, 4);
    // aWo: split-K x2 -> skredP with bias + residual(Y1) -> Y22 pairs
    gemm_bf16_skd_k<3, 0><<<dim3(8, 32, 2), 256, 0, stream>>>(
        1024, 512, OA2, 2048, 1024, aWo2, 2048, 1024, PATT, P4M);
    skredP_k<<<16384, 256, 0, stream>>>(PATT, P4M, 2, aWo_b, Y1, Y22, P4M);

    // ---- quantize: G1 = Y22 @ hW^T + h_b (ragged split-K x8) ----
    gemm_bf16_sk_k<3><<<dim3(1, 32, 8), 256, 0, stream>>>(
        64, 128, Y22, 2048, 1024, hW2, 2048, 1024, PH, 262144LL);
    skredN_k<<<1024, 256, 0, stream>>>(PH, 262144LL, 8, h_b, nullptr, 64,
                                       G1, 262144LL);
    hc_quant_k<<<4096, 64, 0, stream>>>(G1, h_lnw, h_lnb, HCQ2);

    // ---- decoder (collapsed masked rows) ----
    G3D(0, 8, 32, 1, 4096, 1024, 64, HCQ2, 128, 64, LL0, LL0,
        e2dW2, 128, 64, LL0, LL0, DXV, 1024, 0, LL0, LL0,
        nullptr, nullptr, 0, 1.f, 1);
    dxm_k<<<4, 256, 0, stream>>>(mtok, e2d_W, dxm);
    layernorm_k<<<1, 256, 0, stream>>>(dxm, lnm, dn_w, dn_b, 1024, 1, LL0);
    layernorm_pair_k<<<4096, 256, 0, stream>>>(DXV, LNDXV2, dn_w, dn_b, 1024, 4096, LL0);
    projm_k<<<12, 256, 0, stream>>>(lnm, bWq, bWk, bWv, qm, km, vm);
    // merged K|V projection: N=2048 (bWk2, bWv2 contiguous), OUT0 f32 into
    // fused KVm (S1; SA/P2 dead after PV). 512 blocks, NPASS=1.
    G1D(0, 16, 32, 1, 4096, 2048, 1024, LNDXV2, 2048, 1024, LL0, LL0,
        bWk2, 2048, 1024, LL0, LL0, KVm, 2048, 0, LL0, LL0,
        nullptr, nullptr, 0, 1.f, 1);
    dec_attn_k<<<dim3(4, 8), 256, 0, stream>>>(KVm, qm, km, vm, OBm);
    ydm_k<<<32, 256, 0, stream>>>(OBm, bWo, bWo_b, dxm, ydm);
    outm_k<<<64, 256, 0, stream>>>(ydm, dout_W, dout_b, outm);
    bcast_k<<<8192, 256, 0, stream>>>(outm, out);
    #undef G3D
    #undef G1D
}

// Round 6
// 1059.288 us; speedup vs baseline: 1.3277x; 1.0347x over previous
//
#include <hip/hip_runtime.h>

// ---------------------------------------------------------------------------
// B=8, N=1024, CIN=2048, HID=1024, HC=64, LV=512, NH_SSD=16, HD=128, DS=64.
// Encoder rows = 4096. Decoder collapsed to 1 row/batch. All large GEMMs:
// split-bf16 MFMA (x3 passes = f32-grade pre-quantizer; x1 post-quantizer),
// staged via __builtin_amdgcn_global_load_lds width=16 (DIRECT path).
// DIRECT GEMM: double-buffered 64KB LDS (2 blocks/CU), vmcnt(0)+barrier,
// source-swizzled staging. XCD-chunked block remap (bijective) gives each
// XCD a contiguous tile band -> A-panels L2-resident (staging was L2/L3
// service-bound at 58us/dispatch). exp GEMM pair merged via gridDim.z.
// Split-K x2 for 256-block GEMMs; Q|K and K|V projections merged (N=2048).
// One-pass register LayerNorm/RMSNorm (was 3x re-read).
// ---------------------------------------------------------------------------

typedef short bf16x8 __attribute__((ext_vector_type(8)));
typedef float f32x4 __attribute__((ext_vector_type(4)));

__device__ __forceinline__ unsigned short bf16_rne(float f) {
    unsigned u = __float_as_uint(f);
    unsigned r = u + 0x7FFFu + ((u >> 16) & 1u);
    return (unsigned short)(r >> 16);
}
__device__ __forceinline__ float bf16_tof(unsigned short h) {
    return __uint_as_float(((unsigned)h) << 16);
}
__device__ __forceinline__ void store_pair(unsigned short* dst, long long row,
                                           int width, int c, float v) {
    unsigned short hi = bf16_rne(v);
    unsigned short lo = bf16_rne(v - bf16_tof(hi));
    long long base = row * (2LL * width);
    dst[base + c] = hi;
    dst[base + width + c] = lo;
}
// Async global->LDS, 16B per lane. LDS dest = wave-uniform base + lane*16.
__device__ __forceinline__ void async_ld16(const unsigned short* g, unsigned short* l) {
    __builtin_amdgcn_global_load_lds(
        (const __attribute__((address_space(1))) unsigned int*)g,
        (__attribute__((address_space(3))) unsigned int*)l, 16, 0, 0);
}

// XCD-chunked bijective block remap (T1): hardware round-robins linear id
// mod 8 across XCDs; remap so each XCD owns a CONTIGUOUS band of logical
// tiles -> neighbor blocks sharing operand panels co-reside on one L2.
// Identity when nwg % 8 != 0 (bijectivity guard, ERRATA #11).
__device__ __forceinline__ void xcd_remap(int& bx, int& by) {
    const int Gx = gridDim.x;
    const int nwg = Gx * gridDim.y;
    if ((nwg & 7) != 0) return;
    int lin = bx + Gx * by;
    int logical = (lin & 7) * (nwg >> 3) + (lin >> 3);
    bx = logical % Gx;
    by = logical / Gx;
}

// ---------------------------------------------------------------------------
// Reduction helpers (blockDim 256)
// ---------------------------------------------------------------------------
__device__ __forceinline__ float block_sum256(float v) {
    #pragma unroll
    for (int o = 32; o > 0; o >>= 1) v += __shfl_xor(v, o, 64);
    __shared__ float sm[4];
    int w = threadIdx.x >> 6;
    __syncthreads();
    if ((threadIdx.x & 63) == 0) sm[w] = v;
    __syncthreads();
    return sm[0] + sm[1] + sm[2] + sm[3];
}
__device__ __forceinline__ float block_max256(float v) {
    #pragma unroll
    for (int o = 32; o > 0; o >>= 1) v = fmaxf(v, __shfl_xor(v, o, 64));
    __shared__ float smx[4];
    int w = threadIdx.x >> 6;
    __syncthreads();
    if ((threadIdx.x & 63) == 0) smx[w] = v;
    __syncthreads();
    return fmaxf(fmaxf(smx[0], smx[1]), fmaxf(smx[2], smx[3]));
}

// ---------------------------------------------------------------------------
// Split-bf16 MFMA GEMM. C[m,n] = alpha * sum_k A[m,k]*B[n,k] (+bias)(+res)
// NPASS=3: hh+lh+hl (f32-grade). NPASS=1: hh only.
// OUT=0: f32 C. OUT=1: split-pair C. OUT=2: transposed split-pair per
// 512-row batch.
// DIRECT=true: global_load_lds staging, double-buffered (64KB @ NPASS=3 ->
//   2 blocks/CU), vmcnt(0)+barrier then stage-next, source-swizzled for
//   conflict-free b128. Requires full tiles and K % 32 == 0.
// DIRECT=false: guarded reg staging (ragged N ok), 2-barrier loop.
// ---------------------------------------------------------------------------
template<int NPASS, int OUT, bool DIRECT>
__global__ __launch_bounds__(256, 2) void gemm_bf16_k(
    int M, int N, int K,
    const unsigned short* __restrict__ A2, int lda2, int aLo, long long sAb, long long sAh,
    const unsigned short* __restrict__ B2, int ldb2, int bLo, long long sBb, long long sBh,
    void* __restrict__ Cv, int ldc, int cLo, long long sCb, long long sCh,
    const float* __restrict__ bias, const float* __restrict__ res, int ldr,
    float alpha, int nh)
{
    constexpr int ST   = DIRECT ? 32 : 40;
    constexpr int NARR = (NPASS == 3) ? 4 : 2;
    constexpr int NB   = DIRECT ? 2 : 1;
    constexpr int O_AH = 0;
    constexpr int O_BH = 128 * ST;
    constexpr int O_AL = 2 * 128 * ST;
    constexpr int O_BL = 3 * 128 * ST;
    constexpr int BUFSZ = 128 * ST * NARR;
    __shared__ unsigned short SM[NB * BUFSZ];

    const int z  = blockIdx.z;
    const int bb = z / nh, hh = z - bb * nh;
    A2 += bb * sAb + hh * sAh;
    B2 += bb * sBb + hh * sBh;

    int bx = blockIdx.x, by = blockIdx.y;
    xcd_remap(bx, by);
    const int t    = threadIdx.x;
    const int m0   = by * 128;
    const int n0   = bx * 128;
    const int lane = t & 63, wave = t >> 6;
    const int wm   = (wave >> 1) * 64, wn = (wave & 1) * 64;
    const int lr   = lane & 15, quad = lane >> 4;

    f32x4 acc[4][4];
    #pragma unroll
    for (int i = 0; i < 4; ++i)
        #pragma unroll
        for (int j = 0; j < 4; ++j) acc[i][j] = (f32x4){0.f, 0.f, 0.f, 0.f};

    if constexpr (DIRECT) {
        const int drow  = lane >> 2;                       // row in 16-chunk
        const int dcswz = (((lane & 3) ^ ((lane >> 2) & 3) ^ ((lane >> 4) & 3)) << 3);
        const int rsw   = ((quad ^ ((lr & 3) ^ (lr >> 2))) << 3);

        auto stage = [&](int k0, int buf) {
            unsigned short* bp = &SM[buf * BUFSZ];
            #pragma unroll
            for (int j = 0; j < 2; ++j) {
                int rr = wave * 32 + j * 16;               // chunk base row
                int gr = rr + drow;
                const unsigned short* gA = A2 + (long long)(m0 + gr) * lda2 + k0 + dcswz;
                async_ld16(gA, &bp[O_AH + rr * 32]);
                if (NPASS == 3) async_ld16(gA + aLo, &bp[O_AL + rr * 32]);
                const unsigned short* gB = B2 + (long long)(n0 + gr) * ldb2 + k0 + dcswz;
                async_ld16(gB, &bp[O_BH + rr * 32]);
                if (NPASS == 3) async_ld16(gB + bLo, &bp[O_BL + rr * 32]);
            }
        };

        const int nt = K >> 5;
        stage(0, 0);
        int cur = 0;
        for (int it = 0; it < nt; ++it) {
            asm volatile("s_waitcnt vmcnt(0)" ::: "memory");
            __builtin_amdgcn_s_barrier();
            if (it + 1 < nt) stage((it + 1) << 5, cur ^ 1);

            const unsigned short* bp = &SM[cur * BUFSZ];
            bf16x8 ah[4], bh[4], al[4], bl[4];
            #pragma unroll
            for (int i = 0; i < 4; ++i) {
                int ra = O_AH + (wm + i * 16 + lr) * 32 + rsw;
                int rb = O_BH + (wn + i * 16 + lr) * 32 + rsw;
                ah[i] = *(const bf16x8*)&bp[ra];
                bh[i] = *(const bf16x8*)&bp[rb];
                if (NPASS == 3) {
                    al[i] = *(const bf16x8*)&bp[ra + (O_AL - O_AH)];
                    bl[i] = *(const bf16x8*)&bp[rb + (O_BL - O_BH)];
                }
            }
            #pragma unroll
            for (int mi = 0; mi < 4; ++mi)
                #pragma unroll
                for (int ni = 0; ni < 4; ++ni) {
                    acc[mi][ni] = __builtin_amdgcn_mfma_f32_16x16x32_bf16(
                        ah[mi], bh[ni], acc[mi][ni], 0, 0, 0);
                    if (NPASS == 3) {
                        acc[mi][ni] = __builtin_amdgcn_mfma_f32_16x16x32_bf16(
                            al[mi], bh[ni], acc[mi][ni], 0, 0, 0);
                        acc[mi][ni] = __builtin_amdgcn_mfma_f32_16x16x32_bf16(
                            ah[mi], bl[ni], acc[mi][ni], 0, 0, 0);
                    }
                }
            cur ^= 1;
        }
    } else {
        // ---- ragged reg-staging path ----
        const int srow = t >> 2;          // row 0..63 (+64)
        const int scol = (t & 3) * 8;

        for (int k0 = 0; k0 < K; k0 += 32) {
            __syncthreads();
            #pragma unroll
            for (int half = 0; half < 2; ++half) {
                int r = srow + half * 64;
                const unsigned short* pA = A2 + (long long)(m0 + r) * lda2 + k0 + scol;
                *(uint4*)&SM[O_AH + r * ST + scol] = *(const uint4*)pA;
                if (NPASS == 3)
                    *(uint4*)&SM[O_AL + r * ST + scol] = *(const uint4*)(pA + aLo);
                int rb = n0 + r;
                uint4 vh = {0u, 0u, 0u, 0u}, vl = {0u, 0u, 0u, 0u};
                if (rb < N) {
                    const unsigned short* pB = B2 + (long long)rb * ldb2 + k0 + scol;
                    vh = *(const uint4*)pB;
                    if (NPASS == 3) vl = *(const uint4*)(pB + bLo);
                }
                *(uint4*)&SM[O_BH + r * ST + scol] = vh;
                if (NPASS == 3) *(uint4*)&SM[O_BL + r * ST + scol] = vl;
            }
            __syncthreads();

            bf16x8 ah[4], bh[4], al[4], bl[4];
            #pragma unroll
            for (int i = 0; i < 4; ++i) {
                int ra = (wm + i * 16 + lr) * ST + quad * 8;
                int rb = (wn + i * 16 + lr) * ST + quad * 8;
                ah[i] = *(const bf16x8*)&SM[O_AH + ra];
                bh[i] = *(const bf16x8*)&SM[O_BH + rb];
                if (NPASS == 3) {
                    al[i] = *(const bf16x8*)&SM[O_AL + ra];
                    bl[i] = *(const bf16x8*)&SM[O_BL + rb];
                }
            }
            #pragma unroll
            for (int mi = 0; mi < 4; ++mi)
                #pragma unroll
                for (int ni = 0; ni < 4; ++ni) {
                    acc[mi][ni] = __builtin_amdgcn_mfma_f32_16x16x32_bf16(
                        ah[mi], bh[ni], acc[mi][ni], 0, 0, 0);
                    if (NPASS == 3) {
                        acc[mi][ni] = __builtin_amdgcn_mfma_f32_16x16x32_bf16(
                            al[mi], bh[ni], acc[mi][ni], 0, 0, 0);
                        acc[mi][ni] = __builtin_amdgcn_mfma_f32_16x16x32_bf16(
                            ah[mi], bl[ni], acc[mi][ni], 0, 0, 0);
                    }
                }
        }
    }

    // D layout: col = lane&15, row = quad*4 + r
    if (OUT == 0) {
        float* C = (float*)Cv + bb * sCb + hh * sCh;
        #pragma unroll
        for (int mi = 0; mi < 4; ++mi)
            #pragma unroll
            for (int ni = 0; ni < 4; ++ni) {
                int col = n0 + wn + ni * 16 + lr;
                if (col >= N) continue;
                float bv = bias ? bias[col] : 0.f;
                #pragma unroll
                for (int r = 0; r < 4; ++r) {
                    int row = m0 + wm + mi * 16 + quad * 4 + r;
                    float v = alpha * acc[mi][ni][r] + bv;
                    if (res) v += res[(long long)row * ldr + col];
                    C[(long long)row * ldc + col] = v;
                }
            }
    } else if (OUT == 1) {
        unsigned short* C = (unsigned short*)Cv + bb * sCb + hh * sCh;
        #pragma unroll
        for (int mi = 0; mi < 4; ++mi)
            #pragma unroll
            for (int ni = 0; ni < 4; ++ni) {
                int col = n0 + wn + ni * 16 + lr;
                if (col >= N) continue;
                float bv = bias ? bias[col] : 0.f;
                #pragma unroll
                for (int r = 0; r < 4; ++r) {
                    int row = m0 + wm + mi * 16 + quad * 4 + r;
                    float v = alpha * acc[mi][ni][r] + bv;
                    if (res) v += res[(long long)row * ldr + col];
                    unsigned short hi = bf16_rne(v);
                    unsigned short lo = bf16_rne(v - bf16_tof(hi));
                    long long p = (long long)row * ldc + col;
                    C[p] = hi;
                    C[p + cLo] = lo;
                }
            }
    } else {  // OUT == 2: transposed pairs per 512-row batch
        unsigned short* C = (unsigned short*)Cv;
        #pragma unroll
        for (int mi = 0; mi < 4; ++mi)
            #pragma unroll
            for (int ni = 0; ni < 4; ++ni) {
                int col = n0 + wn + ni * 16 + lr;
                if (col >= N) continue;
                int row0 = m0 + wm + mi * 16 + quad * 4;
                int b = row0 >> 9, seq0 = row0 & 511;
                ushort4 h4, l4;
                unsigned short* hp = (unsigned short*)&h4;
                unsigned short* lp = (unsigned short*)&l4;
                #pragma unroll
                for (int r = 0; r < 4; ++r) {
                    float v = acc[mi][ni][r];
                    unsigned short hi = bf16_rne(v);
                    hp[r] = hi;
                    lp[r] = bf16_rne(v - bf16_tof(hi));
                }
                long long p = b * sCb + (long long)col * ldc + seq0;
                *(ushort4*)&C[p] = h4;
                *(ushort4*)&C[p + cLo] = l4;
            }
    }
}

// ---------------------------------------------------------------------------
// DIRECT pipelined split-K GEMM -> f32 partial planes.
// grid (N/128, M/128, nkc); block z accumulates K range [z*KC, (z+1)*KC).
// TR=0: partial[row*N + col]. TR=1 (for OUT2 consumers): partial at
// [b*(N*512) + col*512 + seq] (b=row>>9, seq=row&511), float4 along seq.
// ---------------------------------------------------------------------------
template<int NPASS, int TR>
__global__ __launch_bounds__(256, 2) void gemm_bf16_skd_k(
    int N, int KC,
    const unsigned short* __restrict__ A2, int lda2, int aLo,
    const unsigned short* __restrict__ B2, int ldb2, int bLo,
    float* __restrict__ P, long long sCk)
{
    constexpr int NARR = (NPASS == 3) ? 4 : 2;
    constexpr int O_AH = 0;
    constexpr int O_BH = 128 * 32;
    constexpr int O_AL = 2 * 128 * 32;
    constexpr int O_BL = 3 * 128 * 32;
    constexpr int BUFSZ = 128 * 32 * NARR;
    __shared__ unsigned short SM[2 * BUFSZ];

    int bx = blockIdx.x, by = blockIdx.y;
    xcd_remap(bx, by);
    const int t    = threadIdx.x;
    const int m0   = by * 128;
    const int n0   = bx * 128;
    const int kbeg = blockIdx.z * KC;
    const int lane = t & 63, wave = t >> 6;
    const int wm   = (wave >> 1) * 64, wn = (wave & 1) * 64;
    const int lr   = lane & 15, quad = lane >> 4;

    f32x4 acc[4][4];
    #pragma unroll
    for (int i = 0; i < 4; ++i)
        #pragma unroll
        for (int j = 0; j < 4; ++j) acc[i][j] = (f32x4){0.f, 0.f, 0.f, 0.f};

    const int drow  = lane >> 2;
    const int dcswz = (((lane & 3) ^ ((lane >> 2) & 3) ^ ((lane >> 4) & 3)) << 3);
    const int rsw   = ((quad ^ ((lr & 3) ^ (lr >> 2))) << 3);

    auto stage = [&](int k0, int buf) {
        unsigned short* bp = &SM[buf * BUFSZ];
        #pragma unroll
        for (int j = 0; j < 2; ++j) {
            int rr = wave * 32 + j * 16;
            int gr = rr + drow;
            const unsigned short* gA = A2 + (long long)(m0 + gr) * lda2 + k0 + dcswz;
            async_ld16(gA, &bp[O_AH + rr * 32]);
            if (NPASS == 3) async_ld16(gA + aLo, &bp[O_AL + rr * 32]);
            const unsigned short* gB = B2 + (long long)(n0 + gr) * ldb2 + k0 + dcswz;
            async_ld16(gB, &bp[O_BH + rr * 32]);
            if (NPASS == 3) async_ld16(gB + bLo, &bp[O_BL + rr * 32]);
        }
    };

    const int nt = KC >> 5;
    stage(kbeg, 0);
    int cur = 0;
    for (int it = 0; it < nt; ++it) {
        asm volatile("s_waitcnt vmcnt(0)" ::: "memory");
        __builtin_amdgcn_s_barrier();
        if (it + 1 < nt) stage(kbeg + ((it + 1) << 5), cur ^ 1);

        const unsigned short* bp = &SM[cur * BUFSZ];
        bf16x8 ah[4], bh[4], al[4], bl[4];
        #pragma unroll
        for (int i = 0; i < 4; ++i) {
            int ra = O_AH + (wm + i * 16 + lr) * 32 + rsw;
            int rb = O_BH + (wn + i * 16 + lr) * 32 + rsw;
            ah[i] = *(const bf16x8*)&bp[ra];
            bh[i] = *(const bf16x8*)&bp[rb];
            if (NPASS == 3) {
                al[i] = *(const bf16x8*)&bp[ra + (O_AL - O_AH)];
                bl[i] = *(const bf16x8*)&bp[rb + (O_BL - O_BH)];
            }
        }
        #pragma unroll
        for (int mi = 0; mi < 4; ++mi)
            #pragma unroll
            for (int ni = 0; ni < 4; ++ni) {
                acc[mi][ni] = __builtin_amdgcn_mfma_f32_16x16x32_bf16(
                    ah[mi], bh[ni], acc[mi][ni], 0, 0, 0);
                if (NPASS == 3) {
                    acc[mi][ni] = __builtin_amdgcn_mfma_f32_16x16x32_bf16(
                        al[mi], bh[ni], acc[mi][ni], 0, 0, 0);
                    acc[mi][ni] = __builtin_amdgcn_mfma_f32_16x16x32_bf16(
                        ah[mi], bl[ni], acc[mi][ni], 0, 0, 0);
                }
            }
        cur ^= 1;
    }

    float* Pc = P + (long long)blockIdx.z * sCk;
    if (TR == 0) {
        #pragma unroll
        for (int mi = 0; mi < 4; ++mi)
            #pragma unroll
            for (int ni = 0; ni < 4; ++ni) {
                int col = n0 + wn + ni * 16 + lr;
                #pragma unroll
                for (int r = 0; r < 4; ++r) {
                    int row = m0 + wm + mi * 16 + quad * 4 + r;
                    Pc[(long long)row * N + col] = acc[mi][ni][r];
                }
            }
    } else {
        #pragma unroll
        for (int mi = 0; mi < 4; ++mi)
            #pragma unroll
            for (int ni = 0; ni < 4; ++ni) {
                int col = n0 + wn + ni * 16 + lr;
                int row0 = m0 + wm + mi * 16 + quad * 4;
                int b = row0 >> 9, seq0 = row0 & 511;
                *(float4*)&Pc[(long long)b * ((long long)N * 512)
                              + (long long)col * 512 + seq0] =
                    *(float4*)&acc[mi][ni];
            }
    }
}

// ---------------------------------------------------------------------------
// Split-K ragged GEMM for thin-N ops (xproj N=144, hW N=64).
// ---------------------------------------------------------------------------
template<int NPASS>
__global__ __launch_bounds__(256, 2) void gemm_bf16_sk_k(
    int N, int KC,
    const unsigned short* __restrict__ A2, int lda2, int aLo,
    const unsigned short* __restrict__ B2, int ldb2, int bLo,
    float* __restrict__ C, long long sCk)
{
    constexpr int ST = 40;
    __shared__ unsigned short Ah[128 * ST];
    __shared__ unsigned short Bh[128 * ST];
    __shared__ unsigned short Al[128 * ST];
    __shared__ unsigned short Bl[128 * ST];

    int bx = blockIdx.x, by = blockIdx.y;
    xcd_remap(bx, by);
    const int t    = threadIdx.x;
    const int m0   = by * 128;
    const int n0   = bx * 128;
    const int kbeg = blockIdx.z * KC;
    const int lane = t & 63, wave = t >> 6;
    const int wm   = (wave >> 1) * 64, wn = (wave & 1) * 64;
    const int lr   = lane & 15, quad = lane >> 4;

    f32x4 acc[4][4];
    #pragma unroll
    for (int i = 0; i < 4; ++i)
        #pragma unroll
        for (int j = 0; j < 4; ++j) acc[i][j] = (f32x4){0.f, 0.f, 0.f, 0.f};

    const int srow = t >> 2;
    const int scol = (t & 3) * 8;

    for (int k0 = kbeg; k0 < kbeg + KC; k0 += 32) {
        __syncthreads();
        #pragma unroll
        for (int half = 0; half < 2; ++half) {
            int r = srow + half * 64;
            const unsigned short* pA = A2 + (long long)(m0 + r) * lda2 + k0 + scol;
            *(uint4*)&Ah[r * ST + scol] = *(const uint4*)pA;
            if (NPASS == 3)
                *(uint4*)&Al[r * ST + scol] = *(const uint4*)(pA + aLo);
            int rb = n0 + r;
            uint4 vh = {0u, 0u, 0u, 0u}, vl = {0u, 0u, 0u, 0u};
            if (rb < N) {
                const unsigned short* pB = B2 + (long long)rb * ldb2 + k0 + scol;
                vh = *(const uint4*)pB;
                if (NPASS == 3) vl = *(const uint4*)(pB + bLo);
            }
            *(uint4*)&Bh[r * ST + scol] = vh;
            if (NPASS == 3) *(uint4*)&Bl[r * ST + scol] = vl;
        }
        __syncthreads();

        bf16x8 ah[4], bh[4], al[4], bl[4];
        #pragma unroll
        for (int i = 0; i < 4; ++i) {
            int ra = (wm + i * 16 + lr) * ST + quad * 8;
            int rb = (wn + i * 16 + lr) * ST + quad * 8;
            ah[i] = *(const bf16x8*)&Ah[ra];
            bh[i] = *(const bf16x8*)&Bh[rb];
            if (NPASS == 3) {
                al[i] = *(const bf16x8*)&Al[ra];
                bl[i] = *(const bf16x8*)&Bl[rb];
            }
        }
        #pragma unroll
        for (int mi = 0; mi < 4; ++mi)
            #pragma unroll
            for (int ni = 0; ni < 4; ++ni) {
                acc[mi][ni] = __builtin_amdgcn_mfma_f32_16x16x32_bf16(
                    ah[mi], bh[ni], acc[mi][ni], 0, 0, 0);
                if (NPASS == 3) {
                    acc[mi][ni] = __builtin_amdgcn_mfma_f32_16x16x32_bf16(
                        al[mi], bh[ni], acc[mi][ni], 0, 0, 0);
                    acc[mi][ni] = __builtin_amdgcn_mfma_f32_16x16x32_bf16(
                        ah[mi], bl[ni], acc[mi][ni], 0, 0, 0);
                }
            }
    }

    float* Cc = C + (long long)blockIdx.z * sCk;
    #pragma unroll
    for (int mi = 0; mi < 4; ++mi)
        #pragma unroll
        for (int ni = 0; ni < 4; ++ni) {
            int col = n0 + wn + ni * 16 + lr;
            if (col >= N) continue;
            #pragma unroll
            for (int r = 0; r < 4; ++r) {
                int row = m0 + wm + mi * 16 + quad * 4 + r;
                Cc[(long long)row * N + col] = acc[mi][ni][r];
            }
        }
}

// ---- split-K reduce epilogues ----
__global__ __launch_bounds__(256) void skredN_k(
    const float* __restrict__ P, long long sCk, int nchunk,
    const float* __restrict__ bias, const float* __restrict__ res, int ncol,
    float* __restrict__ outp, long long n)
{
    long long idx = (long long)blockIdx.x * 256 + threadIdx.x;
    if (idx >= n) return;
    float s = 0.f;
    for (int c = 0; c < nchunk; ++c) s += P[c * sCk + idx];
    if (bias) s += bias[(int)(idx % ncol)];
    if (res) s += res[idx];
    outp[idx] = s;
}

// pairs out, N=1024 layout: pos = row*2048 + col, lo at +1024
__global__ __launch_bounds__(256) void skredP_k(
    const float* __restrict__ P, long long sCk, int nchunk,
    const float* __restrict__ bias, const float* __restrict__ res,
    unsigned short* __restrict__ out2, long long n)
{
    long long idx = (long long)blockIdx.x * 256 + threadIdx.x;
    if (idx >= n) return;
    float s = 0.f;
    for (int c = 0; c < nchunk; ++c) s += P[c * sCk + idx];
    int col = (int)(idx & 1023);
    long long row = idx >> 10;
    if (bias) s += bias[col];
    if (res) s += res[idx];
    unsigned short hi = bf16_rne(s);
    unsigned short lo = bf16_rne(s - bf16_tof(hi));
    long long pos = row * 2048 + col;
    out2[pos] = hi;
    out2[pos + 1024] = lo;
}

// transposed pairs out (VT2 layout): partials already transposed (TR=1):
// idx = b*(1024*512) + col*512 + seq -> out[b*1048576 + col*1024 + seq]
__global__ __launch_bounds__(256) void skredT_k(
    const float* __restrict__ P, long long sCk, int nchunk,
    unsigned short* __restrict__ out2, long long n)
{
    long long idx = (long long)blockIdx.x * 256 + threadIdx.x;
    if (idx >= n) return;
    float s = 0.f;
    for (int c = 0; c < nchunk; ++c) s += P[c * sCk + idx];
    int seq = (int)(idx & 511);
    int col = (int)((idx >> 9) & 1023);
    int b   = (int)(idx >> 19);
    unsigned short hi = bf16_rne(s);
    unsigned short lo = bf16_rne(s - bf16_tof(hi));
    long long pos = (long long)b * 1048576 + (long long)col * 1024 + seq;
    out2[pos] = hi;
    out2[pos + 512] = lo;
}

// ---------------------------------------------------------------------------
// Fused SSD intra-chunk MFMA kernel, v4 (unchanged).
// ---------------------------------------------------------------------------
__global__ __launch_bounds__(256, 2) void ssd_mfma_k(
    const float* __restrict__ G, const float* __restrict__ CUMA,
    const float* __restrict__ DT, const unsigned short* __restrict__ XCT2,
    const float* __restrict__ Z, const float* __restrict__ Dv,
    unsigned short* __restrict__ YS2)
{
    __shared__ unsigned short Xh[3][128 * 32];
    __shared__ unsigned short Xl[3][128 * 32];
    __shared__ unsigned short Wh[2][64 * 32];
    __shared__ unsigned short Wl[2][64 * 32];
    __shared__ float Cs[512];
    __shared__ float Ds[512];
    const int q = blockIdx.x;
    const int h = blockIdx.y, b = blockIdx.z;
    const int t = threadIdx.x;
    const int lane = t & 63, wave = t >> 6;
    const int lr = lane & 15, quad = lane >> 4;

    const float* cbase = CUMA + (b * 16 + h) * 512;
    const float* dtb = DT + (long long)b * 512 * 16 + h;
    for (int s = t; s < 512; s += 256) {
        Cs[s] = cbase[s];
        Ds[s] = dtb[(long long)s * 16];
    }
    const float Dh = Dv[h];

    const int wr = t >> 2;
    const int sw = t & 3;
    const int wbase = wr * 32 + ((sw ^ ((wr >> 1) & 3)) << 3);
    const int frow = wave * 16 + lr;
    const int fbase = frow * 32 + ((quad ^ ((frow >> 1) & 3)) << 3);
    const int drow  = lane >> 2;
    const int dcswz = (((lane & 3) ^ ((lane >> 2) & 3) ^ ((lane >> 4) & 3)) << 3);
    const int xsw   = ((quad ^ ((lr & 3) ^ ((lr >> 2) & 3))) << 3);
    const unsigned short* XB = XCT2 + (long long)b * 2097152
                             + (long long)(h * 128) * 1024;
    __syncthreads();

    for (int ph = 0; ph < 2; ++ph) {
        const int mt = ph ? q : 7 - q;
        const int m0 = mt * 64;
        const int nt = (m0 >> 5) + 2;
        const int lglob = m0 + wr;
        const float cAl = Cs[lglob];
        const float* grow = G + ((long long)(b * 512 + lglob)) * 512;

        float pg[8], pc[8], pd[8];
        auto gen_load = [&](int k0g) {
            const int sb = k0g + sw * 8;
            float4 g0 = *(const float4*)(grow + sb);
            float4 g1 = *(const float4*)(grow + sb + 4);
            float4 c0 = *(const float4*)&Cs[sb];
            float4 c1 = *(const float4*)&Cs[sb + 4];
            float4 d0 = *(const float4*)&Ds[sb];
            float4 d1 = *(const float4*)&Ds[sb + 4];
            pg[0] = g0.x; pg[1] = g0.y; pg[2] = g0.z; pg[3] = g0.w;
            pg[4] = g1.x; pg[5] = g1.y; pg[6] = g1.z; pg[7] = g1.w;
            pc[0] = c0.x; pc[1] = c0.y; pc[2] = c0.z; pc[3] = c0.w;
            pc[4] = c1.x; pc[5] = c1.y; pc[6] = c1.z; pc[7] = c1.w;
            pd[0] = d0.x; pd[1] = d0.y; pd[2] = d0.z; pd[3] = d0.w;
            pd[4] = d1.x; pd[5] = d1.y; pd[6] = d1.z; pd[7] = d1.w;
        };
        auto gen_finish = [&](int k0g, int buf) {
            const int sb = k0g + sw * 8;
            const bool edge = (k0g + 32 > m0);
            unsigned short hv[8], lv[8];
            #pragma unroll
            for (int e = 0; e < 8; ++e) {
                float w = pg[e] * __expf(cAl - pc[e]) * pd[e];
                if (edge) {
                    int sg = sb + e;
                    w = (sg <= lglob) ? w : 0.f;
                    if (sg == lglob) w += Dh;
                }
                unsigned short hi = bf16_rne(w);
                hv[e] = hi;
                lv[e] = bf16_rne(w - bf16_tof(hi));
            }
            *(uint4*)&Wh[buf][wbase] = *(uint4*)hv;
            *(uint4*)&Wl[buf][wbase] = *(uint4*)lv;
        };
        auto stageX = [&](int k0, int buf) {
            #pragma unroll
            for (int j = 0; j < 2; ++j) {
                int rr = wave * 32 + j * 16;
                const unsigned short* gX =
                    XB + (long long)(rr + drow) * 1024 + k0 + dcswz;
                async_ld16(gX,       &Xh[buf][rr * 32]);
                async_ld16(gX + 512, &Xl[buf][rr * 32]);
            }
        };

        f32x4 acc[8];
        #pragma unroll
        for (int j = 0; j < 8; ++j) acc[j] = (f32x4){0.f, 0.f, 0.f, 0.f};

        gen_load(0);
        stageX(0, 0);
        if (nt > 1) stageX(32, 1);
        gen_finish(0, 0);
        if (nt > 1) asm volatile("s_waitcnt vmcnt(4)" ::: "memory");
        else        asm volatile("s_waitcnt vmcnt(0)" ::: "memory");
        asm volatile("s_waitcnt lgkmcnt(0)" ::: "memory");
        __builtin_amdgcn_s_barrier();

        for (int it = 0; it < nt; ++it) {
            const int xb = it % 3;
            const int wb = it & 1;
            if (it + 1 < nt) gen_load((it + 1) << 5);
            if (it + 2 < nt) stageX((it + 2) << 5, (it + 2) % 3);

            bf16x8 ah = *(const bf16x8*)&Wh[wb][fbase];
            bf16x8 al = *(const bf16x8*)&Wl[wb][fbase];
            const unsigned short* xhp = &Xh[xb][0];
            const unsigned short* xlp = &Xl[xb][0];
            #pragma unroll
            for (int ni = 0; ni < 8; ++ni) {
                int base = (ni * 16 + lr) * 32 + xsw;
                bf16x8 bh = *(const bf16x8*)&xhp[base];
                bf16x8 bl = *(const bf16x8*)&xlp[base];
                acc[ni] = __builtin_amdgcn_mfma_f32_16x16x32_bf16(
                    ah, bh, acc[ni], 0, 0, 0);
                acc[ni] = __builtin_amdgcn_mfma_f32_16x16x32_bf16(
                    al, bh, acc[ni], 0, 0, 0);
                acc[ni] = __builtin_amdgcn_mfma_f32_16x16x32_bf16(
                    ah, bl, acc[ni], 0, 0, 0);
            }
            if (it + 1 < nt) gen_finish((it + 1) << 5, wb ^ 1);
            if (it + 2 < nt) asm volatile("s_waitcnt vmcnt(4)" ::: "memory");
            else             asm volatile("s_waitcnt vmcnt(0)" ::: "memory");
            asm volatile("s_waitcnt lgkmcnt(0)" ::: "memory");
            __builtin_amdgcn_s_barrier();
        }

        const int row0 = m0 + wave * 16 + quad * 4;
        #pragma unroll
        for (int ni = 0; ni < 8; ++ni) {
            int chan = h * 128 + ni * 16 + lr;
            #pragma unroll
            for (int r = 0; r < 4; ++r) {
                long long row = (long long)(b * 512 + row0 + r);
                float zz = Z[row * 2048 + chan];
                float y = acc[ni][r] * (zz / (1.f + expf(-zz)));
                store_pair(YS2, row, 2048, chan, y);
            }
        }
    }
}

// ---------------------------------------------------------------------------
// Tiled f32 GEMM (only for the small batched G = Cm @ Bm^T)
// ---------------------------------------------------------------------------
__global__ __launch_bounds__(256) void gemm_f32_k(
    int M, int N, int K,
    const float* __restrict__ A, int lda, long long sAb,
    const float* __restrict__ B, int ldb, long long sBb,
    float* __restrict__ C, int ldc, long long sCb)
{
    __shared__ float As[32][132];
    __shared__ float Bs[32][132];
    const int z = blockIdx.z;
    A += z * sAb; B += z * sBb; C += z * sCb;
    const int n0 = blockIdx.x * 128;
    const int m0 = blockIdx.y * 128;
    const int t  = threadIdx.x;
    const int tx = t & 15, ty = t >> 4;

    float acc[4][16];
    #pragma unroll
    for (int a = 0; a < 4; ++a)
        #pragma unroll
        for (int q = 0; q < 16; ++q) acc[a][q] = 0.f;

    const int ka = (t & 7) << 2;
    const int ra = t >> 3;

    for (int k0 = 0; k0 < K; k0 += 32) {
        __syncthreads();
        #pragma unroll
        for (int i = 0; i < 4; ++i) {
            int row = m0 + ra + i * 32;
            float4 v = *(const float4*)(A + (long long)row * lda + (k0 + ka));
            As[ka + 0][ra + i * 32] = v.x;
            As[ka + 1][ra + i * 32] = v.y;
            As[ka + 2][ra + i * 32] = v.z;
            As[ka + 3][ra + i * 32] = v.w;
            int rowb = n0 + ra + i * 32;
            float4 w = *(const float4*)(B + (long long)rowb * ldb + (k0 + ka));
            Bs[ka + 0][ra + i * 32] = w.x;
            Bs[ka + 1][ra + i * 32] = w.y;
            Bs[ka + 2][ra + i * 32] = w.z;
            Bs[ka + 3][ra + i * 32] = w.w;
        }
        __syncthreads();
        #pragma unroll
        for (int kk = 0; kk < 32; ++kk) {
            float a[8], bm[8];
            *(float4*)&a[0]  = *(const float4*)&As[kk][ty * 4];
            *(float4*)&a[4]  = *(const float4*)&As[kk][64 + ty * 4];
            *(float4*)&bm[0] = *(const float4*)&Bs[kk][tx * 4];
            *(float4*)&bm[4] = *(const float4*)&Bs[kk][64 + tx * 4];
            #pragma unroll
            for (int ri = 0; ri < 2; ++ri)
                #pragma unroll
                for (int ci = 0; ci < 2; ++ci)
                    #pragma unroll
                    for (int i = 0; i < 4; ++i)
                        #pragma unroll
                        for (int j = 0; j < 4; ++j)
                            acc[ri * 2 + ci][i * 4 + j] =
                                fmaf(a[ri * 4 + i], bm[ci * 4 + j], acc[ri * 2 + ci][i * 4 + j]);
        }
    }
    #pragma unroll
    for (int ri = 0; ri < 2; ++ri)
        #pragma unroll
        for (int ci = 0; ci < 2; ++ci) {
            int colb = n0 + ci * 64 + tx * 4;
            #pragma unroll
            for (int i = 0; i < 4; ++i) {
                int row = m0 + ri * 64 + ty * 4 + i;
                *(float4*)(C + (long long)row * ldc + colb) =
                    *(float4*)&acc[ri * 2 + ci][i * 4];
            }
        }
}

// ---------------------------------------------------------------------------
// Elementwise / norm kernels
// ---------------------------------------------------------------------------
__global__ __launch_bounds__(256) void pairify_k(
    const float* __restrict__ src, unsigned short* __restrict__ dst,
    int k_log2, long long n)
{
    long long idx = (long long)blockIdx.x * 256 + threadIdx.x;
    if (idx >= n) return;
    long long r = idx >> k_log2;
    int c = (int)(idx & ((1 << k_log2) - 1));
    store_pair(dst, r, 1 << k_log2, c, src[idx]);
}

__global__ __launch_bounds__(256) void layernorm_k(
    const float* __restrict__ in, float* __restrict__ out,
    const float* __restrict__ w, const float* __restrict__ b,
    int width, int rows_per_b, long long in_bstride)
{
    long long r = blockIdx.x;
    const float* x = in + (r / rows_per_b) * in_bstride + (r % rows_per_b) * (long long)width;
    int t = threadIdx.x;
    float s = 0.f;
    for (int c = t; c < width; c += 256) s += x[c];
    s = block_sum256(s);
    float m = s / (float)width;
    float vs = 0.f;
    for (int c = t; c < width; c += 256) { float d = x[c] - m; vs += d * d; }
    vs = block_sum256(vs);
    float rs = 1.f / sqrtf(vs / (float)width + 1e-5f);
    float* o = out + r * (long long)width;
    for (int c = t; c < width; c += 256) o[c] = (x[c] - m) * rs * w[c] + b[c];
}

// One-pass register-resident LayerNorm -> split pairs. width = NE*256.
// float4-vectorized single read (was 3x re-read of x).
template<int NE>
__global__ __launch_bounds__(256) void layernorm_pair_v_k(
    const float* __restrict__ in, unsigned short* __restrict__ out2,
    const float* __restrict__ w, const float* __restrict__ b,
    int rows_per_b, long long in_bstride)
{
    const int width = NE * 256;
    long long r = blockIdx.x;
    const float* x = in + (r / rows_per_b) * in_bstride
                   + (r % rows_per_b) * (long long)width;
    const int t = threadIdx.x;
    float v[NE];
    float s = 0.f;
    #pragma unroll
    for (int j = 0; j < NE / 4; ++j) {
        float4 f = *(const float4*)(x + j * 1024 + t * 4);
        v[j * 4 + 0] = f.x; v[j * 4 + 1] = f.y;
        v[j * 4 + 2] = f.z; v[j * 4 + 3] = f.w;
        s += f.x + f.y + f.z + f.w;
    }
    s = block_sum256(s);
    float m = s / (float)width;
    float vs = 0.f;
    #pragma unroll
    for (int e = 0; e < NE; ++e) { float d = v[e] - m; vs += d * d; }
    vs = block_sum256(vs);
    float rs = 1.f / sqrtf(vs / (float)width + 1e-5f);
    #pragma unroll
    for (int j = 0; j < NE / 4; ++j)
        #pragma unroll
        for (int e = 0; e < 4; ++e) {
            int c = j * 1024 + t * 4 + e;
            store_pair(out2, r, width, c, (v[j * 4 + e] - m) * rs * w[c] + b[c]);
        }
}

// One-pass register-resident RMSNorm -> split pairs. width = NE*256.
template<int NE>
__global__ __launch_bounds__(256) void rmsnorm_pair_v_k(
    const float* __restrict__ in, unsigned short* __restrict__ out2,
    const float* __restrict__ w)
{
    const int width = NE * 256;
    long long r = blockIdx.x;
    const float* x = in + r * (long long)width;
    const int t = threadIdx.x;
    float v[NE];
    float s = 0.f;
    #pragma unroll
    for (int j = 0; j < NE / 4; ++j) {
        float4 f = *(const float4*)(x + j * 1024 + t * 4);
        v[j * 4 + 0] = f.x; v[j * 4 + 1] = f.y;
        v[j * 4 + 2] = f.z; v[j * 4 + 3] = f.w;
        s += f.x * f.x + f.y * f.y + f.z * f.z + f.w * f.w;
    }
    s = block_sum256(s);
    float rs = 1.f / sqrtf(s / (float)width + 1e-5f);
    #pragma unroll
    for (int j = 0; j < NE / 4; ++j)
        #pragma unroll
        for (int e = 0; e < 4; ++e) {
            int c = j * 1024 + t * 4 + e;
            store_pair(out2, r, width, c, v[j * 4 + e] * rs * w[c]);
        }
}

// Softmax over 512-wide rows, f32 in -> split-pair out IN-PLACE (same bytes).
__global__ __launch_bounds__(256) void softmax_pair_k(float* __restrict__ S,
                                                      unsigned short* __restrict__ P2)
{
    long long r = blockIdx.x;
    float* x = S + r * 512;
    unsigned short* p = P2 + r * 1024;
    int t = threadIdx.x;
    float v0 = x[t], v1 = x[t + 256];
    float mx = block_max256(fmaxf(v0, v1));
    v0 = expf(v0 - mx); v1 = expf(v1 - mx);
    float sum = block_sum256(v0 + v1);
    float inv = 1.f / sum;
    v0 *= inv; v1 *= inv;
    __syncthreads();
    unsigned short h0 = bf16_rne(v0);
    p[t] = h0;       p[512 + t] = bf16_rne(v0 - bf16_tof(h0));
    unsigned short h1 = bf16_rne(v1);
    p[t + 256] = h1; p[512 + t + 256] = bf16_rne(v1 - bf16_tof(h1));
}

// Causal grouped conv with LDS-tile transpose: writes seq-major pairs XC2
// AND chan-major pairs XCT2, both coalesced.
__global__ __launch_bounds__(256) void conv_k(
    const float* __restrict__ XS, const float* __restrict__ W,
    unsigned short* __restrict__ XC2, unsigned short* __restrict__ XCT2)
{
    __shared__ float tile[64][65];
    const int o0  = blockIdx.x * 64;
    const int tt0 = blockIdx.y * 64;
    const int b   = blockIdx.z;
    const int t   = threadIdx.x;

    const int o  = o0 + (t & 63);
    const int g2 = (o >> 1) << 1;
    const float* Wo = W + o * 8;
    float w0 = Wo[0], w1 = Wo[1], w2 = Wo[2], w3 = Wo[3];
    float w4 = Wo[4], w5 = Wo[5], w6 = Wo[6], w7 = Wo[7];
    #pragma unroll
    for (int i = 0; i < 16; ++i) {
        int sl = (t >> 6) + 4 * i;
        int tt = tt0 + sl;
        const float* xb = XS + ((long long)(b * 512 + tt)) * 2048 + g2;
        float acc = w3 * xb[0] + w7 * xb[1];
        if (tt >= 1) acc += w2 * xb[-2048] + w6 * xb[-2047];
        if (tt >= 2) acc += w1 * xb[-4096] + w5 * xb[-4095];
        if (tt >= 3) acc += w0 * xb[-6144] + w4 * xb[-6143];
        tile[sl][t & 63] = acc;
    }
    __syncthreads();
    #pragma unroll
    for (int i = 0; i < 16; ++i) {
        int idx = t + 256 * i;
        int sl = idx >> 6, ol = idx & 63;
        float v = tile[sl][ol];
        unsigned short hi = bf16_rne(v);
        unsigned short lo = bf16_rne(v - bf16_tof(hi));
        long long row = (long long)(b * 512 + tt0 + sl);
        XC2[row * 4096 + o0 + ol] = hi;
        XC2[row * 4096 + 2048 + o0 + ol] = lo;
    }
    #pragma unroll
    for (int i = 0; i < 16; ++i) {
        int idx = t + 256 * i;
        int cl = idx >> 6, s = idx & 63;
        float v = tile[s][cl];
        unsigned short hi = bf16_rne(v);
        unsigned short lo = bf16_rne(v - bf16_tof(hi));
        long long tb = (long long)b * 2097152 + (long long)(o0 + cl) * 1024 + tt0 + s;
        XCT2[tb] = hi;
        XCT2[tb + 512] = lo;
    }
}

__global__ __launch_bounds__(256) void dt_k(
    const float* __restrict__ dtBC, const float* __restrict__ dt_bias, float* __restrict__ DT)
{
    int idx = blockIdx.x * 256 + threadIdx.x;
    int r = idx >> 4, h = idx & 15;
    float xv = dtBC[r * 144 + h] + dt_bias[h];
    DT[idx] = (xv > 20.f) ? xv : log1pf(expf(xv));
}

__global__ __launch_bounds__(64) void cuma_k(
    const float* __restrict__ DT, const float* __restrict__ A_log, float* __restrict__ CUMA)
{
    int h = blockIdx.x, b = blockIdx.y;
    int ln = threadIdx.x;
    float Ah = -expf(A_log[h]);
    float v[8];
    float run = 0.f;
    #pragma unroll
    for (int i = 0; i < 8; ++i) {
        run += Ah * DT[((b * 512) + (ln * 8 + i)) * 16 + h];
        v[i] = run;
    }
    float tot = run;
    float sc = tot;
    #pragma unroll
    for (int o = 1; o <= 32; o <<= 1) {
        float u = __shfl_up(sc, o, 64);
        if (ln >= o) sc += u;
    }
    float excl = sc - tot;
    #pragma unroll
    for (int i = 0; i < 8; ++i)
        CUMA[(b * 16 + h) * 512 + ln * 8 + i] = excl + v[i];
}

// hc = LayerNorm64(G1) -> {-1,+1} as split pairs (lo = 0)
__global__ __launch_bounds__(64) void hc_quant_k(
    const float* __restrict__ G1, const float* __restrict__ w,
    const float* __restrict__ b, unsigned short* __restrict__ HCQ2)
{
    int r = blockIdx.x, ln = threadIdx.x;
    float v = G1[r * 64 + ln];
    float s = v;
    #pragma unroll
    for (int o = 32; o > 0; o >>= 1) s += __shfl_xor(s, o, 64);
    float m = s * (1.f / 64.f);
    float d = v - m;
    float vs = d * d;
    #pragma unroll
    for (int o = 32; o > 0; o >>= 1) vs += __shfl_xor(vs, o, 64);
    vs *= (1.f / 64.f);
    float hc = d * (1.f / sqrtf(vs + 1e-5f)) * w[ln] + b[ln];
    HCQ2[r * 128 + ln] = (hc > 0.f) ? 0x3F80 : 0xBF80;
    HCQ2[r * 128 + 64 + ln] = 0;
}

__global__ __launch_bounds__(256) void dxm_k(
    const float* __restrict__ mtok, const float* __restrict__ e2d, float* __restrict__ dxm)
{
    int c = blockIdx.x * 256 + threadIdx.x;
    float acc = 0.f;
    #pragma unroll
    for (int j = 0; j < 64; ++j) acc = fmaf(mtok[j], e2d[c * 64 + j], acc);
    dxm[c] = acc;
}

__global__ __launch_bounds__(256) void projm_k(
    const float* __restrict__ lnm,
    const float* __restrict__ bWq, const float* __restrict__ bWk, const float* __restrict__ bWv,
    float* __restrict__ qm, float* __restrict__ km, float* __restrict__ vm)
{
    int idx = blockIdx.x * 256 + threadIdx.x;
    int sel = idx >> 10, c = idx & 1023;
    const float* W = (sel == 0) ? bWq : (sel == 1) ? bWk : bWv;
    float* O = (sel == 0) ? qm : (sel == 1) ? km : vm;
    const float* wr = W + (long long)c * 1024;
    float acc = 0.f;
    for (int j = 0; j < 1024; j += 4) {
        float4 a = *(const float4*)(lnm + j);
        float4 w4 = *(const float4*)(wr + j);
        acc = fmaf(a.x, w4.x, fmaf(a.y, w4.y, fmaf(a.z, w4.z, fmaf(a.w, w4.w, acc))));
    }
    O[c] = acc;
}

// Collapsed decoder attention on fused KV buffer: KVm[row][0..1023]=K,
// [1024..2047]=V. 1 query/(b,h); keys = 512 visible + mask key x512.
__global__ __launch_bounds__(256) void dec_attn_k(
    const float* __restrict__ KVm,
    const float* __restrict__ qm, const float* __restrict__ km,
    const float* __restrict__ vm, float* __restrict__ OBm)
{
    int h = blockIdx.x, b = blockIdx.y;
    int t = threadIdx.x;
    __shared__ __align__(16) float qs[256];
    __shared__ __align__(16) float ps[512];
    qs[t] = qm[h * 256 + t];
    __syncthreads();
    float s[2];
    #pragma unroll
    for (int i = 0; i < 2; ++i) {
        int r = t + i * 256;
        const float* kr = KVm + ((long long)(b * 512 + r)) * 2048 + h * 256;
        float acc = 0.f;
        for (int c = 0; c < 256; c += 4) {
            float4 k4 = *(const float4*)(kr + c);
            float4 q4 = *(const float4*)(qs + c);
            acc = fmaf(k4.x, q4.x, fmaf(k4.y, q4.y, fmaf(k4.z, q4.z, fmaf(k4.w, q4.w, acc))));
        }
        s[i] = acc * (1.f / 16.f);
    }
    float accm = 0.f;
    for (int c = 0; c < 256; c += 4) {
        float4 k4 = *(const float4*)(km + h * 256 + c);
        float4 q4 = *(const float4*)(qs + c);
        accm = fmaf(k4.x, q4.x, fmaf(k4.y, q4.y, fmaf(k4.z, q4.z, fmaf(k4.w, q4.w, accm))));
    }
    float smv = accm * (1.f / 16.f);
    float mx = block_max256(fmaxf(fmaxf(s[0], s[1]), smv));
    float p0 = expf(s[0] - mx), p1 = expf(s[1] - mx);
    ps[t] = p0; ps[t + 256] = p1;
    float pm = expf(smv - mx) * 512.f;
    float sum = block_sum256(p0 + p1) + pm;
    float inv = 1.f / sum;
    __syncthreads();
    float o = pm * vm[h * 256 + t];
    const float* vcol = KVm + (long long)b * 512 * 2048 + 1024 + h * 256 + t;
    for (int j = 0; j < 512; ++j)
        o = fmaf(ps[j], vcol[(long long)j * 2048], o);
    OBm[b * 1024 + h * 256 + t] = o * inv;
}

__global__ __launch_bounds__(256) void ydm_k(
    const float* __restrict__ OBm, const float* __restrict__ bWo,
    const float* __restrict__ bWo_b, const float* __restrict__ dxm,
    float* __restrict__ ydm)
{
    int idx = blockIdx.x * 256 + threadIdx.x;
    int b = idx >> 10, c = idx & 1023;
    const float* ar = OBm + b * 1024;
    const float* wr = bWo + (long long)c * 1024;
    float acc = 0.f;
    for (int j = 0; j < 1024; j += 4) {
        float4 a = *(const float4*)(ar + j);
        float4 w4 = *(const float4*)(wr + j);
        acc = fmaf(a.x, w4.x, fmaf(a.y, w4.y, fmaf(a.z, w4.z, fmaf(a.w, w4.w, acc))));
    }
    ydm[idx] = acc + bWo_b[c] + dxm[c];
}

__global__ __launch_bounds__(256) void outm_k(
    const float* __restrict__ ydm, const float* __restrict__ dout_W,
    const float* __restrict__ dout_b, float* __restrict__ outm)
{
    int idx = blockIdx.x * 256 + threadIdx.x;
    int b = idx >> 11, c = idx & 2047;
    const float* ar = ydm + b * 1024;
    const float* wr = dout_W + (long long)c * 1024;
    float acc = 0.f;
    for (int j = 0; j < 1024; j += 4) {
        float4 a = *(const float4*)(ar + j);
        float4 w4 = *(const float4*)(wr + j);
        acc = fmaf(a.x, w4.x, fmaf(a.y, w4.y, fmaf(a.z, w4.z, fmaf(a.w, w4.w, acc))));
    }
    outm[idx] = acc + dout_b[c];
}

__global__ __launch_bounds__(256) void bcast_k(
    const float* __restrict__ outm, float* __restrict__ out)
{
    int idx = blockIdx.x * 256 + threadIdx.x;
    int c4 = idx & 511;
    int b = idx >> 18;
    ((float4*)out)[idx] = ((const float4*)outm)[b * 512 + c4];
}

// ---------------------------------------------------------------------------
// Host-side launcher
// ---------------------------------------------------------------------------
static inline void pairify(hipStream_t s, const float* src, unsigned short* dst,
                           int k_log2, long long n)
{
    pairify_k<<<(int)((n + 255) / 256), 256, 0, s>>>(src, dst, k_log2, n);
}

extern "C" void kernel_launch(void* const* d_in, const int* in_sizes, int n_in,
                              void* d_out, int out_size, void* d_ws, size_t ws_size,
                              hipStream_t stream)
{
    const float* x       = (const float*)d_in[0];
    const float* ln0_w   = (const float*)d_in[1];
    const float* ln0_b   = (const float*)d_in[2];
    const float* in_W    = (const float*)d_in[3];
    const float* rms_w   = (const float*)d_in[4];
    const float* exp_W   = (const float*)d_in[5];
    const float* conv_W  = (const float*)d_in[6];
    const float* xproj_W = (const float*)d_in[7];
    const float* dt_bias = (const float*)d_in[8];
    const float* A_log   = (const float*)d_in[9];
    const float* Dv      = (const float*)d_in[10];
    const float* outp_W  = (const float*)d_in[11];
    const float* outp_b  = (const float*)d_in[12];
    const float* n1_w    = (const float*)d_in[13];
    const float* n1_b    = (const float*)d_in[14];
    const float* aWq     = (const float*)d_in[15];
    const float* aWk     = (const float*)d_in[16];
    const float* aWv     = (const float*)d_in[17];
    const float* aWo     = (const float*)d_in[18];
    const float* aWo_b   = (const float*)d_in[19];
    const float* h_W     = (const float*)d_in[20];
    const float* h_b     = (const float*)d_in[21];
    const float* h_lnw   = (const float*)d_in[22];
    const float* h_lnb   = (const float*)d_in[23];
    const float* mtok    = (const float*)d_in[24];
    const float* e2d_W   = (const float*)d_in[25];
    const float* dn_w    = (const float*)d_in[26];
    const float* dn_b    = (const float*)d_in[27];
    const float* bWq     = (const float*)d_in[28];
    const float* bWk     = (const float*)d_in[29];
    const float* bWv     = (const float*)d_in[30];
    const float* bWo     = (const float*)d_in[31];
    const float* bWo_b   = (const float*)d_in[32];
    const float* dout_W  = (const float*)d_in[33];
    const float* dout_b  = (const float*)d_in[34];

    float* ws  = (float*)d_ws;
    float* out = (float*)d_out;

    float* S1 = ws;
    float* S2 = ws + 8388608;
    float* S3 = ws + 16777216;
    float* S4 = ws + 25165824;
    float* S5 = ws + 33554432;
    float* S6 = ws + 37748736;
    float* S7 = ws + 41943040;
    float* S8 = ws + 46137344;
    float* S9 = ws + 50331648;
    float* SP = ws + 54525952;

    unsigned short* XV2     = (unsigned short*)S1;
    unsigned short* exp_W2  = (unsigned short*)S1;
    unsigned short* XCT2    = (unsigned short*)S1;
    float*          POUTP   = S1;            // outp split-K partials
    float*          SA      = S1;
    unsigned short* P2      = (unsigned short*)S1;
    float*          KVm     = S1;            // fused K|V decoder buffer (32MB)
    unsigned short* in_W2   = (unsigned short*)S2;
    float*          XS      = S2;
    unsigned short* YS2     = (unsigned short*)S2;
    float*          PX      = S2;            // xproj split-K partials
    unsigned short* QKA2    = (unsigned short*)S2;  // merged Q|K pairs (32MB)
    unsigned short* XC2     = (unsigned short*)S3;
    float*          PIN     = S3;            // in split-K partials
    unsigned short* outp_W2 = (unsigned short*)S3;
    float*          PATT    = S3;            // aWv / aWo split-K partials
    float*          PH      = S3;            // hW split-K partials
    float*          DXV     = S3;
    unsigned short* LNDXV2  = (unsigned short*)(S3 + 4194304);
    float*          Z       = S4;
    unsigned short* aWq2    = (unsigned short*)S4;
    unsigned short* aWk2    = (unsigned short*)S4 + 2097152;
    unsigned short* aWv2    = (unsigned short*)S4 + 4194304;
    unsigned short* aWo2    = (unsigned short*)S4 + 6291456;
    unsigned short* bWk2    = (unsigned short*)S4 + 8388608;
    unsigned short* bWv2    = (unsigned short*)S4 + 10485760;
    float*          T       = S5;
    unsigned short* Y22     = (unsigned short*)S5;
    unsigned short* HR2     = (unsigned short*)S6;
    float*          Y1      = S6;
    unsigned short* LNY2    = (unsigned short*)S7;
    unsigned short* OA2     = (unsigned short*)S7;
    unsigned short* VT2     = (unsigned short*)S9;

    float* dtBC = SP;
    float* DT   = SP + 589824;
    float* CUMA = SP + 655360;
    float* G    = SP + 720896;
    unsigned short* xprojW2 = (unsigned short*)(SP + 2818048);
    unsigned short* hW2     = (unsigned short*)(SP + 3112960);
    unsigned short* e2dW2   = (unsigned short*)(SP + 3178496);
    float* G1   = SP + 720896;
    unsigned short* HCQ2 = (unsigned short*)(SP + 983040);
    float* dxm  = SP + 1245184;
    float* lnm  = SP + 1246208;
    float* qm   = SP + 1247232;
    float* km   = SP + 1248256;
    float* vm   = SP + 1249280;
    float* OBm  = SP + 1250304;
    float* ydm  = SP + 1258496;
    float* outm = SP + 1266688;

    const long long LL0 = 0;
    const long long P4M = 4194304;
    #define G3D(OUTM, GX, GY, GZ, ...) \
        gemm_bf16_k<3, OUTM, true><<<dim3(GX, GY, GZ), 256, 0, stream>>>(__VA_ARGS__)
    #define G1D(OUTM, GX, GY, GZ, ...) \
        gemm_bf16_k<1, OUTM, true><<<dim3(GX, GY, GZ), 256, 0, stream>>>(__VA_ARGS__)

    // ---- weight prep (phase A) ----
    pairify(stream, in_W,    in_W2,   11, 1024LL * 2048);
    pairify(stream, xproj_W, xprojW2, 11, 144LL * 2048);
    pairify(stream, h_W,     hW2,     10, 64LL * 1024);
    pairify(stream, e2d_W,   e2dW2,    6, 1024LL * 64);

    // ---- encoder trunk ----
    layernorm_pair_v_k<8><<<4096, 256, 0, stream>>>(x, XV2, ln0_w, ln0_b, 512,
                                                    (long long)1024 * 2048);
    // in: M=4096 N=1024 K=2048 -> DIRECT split-K x2 (512 blocks, 2/CU)
    gemm_bf16_skd_k<3, 0><<<dim3(8, 32, 2), 256, 0, stream>>>(
        1024, 1024, XV2, 4096, 2048, in_W2, 4096, 2048, PIN, P4M);
    skredN_k<<<16384, 256, 0, stream>>>(PIN, P4M, 2, nullptr, nullptr, 1024,
                                        T, P4M);
    pairify(stream, exp_W, exp_W2, 10, 4096LL * 1024);   // S1 (XV2 dead)
    rmsnorm_pair_v_k<4><<<4096, 256, 0, stream>>>(T, HR2, rms_w);
    // merged exp GEMM: z=0 -> XS half (weights rows 0..2047), z=1 -> Z half
    // (weight rows 2048..4095, C offset = Z - XS = 16M floats). A read once.
    G3D(0, 16, 32, 2, 4096, 2048, 1024, HR2, 2048, 1024, LL0, LL0,
        exp_W2, 2048, 1024, (long long)2048 * 2048, LL0,
        XS, 2048, 0, 16777216LL, LL0,
        nullptr, nullptr, 0, 1.f, 1);
    conv_k<<<dim3(32, 8, 8), 256, 0, stream>>>(XS, conv_W, XC2, XCT2);
    // xproj: ragged split-K x8
    gemm_bf16_sk_k<3><<<dim3(2, 32, 8), 256, 0, stream>>>(
        144, 256, XC2, 4096, 2048, xprojW2, 4096, 2048, PX, 589824LL);
    skredN_k<<<2304, 256, 0, stream>>>(PX, 589824LL, 8, nullptr, nullptr, 144,
                                       dtBC, 589824LL);
    dt_k<<<256, 256, 0, stream>>>(dtBC, dt_bias, DT);
    cuma_k<<<dim3(16, 8), 64, 0, stream>>>(DT, A_log, CUMA);
    gemm_f32_k<<<dim3(4, 4, 8), 256, 0, stream>>>(
        512, 512, 64, dtBC + 80, 144, (long long)512 * 144,
        dtBC + 16, 144, (long long)512 * 144, G, 512, (long long)512 * 512);
    ssd_mfma_k<<<dim3(4, 16, 8), 256, 0, stream>>>(G, CUMA, DT, XCT2, Z, Dv, YS2);

    // ---- weight prep (phase B: S3/S4 now dead) ----
    pairify(stream, outp_W, outp_W2, 11, 1024LL * 2048);
    pairify(stream, aWq, aWq2, 10, 1024LL * 1024);
    pairify(stream, aWk, aWk2, 10, 1024LL * 1024);
    pairify(stream, aWv, aWv2, 10, 1024LL * 1024);
    pairify(stream, aWo, aWo2, 10, 1024LL * 1024);
    pairify(stream, bWk, bWk2, 10, 1024LL * 1024);
    pairify(stream, bWv, bWv2, 10, 1024LL * 1024);

    // outp: split-K x2, partials in POUTP=S1 (XCT2 dead after ssd)
    gemm_bf16_skd_k<3, 0><<<dim3(8, 32, 2), 256, 0, stream>>>(
        1024, 1024, YS2, 4096, 2048, outp_W2, 4096, 2048, POUTP, P4M);
    skredN_k<<<16384, 256, 0, stream>>>(POUTP, P4M, 2, outp_b, T, 1024,
                                        Y1, P4M);

    // ---- encoder attention (all MFMA) ----
    layernorm_pair_v_k<4><<<4096, 256, 0, stream>>>(Y1, LNY2, n1_w, n1_b,
                                                    4096, LL0);
    // merged Q|K projection: N=2048 (aWq2 and aWk2 are contiguous), 512
    // blocks, OUT1 pairs into QKA2 (ldc=4096, cLo=2048). YS2 (S2) dead.
    G3D(1, 16, 32, 1, 4096, 2048, 1024, LNY2, 2048, 1024, LL0, LL0,
        aWq2, 2048, 1024, LL0, LL0, QKA2, 4096, 2048, LL0, LL0,
        nullptr, nullptr, 0, 1.f, 1);
    // aWv: split-K x2 with transposed partials -> VT2
    gemm_bf16_skd_k<3, 1><<<dim3(8, 32, 2), 256, 0, stream>>>(
        1024, 512, LNY2, 2048, 1024, aWv2, 2048, 1024, PATT, P4M);
    skredT_k<<<16384, 256, 0, stream>>>(PATT, P4M, 2, VT2, P4M);
    // QK^T: Q at QKA2 col 0-1023, K at col 1024-2047
    G3D(0, 4, 4, 32, 512, 512, 256,
        QKA2, 4096, 2048, (long long)512 * 4096, 256,
        QKA2 + 1024, 4096, 2048, (long long)512 * 4096, 256,
        SA, 512, 0, (long long)4 * 512 * 512, (long long)512 * 512,
        nullptr, nullptr, 0, 1.f / 16.f, 4);
    softmax_pair_k<<<16384, 256, 0, stream>>>(SA, P2);
    G3D(1, 2, 4, 32, 512, 256, 512,
        P2, 1024, 512, (long long)4 * 512 * 1024, (long long)512 * 1024,
        VT2, 1024, 512, (long long)1024 * 1024, (long long)256 * 1024,
        OA2, 2048, 1024, (long long)512 * 2048, 256,
        nullptr, nullptr, 0, 1.f, 4);
    // aWo: split-K x2 -> skredP with bias + residual(Y1) -> Y22 pairs
    gemm_bf16_skd_k<3, 0><<<dim3(8, 32, 2), 256, 0, stream>>>(
        1024, 512, OA2, 2048, 1024, aWo2, 2048, 1024, PATT, P4M);
    skredP_k<<<16384, 256, 0, stream>>>(PATT, P4M, 2, aWo_b, Y1, Y22, P4M);

    // ---- quantize: G1 = Y22 @ hW^T + h_b (ragged split-K x8) ----
    gemm_bf16_sk_k<3><<<dim3(1, 32, 8), 256, 0, stream>>>(
        64, 128, Y22, 2048, 1024, hW2, 2048, 1024, PH, 262144LL);
    skredN_k<<<1024, 256, 0, stream>>>(PH, 262144LL, 8, h_b, nullptr, 64,
                                       G1, 262144LL);
    hc_quant_k<<<4096, 64, 0, stream>>>(G1, h_lnw, h_lnb, HCQ2);

    // ---- decoder (collapsed masked rows) ----
    G3D(0, 8, 32, 1, 4096, 1024, 64, HCQ2, 128, 64, LL0, LL0,
        e2dW2, 128, 64, LL0, LL0, DXV, 1024, 0, LL0, LL0,
        nullptr, nullptr, 0, 1.f, 1);
    dxm_k<<<4, 256, 0, stream>>>(mtok, e2d_W, dxm);
    layernorm_k<<<1, 256, 0, stream>>>(dxm, lnm, dn_w, dn_b, 1024, 1, LL0);
    layernorm_pair_v_k<4><<<4096, 256, 0, stream>>>(DXV, LNDXV2, dn_w, dn_b,
                                                    4096, LL0);
    projm_k<<<12, 256, 0, stream>>>(lnm, bWq, bWk, bWv, qm, km, vm);
    // merged K|V projection: N=2048 (bWk2, bWv2 contiguous), OUT0 f32 into
    // fused KVm (S1; SA/P2 dead after PV). 512 blocks, NPASS=1.
    G1D(0, 16, 32, 1, 4096, 2048, 1024, LNDXV2, 2048, 1024, LL0, LL0,
        bWk2, 2048, 1024, LL0, LL0, KVm, 2048, 0, LL0, LL0,
        nullptr, nullptr, 0, 1.f, 1);
    dec_attn_k<<<dim3(4, 8), 256, 0, stream>>>(KVm, qm, km, vm, OBm);
    ydm_k<<<32, 256, 0, stream>>>(OBm, bWo, bWo_b, dxm, ydm);
    outm_k<<<64, 256, 0, stream>>>(ydm, dout_W, dout_b, outm);
    bcast_k<<<8192, 256, 0, stream>>>(outm, out);
    #undef G3D
    #undef G1D
}

// Round 7
// 1032.143 us; speedup vs baseline: 1.3626x; 1.0263x over previous
//
#include <hip/hip_runtime.h>

// ---------------------------------------------------------------------------
// B=8, N=1024, CIN=2048, HID=1024, HC=64, LV=512, NH_SSD=16, HD=128, DS=64.
// Encoder rows = 4096. Decoder collapsed to 1 row/batch. All large GEMMs:
// split-bf16 MFMA (x3 passes = f32-grade pre-quantizer; x1 post-quantizer),
// staged via __builtin_amdgcn_global_load_lds width=16 (DIRECT path).
// DIRECT GEMM: double-buffered 64KB LDS (2 blocks/CU), vmcnt(0)+barrier,
// source-swizzled staging, XCD-chunked bijective block remap. Split-K x2
// for 256-block GEMMs. Round 7: dispatch-count diet — fused reduce+norm
// epilogues (skred_rms/skred_ln/skred_dt/skred_hc), batched pairify (11->2
// launches), fused dxm+LN. -14 dispatches, -~80MB traffic.
// ---------------------------------------------------------------------------

typedef short bf16x8 __attribute__((ext_vector_type(8)));
typedef float f32x4 __attribute__((ext_vector_type(4)));

__device__ __forceinline__ unsigned short bf16_rne(float f) {
    unsigned u = __float_as_uint(f);
    unsigned r = u + 0x7FFFu + ((u >> 16) & 1u);
    return (unsigned short)(r >> 16);
}
__device__ __forceinline__ float bf16_tof(unsigned short h) {
    return __uint_as_float(((unsigned)h) << 16);
}
__device__ __forceinline__ void store_pair(unsigned short* dst, long long row,
                                           int width, int c, float v) {
    unsigned short hi = bf16_rne(v);
    unsigned short lo = bf16_rne(v - bf16_tof(hi));
    long long base = row * (2LL * width);
    dst[base + c] = hi;
    dst[base + width + c] = lo;
}
// Async global->LDS, 16B per lane. LDS dest = wave-uniform base + lane*16.
__device__ __forceinline__ void async_ld16(const unsigned short* g, unsigned short* l) {
    __builtin_amdgcn_global_load_lds(
        (const __attribute__((address_space(1))) unsigned int*)g,
        (__attribute__((address_space(3))) unsigned int*)l, 16, 0, 0);
}

// XCD-chunked bijective block remap (T1). Identity when nwg % 8 != 0.
__device__ __forceinline__ void xcd_remap(int& bx, int& by) {
    const int Gx = gridDim.x;
    const int nwg = Gx * gridDim.y;
    if ((nwg & 7) != 0) return;
    int lin = bx + Gx * by;
    int logical = (lin & 7) * (nwg >> 3) + (lin >> 3);
    bx = logical % Gx;
    by = logical / Gx;
}

// ---------------------------------------------------------------------------
// Reduction helpers (blockDim 256)
// ---------------------------------------------------------------------------
__device__ __forceinline__ float block_sum256(float v) {
    #pragma unroll
    for (int o = 32; o > 0; o >>= 1) v += __shfl_xor(v, o, 64);
    __shared__ float sm[4];
    int w = threadIdx.x >> 6;
    __syncthreads();
    if ((threadIdx.x & 63) == 0) sm[w] = v;
    __syncthreads();
    return sm[0] + sm[1] + sm[2] + sm[3];
}
__device__ __forceinline__ float block_max256(float v) {
    #pragma unroll
    for (int o = 32; o > 0; o >>= 1) v = fmaxf(v, __shfl_xor(v, o, 64));
    __shared__ float smx[4];
    int w = threadIdx.x >> 6;
    __syncthreads();
    if ((threadIdx.x & 63) == 0) smx[w] = v;
    __syncthreads();
    return fmaxf(fmaxf(smx[0], smx[1]), fmaxf(smx[2], smx[3]));
}

// ---------------------------------------------------------------------------
// Split-bf16 MFMA GEMM. C[m,n] = alpha * sum_k A[m,k]*B[n,k] (+bias)(+res)
// NPASS=3: hh+lh+hl (f32-grade). NPASS=1: hh only.
// OUT=0: f32 C. OUT=1: split-pair C. OUT=2: transposed split-pair per
// 512-row batch.
// ---------------------------------------------------------------------------
template<int NPASS, int OUT, bool DIRECT>
__global__ __launch_bounds__(256, 2) void gemm_bf16_k(
    int M, int N, int K,
    const unsigned short* __restrict__ A2, int lda2, int aLo, long long sAb, long long sAh,
    const unsigned short* __restrict__ B2, int ldb2, int bLo, long long sBb, long long sBh,
    void* __restrict__ Cv, int ldc, int cLo, long long sCb, long long sCh,
    const float* __restrict__ bias, const float* __restrict__ res, int ldr,
    float alpha, int nh)
{
    constexpr int ST   = DIRECT ? 32 : 40;
    constexpr int NARR = (NPASS == 3) ? 4 : 2;
    constexpr int NB   = DIRECT ? 2 : 1;
    constexpr int O_AH = 0;
    constexpr int O_BH = 128 * ST;
    constexpr int O_AL = 2 * 128 * ST;
    constexpr int O_BL = 3 * 128 * ST;
    constexpr int BUFSZ = 128 * ST * NARR;
    __shared__ unsigned short SM[NB * BUFSZ];

    const int z  = blockIdx.z;
    const int bb = z / nh, hh = z - bb * nh;
    A2 += bb * sAb + hh * sAh;
    B2 += bb * sBb + hh * sBh;

    int bx = blockIdx.x, by = blockIdx.y;
    xcd_remap(bx, by);
    const int t    = threadIdx.x;
    const int m0   = by * 128;
    const int n0   = bx * 128;
    const int lane = t & 63, wave = t >> 6;
    const int wm   = (wave >> 1) * 64, wn = (wave & 1) * 64;
    const int lr   = lane & 15, quad = lane >> 4;

    f32x4 acc[4][4];
    #pragma unroll
    for (int i = 0; i < 4; ++i)
        #pragma unroll
        for (int j = 0; j < 4; ++j) acc[i][j] = (f32x4){0.f, 0.f, 0.f, 0.f};

    if constexpr (DIRECT) {
        const int drow  = lane >> 2;                       // row in 16-chunk
        const int dcswz = (((lane & 3) ^ ((lane >> 2) & 3) ^ ((lane >> 4) & 3)) << 3);
        const int rsw   = ((quad ^ ((lr & 3) ^ (lr >> 2))) << 3);

        auto stage = [&](int k0, int buf) {
            unsigned short* bp = &SM[buf * BUFSZ];
            #pragma unroll
            for (int j = 0; j < 2; ++j) {
                int rr = wave * 32 + j * 16;               // chunk base row
                int gr = rr + drow;
                const unsigned short* gA = A2 + (long long)(m0 + gr) * lda2 + k0 + dcswz;
                async_ld16(gA, &bp[O_AH + rr * 32]);
                if (NPASS == 3) async_ld16(gA + aLo, &bp[O_AL + rr * 32]);
                const unsigned short* gB = B2 + (long long)(n0 + gr) * ldb2 + k0 + dcswz;
                async_ld16(gB, &bp[O_BH + rr * 32]);
                if (NPASS == 3) async_ld16(gB + bLo, &bp[O_BL + rr * 32]);
            }
        };

        const int nt = K >> 5;
        stage(0, 0);
        int cur = 0;
        for (int it = 0; it < nt; ++it) {
            asm volatile("s_waitcnt vmcnt(0)" ::: "memory");
            __builtin_amdgcn_s_barrier();
            if (it + 1 < nt) stage((it + 1) << 5, cur ^ 1);

            const unsigned short* bp = &SM[cur * BUFSZ];
            bf16x8 ah[4], bh[4], al[4], bl[4];
            #pragma unroll
            for (int i = 0; i < 4; ++i) {
                int ra = O_AH + (wm + i * 16 + lr) * 32 + rsw;
                int rb = O_BH + (wn + i * 16 + lr) * 32 + rsw;
                ah[i] = *(const bf16x8*)&bp[ra];
                bh[i] = *(const bf16x8*)&bp[rb];
                if (NPASS == 3) {
                    al[i] = *(const bf16x8*)&bp[ra + (O_AL - O_AH)];
                    bl[i] = *(const bf16x8*)&bp[rb + (O_BL - O_BH)];
                }
            }
            #pragma unroll
            for (int mi = 0; mi < 4; ++mi)
                #pragma unroll
                for (int ni = 0; ni < 4; ++ni) {
                    acc[mi][ni] = __builtin_amdgcn_mfma_f32_16x16x32_bf16(
                        ah[mi], bh[ni], acc[mi][ni], 0, 0, 0);
                    if (NPASS == 3) {
                        acc[mi][ni] = __builtin_amdgcn_mfma_f32_16x16x32_bf16(
                            al[mi], bh[ni], acc[mi][ni], 0, 0, 0);
                        acc[mi][ni] = __builtin_amdgcn_mfma_f32_16x16x32_bf16(
                            ah[mi], bl[ni], acc[mi][ni], 0, 0, 0);
                    }
                }
            cur ^= 1;
        }
    } else {
        // ---- ragged reg-staging path ----
        const int srow = t >> 2;          // row 0..63 (+64)
        const int scol = (t & 3) * 8;

        for (int k0 = 0; k0 < K; k0 += 32) {
            __syncthreads();
            #pragma unroll
            for (int half = 0; half < 2; ++half) {
                int r = srow + half * 64;
                const unsigned short* pA = A2 + (long long)(m0 + r) * lda2 + k0 + scol;
                *(uint4*)&SM[O_AH + r * ST + scol] = *(const uint4*)pA;
                if (NPASS == 3)
                    *(uint4*)&SM[O_AL + r * ST + scol] = *(const uint4*)(pA + aLo);
                int rb = n0 + r;
                uint4 vh = {0u, 0u, 0u, 0u}, vl = {0u, 0u, 0u, 0u};
                if (rb < N) {
                    const unsigned short* pB = B2 + (long long)rb * ldb2 + k0 + scol;
                    vh = *(const uint4*)pB;
                    if (NPASS == 3) vl = *(const uint4*)(pB + bLo);
                }
                *(uint4*)&SM[O_BH + r * ST + scol] = vh;
                if (NPASS == 3) *(uint4*)&SM[O_BL + r * ST + scol] = vl;
            }
            __syncthreads();

            bf16x8 ah[4], bh[4], al[4], bl[4];
            #pragma unroll
            for (int i = 0; i < 4; ++i) {
                int ra = (wm + i * 16 + lr) * ST + quad * 8;
                int rb = (wn + i * 16 + lr) * ST + quad * 8;
                ah[i] = *(const bf16x8*)&SM[O_AH + ra];
                bh[i] = *(const bf16x8*)&SM[O_BH + rb];
                if (NPASS == 3) {
                    al[i] = *(const bf16x8*)&SM[O_AL + ra];
                    bl[i] = *(const bf16x8*)&SM[O_BL + rb];
                }
            }
            #pragma unroll
            for (int mi = 0; mi < 4; ++mi)
                #pragma unroll
                for (int ni = 0; ni < 4; ++ni) {
                    acc[mi][ni] = __builtin_amdgcn_mfma_f32_16x16x32_bf16(
                        ah[mi], bh[ni], acc[mi][ni], 0, 0, 0);
                    if (NPASS == 3) {
                        acc[mi][ni] = __builtin_amdgcn_mfma_f32_16x16x32_bf16(
                            al[mi], bh[ni], acc[mi][ni], 0, 0, 0);
                        acc[mi][ni] = __builtin_amdgcn_mfma_f32_16x16x32_bf16(
                            ah[mi], bl[ni], acc[mi][ni], 0, 0, 0);
                    }
                }
        }
    }

    // D layout: col = lane&15, row = quad*4 + r
    if (OUT == 0) {
        float* C = (float*)Cv + bb * sCb + hh * sCh;
        #pragma unroll
        for (int mi = 0; mi < 4; ++mi)
            #pragma unroll
            for (int ni = 0; ni < 4; ++ni) {
                int col = n0 + wn + ni * 16 + lr;
                if (col >= N) continue;
                float bv = bias ? bias[col] : 0.f;
                #pragma unroll
                for (int r = 0; r < 4; ++r) {
                    int row = m0 + wm + mi * 16 + quad * 4 + r;
                    float v = alpha * acc[mi][ni][r] + bv;
                    if (res) v += res[(long long)row * ldr + col];
                    C[(long long)row * ldc + col] = v;
                }
            }
    } else if (OUT == 1) {
        unsigned short* C = (unsigned short*)Cv + bb * sCb + hh * sCh;
        #pragma unroll
        for (int mi = 0; mi < 4; ++mi)
            #pragma unroll
            for (int ni = 0; ni < 4; ++ni) {
                int col = n0 + wn + ni * 16 + lr;
                if (col >= N) continue;
                float bv = bias ? bias[col] : 0.f;
                #pragma unroll
                for (int r = 0; r < 4; ++r) {
                    int row = m0 + wm + mi * 16 + quad * 4 + r;
                    float v = alpha * acc[mi][ni][r] + bv;
                    if (res) v += res[(long long)row * ldr + col];
                    unsigned short hi = bf16_rne(v);
                    unsigned short lo = bf16_rne(v - bf16_tof(hi));
                    long long p = (long long)row * ldc + col;
                    C[p] = hi;
                    C[p + cLo] = lo;
                }
            }
    } else {  // OUT == 2: transposed pairs per 512-row batch
        unsigned short* C = (unsigned short*)Cv;
        #pragma unroll
        for (int mi = 0; mi < 4; ++mi)
            #pragma unroll
            for (int ni = 0; ni < 4; ++ni) {
                int col = n0 + wn + ni * 16 + lr;
                if (col >= N) continue;
                int row0 = m0 + wm + mi * 16 + quad * 4;
                int b = row0 >> 9, seq0 = row0 & 511;
                ushort4 h4, l4;
                unsigned short* hp = (unsigned short*)&h4;
                unsigned short* lp = (unsigned short*)&l4;
                #pragma unroll
                for (int r = 0; r < 4; ++r) {
                    float v = acc[mi][ni][r];
                    unsigned short hi = bf16_rne(v);
                    hp[r] = hi;
                    lp[r] = bf16_rne(v - bf16_tof(hi));
                }
                long long p = b * sCb + (long long)col * ldc + seq0;
                *(ushort4*)&C[p] = h4;
                *(ushort4*)&C[p + cLo] = l4;
            }
    }
}

// ---------------------------------------------------------------------------
// DIRECT pipelined split-K GEMM -> f32 partial planes.
// TR=0: partial[row*N + col]. TR=1: transposed partials (float4 along seq).
// ---------------------------------------------------------------------------
template<int NPASS, int TR>
__global__ __launch_bounds__(256, 2) void gemm_bf16_skd_k(
    int N, int KC,
    const unsigned short* __restrict__ A2, int lda2, int aLo,
    const unsigned short* __restrict__ B2, int ldb2, int bLo,
    float* __restrict__ P, long long sCk)
{
    constexpr int NARR = (NPASS == 3) ? 4 : 2;
    constexpr int O_AH = 0;
    constexpr int O_BH = 128 * 32;
    constexpr int O_AL = 2 * 128 * 32;
    constexpr int O_BL = 3 * 128 * 32;
    constexpr int BUFSZ = 128 * 32 * NARR;
    __shared__ unsigned short SM[2 * BUFSZ];

    int bx = blockIdx.x, by = blockIdx.y;
    xcd_remap(bx, by);
    const int t    = threadIdx.x;
    const int m0   = by * 128;
    const int n0   = bx * 128;
    const int kbeg = blockIdx.z * KC;
    const int lane = t & 63, wave = t >> 6;
    const int wm   = (wave >> 1) * 64, wn = (wave & 1) * 64;
    const int lr   = lane & 15, quad = lane >> 4;

    f32x4 acc[4][4];
    #pragma unroll
    for (int i = 0; i < 4; ++i)
        #pragma unroll
        for (int j = 0; j < 4; ++j) acc[i][j] = (f32x4){0.f, 0.f, 0.f, 0.f};

    const int drow  = lane >> 2;
    const int dcswz = (((lane & 3) ^ ((lane >> 2) & 3) ^ ((lane >> 4) & 3)) << 3);
    const int rsw   = ((quad ^ ((lr & 3) ^ (lr >> 2))) << 3);

    auto stage = [&](int k0, int buf) {
        unsigned short* bp = &SM[buf * BUFSZ];
        #pragma unroll
        for (int j = 0; j < 2; ++j) {
            int rr = wave * 32 + j * 16;
            int gr = rr + drow;
            const unsigned short* gA = A2 + (long long)(m0 + gr) * lda2 + k0 + dcswz;
            async_ld16(gA, &bp[O_AH + rr * 32]);
            if (NPASS == 3) async_ld16(gA + aLo, &bp[O_AL + rr * 32]);
            const unsigned short* gB = B2 + (long long)(n0 + gr) * ldb2 + k0 + dcswz;
            async_ld16(gB, &bp[O_BH + rr * 32]);
            if (NPASS == 3) async_ld16(gB + bLo, &bp[O_BL + rr * 32]);
        }
    };

    const int nt = KC >> 5;
    stage(kbeg, 0);
    int cur = 0;
    for (int it = 0; it < nt; ++it) {
        asm volatile("s_waitcnt vmcnt(0)" ::: "memory");
        __builtin_amdgcn_s_barrier();
        if (it + 1 < nt) stage(kbeg + ((it + 1) << 5), cur ^ 1);

        const unsigned short* bp = &SM[cur * BUFSZ];
        bf16x8 ah[4], bh[4], al[4], bl[4];
        #pragma unroll
        for (int i = 0; i < 4; ++i) {
            int ra = O_AH + (wm + i * 16 + lr) * 32 + rsw;
            int rb = O_BH + (wn + i * 16 + lr) * 32 + rsw;
            ah[i] = *(const bf16x8*)&bp[ra];
            bh[i] = *(const bf16x8*)&bp[rb];
            if (NPASS == 3) {
                al[i] = *(const bf16x8*)&bp[ra + (O_AL - O_AH)];
                bl[i] = *(const bf16x8*)&bp[rb + (O_BL - O_BH)];
            }
        }
        #pragma unroll
        for (int mi = 0; mi < 4; ++mi)
            #pragma unroll
            for (int ni = 0; ni < 4; ++ni) {
                acc[mi][ni] = __builtin_amdgcn_mfma_f32_16x16x32_bf16(
                    ah[mi], bh[ni], acc[mi][ni], 0, 0, 0);
                if (NPASS == 3) {
                    acc[mi][ni] = __builtin_amdgcn_mfma_f32_16x16x32_bf16(
                        al[mi], bh[ni], acc[mi][ni], 0, 0, 0);
                    acc[mi][ni] = __builtin_amdgcn_mfma_f32_16x16x32_bf16(
                        ah[mi], bl[ni], acc[mi][ni], 0, 0, 0);
                }
            }
        cur ^= 1;
    }

    float* Pc = P + (long long)blockIdx.z * sCk;
    if (TR == 0) {
        #pragma unroll
        for (int mi = 0; mi < 4; ++mi)
            #pragma unroll
            for (int ni = 0; ni < 4; ++ni) {
                int col = n0 + wn + ni * 16 + lr;
                #pragma unroll
                for (int r = 0; r < 4; ++r) {
                    int row = m0 + wm + mi * 16 + quad * 4 + r;
                    Pc[(long long)row * N + col] = acc[mi][ni][r];
                }
            }
    } else {
        #pragma unroll
        for (int mi = 0; mi < 4; ++mi)
            #pragma unroll
            for (int ni = 0; ni < 4; ++ni) {
                int col = n0 + wn + ni * 16 + lr;
                int row0 = m0 + wm + mi * 16 + quad * 4;
                int b = row0 >> 9, seq0 = row0 & 511;
                *(float4*)&Pc[(long long)b * ((long long)N * 512)
                              + (long long)col * 512 + seq0] =
                    *(float4*)&acc[mi][ni];
            }
    }
}

// ---------------------------------------------------------------------------
// Split-K ragged GEMM for thin-N ops (xproj N=144, hW N=64).
// ---------------------------------------------------------------------------
template<int NPASS>
__global__ __launch_bounds__(256, 2) void gemm_bf16_sk_k(
    int N, int KC,
    const unsigned short* __restrict__ A2, int lda2, int aLo,
    const unsigned short* __restrict__ B2, int ldb2, int bLo,
    float* __restrict__ C, long long sCk)
{
    constexpr int ST = 40;
    __shared__ unsigned short Ah[128 * ST];
    __shared__ unsigned short Bh[128 * ST];
    __shared__ unsigned short Al[128 * ST];
    __shared__ unsigned short Bl[128 * ST];

    int bx = blockIdx.x, by = blockIdx.y;
    xcd_remap(bx, by);
    const int t    = threadIdx.x;
    const int m0   = by * 128;
    const int n0   = bx * 128;
    const int kbeg = blockIdx.z * KC;
    const int lane = t & 63, wave = t >> 6;
    const int wm   = (wave >> 1) * 64, wn = (wave & 1) * 64;
    const int lr   = lane & 15, quad = lane >> 4;

    f32x4 acc[4][4];
    #pragma unroll
    for (int i = 0; i < 4; ++i)
        #pragma unroll
        for (int j = 0; j < 4; ++j) acc[i][j] = (f32x4){0.f, 0.f, 0.f, 0.f};

    const int srow = t >> 2;
    const int scol = (t & 3) * 8;

    for (int k0 = kbeg; k0 < kbeg + KC; k0 += 32) {
        __syncthreads();
        #pragma unroll
        for (int half = 0; half < 2; ++half) {
            int r = srow + half * 64;
            const unsigned short* pA = A2 + (long long)(m0 + r) * lda2 + k0 + scol;
            *(uint4*)&Ah[r * ST + scol] = *(const uint4*)pA;
            if (NPASS == 3)
                *(uint4*)&Al[r * ST + scol] = *(const uint4*)(pA + aLo);
            int rb = n0 + r;
            uint4 vh = {0u, 0u, 0u, 0u}, vl = {0u, 0u, 0u, 0u};
            if (rb < N) {
                const unsigned short* pB = B2 + (long long)rb * ldb2 + k0 + scol;
                vh = *(const uint4*)pB;
                if (NPASS == 3) vl = *(const uint4*)(pB + bLo);
            }
            *(uint4*)&Bh[r * ST + scol] = vh;
            if (NPASS == 3) *(uint4*)&Bl[r * ST + scol] = vl;
        }
        __syncthreads();

        bf16x8 ah[4], bh[4], al[4], bl[4];
        #pragma unroll
        for (int i = 0; i < 4; ++i) {
            int ra = (wm + i * 16 + lr) * ST + quad * 8;
            int rb = (wn + i * 16 + lr) * ST + quad * 8;
            ah[i] = *(const bf16x8*)&Ah[ra];
            bh[i] = *(const bf16x8*)&Bh[rb];
            if (NPASS == 3) {
                al[i] = *(const bf16x8*)&Al[ra];
                bl[i] = *(const bf16x8*)&Bl[rb];
            }
        }
        #pragma unroll
        for (int mi = 0; mi < 4; ++mi)
            #pragma unroll
            for (int ni = 0; ni < 4; ++ni) {
                acc[mi][ni] = __builtin_amdgcn_mfma_f32_16x16x32_bf16(
                    ah[mi], bh[ni], acc[mi][ni], 0, 0, 0);
                if (NPASS == 3) {
                    acc[mi][ni] = __builtin_amdgcn_mfma_f32_16x16x32_bf16(
                        al[mi], bh[ni], acc[mi][ni], 0, 0, 0);
                    acc[mi][ni] = __builtin_amdgcn_mfma_f32_16x16x32_bf16(
                        ah[mi], bl[ni], acc[mi][ni], 0, 0, 0);
                }
            }
    }

    float* Cc = C + (long long)blockIdx.z * sCk;
    #pragma unroll
    for (int mi = 0; mi < 4; ++mi)
        #pragma unroll
        for (int ni = 0; ni < 4; ++ni) {
            int col = n0 + wn + ni * 16 + lr;
            if (col >= N) continue;
            #pragma unroll
            for (int r = 0; r < 4; ++r) {
                int row = m0 + wm + mi * 16 + quad * 4 + r;
                Cc[(long long)row * N + col] = acc[mi][ni][r];
            }
        }
}

// ---- fused split-K reduce epilogues ----

// in-GEMM: partials(2 planes, 1024 cols) -> T (f32) + RMSNorm pairs HR2.
__global__ __launch_bounds__(256) void skred_rms_k(
    const float* __restrict__ P, long long sCk,
    float* __restrict__ T, unsigned short* __restrict__ HR2,
    const float* __restrict__ w)
{
    long long r = blockIdx.x;
    const int t = threadIdx.x;
    long long base = r * 1024 + t * 4;
    float4 a = *(const float4*)&P[base];
    float4 bq = *(const float4*)&P[sCk + base];
    float v[4] = {a.x + bq.x, a.y + bq.y, a.z + bq.z, a.w + bq.w};
    *(float4*)&T[base] = *(float4*)v;
    float s = v[0]*v[0] + v[1]*v[1] + v[2]*v[2] + v[3]*v[3];
    s = block_sum256(s);
    float rs = 1.f / sqrtf(s * (1.f / 1024.f) + 1e-5f);
    #pragma unroll
    for (int e = 0; e < 4; ++e) {
        int c = t * 4 + e;
        store_pair(HR2, r, 1024, c, v[e] * rs * w[c]);
    }
}

// outp-GEMM: partials + bias + residual -> Y1 (f32) + LayerNorm pairs LNY2.
__global__ __launch_bounds__(256) void skred_ln_k(
    const float* __restrict__ P, long long sCk,
    const float* __restrict__ bias, const float* __restrict__ res,
    float* __restrict__ Y1, unsigned short* __restrict__ LNY2,
    const float* __restrict__ w, const float* __restrict__ b)
{
    long long r = blockIdx.x;
    const int t = threadIdx.x;
    long long base = r * 1024 + t * 4;
    float4 a  = *(const float4*)&P[base];
    float4 bq = *(const float4*)&P[sCk + base];
    float4 rv = *(const float4*)&res[base];
    float4 bi = *(const float4*)&bias[t * 4];
    float v[4] = {a.x + bq.x + rv.x + bi.x, a.y + bq.y + rv.y + bi.y,
                  a.z + bq.z + rv.z + bi.z, a.w + bq.w + rv.w + bi.w};
    *(float4*)&Y1[base] = *(float4*)v;
    float s = v[0] + v[1] + v[2] + v[3];
    s = block_sum256(s);
    float m = s * (1.f / 1024.f);
    float vs = 0.f;
    #pragma unroll
    for (int e = 0; e < 4; ++e) { float d = v[e] - m; vs += d * d; }
    vs = block_sum256(vs);
    float rs = 1.f / sqrtf(vs * (1.f / 1024.f) + 1e-5f);
    #pragma unroll
    for (int e = 0; e < 4; ++e) {
        int c = t * 4 + e;
        store_pair(LNY2, r, 1024, c, (v[e] - m) * rs * w[c] + b[c]);
    }
}

// xproj: 8-chunk reduce -> dtBC, plus softplus(dt_bias) -> DT for cols<16.
__global__ __launch_bounds__(256) void skred_dt_k(
    const float* __restrict__ P, long long sCk,
    const float* __restrict__ dt_bias,
    float* __restrict__ dtBC, float* __restrict__ DT, long long n)
{
    long long idx = (long long)blockIdx.x * 256 + threadIdx.x;
    if (idx >= n) return;
    float s = 0.f;
    #pragma unroll
    for (int c = 0; c < 8; ++c) s += P[c * sCk + idx];
    dtBC[idx] = s;
    long long row = idx / 144;
    int col = (int)(idx - row * 144);
    if (col < 16) {
        float xv = s + dt_bias[col];
        DT[row * 16 + col] = (xv > 20.f) ? xv : log1pf(expf(xv));
    }
}

// hW: 8-chunk reduce + h_b + LayerNorm64 + sign-quant -> HCQ2 pairs (lo=0).
__global__ __launch_bounds__(64) void skred_hc_k(
    const float* __restrict__ P, long long sCk,
    const float* __restrict__ h_b,
    const float* __restrict__ w, const float* __restrict__ b,
    unsigned short* __restrict__ HCQ2)
{
    int r = blockIdx.x, ln = threadIdx.x;
    long long base = (long long)r * 64 + ln;
    float v = 0.f;
    #pragma unroll
    for (int c = 0; c < 8; ++c) v += P[c * sCk + base];
    v += h_b[ln];
    float s = v;
    #pragma unroll
    for (int o = 32; o > 0; o >>= 1) s += __shfl_xor(s, o, 64);
    float m = s * (1.f / 64.f);
    float d = v - m;
    float vs = d * d;
    #pragma unroll
    for (int o = 32; o > 0; o >>= 1) vs += __shfl_xor(vs, o, 64);
    vs *= (1.f / 64.f);
    float hc = d * (1.f / sqrtf(vs + 1e-5f)) * w[ln] + b[ln];
    HCQ2[r * 128 + ln] = (hc > 0.f) ? 0x3F80 : 0xBF80;
    HCQ2[r * 128 + 64 + ln] = 0;
}

// pairs out, N=1024 layout (aWo epilogue): bias + residual -> Y22 pairs.
__global__ __launch_bounds__(256) void skredP_k(
    const float* __restrict__ P, long long sCk, int nchunk,
    const float* __restrict__ bias, const float* __restrict__ res,
    unsigned short* __restrict__ out2, long long n)
{
    long long idx = (long long)blockIdx.x * 256 + threadIdx.x;
    if (idx >= n) return;
    float s = 0.f;
    for (int c = 0; c < nchunk; ++c) s += P[c * sCk + idx];
    int col = (int)(idx & 1023);
    long long row = idx >> 10;
    if (bias) s += bias[col];
    if (res) s += res[idx];
    unsigned short hi = bf16_rne(s);
    unsigned short lo = bf16_rne(s - bf16_tof(hi));
    long long pos = row * 2048 + col;
    out2[pos] = hi;
    out2[pos + 1024] = lo;
}

// transposed pairs out (VT2 layout), partials TR=1.
__global__ __launch_bounds__(256) void skredT_k(
    const float* __restrict__ P, long long sCk, int nchunk,
    unsigned short* __restrict__ out2, long long n)
{
    long long idx = (long long)blockIdx.x * 256 + threadIdx.x;
    if (idx >= n) return;
    float s = 0.f;
    for (int c = 0; c < nchunk; ++c) s += P[c * sCk + idx];
    int seq = (int)(idx & 511);
    int col = (int)((idx >> 9) & 1023);
    int b   = (int)(idx >> 19);
    unsigned short hi = bf16_rne(s);
    unsigned short lo = bf16_rne(s - bf16_tof(hi));
    long long pos = (long long)b * 1048576 + (long long)col * 1024 + seq;
    out2[pos] = hi;
    out2[pos + 512] = lo;
}

// ---------------------------------------------------------------------------
// Fused SSD intra-chunk MFMA kernel, v4 (unchanged).
// ---------------------------------------------------------------------------
__global__ __launch_bounds__(256, 2) void ssd_mfma_k(
    const float* __restrict__ G, const float* __restrict__ CUMA,
    const float* __restrict__ DT, const unsigned short* __restrict__ XCT2,
    const float* __restrict__ Z, const float* __restrict__ Dv,
    unsigned short* __restrict__ YS2)
{
    __shared__ unsigned short Xh[3][128 * 32];
    __shared__ unsigned short Xl[3][128 * 32];
    __shared__ unsigned short Wh[2][64 * 32];
    __shared__ unsigned short Wl[2][64 * 32];
    __shared__ float Cs[512];
    __shared__ float Ds[512];
    const int q = blockIdx.x;
    const int h = blockIdx.y, b = blockIdx.z;
    const int t = threadIdx.x;
    const int lane = t & 63, wave = t >> 6;
    const int lr = lane & 15, quad = lane >> 4;

    const float* cbase = CUMA + (b * 16 + h) * 512;
    const float* dtb = DT + (long long)b * 512 * 16 + h;
    for (int s = t; s < 512; s += 256) {
        Cs[s] = cbase[s];
        Ds[s] = dtb[(long long)s * 16];
    }
    const float Dh = Dv[h];

    const int wr = t >> 2;
    const int sw = t & 3;
    const int wbase = wr * 32 + ((sw ^ ((wr >> 1) & 3)) << 3);
    const int frow = wave * 16 + lr;
    const int fbase = frow * 32 + ((quad ^ ((frow >> 1) & 3)) << 3);
    const int drow  = lane >> 2;
    const int dcswz = (((lane & 3) ^ ((lane >> 2) & 3) ^ ((lane >> 4) & 3)) << 3);
    const int xsw   = ((quad ^ ((lr & 3) ^ ((lr >> 2) & 3))) << 3);
    const unsigned short* XB = XCT2 + (long long)b * 2097152
                             + (long long)(h * 128) * 1024;
    __syncthreads();

    for (int ph = 0; ph < 2; ++ph) {
        const int mt = ph ? q : 7 - q;
        const int m0 = mt * 64;
        const int nt = (m0 >> 5) + 2;
        const int lglob = m0 + wr;
        const float cAl = Cs[lglob];
        const float* grow = G + ((long long)(b * 512 + lglob)) * 512;

        float pg[8], pc[8], pd[8];
        auto gen_load = [&](int k0g) {
            const int sb = k0g + sw * 8;
            float4 g0 = *(const float4*)(grow + sb);
            float4 g1 = *(const float4*)(grow + sb + 4);
            float4 c0 = *(const float4*)&Cs[sb];
            float4 c1 = *(const float4*)&Cs[sb + 4];
            float4 d0 = *(const float4*)&Ds[sb];
            float4 d1 = *(const float4*)&Ds[sb + 4];
            pg[0] = g0.x; pg[1] = g0.y; pg[2] = g0.z; pg[3] = g0.w;
            pg[4] = g1.x; pg[5] = g1.y; pg[6] = g1.z; pg[7] = g1.w;
            pc[0] = c0.x; pc[1] = c0.y; pc[2] = c0.z; pc[3] = c0.w;
            pc[4] = c1.x; pc[5] = c1.y; pc[6] = c1.z; pc[7] = c1.w;
            pd[0] = d0.x; pd[1] = d0.y; pd[2] = d0.z; pd[3] = d0.w;
            pd[4] = d1.x; pd[5] = d1.y; pd[6] = d1.z; pd[7] = d1.w;
        };
        auto gen_finish = [&](int k0g, int buf) {
            const int sb = k0g + sw * 8;
            const bool edge = (k0g + 32 > m0);
            unsigned short hv[8], lv[8];
            #pragma unroll
            for (int e = 0; e < 8; ++e) {
                float w = pg[e] * __expf(cAl - pc[e]) * pd[e];
                if (edge) {
                    int sg = sb + e;
                    w = (sg <= lglob) ? w : 0.f;
                    if (sg == lglob) w += Dh;
                }
                unsigned short hi = bf16_rne(w);
                hv[e] = hi;
                lv[e] = bf16_rne(w - bf16_tof(hi));
            }
            *(uint4*)&Wh[buf][wbase] = *(uint4*)hv;
            *(uint4*)&Wl[buf][wbase] = *(uint4*)lv;
        };
        auto stageX = [&](int k0, int buf) {
            #pragma unroll
            for (int j = 0; j < 2; ++j) {
                int rr = wave * 32 + j * 16;
                const unsigned short* gX =
                    XB + (long long)(rr + drow) * 1024 + k0 + dcswz;
                async_ld16(gX,       &Xh[buf][rr * 32]);
                async_ld16(gX + 512, &Xl[buf][rr * 32]);
            }
        };

        f32x4 acc[8];
        #pragma unroll
        for (int j = 0; j < 8; ++j) acc[j] = (f32x4){0.f, 0.f, 0.f, 0.f};

        gen_load(0);
        stageX(0, 0);
        if (nt > 1) stageX(32, 1);
        gen_finish(0, 0);
        if (nt > 1) asm volatile("s_waitcnt vmcnt(4)" ::: "memory");
        else        asm volatile("s_waitcnt vmcnt(0)" ::: "memory");
        asm volatile("s_waitcnt lgkmcnt(0)" ::: "memory");
        __builtin_amdgcn_s_barrier();

        for (int it = 0; it < nt; ++it) {
            const int xb = it % 3;
            const int wb = it & 1;
            if (it + 1 < nt) gen_load((it + 1) << 5);
            if (it + 2 < nt) stageX((it + 2) << 5, (it + 2) % 3);

            bf16x8 ah = *(const bf16x8*)&Wh[wb][fbase];
            bf16x8 al = *(const bf16x8*)&Wl[wb][fbase];
            const unsigned short* xhp = &Xh[xb][0];
            const unsigned short* xlp = &Xl[xb][0];
            #pragma unroll
            for (int ni = 0; ni < 8; ++ni) {
                int base = (ni * 16 + lr) * 32 + xsw;
                bf16x8 bh = *(const bf16x8*)&xhp[base];
                bf16x8 bl = *(const bf16x8*)&xlp[base];
                acc[ni] = __builtin_amdgcn_mfma_f32_16x16x32_bf16(
                    ah, bh, acc[ni], 0, 0, 0);
                acc[ni] = __builtin_amdgcn_mfma_f32_16x16x32_bf16(
                    al, bh, acc[ni], 0, 0, 0);
                acc[ni] = __builtin_amdgcn_mfma_f32_16x16x32_bf16(
                    ah, bl, acc[ni], 0, 0, 0);
            }
            if (it + 1 < nt) gen_finish((it + 1) << 5, wb ^ 1);
            if (it + 2 < nt) asm volatile("s_waitcnt vmcnt(4)" ::: "memory");
            else             asm volatile("s_waitcnt vmcnt(0)" ::: "memory");
            asm volatile("s_waitcnt lgkmcnt(0)" ::: "memory");
            __builtin_amdgcn_s_barrier();
        }

        const int row0 = m0 + wave * 16 + quad * 4;
        #pragma unroll
        for (int ni = 0; ni < 8; ++ni) {
            int chan = h * 128 + ni * 16 + lr;
            #pragma unroll
            for (int r = 0; r < 4; ++r) {
                long long row = (long long)(b * 512 + row0 + r);
                float zz = Z[row * 2048 + chan];
                float y = acc[ni][r] * (zz / (1.f + expf(-zz)));
                store_pair(YS2, row, 2048, chan, y);
            }
        }
    }
}

// ---------------------------------------------------------------------------
// Tiled f32 GEMM (only for the small batched G = Cm @ Bm^T)
// ---------------------------------------------------------------------------
__global__ __launch_bounds__(256) void gemm_f32_k(
    int M, int N, int K,
    const float* __restrict__ A, int lda, long long sAb,
    const float* __restrict__ B, int ldb, long long sBb,
    float* __restrict__ C, int ldc, long long sCb)
{
    __shared__ float As[32][132];
    __shared__ float Bs[32][132];
    const int z = blockIdx.z;
    A += z * sAb; B += z * sBb; C += z * sCb;
    const int n0 = blockIdx.x * 128;
    const int m0 = blockIdx.y * 128;
    const int t  = threadIdx.x;
    const int tx = t & 15, ty = t >> 4;

    float acc[4][16];
    #pragma unroll
    for (int a = 0; a < 4; ++a)
        #pragma unroll
        for (int q = 0; q < 16; ++q) acc[a][q] = 0.f;

    const int ka = (t & 7) << 2;
    const int ra = t >> 3;

    for (int k0 = 0; k0 < K; k0 += 32) {
        __syncthreads();
        #pragma unroll
        for (int i = 0; i < 4; ++i) {
            int row = m0 + ra + i * 32;
            float4 v = *(const float4*)(A + (long long)row * lda + (k0 + ka));
            As[ka + 0][ra + i * 32] = v.x;
            As[ka + 1][ra + i * 32] = v.y;
            As[ka + 2][ra + i * 32] = v.z;
            As[ka + 3][ra + i * 32] = v.w;
            int rowb = n0 + ra + i * 32;
            float4 w = *(const float4*)(B + (long long)rowb * ldb + (k0 + ka));
            Bs[ka + 0][ra + i * 32] = w.x;
            Bs[ka + 1][ra + i * 32] = w.y;
            Bs[ka + 2][ra + i * 32] = w.z;
            Bs[ka + 3][ra + i * 32] = w.w;
        }
        __syncthreads();
        #pragma unroll
        for (int kk = 0; kk < 32; ++kk) {
            float a[8], bm[8];
            *(float4*)&a[0]  = *(const float4*)&As[kk][ty * 4];
            *(float4*)&a[4]  = *(const float4*)&As[kk][64 + ty * 4];
            *(float4*)&bm[0] = *(const float4*)&Bs[kk][tx * 4];
            *(float4*)&bm[4] = *(const float4*)&Bs[kk][64 + tx * 4];
            #pragma unroll
            for (int ri = 0; ri < 2; ++ri)
                #pragma unroll
                for (int ci = 0; ci < 2; ++ci)
                    #pragma unroll
                    for (int i = 0; i < 4; ++i)
                        #pragma unroll
                        for (int j = 0; j < 4; ++j)
                            acc[ri * 2 + ci][i * 4 + j] =
                                fmaf(a[ri * 4 + i], bm[ci * 4 + j], acc[ri * 2 + ci][i * 4 + j]);
        }
    }
    #pragma unroll
    for (int ri = 0; ri < 2; ++ri)
        #pragma unroll
        for (int ci = 0; ci < 2; ++ci) {
            int colb = n0 + ci * 64 + tx * 4;
            #pragma unroll
            for (int i = 0; i < 4; ++i) {
                int row = m0 + ri * 64 + ty * 4 + i;
                *(float4*)(C + (long long)row * ldc + colb) =
                    *(float4*)&acc[ri * 2 + ci][i * 4];
            }
        }
}

// ---------------------------------------------------------------------------
// Elementwise / norm kernels
// ---------------------------------------------------------------------------
__global__ __launch_bounds__(256) void pairify_k(
    const float* __restrict__ src, unsigned short* __restrict__ dst,
    int k_log2, long long n)
{
    long long idx = (long long)blockIdx.x * 256 + threadIdx.x;
    if (idx >= n) return;
    long long r = idx >> k_log2;
    int c = (int)(idx & ((1 << k_log2) - 1));
    store_pair(dst, r, 1 << k_log2, c, src[idx]);
}

// Batched pairify: one launch, segment per blockIdx.y.
struct PairSegs {
    const float* src[7];
    unsigned short* dst[7];
    long long n[7];
    int klog2[7];
};
__global__ __launch_bounds__(256) void pairify_multi_k(PairSegs segs)
{
    int sg = blockIdx.y;
    long long idx = (long long)blockIdx.x * 256 + threadIdx.x;
    if (idx >= segs.n[sg]) return;
    int kl = segs.klog2[sg];
    long long r = idx >> kl;
    int c = (int)(idx & ((1LL << kl) - 1));
    store_pair(segs.dst[sg], r, 1 << kl, c, segs.src[sg][idx]);
}

// One-pass register-resident LayerNorm -> split pairs. width = NE*256.
template<int NE>
__global__ __launch_bounds__(256) void layernorm_pair_v_k(
    const float* __restrict__ in, unsigned short* __restrict__ out2,
    const float* __restrict__ w, const float* __restrict__ b,
    int rows_per_b, long long in_bstride)
{
    const int width = NE * 256;
    long long r = blockIdx.x;
    const float* x = in + (r / rows_per_b) * in_bstride
                   + (r % rows_per_b) * (long long)width;
    const int t = threadIdx.x;
    float v[NE];
    float s = 0.f;
    #pragma unroll
    for (int j = 0; j < NE / 4; ++j) {
        float4 f = *(const float4*)(x + j * 1024 + t * 4);
        v[j * 4 + 0] = f.x; v[j * 4 + 1] = f.y;
        v[j * 4 + 2] = f.z; v[j * 4 + 3] = f.w;
        s += f.x + f.y + f.z + f.w;
    }
    s = block_sum256(s);
    float m = s / (float)width;
    float vs = 0.f;
    #pragma unroll
    for (int e = 0; e < NE; ++e) { float d = v[e] - m; vs += d * d; }
    vs = block_sum256(vs);
    float rs = 1.f / sqrtf(vs / (float)width + 1e-5f);
    #pragma unroll
    for (int j = 0; j < NE / 4; ++j)
        #pragma unroll
        for (int e = 0; e < 4; ++e) {
            int c = j * 1024 + t * 4 + e;
            store_pair(out2, r, width, c, (v[j * 4 + e] - m) * rs * w[c] + b[c]);
        }
}

// Softmax over 512-wide rows, f32 in -> split-pair out IN-PLACE (same bytes).
__global__ __launch_bounds__(256) void softmax_pair_k(float* __restrict__ S,
                                                      unsigned short* __restrict__ P2)
{
    long long r = blockIdx.x;
    float* x = S + r * 512;
    unsigned short* p = P2 + r * 1024;
    int t = threadIdx.x;
    float v0 = x[t], v1 = x[t + 256];
    float mx = block_max256(fmaxf(v0, v1));
    v0 = expf(v0 - mx); v1 = expf(v1 - mx);
    float sum = block_sum256(v0 + v1);
    float inv = 1.f / sum;
    v0 *= inv; v1 *= inv;
    __syncthreads();
    unsigned short h0 = bf16_rne(v0);
    p[t] = h0;       p[512 + t] = bf16_rne(v0 - bf16_tof(h0));
    unsigned short h1 = bf16_rne(v1);
    p[t + 256] = h1; p[512 + t + 256] = bf16_rne(v1 - bf16_tof(h1));
}

// Causal grouped conv with LDS-tile transpose: writes seq-major pairs XC2
// AND chan-major pairs XCT2, both coalesced.
__global__ __launch_bounds__(256) void conv_k(
    const float* __restrict__ XS, const float* __restrict__ W,
    unsigned short* __restrict__ XC2, unsigned short* __restrict__ XCT2)
{
    __shared__ float tile[64][65];
    const int o0  = blockIdx.x * 64;
    const int tt0 = blockIdx.y * 64;
    const int b   = blockIdx.z;
    const int t   = threadIdx.x;

    const int o  = o0 + (t & 63);
    const int g2 = (o >> 1) << 1;
    const float* Wo = W + o * 8;
    float w0 = Wo[0], w1 = Wo[1], w2 = Wo[2], w3 = Wo[3];
    float w4 = Wo[4], w5 = Wo[5], w6 = Wo[6], w7 = Wo[7];
    #pragma unroll
    for (int i = 0; i < 16; ++i) {
        int sl = (t >> 6) + 4 * i;
        int tt = tt0 + sl;
        const float* xb = XS + ((long long)(b * 512 + tt)) * 2048 + g2;
        float acc = w3 * xb[0] + w7 * xb[1];
        if (tt >= 1) acc += w2 * xb[-2048] + w6 * xb[-2047];
        if (tt >= 2) acc += w1 * xb[-4096] + w5 * xb[-4095];
        if (tt >= 3) acc += w0 * xb[-6144] + w4 * xb[-6143];
        tile[sl][t & 63] = acc;
    }
    __syncthreads();
    #pragma unroll
    for (int i = 0; i < 16; ++i) {
        int idx = t + 256 * i;
        int sl = idx >> 6, ol = idx & 63;
        float v = tile[sl][ol];
        unsigned short hi = bf16_rne(v);
        unsigned short lo = bf16_rne(v - bf16_tof(hi));
        long long row = (long long)(b * 512 + tt0 + sl);
        XC2[row * 4096 + o0 + ol] = hi;
        XC2[row * 4096 + 2048 + o0 + ol] = lo;
    }
    #pragma unroll
    for (int i = 0; i < 16; ++i) {
        int idx = t + 256 * i;
        int cl = idx >> 6, s = idx & 63;
        float v = tile[s][cl];
        unsigned short hi = bf16_rne(v);
        unsigned short lo = bf16_rne(v - bf16_tof(hi));
        long long tb = (long long)b * 2097152 + (long long)(o0 + cl) * 1024 + tt0 + s;
        XCT2[tb] = hi;
        XCT2[tb + 512] = lo;
    }
}

__global__ __launch_bounds__(64) void cuma_k(
    const float* __restrict__ DT, const float* __restrict__ A_log, float* __restrict__ CUMA)
{
    int h = blockIdx.x, b = blockIdx.y;
    int ln = threadIdx.x;
    float Ah = -expf(A_log[h]);
    float v[8];
    float run = 0.f;
    #pragma unroll
    for (int i = 0; i < 8; ++i) {
        run += Ah * DT[((b * 512) + (ln * 8 + i)) * 16 + h];
        v[i] = run;
    }
    float tot = run;
    float sc = tot;
    #pragma unroll
    for (int o = 1; o <= 32; o <<= 1) {
        float u = __shfl_up(sc, o, 64);
        if (ln >= o) sc += u;
    }
    float excl = sc - tot;
    #pragma unroll
    for (int i = 0; i < 8; ++i)
        CUMA[(b * 16 + h) * 512 + ln * 8 + i] = excl + v[i];
}

// Fused dxm = mtok @ e2d^T, then LayerNorm -> lnm. One block.
__global__ __launch_bounds__(256) void dxm_ln_k(
    const float* __restrict__ mtok, const float* __restrict__ e2d,
    const float* __restrict__ w, const float* __restrict__ b,
    float* __restrict__ dxm, float* __restrict__ lnm)
{
    __shared__ float dx[1024];
    const int t = threadIdx.x;
    float mv[64];
    #pragma unroll
    for (int j = 0; j < 64; ++j) mv[j] = mtok[j];
    float loc[4];
    #pragma unroll
    for (int q = 0; q < 4; ++q) {
        int c = q * 256 + t;
        const float* er = e2d + (long long)c * 64;
        float acc = 0.f;
        #pragma unroll
        for (int j = 0; j < 64; ++j) acc = fmaf(mv[j], er[j], acc);
        loc[q] = acc;
        dx[c] = acc;
        dxm[c] = acc;
    }
    float s = loc[0] + loc[1] + loc[2] + loc[3];
    s = block_sum256(s);
    float m = s * (1.f / 1024.f);
    float vs = 0.f;
    #pragma unroll
    for (int q = 0; q < 4; ++q) { float d = loc[q] - m; vs += d * d; }
    vs = block_sum256(vs);
    float rs = 1.f / sqrtf(vs * (1.f / 1024.f) + 1e-5f);
    #pragma unroll
    for (int q = 0; q < 4; ++q) {
        int c = q * 256 + t;
        lnm[c] = (loc[q] - m) * rs * w[c] + b[c];
    }
}

__global__ __launch_bounds__(256) void projm_k(
    const float* __restrict__ lnm,
    const float* __restrict__ bWq, const float* __restrict__ bWk, const float* __restrict__ bWv,
    float* __restrict__ qm, float* __restrict__ km, float* __restrict__ vm)
{
    int idx = blockIdx.x * 256 + threadIdx.x;
    int sel = idx >> 10, c = idx & 1023;
    const float* W = (sel == 0) ? bWq : (sel == 1) ? bWk : bWv;
    float* O = (sel == 0) ? qm : (sel == 1) ? km : vm;
    const float* wr = W + (long long)c * 1024;
    float acc = 0.f;
    for (int j = 0; j < 1024; j += 4) {
        float4 a = *(const float4*)(lnm + j);
        float4 w4 = *(const float4*)(wr + j);
        acc = fmaf(a.x, w4.x, fmaf(a.y, w4.y, fmaf(a.z, w4.z, fmaf(a.w, w4.w, acc))));
    }
    O[c] = acc;
}

// Collapsed decoder attention on fused KV buffer: KVm[row][0..1023]=K,
// [1024..2047]=V. 1 query/(b,h); keys = 512 visible + mask key x512.
__global__ __launch_bounds__(256) void dec_attn_k(
    const float* __restrict__ KVm,
    const float* __restrict__ qm, const float* __restrict__ km,
    const float* __restrict__ vm, float* __restrict__ OBm)
{
    int h = blockIdx.x, b = blockIdx.y;
    int t = threadIdx.x;
    __shared__ __align__(16) float qs[256];
    __shared__ __align__(16) float ps[512];
    qs[t] = qm[h * 256 + t];
    __syncthreads();
    float s[2];
    #pragma unroll
    for (int i = 0; i < 2; ++i) {
        int r = t + i * 256;
        const float* kr = KVm + ((long long)(b * 512 + r)) * 2048 + h * 256;
        float acc = 0.f;
        for (int c = 0; c < 256; c += 4) {
            float4 k4 = *(const float4*)(kr + c);
            float4 q4 = *(const float4*)(qs + c);
            acc = fmaf(k4.x, q4.x, fmaf(k4.y, q4.y, fmaf(k4.z, q4.z, fmaf(k4.w, q4.w, acc))));
        }
        s[i] = acc * (1.f / 16.f);
    }
    float accm = 0.f;
    for (int c = 0; c < 256; c += 4) {
        float4 k4 = *(const float4*)(km + h * 256 + c);
        float4 q4 = *(const float4*)(qs + c);
        accm = fmaf(k4.x, q4.x, fmaf(k4.y, q4.y, fmaf(k4.z, q4.z, fmaf(k4.w, q4.w, accm))));
    }
    float smv = accm * (1.f / 16.f);
    float mx = block_max256(fmaxf(fmaxf(s[0], s[1]), smv));
    float p0 = expf(s[0] - mx), p1 = expf(s[1] - mx);
    ps[t] = p0; ps[t + 256] = p1;
    float pm = expf(smv - mx) * 512.f;
    float sum = block_sum256(p0 + p1) + pm;
    float inv = 1.f / sum;
    __syncthreads();
    float o = pm * vm[h * 256 + t];
    const float* vcol = KVm + (long long)b * 512 * 2048 + 1024 + h * 256 + t;
    for (int j = 0; j < 512; ++j)
        o = fmaf(ps[j], vcol[(long long)j * 2048], o);
    OBm[b * 1024 + h * 256 + t] = o * inv;
}

__global__ __launch_bounds__(256) void ydm_k(
    const float* __restrict__ OBm, const float* __restrict__ bWo,
    const float* __restrict__ bWo_b, const float* __restrict__ dxm,
    float* __restrict__ ydm)
{
    int idx = blockIdx.x * 256 + threadIdx.x;
    int b = idx >> 10, c = idx & 1023;
    const float* ar = OBm + b * 1024;
    const float* wr = bWo + (long long)c * 1024;
    float acc = 0.f;
    for (int j = 0; j < 1024; j += 4) {
        float4 a = *(const float4*)(ar + j);
        float4 w4 = *(const float4*)(wr + j);
        acc = fmaf(a.x, w4.x, fmaf(a.y, w4.y, fmaf(a.z, w4.z, fmaf(a.w, w4.w, acc))));
    }
    ydm[idx] = acc + bWo_b[c] + dxm[c];
}

__global__ __launch_bounds__(256) void outm_k(
    const float* __restrict__ ydm, const float* __restrict__ dout_W,
    const float* __restrict__ dout_b, float* __restrict__ outm)
{
    int idx = blockIdx.x * 256 + threadIdx.x;
    int b = idx >> 11, c = idx & 2047;
    const float* ar = ydm + b * 1024;
    const float* wr = dout_W + (long long)c * 1024;
    float acc = 0.f;
    for (int j = 0; j < 1024; j += 4) {
        float4 a = *(const float4*)(ar + j);
        float4 w4 = *(const float4*)(wr + j);
        acc = fmaf(a.x, w4.x, fmaf(a.y, w4.y, fmaf(a.z, w4.z, fmaf(a.w, w4.w, acc))));
    }
    outm[idx] = acc + dout_b[c];
}

__global__ __launch_bounds__(256) void bcast_k(
    const float* __restrict__ outm, float* __restrict__ out)
{
    int idx = blockIdx.x * 256 + threadIdx.x;
    int c4 = idx & 511;
    int b = idx >> 18;
    ((float4*)out)[idx] = ((const float4*)outm)[b * 512 + c4];
}

// ---------------------------------------------------------------------------
// Host-side launcher
// ---------------------------------------------------------------------------
extern "C" void kernel_launch(void* const* d_in, const int* in_sizes, int n_in,
                              void* d_out, int out_size, void* d_ws, size_t ws_size,
                              hipStream_t stream)
{
    const float* x       = (const float*)d_in[0];
    const float* ln0_w   = (const float*)d_in[1];
    const float* ln0_b   = (const float*)d_in[2];
    const float* in_W    = (const float*)d_in[3];
    const float* rms_w   = (const float*)d_in[4];
    const float* exp_W   = (const float*)d_in[5];
    const float* conv_W  = (const float*)d_in[6];
    const float* xproj_W = (const float*)d_in[7];
    const float* dt_bias = (const float*)d_in[8];
    const float* A_log   = (const float*)d_in[9];
    const float* Dv      = (const float*)d_in[10];
    const float* outp_W  = (const float*)d_in[11];
    const float* outp_b  = (const float*)d_in[12];
    const float* n1_w    = (const float*)d_in[13];
    const float* n1_b    = (const float*)d_in[14];
    const float* aWq     = (const float*)d_in[15];
    const float* aWk     = (const float*)d_in[16];
    const float* aWv     = (const float*)d_in[17];
    const float* aWo     = (const float*)d_in[18];
    const float* aWo_b   = (const float*)d_in[19];
    const float* h_W     = (const float*)d_in[20];
    const float* h_b     = (const float*)d_in[21];
    const float* h_lnw   = (const float*)d_in[22];
    const float* h_lnb   = (const float*)d_in[23];
    const float* mtok    = (const float*)d_in[24];
    const float* e2d_W   = (const float*)d_in[25];
    const float* dn_w    = (const float*)d_in[26];
    const float* dn_b    = (const float*)d_in[27];
    const float* bWq     = (const float*)d_in[28];
    const float* bWk     = (const float*)d_in[29];
    const float* bWv     = (const float*)d_in[30];
    const float* bWo     = (const float*)d_in[31];
    const float* bWo_b   = (const float*)d_in[32];
    const float* dout_W  = (const float*)d_in[33];
    const float* dout_b  = (const float*)d_in[34];

    float* ws  = (float*)d_ws;
    float* out = (float*)d_out;

    float* S1 = ws;
    float* S2 = ws + 8388608;
    float* S3 = ws + 16777216;
    float* S4 = ws + 25165824;
    float* S5 = ws + 33554432;
    float* S6 = ws + 37748736;
    float* S7 = ws + 41943040;
    float* S8 = ws + 46137344;
    float* S9 = ws + 50331648;
    float* SP = ws + 54525952;

    unsigned short* XV2     = (unsigned short*)S1;
    unsigned short* exp_W2  = (unsigned short*)S1;
    unsigned short* XCT2    = (unsigned short*)S1;
    float*          POUTP   = S1;            // outp split-K partials
    float*          SA      = S1;
    unsigned short* P2      = (unsigned short*)S1;
    float*          KVm     = S1;            // fused K|V decoder buffer (32MB)
    unsigned short* in_W2   = (unsigned short*)S2;
    float*          XS      = S2;
    unsigned short* YS2     = (unsigned short*)S2;
    float*          PX      = S2;            // xproj split-K partials
    unsigned short* QKA2    = (unsigned short*)S2;  // merged Q|K pairs (32MB)
    unsigned short* XC2     = (unsigned short*)S3;
    float*          PIN     = S3;            // in split-K partials
    unsigned short* outp_W2 = (unsigned short*)S3;
    float*          PATT    = S3;            // aWv / aWo split-K partials
    float*          PH      = S3;            // hW split-K partials
    float*          DXV     = S3;
    unsigned short* LNDXV2  = (unsigned short*)(S3 + 4194304);
    float*          Z       = S4;
    unsigned short* aWq2    = (unsigned short*)S4;
    unsigned short* aWk2    = (unsigned short*)S4 + 2097152;
    unsigned short* aWv2    = (unsigned short*)S4 + 4194304;
    unsigned short* aWo2    = (unsigned short*)S4 + 6291456;
    unsigned short* bWk2    = (unsigned short*)S4 + 8388608;
    unsigned short* bWv2    = (unsigned short*)S4 + 10485760;
    float*          T       = S5;
    unsigned short* Y22     = (unsigned short*)S5;
    unsigned short* HR2     = (unsigned short*)S6;
    float*          Y1      = S6;
    unsigned short* LNY2    = (unsigned short*)S7;
    unsigned short* OA2     = (unsigned short*)S7;
    unsigned short* VT2     = (unsigned short*)S9;

    float* dtBC = SP;
    float* DT   = SP + 589824;
    float* CUMA = SP + 655360;
    float* G    = SP + 720896;
    unsigned short* xprojW2 = (unsigned short*)(SP + 2818048);
    unsigned short* hW2     = (unsigned short*)(SP + 3112960);
    unsigned short* e2dW2   = (unsigned short*)(SP + 3178496);
    unsigned short* HCQ2 = (unsigned short*)(SP + 983040);
    float* dxm  = SP + 1245184;
    float* lnm  = SP + 1246208;
    float* qm   = SP + 1247232;
    float* km   = SP + 1248256;
    float* vm   = SP + 1249280;
    float* OBm  = SP + 1250304;
    float* ydm  = SP + 1258496;
    float* outm = SP + 1266688;

    const long long LL0 = 0;
    const long long P4M = 4194304;
    #define G3D(OUTM, GX, GY, GZ, ...) \
        gemm_bf16_k<3, OUTM, true><<<dim3(GX, GY, GZ), 256, 0, stream>>>(__VA_ARGS__)
    #define G1D(OUTM, GX, GY, GZ, ...) \
        gemm_bf16_k<1, OUTM, true><<<dim3(GX, GY, GZ), 256, 0, stream>>>(__VA_ARGS__)

    // ---- weight prep (phase A, one batched launch) ----
    {
        PairSegs sA = {};
        sA.src[0] = in_W;    sA.dst[0] = in_W2;   sA.n[0] = 1024LL * 2048; sA.klog2[0] = 11;
        sA.src[1] = xproj_W; sA.dst[1] = xprojW2; sA.n[1] = 144LL * 2048;  sA.klog2[1] = 11;
        sA.src[2] = h_W;     sA.dst[2] = hW2;     sA.n[2] = 64LL * 1024;   sA.klog2[2] = 10;
        sA.src[3] = e2d_W;   sA.dst[3] = e2dW2;   sA.n[3] = 1024LL * 64;   sA.klog2[3] = 6;
        pairify_multi_k<<<dim3(8192, 4), 256, 0, stream>>>(sA);
    }

    // ---- encoder trunk ----
    layernorm_pair_v_k<8><<<4096, 256, 0, stream>>>(x, XV2, ln0_w, ln0_b, 512,
                                                    (long long)1024 * 2048);
    // in: M=4096 N=1024 K=2048 -> DIRECT split-K x2, fused reduce+RMSNorm
    gemm_bf16_skd_k<3, 0><<<dim3(8, 32, 2), 256, 0, stream>>>(
        1024, 1024, XV2, 4096, 2048, in_W2, 4096, 2048, PIN, P4M);
    skred_rms_k<<<4096, 256, 0, stream>>>(PIN, P4M, T, HR2, rms_w);
    pairify_k<<<16384, 256, 0, stream>>>(exp_W, exp_W2, 10, 4096LL * 1024);
    // merged exp GEMM: z=0 -> XS, z=1 -> Z (A read once)
    G3D(0, 16, 32, 2, 4096, 2048, 1024, HR2, 2048, 1024, LL0, LL0,
        exp_W2, 2048, 1024, (long long)2048 * 2048, LL0,
        XS, 2048, 0, 16777216LL, LL0,
        nullptr, nullptr, 0, 1.f, 1);
    conv_k<<<dim3(32, 8, 8), 256, 0, stream>>>(XS, conv_W, XC2, XCT2);
    // xproj: ragged split-K x8, fused reduce + softplus->DT
    gemm_bf16_sk_k<3><<<dim3(2, 32, 8), 256, 0, stream>>>(
        144, 256, XC2, 4096, 2048, xprojW2, 4096, 2048, PX, 589824LL);
    skred_dt_k<<<2304, 256, 0, stream>>>(PX, 589824LL, dt_bias, dtBC, DT,
                                         589824LL);
    cuma_k<<<dim3(16, 8), 64, 0, stream>>>(DT, A_log, CUMA);
    gemm_f32_k<<<dim3(4, 4, 8), 256, 0, stream>>>(
        512, 512, 64, dtBC + 80, 144, (long long)512 * 144,
        dtBC + 16, 144, (long long)512 * 144, G, 512, (long long)512 * 512);
    ssd_mfma_k<<<dim3(4, 16, 8), 256, 0, stream>>>(G, CUMA, DT, XCT2, Z, Dv, YS2);

    // ---- weight prep (phase B: S3/S4 now dead, one batched launch) ----
    {
        PairSegs sB = {};
        sB.src[0] = outp_W; sB.dst[0] = outp_W2; sB.n[0] = 1024LL * 2048; sB.klog2[0] = 11;
        sB.src[1] = aWq;    sB.dst[1] = aWq2;    sB.n[1] = 1024LL * 1024; sB.klog2[1] = 10;
        sB.src[2] = aWk;    sB.dst[2] = aWk2;    sB.n[2] = 1024LL * 1024; sB.klog2[2] = 10;
        sB.src[3] = aWv;    sB.dst[3] = aWv2;    sB.n[3] = 1024LL * 1024; sB.klog2[3] = 10;
        sB.src[4] = aWo;    sB.dst[4] = aWo2;    sB.n[4] = 1024LL * 1024; sB.klog2[4] = 10;
        sB.src[5] = bWk;    sB.dst[5] = bWk2;    sB.n[5] = 1024LL * 1024; sB.klog2[5] = 10;
        sB.src[6] = bWv;    sB.dst[6] = bWv2;    sB.n[6] = 1024LL * 1024; sB.klog2[6] = 10;
        pairify_multi_k<<<dim3(8192, 7), 256, 0, stream>>>(sB);
    }

    // outp: split-K x2, fused reduce + bias + residual + LayerNorm
    gemm_bf16_skd_k<3, 0><<<dim3(8, 32, 2), 256, 0, stream>>>(
        1024, 1024, YS2, 4096, 2048, outp_W2, 4096, 2048, POUTP, P4M);
    skred_ln_k<<<4096, 256, 0, stream>>>(POUTP, P4M, outp_b, T, Y1, LNY2,
                                         n1_w, n1_b);

    // ---- encoder attention (all MFMA) ----
    // merged Q|K projection: N=2048, OUT1 pairs into QKA2
    G3D(1, 16, 32, 1, 4096, 2048, 1024, LNY2, 2048, 1024, LL0, LL0,
        aWq2, 2048, 1024, LL0, LL0, QKA2, 4096, 2048, LL0, LL0,
        nullptr, nullptr, 0, 1.f, 1);
    // aWv: split-K x2 with transposed partials -> VT2
    gemm_bf16_skd_k<3, 1><<<dim3(8, 32, 2), 256, 0, stream>>>(
        1024, 512, LNY2, 2048, 1024, aWv2, 2048, 1024, PATT, P4M);
    skredT_k<<<16384, 256, 0, stream>>>(PATT, P4M, 2, VT2, P4M);
    // QK^T: Q at QKA2 col 0-1023, K at col 1024-2047
    G3D(0, 4, 4, 32, 512, 512, 256,
        QKA2, 4096, 2048, (long long)512 * 4096, 256,
        QKA2 + 1024, 4096, 2048, (long long)512 * 4096, 256,
        SA, 512, 0, (long long)4 * 512 * 512, (long long)512 * 512,
        nullptr, nullptr, 0, 1.f / 16.f, 4);
    softmax_pair_k<<<16384, 256, 0, stream>>>(SA, P2);
    G3D(1, 2, 4, 32, 512, 256, 512,
        P2, 1024, 512, (long long)4 * 512 * 1024, (long long)512 * 1024,
        VT2, 1024, 512, (long long)1024 * 1024, (long long)256 * 1024,
        OA2, 2048, 1024, (long long)512 * 2048, 256,
        nullptr, nullptr, 0, 1.f, 4);
    // aWo: split-K x2 -> skredP with bias + residual(Y1) -> Y22 pairs
    gemm_bf16_skd_k<3, 0><<<dim3(8, 32, 2), 256, 0, stream>>>(
        1024, 512, OA2, 2048, 1024, aWo2, 2048, 1024, PATT, P4M);
    skredP_k<<<16384, 256, 0, stream>>>(PATT, P4M, 2, aWo_b, Y1, Y22, P4M);

    // ---- quantize: hW split-K x8, fused reduce + LN64 + sign-quant ----
    gemm_bf16_sk_k<3><<<dim3(1, 32, 8), 256, 0, stream>>>(
        64, 128, Y22, 2048, 1024, hW2, 2048, 1024, PH, 262144LL);
    skred_hc_k<<<4096, 64, 0, stream>>>(PH, 262144LL, h_b, h_lnw, h_lnb, HCQ2);

    // ---- decoder (collapsed masked rows) ----
    G3D(0, 8, 32, 1, 4096, 1024, 64, HCQ2, 128, 64, LL0, LL0,
        e2dW2, 128, 64, LL0, LL0, DXV, 1024, 0, LL0, LL0,
        nullptr, nullptr, 0, 1.f, 1);
    dxm_ln_k<<<1, 256, 0, stream>>>(mtok, e2d_W, dn_w, dn_b, dxm, lnm);
    layernorm_pair_v_k<4><<<4096, 256, 0, stream>>>(DXV, LNDXV2, dn_w, dn_b,
                                                    4096, LL0);
    projm_k<<<12, 256, 0, stream>>>(lnm, bWq, bWk, bWv, qm, km, vm);
    // merged K|V projection: N=2048, OUT0 f32 into fused KVm
    G1D(0, 16, 32, 1, 4096, 2048, 1024, LNDXV2, 2048, 1024, LL0, LL0,
        bWk2, 2048, 1024, LL0, LL0, KVm, 2048, 0, LL0, LL0,
        nullptr, nullptr, 0, 1.f, 1);
    dec_attn_k<<<dim3(4, 8), 256, 0, stream>>>(KVm, qm, km, vm, OBm);
    ydm_k<<<32, 256, 0, stream>>>(OBm, bWo, bWo_b, dxm, ydm);
    outm_k<<<64, 256, 0, stream>>>(ydm, dout_W, dout_b, outm);
    bcast_k<<<8192, 256, 0, stream>>>(outm, out);
    #undef G3D
    #undef G1D
}